// Round 9
// baseline (1054.392 us; speedup 1.0000x reference)
//
#include <hip/hip_runtime.h>
#include <math.h>

#define NN 10000
#define EE 320000
#define GG 32
#define LL 6
#define TABN 2048
#define TABB (TABN / 64)
#define DTAB 5.45f
#define DCUT 5.4f

__device__ __forceinline__ float fsilu(float x) { return x / (1.0f + __expf(-x)); }
__device__ __forceinline__ float fgelu(float x) {
  float y = 0.7978845608f * (x + 0.044715f * x * x * x);
  float t = 1.0f - 2.0f / (__expf(2.0f * y) + 1.0f);
  return 0.5f * x * (1.0f + t);
}

// ---------------- CSR build ----------------
__global__ void k_hist(const int* __restrict__ dst, int* __restrict__ deg) {
  int e = blockIdx.x * blockDim.x + threadIdx.x;
  if (e < EE) atomicAdd(&deg[dst[e]], 1);
}

// parallel scan: each thread serially scans a chunk, then one scan of totals
__global__ void k_scan(const int* __restrict__ cnt, int* __restrict__ off, int n) {
  __shared__ int tsum[1024];
  int chunk = (n + 1023) / 1024;
  int base = (int)threadIdx.x * chunk;
  int local = 0;
  for (int i = 0; i < chunk; i++) {
    int idx = base + i;
    local += (idx < n) ? cnt[idx] : 0;
  }
  tsum[threadIdx.x] = local;
  __syncthreads();
  for (int o = 1; o < 1024; o <<= 1) {
    int tv = (threadIdx.x >= (unsigned)o) ? tsum[threadIdx.x - o] : 0;
    __syncthreads();
    tsum[threadIdx.x] += tv;
    __syncthreads();
  }
  int run = tsum[threadIdx.x] - local;  // exclusive prefix of this chunk
  for (int i = 0; i < chunk; i++) {
    int idx = base + i;
    if (idx < n) {
      run += cnt[idx];
      off[idx + 1] = run;
    }
  }
  if (threadIdx.x == 0) off[0] = 0;
}

// scatter + geometry fused: one pass assigns CSR slots and computes distances
__global__ void k_scatter(const int* __restrict__ esrc, const int* __restrict__ edst,
                          const float* __restrict__ pos, const int* __restrict__ row_off,
                          int* __restrict__ cursor, float* __restrict__ d_csr,
                          int* __restrict__ src_csr, int* __restrict__ dst_csr) {
  int e = blockIdx.x * blockDim.x + threadIdx.x;
  if (e < EE) {
    int d = edst[e];
    int s = esrc[e];
    int p = atomicAdd(&cursor[d], 1);
    int slot = row_off[d] + p;
    float rx = pos[d * 3 + 0] - pos[s * 3 + 0];
    float ry = pos[d * 3 + 1] - pos[s * 3 + 1];
    float rz = pos[d * 3 + 2] - pos[s * 3 + 2];
    d_csr[slot] = sqrtf(rx * rx + ry * ry + rz * rz + 1e-6f);
    src_csr[slot] = s;
    dst_csr[slot] = d;
  }
}

// ---------------- active-edge count + degree histogram (fused) ----------------
__global__ void k_act_cnt(const int* __restrict__ row_off, const float* __restrict__ d_csr,
                          int* __restrict__ acnt, int* __restrict__ dbkt) {
  int n = blockIdx.x * blockDim.x + threadIdx.x;
  if (n >= NN) return;
  int c = 0;
  for (int j = row_off[n]; j < row_off[n + 1]; ++j) c += (d_csr[j] < DCUT) ? 1 : 0;
  acnt[n] = c;
  int b = 127 - min(127, c);
  atomicAdd(&dbkt[b], 1);
}

__global__ void k_act_fill(const int* __restrict__ row_off, const float* __restrict__ d_csr,
                           const int* __restrict__ act_off, int* __restrict__ act_idx) {
  int n = blockIdx.x * blockDim.x + threadIdx.x;
  if (n >= NN) return;
  int a = act_off[n];
  for (int j = row_off[n]; j < row_off[n + 1]; ++j)
    if (d_csr[j] < DCUT) act_idx[a++] = j;
}

__global__ void k_dscatter(const int* __restrict__ acnt, const int* __restrict__ dboff,
                           int* __restrict__ dbcur, int* __restrict__ order) {
  int n = blockIdx.x * blockDim.x + threadIdx.x;
  if (n < NN) {
    int b = 127 - min(127, acnt[n]);
    int p = atomicAdd(&dbcur[b], 1);
    order[dboff[b] + p] = n;
  }
}

// ---------------- compacted geometry per active edge (direct CSR arrays) ----------------
__global__ void k_geom_act(const int* __restrict__ act_idx, const int* __restrict__ src_csr,
                           const int* __restrict__ dst_csr, const float* __restrict__ pos,
                           const int* __restrict__ act_off, float* __restrict__ d_a,
                           int* __restrict__ src_a, float* __restrict__ sh_a) {
  int a = blockIdx.x * blockDim.x + threadIdx.x;
  if (a >= act_off[NN]) return;
  int j = act_idx[a];
  int s = src_csr[j], dd = dst_csr[j];
  float rx = pos[dd * 3 + 0] - pos[s * 3 + 0];
  float ry = pos[dd * 3 + 1] - pos[s * 3 + 1];
  float rz = pos[dd * 3 + 2] - pos[s * 3 + 2];
  float d = sqrtf(rx * rx + ry * ry + rz * rz + 1e-6f);
  float inv = 1.0f / d;
  float x = rx * inv, y = ry * inv, z = rz * inv;
  d_a[a] = d;
  src_a[a] = s;
  const float s3 = 1.7320508075688772f;
  const float s5 = 2.23606797749979f;
  const float s15 = 3.872983346207417f;
  sh_a[a * 8 + 0] = s3 * x;
  sh_a[a * 8 + 1] = s3 * y;
  sh_a[a * 8 + 2] = s3 * z;
  sh_a[a * 8 + 3] = s15 * x * y;
  sh_a[a * 8 + 4] = s15 * y * z;
  sh_a[a * 8 + 5] = 0.5f * s5 * (3.0f * z * z - 1.0f);
  sh_a[a * 8 + 6] = s15 * x * z;
  sh_a[a * 8 + 7] = 0.5f * s15 * (x * x - y * y);
}

// ---------------- radial MLP table w(d): 16 entries/block for parallelism ----------------
__global__ void k_build_wtab(const float* __restrict__ Wrad1, const float* __restrict__ brad1,
                             const float* __restrict__ Wrad2, const float* __restrict__ brad2,
                             float* __restrict__ wtab) {
  int l = blockIdx.x / (TABN / 16);
  int blk = blockIdx.x % (TABN / 16);
  __shared__ float W1[128 * 64];
  __shared__ float W2[64 * 64];
  __shared__ float b1[64], b2[64];
  __shared__ float rbf_s[4][128];
  __shared__ float h_s[4][64];
  const float* w1p = Wrad1 + (size_t)l * 128 * 64;
  const float* w2p = Wrad2 + (size_t)l * 64 * 64;
  for (int i = threadIdx.x; i < 128 * 64; i += 256) W1[i] = w1p[i];
  for (int i = threadIdx.x; i < 64 * 64; i += 256) W2[i] = w2p[i];
  if (threadIdx.x < 64) {
    b1[threadIdx.x] = brad1[(size_t)l * 64 + threadIdx.x];
    b2[threadIdx.x] = brad2[(size_t)l * 64 + threadIdx.x];
  }
  __syncthreads();
  int wv = threadIdx.x >> 6, lane = threadIdx.x & 63;
  const float width = 5.0f / 128.0f;
  for (int k = wv; k < 16; k += 4) {
    int i = blk * 16 + k;
    float d = (float)i * (DTAB / (float)(TABN - 1));
    float c0 = (5.0f * (float)lane) / 127.0f;
    float c1 = (5.0f * (float)(lane + 64)) / 127.0f;
    float t0 = (d - c0) / width, t1 = (d - c1) / width;
    rbf_s[wv][lane] = __expf(-0.5f * t0 * t0);
    rbf_s[wv][lane + 64] = __expf(-0.5f * t1 * t1);
    float acc = b1[lane];
    #pragma unroll 8
    for (int i2 = 0; i2 < 128; i2++) acc += rbf_s[wv][i2] * W1[i2 * 64 + lane];
    acc = fsilu(acc);
    h_s[wv][lane] = acc;
    float acc2 = b2[lane];
    #pragma unroll 8
    for (int i2 = 0; i2 < 64; i2++) acc2 += h_s[wv][i2] * W2[i2 * 64 + lane];
    wtab[((size_t)l * TABN + i) * 64 + lane] = fsilu(acc2);
  }
}

// ---------------- fused product-table build: gs, gv, gt in one kernel ----------------
#define EB 8
__global__ __launch_bounds__(320) void k_build_tabs(
    const float* __restrict__ wtab, const float* __restrict__ Ww_s,
    const float* __restrict__ Ww_v, const float* __restrict__ Ww_vv,
    const float* __restrict__ Ww_t, const float* __restrict__ Ww_tt,
    float* __restrict__ gs_tab, float* __restrict__ gv_tab, float* __restrict__ gt_tab) {
  int l = blockIdx.x / (TABN / EB);
  int eb = (blockIdx.x % (TABN / EB)) * EB;
  __shared__ float ws[EB][64];
  int tid = threadIdx.x;
  for (int i = tid; i < EB * 64; i += 320)
    ws[i >> 6][i & 63] = wtab[((size_t)l * TABN + eb + (i >> 6)) * 64 + (i & 63)];
  __syncthreads();
  float acc[EB] = {};
  if (tid < 128) {
    int col = tid;
    const float* W = Ww_s + (size_t)l * 64 * 128;
    #pragma unroll 8
    for (int i = 0; i < 64; i++) {
      float w = W[i * 128 + col];
      #pragma unroll
      for (int e = 0; e < EB; e++) acc[e] += ws[e][i] * w;
    }
    #pragma unroll
    for (int e = 0; e < EB; e++)
      gs_tab[((size_t)l * TABN + eb + e) * 128 + col] = acc[e];
  } else if (tid < 256) {
    int cc = tid - 128;
    int c = cc >> 1;
    const float* W = ((cc & 1) ? Ww_vv : Ww_v) + (size_t)l * 64 * 64;
    #pragma unroll 8
    for (int i = 0; i < 64; i++) {
      float w = W[i * 64 + c];
      #pragma unroll
      for (int e = 0; e < EB; e++) acc[e] += ws[e][i] * w;
    }
    #pragma unroll
    for (int e = 0; e < EB; e++)
      gv_tab[((size_t)l * TABN + eb + e) * 128 + cc] = acc[e];
  } else {
    int cc = tid - 256;
    int c = cc >> 1;
    const float* W = ((cc & 1) ? Ww_tt : Ww_t) + (size_t)l * 64 * 32;
    #pragma unroll 8
    for (int i = 0; i < 64; i++) {
      float w = W[i * 32 + c];
      #pragma unroll
      for (int e = 0; e < EB; e++) acc[e] += ws[e][i] * w;
    }
    #pragma unroll
    for (int e = 0; e < EB; e++)
      gt_tab[((size_t)l * TABN + eb + e) * 64 + cc] = acc[e];
  }
}

// ---------------- init s ----------------
__global__ void k_init_s(const int* __restrict__ node_atom, const float* __restrict__ atom_emb,
                         float* __restrict__ s) {
  int i = blockIdx.x * blockDim.x + threadIdx.x;
  if (i < NN * 128) {
    int n = i >> 7, c = i & 127;
    s[i] = atom_emb[node_atom[n] * 128 + c];
  }
}

// ---------------- layer-0 transforms: s only (v = t = 0) ----------------
__global__ __launch_bounds__(256) void k_node_tf0(
    const float* __restrict__ s, const float* __restrict__ Ws_src,
    const float* __restrict__ Ws_v, const float* __restrict__ Ws_t,
    float* __restrict__ sWsrc, float* __restrict__ sWv, float* __restrict__ sWt) {
  int nb = blockIdx.x * 16;
  int tid = threadIdx.x;
  __shared__ float s16[16][129];
  for (int idx = tid; idx < 16 * 128; idx += 256) {
    int n = idx >> 7, c = idx & 127;
    s16[n][c] = s[(size_t)(nb + n) * 128 + c];
  }
  __syncthreads();
  {
    int col = tid & 127, ng = tid >> 7;
    float acc[8] = {0, 0, 0, 0, 0, 0, 0, 0};
    for (int c = 0; c < 128; c++) {
      float w = Ws_src[c * 128 + col];
      #pragma unroll
      for (int n = 0; n < 8; n++) acc[n] += s16[ng * 8 + n][c] * w;
    }
    #pragma unroll
    for (int n = 0; n < 8; n++) sWsrc[(size_t)(nb + ng * 8 + n) * 128 + col] = acc[n];
  }
  {
    int col = tid & 63, ng = tid >> 6;
    float acc[4] = {0, 0, 0, 0};
    for (int c = 0; c < 128; c++) {
      float w = Ws_v[c * 64 + col];
      #pragma unroll
      for (int n = 0; n < 4; n++) acc[n] += s16[ng * 4 + n][c] * w;
    }
    #pragma unroll
    for (int n = 0; n < 4; n++) sWv[(size_t)(nb + ng * 4 + n) * 64 + col] = acc[n];
  }
  {
    int col = tid & 31, ng = tid >> 5;
    float acc[2] = {0, 0};
    for (int c = 0; c < 128; c++) {
      float w = Ws_t[c * 32 + col];
      acc[0] += s16[ng * 2 + 0][c] * w;
      acc[1] += s16[ng * 2 + 1][c] * w;
    }
    sWt[(size_t)(nb + ng * 2 + 0) * 32 + col] = acc[0];
    sWt[(size_t)(nb + ng * 2 + 1) * 32 + col] = acc[1];
  }
}

// ---------------- mega: single-pass online-softmax, 4-edge unrolled update ----------------
__global__ __launch_bounds__(256) void k_mega(
    const int* __restrict__ row_off, const int* __restrict__ act_off,
    const int* __restrict__ order,
    const int* __restrict__ src_a, const float* __restrict__ d_a,
    const float* __restrict__ gsL, const float* __restrict__ gvL,
    const float* __restrict__ gtL, const float* __restrict__ attn_l,
    const float* __restrict__ sWsrc, const float* __restrict__ sWv,
    const float* __restrict__ sWt, const float* __restrict__ vW,
    const float* __restrict__ tW, const float* __restrict__ sh_a,
    float* __restrict__ agg_s, float* __restrict__ agg_v, float* __restrict__ agg_t) {
  int wv = threadIdx.x >> 6, lane = threadIdx.x & 63;
  int lt = lane & 31;
  int slot = blockIdx.x * 4 + wv;
  if (slot >= NN) return;
  int n = order[slot];
  int alo = act_off[n], ahi = act_off[n + 1];
  int nact = ahi - alo;
  int ninact = (row_off[n + 1] - row_off[n]) - nact;
  const float sc = (float)(TABN - 1) / DTAB;
  float atnA = attn_l[lane];
  float atnB = attn_l[64 + lane];
  float rm0, rm1, rm2, rm3;
  rm0 = rm1 = rm2 = rm3 = (ninact > 0) ? 0.0f : -1e30f;
  float rs0 = 0.f, rs1 = 0.f, rs2 = 0.f, rs3 = 0.f;
  float as0 = 0.f, as1 = 0.f;
  float av0 = 0.f, av1 = 0.f, av2 = 0.f;
  float at0 = 0.f, at1 = 0.f, at2 = 0.f, at3 = 0.f, at4 = 0.f;
  int a = alo;
  // ---- 4-edge unrolled main loop (all indices compile-time after unroll) ----
  for (; a + 3 < ahi; a += 4) {
    int sn[4], ii[4];
    float ffr[4], g1[4];
    #pragma unroll
    for (int e = 0; e < 4; e++) {
      float x = fminf(d_a[a + e] * sc, (float)(TABN - 1) - 1.0f);
      ii[e] = (int)x;
      ffr[e] = x - (float)ii[e];
      g1[e] = 1.0f - ffr[e];
      sn[e] = src_a[a + e];
    }
    float m0[4], m1[4];
    #pragma unroll
    for (int e = 0; e < 4; e++) {
      const float* g = gsL + (size_t)ii[e] * 128;
      float gsA = g[lane] * g1[e] + g[128 + lane] * ffr[e];
      float gsB = g[64 + lane] * g1[e] + g[192 + lane] * ffr[e];
      m0[e] = sWsrc[(size_t)sn[e] * 128 + lane] * gsA;
      m1[e] = sWsrc[(size_t)sn[e] * 128 + 64 + lane] * gsB;
    }
    float gav[4], gbv[4], sv[4], vv0[4], vv1[4], vv2[4];
    float4 s1[4], s2[4];
    #pragma unroll
    for (int e = 0; e < 4; e++) {
      const float* gv0 = gvL + (size_t)ii[e] * 128;
      float2 p0 = *(const float2*)&gv0[2 * lane];
      float2 p1 = *(const float2*)&gv0[128 + 2 * lane];
      gav[e] = p0.x * g1[e] + p1.x * ffr[e];
      gbv[e] = p0.y * g1[e] + p1.y * ffr[e];
      sv[e] = sWv[(size_t)sn[e] * 64 + lane];
      s1[e] = *(const float4*)&sh_a[(size_t)(a + e) * 8];
      s2[e] = *(const float4*)&sh_a[(size_t)(a + e) * 8 + 4];
      const float* vp = &vW[(size_t)sn[e] * 192 + lane];
      vv0[e] = vp[0]; vv1[e] = vp[64]; vv2[e] = vp[128];
    }
    float gat[4] = {}, gbt[4] = {}, stt[4] = {};
    float te0[4] = {}, te1[4] = {}, te2[4] = {}, te3[4] = {}, te4[4] = {};
    if (lane < 32) {
      #pragma unroll
      for (int e = 0; e < 4; e++) {
        const float* gt0 = gtL + (size_t)ii[e] * 64;
        float2 q0 = *(const float2*)&gt0[2 * lt];
        float2 q1 = *(const float2*)&gt0[64 + 2 * lt];
        gat[e] = q0.x * g1[e] + q1.x * ffr[e];
        gbt[e] = q0.y * g1[e] + q1.y * ffr[e];
        stt[e] = sWt[(size_t)sn[e] * 32 + lane];
        const float* tp = &tW[(size_t)sn[e] * 160 + lane];
        te0[e] = tp[0]; te1[e] = tp[32]; te2[e] = tp[64]; te3[e] = tp[96]; te4[e] = tp[128];
      }
    }
    float p01[4], p23[4];
    #pragma unroll
    for (int e = 0; e < 4; e++) { p01[e] = m0[e] * atnA; p23[e] = m1[e] * atnB; }
    #pragma unroll
    for (int mm = 1; mm < 32; mm <<= 1) {
      #pragma unroll
      for (int e = 0; e < 4; e++) {
        p01[e] += __shfl_xor(p01[e], mm);
        p23[e] += __shfl_xor(p23[e], mm);
      }
    }
    float l0[4], l1[4], l2[4], l3[4];
    #pragma unroll
    for (int e = 0; e < 4; e++) {
      l0[e] = __shfl(p01[e], 0); l1[e] = __shfl(p01[e], 32);
      l2[e] = __shfl(p23[e], 0); l3[e] = __shfl(p23[e], 32);
    }
    // combined 4-edge online-softmax update
    float nm0 = rm0, nm1 = rm1, nm2 = rm2, nm3 = rm3;
    #pragma unroll
    for (int e = 0; e < 4; e++) {
      nm0 = fmaxf(nm0, l0[e]); nm1 = fmaxf(nm1, l1[e]);
      nm2 = fmaxf(nm2, l2[e]); nm3 = fmaxf(nm3, l3[e]);
    }
    float w0[4], w1[4], w2[4], w3[4];
    #pragma unroll
    for (int e = 0; e < 4; e++) {
      w0[e] = __expf(l0[e] - nm0); w1[e] = __expf(l1[e] - nm1);
      w2[e] = __expf(l2[e] - nm2); w3[e] = __expf(l3[e] - nm3);
    }
    float aw0 = 0.f, aw1 = 0.f, aw2 = 0.f, aw3 = 0.f;
    float addS0 = 0.f, addS1 = 0.f;
    float addV0 = 0.f, addV1 = 0.f, addV2 = 0.f;
    float addT0 = 0.f, addT1 = 0.f, addT2 = 0.f, addT3 = 0.f, addT4 = 0.f;
    #pragma unroll
    for (int e = 0; e < 4; e++) {
      aw0 += w0[e]; aw1 += w1[e]; aw2 += w2[e]; aw3 += w3[e];
      float wS0 = (lane < 32) ? w0[e] : w1[e];
      float wS1 = (lane < 32) ? w2[e] : w3[e];
      addS0 += wS0 * m0[e];
      addS1 += wS1 * m1[e];
      float wV = (lane < 16) ? w0[e] : (lane < 32) ? w1[e] : (lane < 48) ? w2[e] : w3[e];
      float avv = sv[e] * gav[e];
      addV0 += wV * (avv * s1[e].x + vv0[e] * gbv[e]);
      addV1 += wV * (avv * s1[e].y + vv1[e] * gbv[e]);
      addV2 += wV * (avv * s1[e].z + vv2[e] * gbv[e]);
      float wT = (lane < 8) ? w0[e] : (lane < 16) ? w1[e] : (lane < 24) ? w2[e] : w3[e];
      float att = stt[e] * gat[e];
      addT0 += wT * (att * s1[e].w + te0[e] * gbt[e]);
      addT1 += wT * (att * s2[e].x + te1[e] * gbt[e]);
      addT2 += wT * (att * s2[e].y + te2[e] * gbt[e]);
      addT3 += wT * (att * s2[e].z + te3[e] * gbt[e]);
      addT4 += wT * (att * s2[e].w + te4[e] * gbt[e]);
    }
    if (nm0 == rm0 && nm1 == rm1 && nm2 == rm2 && nm3 == rm3) {
      rs0 += aw0; rs1 += aw1; rs2 += aw2; rs3 += aw3;
      as0 += addS0; as1 += addS1;
      av0 += addV0; av1 += addV1; av2 += addV2;
      at0 += addT0; at1 += addT1; at2 += addT2; at3 += addT3; at4 += addT4;
    } else {
      float f0 = __expf(rm0 - nm0), f1 = __expf(rm1 - nm1);
      float f2 = __expf(rm2 - nm2), f3 = __expf(rm3 - nm3);
      rm0 = nm0; rm1 = nm1; rm2 = nm2; rm3 = nm3;
      rs0 = rs0 * f0 + aw0; rs1 = rs1 * f1 + aw1;
      rs2 = rs2 * f2 + aw2; rs3 = rs3 * f3 + aw3;
      float fS0 = (lane < 32) ? f0 : f1, fS1 = (lane < 32) ? f2 : f3;
      as0 = as0 * fS0 + addS0; as1 = as1 * fS1 + addS1;
      float fV = (lane < 16) ? f0 : (lane < 32) ? f1 : (lane < 48) ? f2 : f3;
      av0 = av0 * fV + addV0; av1 = av1 * fV + addV1; av2 = av2 * fV + addV2;
      float fT = (lane < 8) ? f0 : (lane < 16) ? f1 : (lane < 24) ? f2 : f3;
      at0 = at0 * fT + addT0; at1 = at1 * fT + addT1; at2 = at2 * fT + addT2;
      at3 = at3 * fT + addT3; at4 = at4 * fT + addT4;
    }
  }
  // ---- 2-edge tail ----
  for (; a + 1 < ahi; a += 2) {
    int aA = a, aB = a + 1;
    float dA = d_a[aA], dB = d_a[aB];
    int snA = src_a[aA], snB = src_a[aB];
    float xA = fminf(dA * sc, (float)(TABN - 1) - 1.0f);
    float xB = fminf(dB * sc, (float)(TABN - 1) - 1.0f);
    int iA = (int)xA, iB = (int)xB;
    float fA = xA - (float)iA, fB = xB - (float)iB;
    float g1A = 1.0f - fA, g1B = 1.0f - fB;
    const float* gA = gsL + (size_t)iA * 128;
    const float* gB = gsL + (size_t)iB * 128;
    float gsA_A = gA[lane] * g1A + gA[128 + lane] * fA;
    float gsB_A = gA[64 + lane] * g1A + gA[192 + lane] * fA;
    float gsA_B = gB[lane] * g1B + gB[128 + lane] * fB;
    float gsB_B = gB[64 + lane] * g1B + gB[192 + lane] * fB;
    float m0A = sWsrc[(size_t)snA * 128 + lane] * gsA_A;
    float m1A = sWsrc[(size_t)snA * 128 + 64 + lane] * gsB_A;
    float m0B = sWsrc[(size_t)snB * 128 + lane] * gsA_B;
    float m1B = sWsrc[(size_t)snB * 128 + 64 + lane] * gsB_B;
    const float* gvA = gvL + (size_t)iA * 128;
    const float* gvB = gvL + (size_t)iB * 128;
    float2 pA0 = *(const float2*)&gvA[2 * lane];
    float2 pA1 = *(const float2*)&gvA[128 + 2 * lane];
    float2 pB0 = *(const float2*)&gvB[2 * lane];
    float2 pB1 = *(const float2*)&gvB[128 + 2 * lane];
    float gavA = pA0.x * g1A + pA1.x * fA;
    float gbvA = pA0.y * g1A + pA1.y * fA;
    float gavB = pB0.x * g1B + pB1.x * fB;
    float gbvB = pB0.y * g1B + pB1.y * fB;
    float svA = sWv[(size_t)snA * 64 + lane];
    float svB = sWv[(size_t)snB * 64 + lane];
    float4 s1A = *(const float4*)&sh_a[(size_t)aA * 8];
    float4 s2A = *(const float4*)&sh_a[(size_t)aA * 8 + 4];
    float4 s1B = *(const float4*)&sh_a[(size_t)aB * 8];
    float4 s2B = *(const float4*)&sh_a[(size_t)aB * 8 + 4];
    const float* vpA = &vW[(size_t)snA * 192 + lane];
    const float* vpB = &vW[(size_t)snB * 192 + lane];
    float vA0 = vpA[0], vA1 = vpA[64], vA2 = vpA[128];
    float vB0 = vpB[0], vB1 = vpB[64], vB2 = vpB[128];
    float gatA = 0.f, gbtA = 0.f, gatB = 0.f, gbtB = 0.f;
    float stA = 0.f, stB = 0.f;
    float tA0 = 0.f, tA1 = 0.f, tA2 = 0.f, tA3 = 0.f, tA4 = 0.f;
    float tB0 = 0.f, tB1 = 0.f, tB2 = 0.f, tB3 = 0.f, tB4 = 0.f;
    if (lane < 32) {
      const float* gtA = gtL + (size_t)iA * 64;
      const float* gtB = gtL + (size_t)iB * 64;
      float2 qA0 = *(const float2*)&gtA[2 * lt];
      float2 qA1 = *(const float2*)&gtA[64 + 2 * lt];
      float2 qB0 = *(const float2*)&gtB[2 * lt];
      float2 qB1 = *(const float2*)&gtB[64 + 2 * lt];
      gatA = qA0.x * g1A + qA1.x * fA;
      gbtA = qA0.y * g1A + qA1.y * fA;
      gatB = qB0.x * g1B + qB1.x * fB;
      gbtB = qB0.y * g1B + qB1.y * fB;
      stA = sWt[(size_t)snA * 32 + lane];
      stB = sWt[(size_t)snB * 32 + lane];
      const float* tpA = &tW[(size_t)snA * 160 + lane];
      const float* tpB = &tW[(size_t)snB * 160 + lane];
      tA0 = tpA[0]; tA1 = tpA[32]; tA2 = tpA[64]; tA3 = tpA[96]; tA4 = tpA[128];
      tB0 = tpB[0]; tB1 = tpB[32]; tB2 = tpB[64]; tB3 = tpB[96]; tB4 = tpB[128];
    }
    float p01A = m0A * atnA, p23A = m1A * atnB;
    float p01B = m0B * atnA, p23B = m1B * atnB;
    #pragma unroll
    for (int mm = 1; mm < 32; mm <<= 1) {
      p01A += __shfl_xor(p01A, mm);
      p23A += __shfl_xor(p23A, mm);
      p01B += __shfl_xor(p01B, mm);
      p23B += __shfl_xor(p23B, mm);
    }
    float l0A = __shfl(p01A, 0), l1A = __shfl(p01A, 32);
    float l2A = __shfl(p23A, 0), l3A = __shfl(p23A, 32);
    float l0B = __shfl(p01B, 0), l1B = __shfl(p01B, 32);
    float l2B = __shfl(p23B, 0), l3B = __shfl(p23B, 32);
    float nm0 = fmaxf(rm0, fmaxf(l0A, l0B));
    float nm1 = fmaxf(rm1, fmaxf(l1A, l1B));
    float nm2 = fmaxf(rm2, fmaxf(l2A, l2B));
    float nm3 = fmaxf(rm3, fmaxf(l3A, l3B));
    float wA0 = __expf(l0A - nm0), wA1 = __expf(l1A - nm1);
    float wA2 = __expf(l2A - nm2), wA3 = __expf(l3A - nm3);
    float wB0 = __expf(l0B - nm0), wB1 = __expf(l1B - nm1);
    float wB2 = __expf(l2B - nm2), wB3 = __expf(l3B - nm3);
    float wSA0 = (lane < 32) ? wA0 : wA1, wSA1 = (lane < 32) ? wA2 : wA3;
    float wSB0 = (lane < 32) ? wB0 : wB1, wSB1 = (lane < 32) ? wB2 : wB3;
    float addS0 = wSA0 * m0A + wSB0 * m0B;
    float addS1 = wSA1 * m1A + wSB1 * m1B;
    float wVA = (lane < 16) ? wA0 : (lane < 32) ? wA1 : (lane < 48) ? wA2 : wA3;
    float wVB = (lane < 16) ? wB0 : (lane < 32) ? wB1 : (lane < 48) ? wB2 : wB3;
    float avvA = svA * gavA, avvB = svB * gavB;
    float addV0 = wVA * (avvA * s1A.x + vA0 * gbvA) + wVB * (avvB * s1B.x + vB0 * gbvB);
    float addV1 = wVA * (avvA * s1A.y + vA1 * gbvA) + wVB * (avvB * s1B.y + vB1 * gbvB);
    float addV2 = wVA * (avvA * s1A.z + vA2 * gbvA) + wVB * (avvB * s1B.z + vB2 * gbvB);
    float wTA = (lane < 8) ? wA0 : (lane < 16) ? wA1 : (lane < 24) ? wA2 : wA3;
    float wTB = (lane < 8) ? wB0 : (lane < 16) ? wB1 : (lane < 24) ? wB2 : wB3;
    float attA = stA * gatA, attB = stB * gatB;
    float addT0 = wTA * (attA * s1A.w + tA0 * gbtA) + wTB * (attB * s1B.w + tB0 * gbtB);
    float addT1 = wTA * (attA * s2A.x + tA1 * gbtA) + wTB * (attB * s2B.x + tB1 * gbtB);
    float addT2 = wTA * (attA * s2A.y + tA2 * gbtA) + wTB * (attB * s2B.y + tB2 * gbtB);
    float addT3 = wTA * (attA * s2A.z + tA3 * gbtA) + wTB * (attB * s2B.z + tB3 * gbtB);
    float addT4 = wTA * (attA * s2A.w + tA4 * gbtA) + wTB * (attB * s2B.w + tB4 * gbtB);
    if (nm0 == rm0 && nm1 == rm1 && nm2 == rm2 && nm3 == rm3) {
      rs0 += wA0 + wB0; rs1 += wA1 + wB1; rs2 += wA2 + wB2; rs3 += wA3 + wB3;
      as0 += addS0; as1 += addS1;
      av0 += addV0; av1 += addV1; av2 += addV2;
      at0 += addT0; at1 += addT1; at2 += addT2; at3 += addT3; at4 += addT4;
    } else {
      float f0 = __expf(rm0 - nm0), f1 = __expf(rm1 - nm1);
      float f2 = __expf(rm2 - nm2), f3 = __expf(rm3 - nm3);
      rm0 = nm0; rm1 = nm1; rm2 = nm2; rm3 = nm3;
      rs0 = rs0 * f0 + wA0 + wB0; rs1 = rs1 * f1 + wA1 + wB1;
      rs2 = rs2 * f2 + wA2 + wB2; rs3 = rs3 * f3 + wA3 + wB3;
      float fS0 = (lane < 32) ? f0 : f1, fS1 = (lane < 32) ? f2 : f3;
      as0 = as0 * fS0 + addS0; as1 = as1 * fS1 + addS1;
      float fV = (lane < 16) ? f0 : (lane < 32) ? f1 : (lane < 48) ? f2 : f3;
      av0 = av0 * fV + addV0; av1 = av1 * fV + addV1; av2 = av2 * fV + addV2;
      float fT = (lane < 8) ? f0 : (lane < 16) ? f1 : (lane < 24) ? f2 : f3;
      at0 = at0 * fT + addT0; at1 = at1 * fT + addT1; at2 = at2 * fT + addT2;
      at3 = at3 * fT + addT3; at4 = at4 * fT + addT4;
    }
  }
  // ---- 1-edge tail ----
  for (; a < ahi; ++a) {
    float x = d_a[a] * sc;
    x = fminf(x, (float)(TABN - 1) - 1.0f);
    int i0 = (int)x; float f = x - (float)i0; float g1 = 1.0f - f;
    int sn = src_a[a];
    const float* g0 = gsL + (size_t)i0 * 128;
    float gsA = g0[lane] * g1 + g0[128 + lane] * f;
    float gsB = g0[64 + lane] * g1 + g0[192 + lane] * f;
    float m0 = sWsrc[(size_t)sn * 128 + lane] * gsA;
    float m1 = sWsrc[(size_t)sn * 128 + 64 + lane] * gsB;
    float p01 = m0 * atnA;
    float p23 = m1 * atnB;
    #pragma unroll
    for (int mm = 1; mm < 32; mm <<= 1) {
      p01 += __shfl_xor(p01, mm);
      p23 += __shfl_xor(p23, mm);
    }
    float l0 = __shfl(p01, 0), l1 = __shfl(p01, 32);
    float l2 = __shfl(p23, 0), l3 = __shfl(p23, 32);
    float nm0 = fmaxf(rm0, l0), nm1 = fmaxf(rm1, l1);
    float nm2 = fmaxf(rm2, l2), nm3 = fmaxf(rm3, l3);
    float f0 = __expf(rm0 - nm0), f1 = __expf(rm1 - nm1);
    float f2 = __expf(rm2 - nm2), f3 = __expf(rm3 - nm3);
    float w0 = __expf(l0 - nm0), w1 = __expf(l1 - nm1);
    float w2 = __expf(l2 - nm2), w3 = __expf(l3 - nm3);
    rm0 = nm0; rm1 = nm1; rm2 = nm2; rm3 = nm3;
    rs0 = rs0 * f0 + w0; rs1 = rs1 * f1 + w1;
    rs2 = rs2 * f2 + w2; rs3 = rs3 * f3 + w3;
    float fS0 = (lane < 32) ? f0 : f1;
    float fS1 = (lane < 32) ? f2 : f3;
    float wS0 = (lane < 32) ? w0 : w1;
    float wS1 = (lane < 32) ? w2 : w3;
    as0 = as0 * fS0 + wS0 * m0;
    as1 = as1 * fS1 + wS1 * m1;
    const float* gv0 = gvL + (size_t)i0 * 128;
    float2 p0 = *(const float2*)&gv0[2 * lane];
    float2 p1 = *(const float2*)&gv0[128 + 2 * lane];
    float gav = p0.x * g1 + p1.x * f;
    float gbv = p0.y * g1 + p1.y * f;
    float fV = (lane < 16) ? f0 : (lane < 32) ? f1 : (lane < 48) ? f2 : f3;
    float wV = (lane < 16) ? w0 : (lane < 32) ? w1 : (lane < 48) ? w2 : w3;
    float avv = sWv[(size_t)sn * 64 + lane] * gav;
    float4 s1 = *(const float4*)&sh_a[(size_t)a * 8];
    float4 s2 = *(const float4*)&sh_a[(size_t)a * 8 + 4];
    const float* vp = &vW[(size_t)sn * 192 + lane];
    av0 = av0 * fV + wV * (avv * s1.x + vp[0] * gbv);
    av1 = av1 * fV + wV * (avv * s1.y + vp[64] * gbv);
    av2 = av2 * fV + wV * (avv * s1.z + vp[128] * gbv);
    if (lane < 32) {
      const float* gt0 = gtL + (size_t)i0 * 64;
      float2 q0 = *(const float2*)&gt0[2 * lt];
      float2 q1 = *(const float2*)&gt0[64 + 2 * lt];
      float gat = q0.x * g1 + q1.x * f;
      float gbt = q0.y * g1 + q1.y * f;
      float fT = (lane < 8) ? f0 : (lane < 16) ? f1 : (lane < 24) ? f2 : f3;
      float wT = (lane < 8) ? w0 : (lane < 16) ? w1 : (lane < 24) ? w2 : w3;
      float att = sWt[(size_t)sn * 32 + lane] * gat;
      const float* tp = &tW[(size_t)sn * 160 + lane];
      at0 = at0 * fT + wT * (att * s1.w + tp[0] * gbt);
      at1 = at1 * fT + wT * (att * s2.x + tp[32] * gbt);
      at2 = at2 * fT + wT * (att * s2.y + tp[64] * gbt);
      at3 = at3 * fT + wT * (att * s2.z + tp[96] * gbt);
      at4 = at4 * fT + wT * (att * s2.w + tp[128] * gbt);
    }
  }
  if (ninact > 0) {
    rs0 += (float)ninact * __expf(-rm0);
    rs1 += (float)ninact * __expf(-rm1);
    rs2 += (float)ninact * __expf(-rm2);
    rs3 += (float)ninact * __expf(-rm3);
  }
  float r0 = 1.0f / (rs0 + 1e-9f), r1 = 1.0f / (rs1 + 1e-9f);
  float r2 = 1.0f / (rs2 + 1e-9f), r3 = 1.0f / (rs3 + 1e-9f);
  float rS0 = (lane < 32) ? r0 : r1;
  float rS1 = (lane < 32) ? r2 : r3;
  float rV = (lane < 16) ? r0 : (lane < 32) ? r1 : (lane < 48) ? r2 : r3;
  agg_s[(size_t)n * 128 + lane] = as0 * rS0;
  agg_s[(size_t)n * 128 + 64 + lane] = as1 * rS1;
  agg_v[(size_t)n * 192 + lane * 3 + 0] = av0 * rV;
  agg_v[(size_t)n * 192 + lane * 3 + 1] = av1 * rV;
  agg_v[(size_t)n * 192 + lane * 3 + 2] = av2 * rV;
  if (lane < 32) {
    float rT = (lane < 8) ? r0 : (lane < 16) ? r1 : (lane < 24) ? r2 : r3;
    agg_t[(size_t)n * 160 + lane * 5 + 0] = at0 * rT;
    agg_t[(size_t)n * 160 + lane * 5 + 1] = at1 * rT;
    agg_t[(size_t)n * 160 + lane * 5 + 2] = at2 * rT;
    agg_t[(size_t)n * 160 + lane * 5 + 3] = at3 * rT;
    agg_t[(size_t)n * 160 + lane * 5 + 4] = at4 * rT;
  }
}

// ---------------- fused node update + next-layer transforms: wave-per-2-nodes, barrier-free ----------------
__global__ __launch_bounds__(256) void k_node_fused(
    float* __restrict__ s, float* __restrict__ v, float* __restrict__ t,
    const float* __restrict__ agg_s, const float* __restrict__ agg_v,
    const float* __restrict__ agg_t, const float* __restrict__ Wo_s,
    const float* __restrict__ Wo_v, const float* __restrict__ Wo_t,
    const float* __restrict__ g_s, const float* __restrict__ b_s,
    const float* __restrict__ g_v, const float* __restrict__ g_t,
    const float* __restrict__ Ws_src, const float* __restrict__ Ws_v,
    const float* __restrict__ Ws_t, const float* __restrict__ Wv_v,
    const float* __restrict__ Wt_t, float* __restrict__ sWsrc,
    float* __restrict__ sWv, float* __restrict__ sWt, float* __restrict__ vW,
    float* __restrict__ tW) {
  int wv = threadIdx.x >> 6, lane = threadIdx.x & 63;
  int lt = lane & 31, nh = lane >> 5;
  int n0 = (blockIdx.x * 4 + wv) * 2;
  int n1 = n0 + 1;
  int nt = n0 + nh;
  __shared__ float stg[4][2][192];
  __shared__ float sN[4][2][128];
  __shared__ float vN[4][2][192];
  __shared__ float tN[4][2][160];
  // ---- stage agg_s (both nodes); load s_old ----
  float aS0 = agg_s[(size_t)n0 * 128 + lane];
  float aS1 = agg_s[(size_t)n0 * 128 + 64 + lane];
  float bS0 = agg_s[(size_t)n1 * 128 + lane];
  float bS1 = agg_s[(size_t)n1 * 128 + 64 + lane];
  float sA0 = s[(size_t)n0 * 128 + lane];
  float sA1 = s[(size_t)n0 * 128 + 64 + lane];
  float sB0 = s[(size_t)n1 * 128 + lane];
  float sB1 = s[(size_t)n1 * 128 + 64 + lane];
  stg[wv][0][lane] = aS0; stg[wv][0][64 + lane] = aS1;
  stg[wv][1][lane] = bS0; stg[wv][1][64 + lane] = bS1;
  asm volatile("s_waitcnt lgkmcnt(0)" ::: "memory");
  // ---- s-matmul: s_new = s_old + agg_s @ Wo_s (weights amortized over 2 nodes) ----
  #pragma unroll 8
  for (int c = 0; c < 128; c++) {
    float w0 = Wo_s[c * 128 + lane];
    float w1 = Wo_s[c * 128 + 64 + lane];
    float ax = stg[wv][0][c], bx = stg[wv][1][c];
    sA0 += ax * w0; sA1 += ax * w1;
    sB0 += bx * w0; sB1 += bx * w1;
  }
  // prefetch agg_v + v_old
  float avA0 = agg_v[(size_t)n0 * 192 + lane];
  float avA1 = agg_v[(size_t)n0 * 192 + 64 + lane];
  float avA2 = agg_v[(size_t)n0 * 192 + 128 + lane];
  float avB0 = agg_v[(size_t)n1 * 192 + lane];
  float avB1 = agg_v[(size_t)n1 * 192 + 64 + lane];
  float avB2 = agg_v[(size_t)n1 * 192 + 128 + lane];
  float voA0 = v[(size_t)n0 * 192 + lane * 3 + 0];
  float voA1 = v[(size_t)n0 * 192 + lane * 3 + 1];
  float voA2 = v[(size_t)n0 * 192 + lane * 3 + 2];
  float voB0 = v[(size_t)n1 * 192 + lane * 3 + 0];
  float voB1 = v[(size_t)n1 * 192 + lane * 3 + 1];
  float voB2 = v[(size_t)n1 * 192 + lane * 3 + 2];
  // ---- LayerNorm(s), both nodes ----
  float smA = sA0 + sA1, sqA = sA0 * sA0 + sA1 * sA1;
  float smB = sB0 + sB1, sqB = sB0 * sB0 + sB1 * sB1;
  #pragma unroll
  for (int m = 1; m < 64; m <<= 1) {
    smA += __shfl_xor(smA, m); sqA += __shfl_xor(sqA, m);
    smB += __shfl_xor(smB, m); sqB += __shfl_xor(sqB, m);
  }
  float muA = smA / 128.0f, muB = smB / 128.0f;
  float varA = sqA / 128.0f - muA * muA; if (varA < 0.f) varA = 0.f;
  float varB = sqB / 128.0f - muB * muB; if (varB < 0.f) varB = 0.f;
  float riA = rsqrtf(varA + 1e-6f), riB = rsqrtf(varB + 1e-6f);
  float gs0 = g_s[lane], gs1 = g_s[64 + lane];
  float bs0 = b_s[lane], bs1 = b_s[64 + lane];
  float yA0 = (sA0 - muA) * riA * gs0 + bs0;
  float yA1 = (sA1 - muA) * riA * gs1 + bs1;
  float yB0 = (sB0 - muB) * riB * gs0 + bs0;
  float yB1 = (sB1 - muB) * riB * gs1 + bs1;
  s[(size_t)n0 * 128 + lane] = yA0;
  s[(size_t)n0 * 128 + 64 + lane] = yA1;
  s[(size_t)n1 * 128 + lane] = yB0;
  s[(size_t)n1 * 128 + 64 + lane] = yB1;
  sN[wv][0][lane] = yA0; sN[wv][0][64 + lane] = yA1;
  sN[wv][1][lane] = yB0; sN[wv][1][64 + lane] = yB1;
  // ---- stage agg_v ----
  stg[wv][0][lane] = avA0; stg[wv][0][64 + lane] = avA1; stg[wv][0][128 + lane] = avA2;
  stg[wv][1][lane] = avB0; stg[wv][1][64 + lane] = avB1; stg[wv][1][128 + lane] = avB2;
  asm volatile("s_waitcnt lgkmcnt(0)" ::: "memory");
  // ---- v-matmul: v_new = v_old + agg_v @ Wo_v ----
  float vA0 = voA0, vA1 = voA1, vA2 = voA2;
  float vB0 = voB0, vB1 = voB1, vB2 = voB2;
  #pragma unroll 8
  for (int c = 0; c < 64; c++) {
    float w = Wo_v[c * 64 + lane];
    vA0 += stg[wv][0][c * 3 + 0] * w;
    vA1 += stg[wv][0][c * 3 + 1] * w;
    vA2 += stg[wv][0][c * 3 + 2] * w;
    vB0 += stg[wv][1][c * 3 + 0] * w;
    vB1 += stg[wv][1][c * 3 + 1] * w;
    vB2 += stg[wv][1][c * 3 + 2] * w;
  }
  // prefetch agg_t + t_old (half-trick: lane<32 → n0, lane>=32 → n1)
  float btA0 = agg_t[(size_t)n0 * 160 + lane];
  float btA1 = agg_t[(size_t)n0 * 160 + 64 + lane];
  float btA2 = (lane < 32) ? agg_t[(size_t)n0 * 160 + 128 + lane] : 0.f;
  float btB0 = agg_t[(size_t)n1 * 160 + lane];
  float btB1 = agg_t[(size_t)n1 * 160 + 64 + lane];
  float btB2 = (lane < 32) ? agg_t[(size_t)n1 * 160 + 128 + lane] : 0.f;
  float to0 = t[(size_t)nt * 160 + lt * 5 + 0];
  float to1 = t[(size_t)nt * 160 + lt * 5 + 1];
  float to2 = t[(size_t)nt * 160 + lt * 5 + 2];
  float to3 = t[(size_t)nt * 160 + lt * 5 + 3];
  float to4 = t[(size_t)nt * 160 + lt * 5 + 4];
  // ---- RMS(v), both nodes ----
  float ssqA = vA0 * vA0 + vA1 * vA1 + vA2 * vA2;
  float ssqB = vB0 * vB0 + vB1 * vB1 + vB2 * vB2;
  #pragma unroll
  for (int m = 1; m < 64; m <<= 1) {
    ssqA += __shfl_xor(ssqA, m);
    ssqB += __shfl_xor(ssqB, m);
  }
  float rivA = rsqrtf(ssqA / 64.0f + 1e-6f);
  float rivB = rsqrtf(ssqB / 64.0f + 1e-6f);
  float gv = g_v[lane];
  float vyA0 = vA0 * rivA * gv, vyA1 = vA1 * rivA * gv, vyA2 = vA2 * rivA * gv;
  float vyB0 = vB0 * rivB * gv, vyB1 = vB1 * rivB * gv, vyB2 = vB2 * rivB * gv;
  v[(size_t)n0 * 192 + lane * 3 + 0] = vyA0;
  v[(size_t)n0 * 192 + lane * 3 + 1] = vyA1;
  v[(size_t)n0 * 192 + lane * 3 + 2] = vyA2;
  v[(size_t)n1 * 192 + lane * 3 + 0] = vyB0;
  v[(size_t)n1 * 192 + lane * 3 + 1] = vyB1;
  v[(size_t)n1 * 192 + lane * 3 + 2] = vyB2;
  vN[wv][0][lane * 3 + 0] = vyA0; vN[wv][0][lane * 3 + 1] = vyA1; vN[wv][0][lane * 3 + 2] = vyA2;
  vN[wv][1][lane * 3 + 0] = vyB0; vN[wv][1][lane * 3 + 1] = vyB1; vN[wv][1][lane * 3 + 2] = vyB2;
  // ---- stage agg_t ----
  stg[wv][0][lane] = btA0; stg[wv][0][64 + lane] = btA1;
  if (lane < 32) stg[wv][0][128 + lane] = btA2;
  stg[wv][1][lane] = btB0; stg[wv][1][64 + lane] = btB1;
  if (lane < 32) stg[wv][1][128 + lane] = btB2;
  asm volatile("s_waitcnt lgkmcnt(0)" ::: "memory");
  // ---- t-matmul: half per node ----
  float at0 = to0, at1 = to1, at2 = to2, at3 = to3, at4 = to4;
  #pragma unroll 4
  for (int c = 0; c < 32; c++) {
    float w = Wo_t[c * 32 + lt];
    at0 += stg[wv][nh][c * 5 + 0] * w;
    at1 += stg[wv][nh][c * 5 + 1] * w;
    at2 += stg[wv][nh][c * 5 + 2] * w;
    at3 += stg[wv][nh][c * 5 + 3] * w;
    at4 += stg[wv][nh][c * 5 + 4] * w;
  }
  // ---- RMS(t): reduce within 32-lane half ----
  float ssqt = at0 * at0 + at1 * at1 + at2 * at2 + at3 * at3 + at4 * at4;
  #pragma unroll
  for (int m = 1; m < 32; m <<= 1) ssqt += __shfl_xor(ssqt, m);
  float rit = rsqrtf(ssqt / 32.0f + 1e-6f);
  float gt = g_t[lt];
  float ty0 = at0 * rit * gt, ty1 = at1 * rit * gt, ty2 = at2 * rit * gt;
  float ty3 = at3 * rit * gt, ty4 = at4 * rit * gt;
  t[(size_t)nt * 160 + lt * 5 + 0] = ty0;
  t[(size_t)nt * 160 + lt * 5 + 1] = ty1;
  t[(size_t)nt * 160 + lt * 5 + 2] = ty2;
  t[(size_t)nt * 160 + lt * 5 + 3] = ty3;
  t[(size_t)nt * 160 + lt * 5 + 4] = ty4;
  tN[wv][nh][lt * 5 + 0] = ty0;
  tN[wv][nh][lt * 5 + 1] = ty1;
  tN[wv][nh][lt * 5 + 2] = ty2;
  tN[wv][nh][lt * 5 + 3] = ty3;
  tN[wv][nh][lt * 5 + 4] = ty4;
  asm volatile("s_waitcnt lgkmcnt(0)" ::: "memory");
  // ---- transforms for next layer ----
  {
    float cA0 = 0.f, cA1 = 0.f, cB0 = 0.f, cB1 = 0.f;
    #pragma unroll 8
    for (int c = 0; c < 128; c++) {
      float w0 = Ws_src[c * 128 + lane];
      float w1 = Ws_src[c * 128 + 64 + lane];
      float aA = sN[wv][0][c], aB = sN[wv][1][c];
      cA0 += aA * w0; cA1 += aA * w1;
      cB0 += aB * w0; cB1 += aB * w1;
    }
    sWsrc[(size_t)n0 * 128 + lane] = cA0;
    sWsrc[(size_t)n0 * 128 + 64 + lane] = cA1;
    sWsrc[(size_t)n1 * 128 + lane] = cB0;
    sWsrc[(size_t)n1 * 128 + 64 + lane] = cB1;
  }
  {
    float cvA = 0.f, cvB = 0.f, ct = 0.f;
    #pragma unroll 8
    for (int c = 0; c < 128; c++) {
      float wvv = Ws_v[c * 64 + lane];
      float wtt = Ws_t[c * 32 + lt];
      float aA = sN[wv][0][c], aB = sN[wv][1][c];
      cvA += aA * wvv; cvB += aB * wvv;
      ct += sN[wv][nh][c] * wtt;
    }
    sWv[(size_t)n0 * 64 + lane] = cvA;
    sWv[(size_t)n1 * 64 + lane] = cvB;
    sWt[(size_t)nt * 32 + lt] = ct;
  }
  {
    float wA0 = 0.f, wA1 = 0.f, wA2 = 0.f, wB0 = 0.f, wB1 = 0.f, wB2 = 0.f;
    #pragma unroll 8
    for (int c = 0; c < 64; c++) {
      float w = Wv_v[c * 64 + lane];
      wA0 += vN[wv][0][c * 3 + 0] * w;
      wA1 += vN[wv][0][c * 3 + 1] * w;
      wA2 += vN[wv][0][c * 3 + 2] * w;
      wB0 += vN[wv][1][c * 3 + 0] * w;
      wB1 += vN[wv][1][c * 3 + 1] * w;
      wB2 += vN[wv][1][c * 3 + 2] * w;
    }
    vW[(size_t)n0 * 192 + lane] = wA0;
    vW[(size_t)n0 * 192 + 64 + lane] = wA1;
    vW[(size_t)n0 * 192 + 128 + lane] = wA2;
    vW[(size_t)n1 * 192 + lane] = wB0;
    vW[(size_t)n1 * 192 + 64 + lane] = wB1;
    vW[(size_t)n1 * 192 + 128 + lane] = wB2;
  }
  {
    float u0 = 0.f, u1 = 0.f, u2 = 0.f, u3 = 0.f, u4 = 0.f;
    #pragma unroll 4
    for (int c = 0; c < 32; c++) {
      float w = Wt_t[c * 32 + lt];
      u0 += tN[wv][nh][c * 5 + 0] * w;
      u1 += tN[wv][nh][c * 5 + 1] * w;
      u2 += tN[wv][nh][c * 5 + 2] * w;
      u3 += tN[wv][nh][c * 5 + 3] * w;
      u4 += tN[wv][nh][c * 5 + 4] * w;
    }
    tW[(size_t)nt * 160 + lt] = u0;
    tW[(size_t)nt * 160 + 32 + lt] = u1;
    tW[(size_t)nt * 160 + 64 + lt] = u2;
    tW[(size_t)nt * 160 + 96 + lt] = u3;
    tW[(size_t)nt * 160 + 128 + lt] = u4;
  }
}

// ---------------- node update, final layer: wave-per-2-nodes, barrier-free ----------------
__global__ __launch_bounds__(256) void k_node_up(
    float* __restrict__ s, float* __restrict__ v, float* __restrict__ t,
    const float* __restrict__ agg_s, const float* __restrict__ agg_v,
    const float* __restrict__ agg_t, const float* __restrict__ Wo_s,
    const float* __restrict__ Wo_v, const float* __restrict__ Wo_t,
    const float* __restrict__ g_s, const float* __restrict__ b_s,
    const float* __restrict__ g_v, const float* __restrict__ g_t) {
  int wv = threadIdx.x >> 6, lane = threadIdx.x & 63;
  int lt = lane & 31, nh = lane >> 5;
  int n0 = (blockIdx.x * 4 + wv) * 2;
  int n1 = n0 + 1;
  int nt = n0 + nh;
  __shared__ float stg[4][2][192];
  float aS0 = agg_s[(size_t)n0 * 128 + lane];
  float aS1 = agg_s[(size_t)n0 * 128 + 64 + lane];
  float bS0 = agg_s[(size_t)n1 * 128 + lane];
  float bS1 = agg_s[(size_t)n1 * 128 + 64 + lane];
  float sA0 = s[(size_t)n0 * 128 + lane];
  float sA1 = s[(size_t)n0 * 128 + 64 + lane];
  float sB0 = s[(size_t)n1 * 128 + lane];
  float sB1 = s[(size_t)n1 * 128 + 64 + lane];
  stg[wv][0][lane] = aS0; stg[wv][0][64 + lane] = aS1;
  stg[wv][1][lane] = bS0; stg[wv][1][64 + lane] = bS1;
  asm volatile("s_waitcnt lgkmcnt(0)" ::: "memory");
  #pragma unroll 8
  for (int c = 0; c < 128; c++) {
    float w0 = Wo_s[c * 128 + lane];
    float w1 = Wo_s[c * 128 + 64 + lane];
    float ax = stg[wv][0][c], bx = stg[wv][1][c];
    sA0 += ax * w0; sA1 += ax * w1;
    sB0 += bx * w0; sB1 += bx * w1;
  }
  float avA0 = agg_v[(size_t)n0 * 192 + lane];
  float avA1 = agg_v[(size_t)n0 * 192 + 64 + lane];
  float avA2 = agg_v[(size_t)n0 * 192 + 128 + lane];
  float avB0 = agg_v[(size_t)n1 * 192 + lane];
  float avB1 = agg_v[(size_t)n1 * 192 + 64 + lane];
  float avB2 = agg_v[(size_t)n1 * 192 + 128 + lane];
  float voA0 = v[(size_t)n0 * 192 + lane * 3 + 0];
  float voA1 = v[(size_t)n0 * 192 + lane * 3 + 1];
  float voA2 = v[(size_t)n0 * 192 + lane * 3 + 2];
  float voB0 = v[(size_t)n1 * 192 + lane * 3 + 0];
  float voB1 = v[(size_t)n1 * 192 + lane * 3 + 1];
  float voB2 = v[(size_t)n1 * 192 + lane * 3 + 2];
  float smA = sA0 + sA1, sqA = sA0 * sA0 + sA1 * sA1;
  float smB = sB0 + sB1, sqB = sB0 * sB0 + sB1 * sB1;
  #pragma unroll
  for (int m = 1; m < 64; m <<= 1) {
    smA += __shfl_xor(smA, m); sqA += __shfl_xor(sqA, m);
    smB += __shfl_xor(smB, m); sqB += __shfl_xor(sqB, m);
  }
  float muA = smA / 128.0f, muB = smB / 128.0f;
  float varA = sqA / 128.0f - muA * muA; if (varA < 0.f) varA = 0.f;
  float varB = sqB / 128.0f - muB * muB; if (varB < 0.f) varB = 0.f;
  float riA = rsqrtf(varA + 1e-6f), riB = rsqrtf(varB + 1e-6f);
  float gs0 = g_s[lane], gs1 = g_s[64 + lane];
  float bs0 = b_s[lane], bs1 = b_s[64 + lane];
  s[(size_t)n0 * 128 + lane] = (sA0 - muA) * riA * gs0 + bs0;
  s[(size_t)n0 * 128 + 64 + lane] = (sA1 - muA) * riA * gs1 + bs1;
  s[(size_t)n1 * 128 + lane] = (sB0 - muB) * riB * gs0 + bs0;
  s[(size_t)n1 * 128 + 64 + lane] = (sB1 - muB) * riB * gs1 + bs1;
  stg[wv][0][lane] = avA0; stg[wv][0][64 + lane] = avA1; stg[wv][0][128 + lane] = avA2;
  stg[wv][1][lane] = avB0; stg[wv][1][64 + lane] = avB1; stg[wv][1][128 + lane] = avB2;
  asm volatile("s_waitcnt lgkmcnt(0)" ::: "memory");
  float vA0 = voA0, vA1 = voA1, vA2 = voA2;
  float vB0 = voB0, vB1 = voB1, vB2 = voB2;
  #pragma unroll 8
  for (int c = 0; c < 64; c++) {
    float w = Wo_v[c * 64 + lane];
    vA0 += stg[wv][0][c * 3 + 0] * w;
    vA1 += stg[wv][0][c * 3 + 1] * w;
    vA2 += stg[wv][0][c * 3 + 2] * w;
    vB0 += stg[wv][1][c * 3 + 0] * w;
    vB1 += stg[wv][1][c * 3 + 1] * w;
    vB2 += stg[wv][1][c * 3 + 2] * w;
  }
  float btA0 = agg_t[(size_t)n0 * 160 + lane];
  float btA1 = agg_t[(size_t)n0 * 160 + 64 + lane];
  float btA2 = (lane < 32) ? agg_t[(size_t)n0 * 160 + 128 + lane] : 0.f;
  float btB0 = agg_t[(size_t)n1 * 160 + lane];
  float btB1 = agg_t[(size_t)n1 * 160 + 64 + lane];
  float btB2 = (lane < 32) ? agg_t[(size_t)n1 * 160 + 128 + lane] : 0.f;
  float to0 = t[(size_t)nt * 160 + lt * 5 + 0];
  float to1 = t[(size_t)nt * 160 + lt * 5 + 1];
  float to2 = t[(size_t)nt * 160 + lt * 5 + 2];
  float to3 = t[(size_t)nt * 160 + lt * 5 + 3];
  float to4 = t[(size_t)nt * 160 + lt * 5 + 4];
  float ssqA = vA0 * vA0 + vA1 * vA1 + vA2 * vA2;
  float ssqB = vB0 * vB0 + vB1 * vB1 + vB2 * vB2;
  #pragma unroll
  for (int m = 1; m < 64; m <<= 1) {
    ssqA += __shfl_xor(ssqA, m);
    ssqB += __shfl_xor(ssqB, m);
  }
  float rivA = rsqrtf(ssqA / 64.0f + 1e-6f);
  float rivB = rsqrtf(ssqB / 64.0f + 1e-6f);
  float gv = g_v[lane];
  v[(size_t)n0 * 192 + lane * 3 + 0] = vA0 * rivA * gv;
  v[(size_t)n0 * 192 + lane * 3 + 1] = vA1 * rivA * gv;
  v[(size_t)n0 * 192 + lane * 3 + 2] = vA2 * rivA * gv;
  v[(size_t)n1 * 192 + lane * 3 + 0] = vB0 * rivB * gv;
  v[(size_t)n1 * 192 + lane * 3 + 1] = vB1 * rivB * gv;
  v[(size_t)n1 * 192 + lane * 3 + 2] = vB2 * rivB * gv;
  stg[wv][0][lane] = btA0; stg[wv][0][64 + lane] = btA1;
  if (lane < 32) stg[wv][0][128 + lane] = btA2;
  stg[wv][1][lane] = btB0; stg[wv][1][64 + lane] = btB1;
  if (lane < 32) stg[wv][1][128 + lane] = btB2;
  asm volatile("s_waitcnt lgkmcnt(0)" ::: "memory");
  float at0 = to0, at1 = to1, at2 = to2, at3 = to3, at4 = to4;
  #pragma unroll 4
  for (int c = 0; c < 32; c++) {
    float w = Wo_t[c * 32 + lt];
    at0 += stg[wv][nh][c * 5 + 0] * w;
    at1 += stg[wv][nh][c * 5 + 1] * w;
    at2 += stg[wv][nh][c * 5 + 2] * w;
    at3 += stg[wv][nh][c * 5 + 3] * w;
    at4 += stg[wv][nh][c * 5 + 4] * w;
  }
  float ssqt = at0 * at0 + at1 * at1 + at2 * at2 + at3 * at3 + at4 * at4;
  #pragma unroll
  for (int m = 1; m < 32; m <<= 1) ssqt += __shfl_xor(ssqt, m);
  float rit = rsqrtf(ssqt / 32.0f + 1e-6f);
  float gt = g_t[lt];
  t[(size_t)nt * 160 + lt * 5 + 0] = at0 * rit * gt;
  t[(size_t)nt * 160 + lt * 5 + 1] = at1 * rit * gt;
  t[(size_t)nt * 160 + lt * 5 + 2] = at2 * rit * gt;
  t[(size_t)nt * 160 + lt * 5 + 3] = at3 * rit * gt;
  t[(size_t)nt * 160 + lt * 5 + 4] = at4 * rit * gt;
}

// ---------------- readout (conflict-free mapping) ----------------
__global__ __launch_bounds__(256) void k_readout(
    const float* __restrict__ s, const int* __restrict__ batch,
    const float* __restrict__ W_feat, const float* __restrict__ b_feat,
    const float* __restrict__ W_out1, const float* __restrict__ b_out1,
    float* __restrict__ graph) {
  __shared__ float st[64][129];
  __shared__ float gacc[GG];
  int nb = blockIdx.x * 64;
  int fb = blockIdx.y;  // 0..7
  for (int idx = threadIdx.x; idx < 64 * 128; idx += 256) {
    int nl = idx >> 7, c = idx & 127;
    int n = nb + nl;
    st[nl][c] = (n < NN) ? s[(size_t)n * 128 + c] : 0.f;
  }
  if (threadIdx.x < GG) gacc[threadIdx.x] = 0.f;
  __syncthreads();
  int wv = threadIdx.x >> 6, lane = threadIdx.x & 63;
  int fg = lane & 15;
  int ns = lane >> 4;
  int f0 = fb * 64 + fg * 4;
  int nodeb = wv * 16 + ns * 4;
  float acc[4][4];
  #pragma unroll
  for (int nn = 0; nn < 4; nn++)
    #pragma unroll
    for (int k = 0; k < 4; k++) acc[nn][k] = b_feat[f0 + k];
  #pragma unroll 4
  for (int c = 0; c < 128; c++) {
    float4 wq = *(const float4*)&W_feat[(size_t)c * 512 + f0];
    #pragma unroll
    for (int nn = 0; nn < 4; nn++) {
      float sv = st[nodeb + nn][c];
      acc[nn][0] += sv * wq.x;
      acc[nn][1] += sv * wq.y;
      acc[nn][2] += sv * wq.z;
      acc[nn][3] += sv * wq.w;
    }
  }
  float wo[4];
  #pragma unroll
  for (int k = 0; k < 4; k++) wo[k] = W_out1[f0 + k];
  float ep[4];
  #pragma unroll
  for (int nn = 0; nn < 4; nn++) {
    float p = 0.f;
    #pragma unroll
    for (int k = 0; k < 4; k++) p += fgelu(acc[nn][k]) * wo[k];
    ep[nn] = p;
  }
  #pragma unroll
  for (int mm = 1; mm < 16; mm <<= 1) {
    #pragma unroll
    for (int nn = 0; nn < 4; nn++) ep[nn] += __shfl_xor(ep[nn], mm);
  }
  if (fg == 0) {
    #pragma unroll
    for (int nn = 0; nn < 4; nn++) {
      int n = nb + nodeb + nn;
      if (n < NN) {
        float e = ep[nn];
        if (fb == 0) e += b_out1[0];
        atomicAdd(&gacc[batch[n]], e);
      }
    }
  }
  __syncthreads();
  if (threadIdx.x < GG && gacc[threadIdx.x] != 0.f)
    atomicAdd(&graph[threadIdx.x], gacc[threadIdx.x]);
}

__global__ void k_finalize(const float* __restrict__ graph, const float* __restrict__ W_read,
                           const float* __restrict__ b_read, float* __restrict__ out) {
  int g = threadIdx.x;
  if (g < GG) out[g] = graph[g] * W_read[0] + b_read[0];
}

// ---------------- host ----------------
extern "C" void kernel_launch(void* const* d_in, const int* in_sizes, int n_in,
                              void* d_out, int out_size, void* d_ws, size_t ws_size,
                              hipStream_t stream) {
  const float* pos = (const float*)d_in[0];
  const int* node_atom = (const int*)d_in[1];
  const int* batch = (const int*)d_in[2];
  const int* esrc = (const int*)d_in[3];
  const int* edst = (const int*)d_in[4];
  const float* atom_emb = (const float*)d_in[5];
  const float* Wrad1 = (const float*)d_in[6];
  const float* brad1 = (const float*)d_in[7];
  const float* Wrad2 = (const float*)d_in[8];
  const float* brad2 = (const float*)d_in[9];
  const float* Ws_src = (const float*)d_in[10];
  const float* Ww_s = (const float*)d_in[11];
  const float* Ws_v = (const float*)d_in[12];
  const float* Ww_v = (const float*)d_in[13];
  const float* Wv_v = (const float*)d_in[14];
  const float* Ww_vv = (const float*)d_in[15];
  const float* Ws_t = (const float*)d_in[16];
  const float* Ww_t = (const float*)d_in[17];
  const float* Wt_t = (const float*)d_in[18];
  const float* Ww_tt = (const float*)d_in[19];
  const float* attn_a = (const float*)d_in[20];
  const float* Wo_s = (const float*)d_in[21];
  const float* Wo_v = (const float*)d_in[22];
  const float* Wo_t = (const float*)d_in[23];
  const float* g_s = (const float*)d_in[24];
  const float* b_s = (const float*)d_in[25];
  const float* g_v = (const float*)d_in[26];
  const float* g_t = (const float*)d_in[27];
  const float* W_feat = (const float*)d_in[28];
  const float* b_feat = (const float*)d_in[29];
  const float* W_out1 = (const float*)d_in[30];
  const float* b_out1 = (const float*)d_in[31];
  const float* W_read = (const float*)d_in[32];
  const float* b_read = (const float*)d_in[33];
  float* out = (float*)d_out;

  char* base = (char*)d_ws;
  size_t off = 0;
  auto alloc = [&](size_t bytes) -> char* {
    off = (off + 255) & ~(size_t)255;
    char* p = base + off;
    off += bytes;
    return p;
  };
  int* deg = (int*)alloc(NN * 4);
  int* row_off = (int*)alloc((NN + 1) * 4);
  int* cursor = (int*)alloc(NN * 4);
  float* d_csr = (float*)alloc((size_t)EE * 4);
  int* src_csr = (int*)alloc((size_t)EE * 4);
  int* dst_csr = (int*)alloc((size_t)EE * 4);
  int* acnt = (int*)alloc(NN * 4);
  int* act_off = (int*)alloc((NN + 1) * 4);
  int* act_idx = (int*)alloc((size_t)EE * 4);
  int* dbkt = (int*)alloc(128 * 4);
  int* dboff = (int*)alloc(129 * 4);
  int* dbcur = (int*)alloc(128 * 4);
  int* order = (int*)alloc(NN * 4);
  float* d_a = (float*)alloc((size_t)EE * 4);
  int* src_a = (int*)alloc((size_t)EE * 4);
  float* sh_a = (float*)alloc((size_t)EE * 8 * 4);
  float* wtab = (float*)alloc((size_t)LL * TABN * 64 * 4);
  float* gs_tab = (float*)alloc((size_t)LL * TABN * 128 * 4);
  float* gv_tab = (float*)alloc((size_t)LL * TABN * 128 * 4);
  float* gt_tab = (float*)alloc((size_t)LL * TABN * 64 * 4);
  float* s = (float*)alloc((size_t)NN * 128 * 4);
  float* v = (float*)alloc((size_t)NN * 192 * 4);
  float* t = (float*)alloc((size_t)NN * 160 * 4);
  float* sWsrc = (float*)alloc((size_t)NN * 128 * 4);
  float* sWv = (float*)alloc((size_t)NN * 64 * 4);
  float* sWt = (float*)alloc((size_t)NN * 32 * 4);
  float* vW = (float*)alloc((size_t)NN * 192 * 4);
  float* tW = (float*)alloc((size_t)NN * 160 * 4);
  float* agg_s = (float*)alloc((size_t)NN * 128 * 4);
  float* agg_v = (float*)alloc((size_t)NN * 192 * 4);
  float* agg_t = (float*)alloc((size_t)NN * 160 * 4);
  float* graph = (float*)alloc(GG * 4);

  hipMemsetAsync(deg, 0, NN * 4, stream);
  hipMemsetAsync(cursor, 0, NN * 4, stream);
  hipMemsetAsync(dbkt, 0, 128 * 4, stream);
  hipMemsetAsync(dbcur, 0, 128 * 4, stream);
  hipMemsetAsync(graph, 0, GG * 4, stream);
  hipMemsetAsync(v, 0, (size_t)NN * 192 * 4, stream);
  hipMemsetAsync(t, 0, (size_t)NN * 160 * 4, stream);
  // layer-0: v = t = 0  =>  vW = tW = 0 (skip the transform matmuls entirely)
  hipMemsetAsync(vW, 0, (size_t)NN * 192 * 4, stream);
  hipMemsetAsync(tW, 0, (size_t)NN * 160 * 4, stream);

  k_hist<<<(EE + 255) / 256, 256, 0, stream>>>(edst, deg);
  k_scan<<<1, 1024, 0, stream>>>(deg, row_off, NN);
  k_scatter<<<(EE + 255) / 256, 256, 0, stream>>>(esrc, edst, pos, row_off, cursor,
                                                  d_csr, src_csr, dst_csr);
  k_act_cnt<<<(NN + 255) / 256, 256, 0, stream>>>(row_off, d_csr, acnt, dbkt);
  k_scan<<<1, 1024, 0, stream>>>(acnt, act_off, NN);
  k_act_fill<<<(NN + 255) / 256, 256, 0, stream>>>(row_off, d_csr, act_off, act_idx);
  k_scan<<<1, 1024, 0, stream>>>(dbkt, dboff, 128);
  k_dscatter<<<(NN + 255) / 256, 256, 0, stream>>>(acnt, dboff, dbcur, order);
  k_geom_act<<<(EE + 255) / 256, 256, 0, stream>>>(act_idx, src_csr, dst_csr, pos, act_off,
                                                   d_a, src_a, sh_a);
  k_build_wtab<<<LL * (TABN / 16), 256, 0, stream>>>(Wrad1, brad1, Wrad2, brad2, wtab);
  k_build_tabs<<<LL * (TABN / EB), 320, 0, stream>>>(wtab, Ww_s, Ww_v, Ww_vv, Ww_t, Ww_tt,
                                                     gs_tab, gv_tab, gt_tab);
  k_init_s<<<(NN * 128 + 255) / 256, 256, 0, stream>>>(node_atom, atom_emb, s);

  // initial transforms (layer 0, s only — v/t are zero)
  k_node_tf0<<<NN / 16, 256, 0, stream>>>(s, Ws_src, Ws_v, Ws_t, sWsrc, sWv, sWt);

  for (int l = 0; l < LL; l++) {
    const float* gsL = gs_tab + (size_t)l * TABN * 128;
    const float* gvL = gv_tab + (size_t)l * TABN * 128;
    const float* gtL = gt_tab + (size_t)l * TABN * 64;
    k_mega<<<NN / 4, 256, 0, stream>>>(row_off, act_off, order, src_a, d_a, gsL, gvL, gtL,
                                       attn_a + (size_t)l * 128,
                                       sWsrc, sWv, sWt, vW, tW, sh_a, agg_s, agg_v, agg_t);
    if (l < LL - 1) {
      k_node_fused<<<NN / 8, 256, 0, stream>>>(
          s, v, t, agg_s, agg_v, agg_t,
          Wo_s + (size_t)l * 128 * 128, Wo_v + (size_t)l * 64 * 64,
          Wo_t + (size_t)l * 32 * 32,
          g_s + (size_t)l * 128, b_s + (size_t)l * 128,
          g_v + (size_t)l * 64, g_t + (size_t)l * 32,
          Ws_src + (size_t)(l + 1) * 128 * 128, Ws_v + (size_t)(l + 1) * 128 * 64,
          Ws_t + (size_t)(l + 1) * 128 * 32, Wv_v + (size_t)(l + 1) * 64 * 64,
          Wt_t + (size_t)(l + 1) * 32 * 32,
          sWsrc, sWv, sWt, vW, tW);
    } else {
      k_node_up<<<NN / 8, 256, 0, stream>>>(s, v, t, agg_s, agg_v, agg_t,
                                            Wo_s + (size_t)l * 128 * 128,
                                            Wo_v + (size_t)l * 64 * 64, Wo_t + (size_t)l * 32 * 32,
                                            g_s + (size_t)l * 128, b_s + (size_t)l * 128,
                                            g_v + (size_t)l * 64, g_t + (size_t)l * 32);
    }
  }
  dim3 rg((NN + 63) / 64, 8);
  k_readout<<<rg, 256, 0, stream>>>(s, batch, W_feat, b_feat, W_out1, b_out1, graph);
  k_finalize<<<1, 64, 0, stream>>>(graph, W_read, b_read, out);
}

// Round 10
// 1005.020 us; speedup vs baseline: 1.0491x; 1.0491x over previous
//
#include <hip/hip_runtime.h>
#include <math.h>

#define NN 10000
#define EE 320000
#define GG 32
#define LL 6
#define TABN 2048
#define TABB (TABN / 64)
#define DTAB 5.45f
#define DCUT 5.4f

__device__ __forceinline__ float fsilu(float x) { return x / (1.0f + __expf(-x)); }
__device__ __forceinline__ float fgelu(float x) {
  float y = 0.7978845608f * (x + 0.044715f * x * x * x);
  float t = 1.0f - 2.0f / (__expf(2.0f * y) + 1.0f);
  return 0.5f * x * (1.0f + t);
}

// ---------------- CSR build ----------------
__global__ void k_hist(const int* __restrict__ dst, int* __restrict__ deg) {
  int e = blockIdx.x * blockDim.x + threadIdx.x;
  if (e < EE) atomicAdd(&deg[dst[e]], 1);
}

// parallel scan: each thread serially scans a chunk, then one scan of totals
__global__ void k_scan(const int* __restrict__ cnt, int* __restrict__ off, int n) {
  __shared__ int tsum[1024];
  int chunk = (n + 1023) / 1024;
  int base = (int)threadIdx.x * chunk;
  int local = 0;
  for (int i = 0; i < chunk; i++) {
    int idx = base + i;
    local += (idx < n) ? cnt[idx] : 0;
  }
  tsum[threadIdx.x] = local;
  __syncthreads();
  for (int o = 1; o < 1024; o <<= 1) {
    int tv = (threadIdx.x >= (unsigned)o) ? tsum[threadIdx.x - o] : 0;
    __syncthreads();
    tsum[threadIdx.x] += tv;
    __syncthreads();
  }
  int run = tsum[threadIdx.x] - local;  // exclusive prefix of this chunk
  for (int i = 0; i < chunk; i++) {
    int idx = base + i;
    if (idx < n) {
      run += cnt[idx];
      off[idx + 1] = run;
    }
  }
  if (threadIdx.x == 0) off[0] = 0;
}

// scatter + geometry fused: one pass assigns CSR slots and computes distances
__global__ void k_scatter(const int* __restrict__ esrc, const int* __restrict__ edst,
                          const float* __restrict__ pos, const int* __restrict__ row_off,
                          int* __restrict__ cursor, float* __restrict__ d_csr,
                          int* __restrict__ src_csr, int* __restrict__ dst_csr) {
  int e = blockIdx.x * blockDim.x + threadIdx.x;
  if (e < EE) {
    int d = edst[e];
    int s = esrc[e];
    int p = atomicAdd(&cursor[d], 1);
    int slot = row_off[d] + p;
    float rx = pos[d * 3 + 0] - pos[s * 3 + 0];
    float ry = pos[d * 3 + 1] - pos[s * 3 + 1];
    float rz = pos[d * 3 + 2] - pos[s * 3 + 2];
    d_csr[slot] = sqrtf(rx * rx + ry * ry + rz * rz + 1e-6f);
    src_csr[slot] = s;
    dst_csr[slot] = d;
  }
}

// ---------------- active-edge count + degree histogram (fused) ----------------
__global__ void k_act_cnt(const int* __restrict__ row_off, const float* __restrict__ d_csr,
                          int* __restrict__ acnt, int* __restrict__ dbkt) {
  int n = blockIdx.x * blockDim.x + threadIdx.x;
  if (n >= NN) return;
  int c = 0;
  for (int j = row_off[n]; j < row_off[n + 1]; ++j) c += (d_csr[j] < DCUT) ? 1 : 0;
  acnt[n] = c;
  int b = 127 - min(127, c);
  atomicAdd(&dbkt[b], 1);
}

__global__ void k_act_fill(const int* __restrict__ row_off, const float* __restrict__ d_csr,
                           const int* __restrict__ act_off, int* __restrict__ act_idx) {
  int n = blockIdx.x * blockDim.x + threadIdx.x;
  if (n >= NN) return;
  int a = act_off[n];
  for (int j = row_off[n]; j < row_off[n + 1]; ++j)
    if (d_csr[j] < DCUT) act_idx[a++] = j;
}

__global__ void k_dscatter(const int* __restrict__ acnt, const int* __restrict__ dboff,
                           int* __restrict__ dbcur, int* __restrict__ order) {
  int n = blockIdx.x * blockDim.x + threadIdx.x;
  if (n < NN) {
    int b = 127 - min(127, acnt[n]);
    int p = atomicAdd(&dbcur[b], 1);
    order[dboff[b] + p] = n;
  }
}

// ---------------- compacted geometry per active edge (direct CSR arrays) ----------------
__global__ void k_geom_act(const int* __restrict__ act_idx, const int* __restrict__ src_csr,
                           const int* __restrict__ dst_csr, const float* __restrict__ pos,
                           const int* __restrict__ act_off, float* __restrict__ d_a,
                           int* __restrict__ src_a, float* __restrict__ sh_a) {
  int a = blockIdx.x * blockDim.x + threadIdx.x;
  if (a >= act_off[NN]) return;
  int j = act_idx[a];
  int s = src_csr[j], dd = dst_csr[j];
  float rx = pos[dd * 3 + 0] - pos[s * 3 + 0];
  float ry = pos[dd * 3 + 1] - pos[s * 3 + 1];
  float rz = pos[dd * 3 + 2] - pos[s * 3 + 2];
  float d = sqrtf(rx * rx + ry * ry + rz * rz + 1e-6f);
  float inv = 1.0f / d;
  float x = rx * inv, y = ry * inv, z = rz * inv;
  d_a[a] = d;
  src_a[a] = s;
  const float s3 = 1.7320508075688772f;
  const float s5 = 2.23606797749979f;
  const float s15 = 3.872983346207417f;
  sh_a[a * 8 + 0] = s3 * x;
  sh_a[a * 8 + 1] = s3 * y;
  sh_a[a * 8 + 2] = s3 * z;
  sh_a[a * 8 + 3] = s15 * x * y;
  sh_a[a * 8 + 4] = s15 * y * z;
  sh_a[a * 8 + 5] = 0.5f * s5 * (3.0f * z * z - 1.0f);
  sh_a[a * 8 + 6] = s15 * x * z;
  sh_a[a * 8 + 7] = 0.5f * s15 * (x * x - y * y);
}

// ---------------- radial MLP table w(d): 16 entries/block for parallelism ----------------
__global__ void k_build_wtab(const float* __restrict__ Wrad1, const float* __restrict__ brad1,
                             const float* __restrict__ Wrad2, const float* __restrict__ brad2,
                             float* __restrict__ wtab) {
  int l = blockIdx.x / (TABN / 16);
  int blk = blockIdx.x % (TABN / 16);
  __shared__ float W1[128 * 64];
  __shared__ float W2[64 * 64];
  __shared__ float b1[64], b2[64];
  __shared__ float rbf_s[4][128];
  __shared__ float h_s[4][64];
  const float* w1p = Wrad1 + (size_t)l * 128 * 64;
  const float* w2p = Wrad2 + (size_t)l * 64 * 64;
  for (int i = threadIdx.x; i < 128 * 64; i += 256) W1[i] = w1p[i];
  for (int i = threadIdx.x; i < 64 * 64; i += 256) W2[i] = w2p[i];
  if (threadIdx.x < 64) {
    b1[threadIdx.x] = brad1[(size_t)l * 64 + threadIdx.x];
    b2[threadIdx.x] = brad2[(size_t)l * 64 + threadIdx.x];
  }
  __syncthreads();
  int wv = threadIdx.x >> 6, lane = threadIdx.x & 63;
  const float width = 5.0f / 128.0f;
  for (int k = wv; k < 16; k += 4) {
    int i = blk * 16 + k;
    float d = (float)i * (DTAB / (float)(TABN - 1));
    float c0 = (5.0f * (float)lane) / 127.0f;
    float c1 = (5.0f * (float)(lane + 64)) / 127.0f;
    float t0 = (d - c0) / width, t1 = (d - c1) / width;
    rbf_s[wv][lane] = __expf(-0.5f * t0 * t0);
    rbf_s[wv][lane + 64] = __expf(-0.5f * t1 * t1);
    float acc = b1[lane];
    #pragma unroll 8
    for (int i2 = 0; i2 < 128; i2++) acc += rbf_s[wv][i2] * W1[i2 * 64 + lane];
    acc = fsilu(acc);
    h_s[wv][lane] = acc;
    float acc2 = b2[lane];
    #pragma unroll 8
    for (int i2 = 0; i2 < 64; i2++) acc2 += h_s[wv][i2] * W2[i2 * 64 + lane];
    wtab[((size_t)l * TABN + i) * 64 + lane] = fsilu(acc2);
  }
}

// ---------------- fused product-table build: gs, gv, gt in one kernel ----------------
#define EB 8
__global__ __launch_bounds__(320) void k_build_tabs(
    const float* __restrict__ wtab, const float* __restrict__ Ww_s,
    const float* __restrict__ Ww_v, const float* __restrict__ Ww_vv,
    const float* __restrict__ Ww_t, const float* __restrict__ Ww_tt,
    float* __restrict__ gs_tab, float* __restrict__ gv_tab, float* __restrict__ gt_tab) {
  int l = blockIdx.x / (TABN / EB);
  int eb = (blockIdx.x % (TABN / EB)) * EB;
  __shared__ float ws[EB][64];
  int tid = threadIdx.x;
  for (int i = tid; i < EB * 64; i += 320)
    ws[i >> 6][i & 63] = wtab[((size_t)l * TABN + eb + (i >> 6)) * 64 + (i & 63)];
  __syncthreads();
  float acc[EB] = {};
  if (tid < 128) {
    int col = tid;
    const float* W = Ww_s + (size_t)l * 64 * 128;
    #pragma unroll 8
    for (int i = 0; i < 64; i++) {
      float w = W[i * 128 + col];
      #pragma unroll
      for (int e = 0; e < EB; e++) acc[e] += ws[e][i] * w;
    }
    #pragma unroll
    for (int e = 0; e < EB; e++)
      gs_tab[((size_t)l * TABN + eb + e) * 128 + col] = acc[e];
  } else if (tid < 256) {
    int cc = tid - 128;
    int c = cc >> 1;
    const float* W = ((cc & 1) ? Ww_vv : Ww_v) + (size_t)l * 64 * 64;
    #pragma unroll 8
    for (int i = 0; i < 64; i++) {
      float w = W[i * 64 + c];
      #pragma unroll
      for (int e = 0; e < EB; e++) acc[e] += ws[e][i] * w;
    }
    #pragma unroll
    for (int e = 0; e < EB; e++)
      gv_tab[((size_t)l * TABN + eb + e) * 128 + cc] = acc[e];
  } else {
    int cc = tid - 256;
    int c = cc >> 1;
    const float* W = ((cc & 1) ? Ww_tt : Ww_t) + (size_t)l * 64 * 32;
    #pragma unroll 8
    for (int i = 0; i < 64; i++) {
      float w = W[i * 32 + c];
      #pragma unroll
      for (int e = 0; e < EB; e++) acc[e] += ws[e][i] * w;
    }
    #pragma unroll
    for (int e = 0; e < EB; e++)
      gt_tab[((size_t)l * TABN + eb + e) * 64 + cc] = acc[e];
  }
}

// ---------------- init s ----------------
__global__ void k_init_s(const int* __restrict__ node_atom, const float* __restrict__ atom_emb,
                         float* __restrict__ s) {
  int i = blockIdx.x * blockDim.x + threadIdx.x;
  if (i < NN * 128) {
    int n = i >> 7, c = i & 127;
    s[i] = atom_emb[node_atom[n] * 128 + c];
  }
}

// ---------------- layer-0 transforms: s only (v = t = 0) ----------------
__global__ __launch_bounds__(256) void k_node_tf0(
    const float* __restrict__ s, const float* __restrict__ Ws_src,
    const float* __restrict__ Ws_v, const float* __restrict__ Ws_t,
    float* __restrict__ sWsrc, float* __restrict__ sWv, float* __restrict__ sWt) {
  int nb = blockIdx.x * 16;
  int tid = threadIdx.x;
  __shared__ float s16[16][129];
  for (int idx = tid; idx < 16 * 128; idx += 256) {
    int n = idx >> 7, c = idx & 127;
    s16[n][c] = s[(size_t)(nb + n) * 128 + c];
  }
  __syncthreads();
  {
    int col = tid & 127, ng = tid >> 7;
    float acc[8] = {0, 0, 0, 0, 0, 0, 0, 0};
    for (int c = 0; c < 128; c++) {
      float w = Ws_src[c * 128 + col];
      #pragma unroll
      for (int n = 0; n < 8; n++) acc[n] += s16[ng * 8 + n][c] * w;
    }
    #pragma unroll
    for (int n = 0; n < 8; n++) sWsrc[(size_t)(nb + ng * 8 + n) * 128 + col] = acc[n];
  }
  {
    int col = tid & 63, ng = tid >> 6;
    float acc[4] = {0, 0, 0, 0};
    for (int c = 0; c < 128; c++) {
      float w = Ws_v[c * 64 + col];
      #pragma unroll
      for (int n = 0; n < 4; n++) acc[n] += s16[ng * 4 + n][c] * w;
    }
    #pragma unroll
    for (int n = 0; n < 4; n++) sWv[(size_t)(nb + ng * 4 + n) * 64 + col] = acc[n];
  }
  {
    int col = tid & 31, ng = tid >> 5;
    float acc[2] = {0, 0};
    for (int c = 0; c < 128; c++) {
      float w = Ws_t[c * 32 + col];
      acc[0] += s16[ng * 2 + 0][c] * w;
      acc[1] += s16[ng * 2 + 1][c] * w;
    }
    sWt[(size_t)(nb + ng * 2 + 0) * 32 + col] = acc[0];
    sWt[(size_t)(nb + ng * 2 + 1) * 32 + col] = acc[1];
  }
}

// ---------------- mega: single-pass online-softmax, pair-combined update ----------------
__global__ __launch_bounds__(256) void k_mega(
    const int* __restrict__ row_off, const int* __restrict__ act_off,
    const int* __restrict__ order,
    const int* __restrict__ src_a, const float* __restrict__ d_a,
    const float* __restrict__ gsL, const float* __restrict__ gvL,
    const float* __restrict__ gtL, const float* __restrict__ attn_l,
    const float* __restrict__ sWsrc, const float* __restrict__ sWv,
    const float* __restrict__ sWt, const float* __restrict__ vW,
    const float* __restrict__ tW, const float* __restrict__ sh_a,
    float* __restrict__ agg_s, float* __restrict__ agg_v, float* __restrict__ agg_t) {
  int wv = threadIdx.x >> 6, lane = threadIdx.x & 63;
  int lt = lane & 31;
  int slot = blockIdx.x * 4 + wv;
  if (slot >= NN) return;
  int n = order[slot];
  int alo = act_off[n], ahi = act_off[n + 1];
  int nact = ahi - alo;
  int ninact = (row_off[n + 1] - row_off[n]) - nact;
  const float sc = (float)(TABN - 1) / DTAB;
  float atnA = attn_l[lane];
  float atnB = attn_l[64 + lane];
  float rm0, rm1, rm2, rm3;
  rm0 = rm1 = rm2 = rm3 = (ninact > 0) ? 0.0f : -1e30f;
  float rs0 = 0.f, rs1 = 0.f, rs2 = 0.f, rs3 = 0.f;
  float as0 = 0.f, as1 = 0.f;
  float av0 = 0.f, av1 = 0.f, av2 = 0.f;
  float at0 = 0.f, at1 = 0.f, at2 = 0.f, at3 = 0.f, at4 = 0.f;
  int a = alo;
  for (; a + 1 < ahi; a += 2) {
    int aA = a, aB = a + 1;
    float dA = d_a[aA], dB = d_a[aB];
    int snA = src_a[aA], snB = src_a[aB];
    float xA = fminf(dA * sc, (float)(TABN - 1) - 1.0f);
    float xB = fminf(dB * sc, (float)(TABN - 1) - 1.0f);
    int iA = (int)xA, iB = (int)xB;
    float fA = xA - (float)iA, fB = xB - (float)iB;
    float g1A = 1.0f - fA, g1B = 1.0f - fB;
    const float* gA = gsL + (size_t)iA * 128;
    const float* gB = gsL + (size_t)iB * 128;
    float gsA_A = gA[lane] * g1A + gA[128 + lane] * fA;
    float gsB_A = gA[64 + lane] * g1A + gA[192 + lane] * fA;
    float gsA_B = gB[lane] * g1B + gB[128 + lane] * fB;
    float gsB_B = gB[64 + lane] * g1B + gB[192 + lane] * fB;
    float m0A = sWsrc[(size_t)snA * 128 + lane] * gsA_A;
    float m1A = sWsrc[(size_t)snA * 128 + 64 + lane] * gsB_A;
    float m0B = sWsrc[(size_t)snB * 128 + lane] * gsA_B;
    float m1B = sWsrc[(size_t)snB * 128 + 64 + lane] * gsB_B;
    const float* gvA = gvL + (size_t)iA * 128;
    const float* gvB = gvL + (size_t)iB * 128;
    float2 pA0 = *(const float2*)&gvA[2 * lane];
    float2 pA1 = *(const float2*)&gvA[128 + 2 * lane];
    float2 pB0 = *(const float2*)&gvB[2 * lane];
    float2 pB1 = *(const float2*)&gvB[128 + 2 * lane];
    float gavA = pA0.x * g1A + pA1.x * fA;
    float gbvA = pA0.y * g1A + pA1.y * fA;
    float gavB = pB0.x * g1B + pB1.x * fB;
    float gbvB = pB0.y * g1B + pB1.y * fB;
    float svA = sWv[(size_t)snA * 64 + lane];
    float svB = sWv[(size_t)snB * 64 + lane];
    float4 s1A = *(const float4*)&sh_a[(size_t)aA * 8];
    float4 s2A = *(const float4*)&sh_a[(size_t)aA * 8 + 4];
    float4 s1B = *(const float4*)&sh_a[(size_t)aB * 8];
    float4 s2B = *(const float4*)&sh_a[(size_t)aB * 8 + 4];
    const float* vpA = &vW[(size_t)snA * 192 + lane];
    const float* vpB = &vW[(size_t)snB * 192 + lane];
    float vA0 = vpA[0], vA1 = vpA[64], vA2 = vpA[128];
    float vB0 = vpB[0], vB1 = vpB[64], vB2 = vpB[128];
    float gatA = 0.f, gbtA = 0.f, gatB = 0.f, gbtB = 0.f;
    float stA = 0.f, stB = 0.f;
    float tA0 = 0.f, tA1 = 0.f, tA2 = 0.f, tA3 = 0.f, tA4 = 0.f;
    float tB0 = 0.f, tB1 = 0.f, tB2 = 0.f, tB3 = 0.f, tB4 = 0.f;
    if (lane < 32) {
      const float* gtA = gtL + (size_t)iA * 64;
      const float* gtB = gtL + (size_t)iB * 64;
      float2 qA0 = *(const float2*)&gtA[2 * lt];
      float2 qA1 = *(const float2*)&gtA[64 + 2 * lt];
      float2 qB0 = *(const float2*)&gtB[2 * lt];
      float2 qB1 = *(const float2*)&gtB[64 + 2 * lt];
      gatA = qA0.x * g1A + qA1.x * fA;
      gbtA = qA0.y * g1A + qA1.y * fA;
      gatB = qB0.x * g1B + qB1.x * fB;
      gbtB = qB0.y * g1B + qB1.y * fB;
      stA = sWt[(size_t)snA * 32 + lane];
      stB = sWt[(size_t)snB * 32 + lane];
      const float* tpA = &tW[(size_t)snA * 160 + lane];
      const float* tpB = &tW[(size_t)snB * 160 + lane];
      tA0 = tpA[0]; tA1 = tpA[32]; tA2 = tpA[64]; tA3 = tpA[96]; tA4 = tpA[128];
      tB0 = tpB[0]; tB1 = tpB[32]; tB2 = tpB[64]; tB3 = tpB[96]; tB4 = tpB[128];
    }
    float p01A = m0A * atnA, p23A = m1A * atnB;
    float p01B = m0B * atnA, p23B = m1B * atnB;
    #pragma unroll
    for (int mm = 1; mm < 32; mm <<= 1) {
      p01A += __shfl_xor(p01A, mm);
      p23A += __shfl_xor(p23A, mm);
      p01B += __shfl_xor(p01B, mm);
      p23B += __shfl_xor(p23B, mm);
    }
    float l0A = __shfl(p01A, 0), l1A = __shfl(p01A, 32);
    float l2A = __shfl(p23A, 0), l3A = __shfl(p23A, 32);
    float l0B = __shfl(p01B, 0), l1B = __shfl(p01B, 32);
    float l2B = __shfl(p23B, 0), l3B = __shfl(p23B, 32);
    // combined two-edge online-softmax update (exactly equivalent to sequential)
    float nm0 = fmaxf(rm0, fmaxf(l0A, l0B));
    float nm1 = fmaxf(rm1, fmaxf(l1A, l1B));
    float nm2 = fmaxf(rm2, fmaxf(l2A, l2B));
    float nm3 = fmaxf(rm3, fmaxf(l3A, l3B));
    float wA0 = __expf(l0A - nm0), wA1 = __expf(l1A - nm1);
    float wA2 = __expf(l2A - nm2), wA3 = __expf(l3A - nm3);
    float wB0 = __expf(l0B - nm0), wB1 = __expf(l1B - nm1);
    float wB2 = __expf(l2B - nm2), wB3 = __expf(l3B - nm3);
    float wSA0 = (lane < 32) ? wA0 : wA1, wSA1 = (lane < 32) ? wA2 : wA3;
    float wSB0 = (lane < 32) ? wB0 : wB1, wSB1 = (lane < 32) ? wB2 : wB3;
    float addS0 = wSA0 * m0A + wSB0 * m0B;
    float addS1 = wSA1 * m1A + wSB1 * m1B;
    float wVA = (lane < 16) ? wA0 : (lane < 32) ? wA1 : (lane < 48) ? wA2 : wA3;
    float wVB = (lane < 16) ? wB0 : (lane < 32) ? wB1 : (lane < 48) ? wB2 : wB3;
    float avvA = svA * gavA, avvB = svB * gavB;
    float addV0 = wVA * (avvA * s1A.x + vA0 * gbvA) + wVB * (avvB * s1B.x + vB0 * gbvB);
    float addV1 = wVA * (avvA * s1A.y + vA1 * gbvA) + wVB * (avvB * s1B.y + vB1 * gbvB);
    float addV2 = wVA * (avvA * s1A.z + vA2 * gbvA) + wVB * (avvB * s1B.z + vB2 * gbvB);
    float wTA = (lane < 8) ? wA0 : (lane < 16) ? wA1 : (lane < 24) ? wA2 : wA3;
    float wTB = (lane < 8) ? wB0 : (lane < 16) ? wB1 : (lane < 24) ? wB2 : wB3;
    float attA = stA * gatA, attB = stB * gatB;
    float addT0 = wTA * (attA * s1A.w + tA0 * gbtA) + wTB * (attB * s1B.w + tB0 * gbtB);
    float addT1 = wTA * (attA * s2A.x + tA1 * gbtA) + wTB * (attB * s2B.x + tB1 * gbtB);
    float addT2 = wTA * (attA * s2A.y + tA2 * gbtA) + wTB * (attB * s2B.y + tB2 * gbtB);
    float addT3 = wTA * (attA * s2A.z + tA3 * gbtA) + wTB * (attB * s2B.z + tB3 * gbtB);
    float addT4 = wTA * (attA * s2A.w + tA4 * gbtA) + wTB * (attB * s2B.w + tB4 * gbtB);
    if (nm0 == rm0 && nm1 == rm1 && nm2 == rm2 && nm3 == rm3) {
      rs0 += wA0 + wB0; rs1 += wA1 + wB1; rs2 += wA2 + wB2; rs3 += wA3 + wB3;
      as0 += addS0; as1 += addS1;
      av0 += addV0; av1 += addV1; av2 += addV2;
      at0 += addT0; at1 += addT1; at2 += addT2; at3 += addT3; at4 += addT4;
    } else {
      float f0 = __expf(rm0 - nm0), f1 = __expf(rm1 - nm1);
      float f2 = __expf(rm2 - nm2), f3 = __expf(rm3 - nm3);
      rm0 = nm0; rm1 = nm1; rm2 = nm2; rm3 = nm3;
      rs0 = rs0 * f0 + wA0 + wB0; rs1 = rs1 * f1 + wA1 + wB1;
      rs2 = rs2 * f2 + wA2 + wB2; rs3 = rs3 * f3 + wA3 + wB3;
      float fS0 = (lane < 32) ? f0 : f1, fS1 = (lane < 32) ? f2 : f3;
      as0 = as0 * fS0 + addS0; as1 = as1 * fS1 + addS1;
      float fV = (lane < 16) ? f0 : (lane < 32) ? f1 : (lane < 48) ? f2 : f3;
      av0 = av0 * fV + addV0; av1 = av1 * fV + addV1; av2 = av2 * fV + addV2;
      float fT = (lane < 8) ? f0 : (lane < 16) ? f1 : (lane < 24) ? f2 : f3;
      at0 = at0 * fT + addT0; at1 = at1 * fT + addT1; at2 = at2 * fT + addT2;
      at3 = at3 * fT + addT3; at4 = at4 * fT + addT4;
    }
  }
  for (; a < ahi; ++a) {
    float x = d_a[a] * sc;
    x = fminf(x, (float)(TABN - 1) - 1.0f);
    int i0 = (int)x; float f = x - (float)i0; float g1 = 1.0f - f;
    int sn = src_a[a];
    const float* g0 = gsL + (size_t)i0 * 128;
    float gsA = g0[lane] * g1 + g0[128 + lane] * f;
    float gsB = g0[64 + lane] * g1 + g0[192 + lane] * f;
    float m0 = sWsrc[(size_t)sn * 128 + lane] * gsA;
    float m1 = sWsrc[(size_t)sn * 128 + 64 + lane] * gsB;
    float p01 = m0 * atnA;
    float p23 = m1 * atnB;
    #pragma unroll
    for (int mm = 1; mm < 32; mm <<= 1) {
      p01 += __shfl_xor(p01, mm);
      p23 += __shfl_xor(p23, mm);
    }
    float l0 = __shfl(p01, 0), l1 = __shfl(p01, 32);
    float l2 = __shfl(p23, 0), l3 = __shfl(p23, 32);
    float nm0 = fmaxf(rm0, l0), nm1 = fmaxf(rm1, l1);
    float nm2 = fmaxf(rm2, l2), nm3 = fmaxf(rm3, l3);
    float f0 = __expf(rm0 - nm0), f1 = __expf(rm1 - nm1);
    float f2 = __expf(rm2 - nm2), f3 = __expf(rm3 - nm3);
    float w0 = __expf(l0 - nm0), w1 = __expf(l1 - nm1);
    float w2 = __expf(l2 - nm2), w3 = __expf(l3 - nm3);
    rm0 = nm0; rm1 = nm1; rm2 = nm2; rm3 = nm3;
    rs0 = rs0 * f0 + w0; rs1 = rs1 * f1 + w1;
    rs2 = rs2 * f2 + w2; rs3 = rs3 * f3 + w3;
    float fS0 = (lane < 32) ? f0 : f1;
    float fS1 = (lane < 32) ? f2 : f3;
    float wS0 = (lane < 32) ? w0 : w1;
    float wS1 = (lane < 32) ? w2 : w3;
    as0 = as0 * fS0 + wS0 * m0;
    as1 = as1 * fS1 + wS1 * m1;
    const float* gv0 = gvL + (size_t)i0 * 128;
    float2 p0 = *(const float2*)&gv0[2 * lane];
    float2 p1 = *(const float2*)&gv0[128 + 2 * lane];
    float gav = p0.x * g1 + p1.x * f;
    float gbv = p0.y * g1 + p1.y * f;
    float fV = (lane < 16) ? f0 : (lane < 32) ? f1 : (lane < 48) ? f2 : f3;
    float wV = (lane < 16) ? w0 : (lane < 32) ? w1 : (lane < 48) ? w2 : w3;
    float avv = sWv[(size_t)sn * 64 + lane] * gav;
    float4 s1 = *(const float4*)&sh_a[(size_t)a * 8];
    float4 s2 = *(const float4*)&sh_a[(size_t)a * 8 + 4];
    const float* vp = &vW[(size_t)sn * 192 + lane];
    av0 = av0 * fV + wV * (avv * s1.x + vp[0] * gbv);
    av1 = av1 * fV + wV * (avv * s1.y + vp[64] * gbv);
    av2 = av2 * fV + wV * (avv * s1.z + vp[128] * gbv);
    if (lane < 32) {
      const float* gt0 = gtL + (size_t)i0 * 64;
      float2 q0 = *(const float2*)&gt0[2 * lt];
      float2 q1 = *(const float2*)&gt0[64 + 2 * lt];
      float gat = q0.x * g1 + q1.x * f;
      float gbt = q0.y * g1 + q1.y * f;
      float fT = (lane < 8) ? f0 : (lane < 16) ? f1 : (lane < 24) ? f2 : f3;
      float wT = (lane < 8) ? w0 : (lane < 16) ? w1 : (lane < 24) ? w2 : w3;
      float att = sWt[(size_t)sn * 32 + lane] * gat;
      const float* tp = &tW[(size_t)sn * 160 + lane];
      at0 = at0 * fT + wT * (att * s1.w + tp[0] * gbt);
      at1 = at1 * fT + wT * (att * s2.x + tp[32] * gbt);
      at2 = at2 * fT + wT * (att * s2.y + tp[64] * gbt);
      at3 = at3 * fT + wT * (att * s2.z + tp[96] * gbt);
      at4 = at4 * fT + wT * (att * s2.w + tp[128] * gbt);
    }
  }
  if (ninact > 0) {
    rs0 += (float)ninact * __expf(-rm0);
    rs1 += (float)ninact * __expf(-rm1);
    rs2 += (float)ninact * __expf(-rm2);
    rs3 += (float)ninact * __expf(-rm3);
  }
  float r0 = 1.0f / (rs0 + 1e-9f), r1 = 1.0f / (rs1 + 1e-9f);
  float r2 = 1.0f / (rs2 + 1e-9f), r3 = 1.0f / (rs3 + 1e-9f);
  float rS0 = (lane < 32) ? r0 : r1;
  float rS1 = (lane < 32) ? r2 : r3;
  float rV = (lane < 16) ? r0 : (lane < 32) ? r1 : (lane < 48) ? r2 : r3;
  agg_s[(size_t)n * 128 + lane] = as0 * rS0;
  agg_s[(size_t)n * 128 + 64 + lane] = as1 * rS1;
  agg_v[(size_t)n * 192 + lane * 3 + 0] = av0 * rV;
  agg_v[(size_t)n * 192 + lane * 3 + 1] = av1 * rV;
  agg_v[(size_t)n * 192 + lane * 3 + 2] = av2 * rV;
  if (lane < 32) {
    float rT = (lane < 8) ? r0 : (lane < 16) ? r1 : (lane < 24) ? r2 : r3;
    agg_t[(size_t)n * 160 + lane * 5 + 0] = at0 * rT;
    agg_t[(size_t)n * 160 + lane * 5 + 1] = at1 * rT;
    agg_t[(size_t)n * 160 + lane * 5 + 2] = at2 * rT;
    agg_t[(size_t)n * 160 + lane * 5 + 3] = at3 * rT;
    agg_t[(size_t)n * 160 + lane * 5 + 4] = at4 * rT;
  }
}

// ---------------- fused node update + next-layer transforms: wave-per-2-nodes, barrier-free ----------------
__global__ __launch_bounds__(256) void k_node_fused(
    float* __restrict__ s, float* __restrict__ v, float* __restrict__ t,
    const float* __restrict__ agg_s, const float* __restrict__ agg_v,
    const float* __restrict__ agg_t, const float* __restrict__ Wo_s,
    const float* __restrict__ Wo_v, const float* __restrict__ Wo_t,
    const float* __restrict__ g_s, const float* __restrict__ b_s,
    const float* __restrict__ g_v, const float* __restrict__ g_t,
    const float* __restrict__ Ws_src, const float* __restrict__ Ws_v,
    const float* __restrict__ Ws_t, const float* __restrict__ Wv_v,
    const float* __restrict__ Wt_t, float* __restrict__ sWsrc,
    float* __restrict__ sWv, float* __restrict__ sWt, float* __restrict__ vW,
    float* __restrict__ tW) {
  int wv = threadIdx.x >> 6, lane = threadIdx.x & 63;
  int lt = lane & 31, nh = lane >> 5;
  int n0 = (blockIdx.x * 4 + wv) * 2;
  int n1 = n0 + 1;
  int nt = n0 + nh;
  __shared__ float stg[4][2][192];
  __shared__ float sN[4][2][128];
  __shared__ float vN[4][2][192];
  __shared__ float tN[4][2][160];
  // ---- stage agg_s (both nodes); load s_old ----
  float aS0 = agg_s[(size_t)n0 * 128 + lane];
  float aS1 = agg_s[(size_t)n0 * 128 + 64 + lane];
  float bS0 = agg_s[(size_t)n1 * 128 + lane];
  float bS1 = agg_s[(size_t)n1 * 128 + 64 + lane];
  float sA0 = s[(size_t)n0 * 128 + lane];
  float sA1 = s[(size_t)n0 * 128 + 64 + lane];
  float sB0 = s[(size_t)n1 * 128 + lane];
  float sB1 = s[(size_t)n1 * 128 + 64 + lane];
  stg[wv][0][lane] = aS0; stg[wv][0][64 + lane] = aS1;
  stg[wv][1][lane] = bS0; stg[wv][1][64 + lane] = bS1;
  asm volatile("s_waitcnt lgkmcnt(0)" ::: "memory");
  // ---- s-matmul: s_new = s_old + agg_s @ Wo_s (weights amortized over 2 nodes) ----
  #pragma unroll 8
  for (int c = 0; c < 128; c++) {
    float w0 = Wo_s[c * 128 + lane];
    float w1 = Wo_s[c * 128 + 64 + lane];
    float ax = stg[wv][0][c], bx = stg[wv][1][c];
    sA0 += ax * w0; sA1 += ax * w1;
    sB0 += bx * w0; sB1 += bx * w1;
  }
  // prefetch agg_v + v_old
  float avA0 = agg_v[(size_t)n0 * 192 + lane];
  float avA1 = agg_v[(size_t)n0 * 192 + 64 + lane];
  float avA2 = agg_v[(size_t)n0 * 192 + 128 + lane];
  float avB0 = agg_v[(size_t)n1 * 192 + lane];
  float avB1 = agg_v[(size_t)n1 * 192 + 64 + lane];
  float avB2 = agg_v[(size_t)n1 * 192 + 128 + lane];
  float voA0 = v[(size_t)n0 * 192 + lane * 3 + 0];
  float voA1 = v[(size_t)n0 * 192 + lane * 3 + 1];
  float voA2 = v[(size_t)n0 * 192 + lane * 3 + 2];
  float voB0 = v[(size_t)n1 * 192 + lane * 3 + 0];
  float voB1 = v[(size_t)n1 * 192 + lane * 3 + 1];
  float voB2 = v[(size_t)n1 * 192 + lane * 3 + 2];
  // ---- LayerNorm(s), both nodes ----
  float smA = sA0 + sA1, sqA = sA0 * sA0 + sA1 * sA1;
  float smB = sB0 + sB1, sqB = sB0 * sB0 + sB1 * sB1;
  #pragma unroll
  for (int m = 1; m < 64; m <<= 1) {
    smA += __shfl_xor(smA, m); sqA += __shfl_xor(sqA, m);
    smB += __shfl_xor(smB, m); sqB += __shfl_xor(sqB, m);
  }
  float muA = smA / 128.0f, muB = smB / 128.0f;
  float varA = sqA / 128.0f - muA * muA; if (varA < 0.f) varA = 0.f;
  float varB = sqB / 128.0f - muB * muB; if (varB < 0.f) varB = 0.f;
  float riA = rsqrtf(varA + 1e-6f), riB = rsqrtf(varB + 1e-6f);
  float gs0 = g_s[lane], gs1 = g_s[64 + lane];
  float bs0 = b_s[lane], bs1 = b_s[64 + lane];
  float yA0 = (sA0 - muA) * riA * gs0 + bs0;
  float yA1 = (sA1 - muA) * riA * gs1 + bs1;
  float yB0 = (sB0 - muB) * riB * gs0 + bs0;
  float yB1 = (sB1 - muB) * riB * gs1 + bs1;
  s[(size_t)n0 * 128 + lane] = yA0;
  s[(size_t)n0 * 128 + 64 + lane] = yA1;
  s[(size_t)n1 * 128 + lane] = yB0;
  s[(size_t)n1 * 128 + 64 + lane] = yB1;
  sN[wv][0][lane] = yA0; sN[wv][0][64 + lane] = yA1;
  sN[wv][1][lane] = yB0; sN[wv][1][64 + lane] = yB1;
  // ---- stage agg_v ----
  stg[wv][0][lane] = avA0; stg[wv][0][64 + lane] = avA1; stg[wv][0][128 + lane] = avA2;
  stg[wv][1][lane] = avB0; stg[wv][1][64 + lane] = avB1; stg[wv][1][128 + lane] = avB2;
  asm volatile("s_waitcnt lgkmcnt(0)" ::: "memory");
  // ---- v-matmul: v_new = v_old + agg_v @ Wo_v ----
  float vA0 = voA0, vA1 = voA1, vA2 = voA2;
  float vB0 = voB0, vB1 = voB1, vB2 = voB2;
  #pragma unroll 8
  for (int c = 0; c < 64; c++) {
    float w = Wo_v[c * 64 + lane];
    vA0 += stg[wv][0][c * 3 + 0] * w;
    vA1 += stg[wv][0][c * 3 + 1] * w;
    vA2 += stg[wv][0][c * 3 + 2] * w;
    vB0 += stg[wv][1][c * 3 + 0] * w;
    vB1 += stg[wv][1][c * 3 + 1] * w;
    vB2 += stg[wv][1][c * 3 + 2] * w;
  }
  // prefetch agg_t + t_old (half-trick: lane<32 → n0, lane>=32 → n1)
  float btA0 = agg_t[(size_t)n0 * 160 + lane];
  float btA1 = agg_t[(size_t)n0 * 160 + 64 + lane];
  float btA2 = (lane < 32) ? agg_t[(size_t)n0 * 160 + 128 + lane] : 0.f;
  float btB0 = agg_t[(size_t)n1 * 160 + lane];
  float btB1 = agg_t[(size_t)n1 * 160 + 64 + lane];
  float btB2 = (lane < 32) ? agg_t[(size_t)n1 * 160 + 128 + lane] : 0.f;
  float to0 = t[(size_t)nt * 160 + lt * 5 + 0];
  float to1 = t[(size_t)nt * 160 + lt * 5 + 1];
  float to2 = t[(size_t)nt * 160 + lt * 5 + 2];
  float to3 = t[(size_t)nt * 160 + lt * 5 + 3];
  float to4 = t[(size_t)nt * 160 + lt * 5 + 4];
  // ---- RMS(v), both nodes ----
  float ssqA = vA0 * vA0 + vA1 * vA1 + vA2 * vA2;
  float ssqB = vB0 * vB0 + vB1 * vB1 + vB2 * vB2;
  #pragma unroll
  for (int m = 1; m < 64; m <<= 1) {
    ssqA += __shfl_xor(ssqA, m);
    ssqB += __shfl_xor(ssqB, m);
  }
  float rivA = rsqrtf(ssqA / 64.0f + 1e-6f);
  float rivB = rsqrtf(ssqB / 64.0f + 1e-6f);
  float gv = g_v[lane];
  float vyA0 = vA0 * rivA * gv, vyA1 = vA1 * rivA * gv, vyA2 = vA2 * rivA * gv;
  float vyB0 = vB0 * rivB * gv, vyB1 = vB1 * rivB * gv, vyB2 = vB2 * rivB * gv;
  v[(size_t)n0 * 192 + lane * 3 + 0] = vyA0;
  v[(size_t)n0 * 192 + lane * 3 + 1] = vyA1;
  v[(size_t)n0 * 192 + lane * 3 + 2] = vyA2;
  v[(size_t)n1 * 192 + lane * 3 + 0] = vyB0;
  v[(size_t)n1 * 192 + lane * 3 + 1] = vyB1;
  v[(size_t)n1 * 192 + lane * 3 + 2] = vyB2;
  vN[wv][0][lane * 3 + 0] = vyA0; vN[wv][0][lane * 3 + 1] = vyA1; vN[wv][0][lane * 3 + 2] = vyA2;
  vN[wv][1][lane * 3 + 0] = vyB0; vN[wv][1][lane * 3 + 1] = vyB1; vN[wv][1][lane * 3 + 2] = vyB2;
  // ---- stage agg_t ----
  stg[wv][0][lane] = btA0; stg[wv][0][64 + lane] = btA1;
  if (lane < 32) stg[wv][0][128 + lane] = btA2;
  stg[wv][1][lane] = btB0; stg[wv][1][64 + lane] = btB1;
  if (lane < 32) stg[wv][1][128 + lane] = btB2;
  asm volatile("s_waitcnt lgkmcnt(0)" ::: "memory");
  // ---- t-matmul: half per node ----
  float at0 = to0, at1 = to1, at2 = to2, at3 = to3, at4 = to4;
  #pragma unroll 4
  for (int c = 0; c < 32; c++) {
    float w = Wo_t[c * 32 + lt];
    at0 += stg[wv][nh][c * 5 + 0] * w;
    at1 += stg[wv][nh][c * 5 + 1] * w;
    at2 += stg[wv][nh][c * 5 + 2] * w;
    at3 += stg[wv][nh][c * 5 + 3] * w;
    at4 += stg[wv][nh][c * 5 + 4] * w;
  }
  // ---- RMS(t): reduce within 32-lane half ----
  float ssqt = at0 * at0 + at1 * at1 + at2 * at2 + at3 * at3 + at4 * at4;
  #pragma unroll
  for (int m = 1; m < 32; m <<= 1) ssqt += __shfl_xor(ssqt, m);
  float rit = rsqrtf(ssqt / 32.0f + 1e-6f);
  float gt = g_t[lt];
  float ty0 = at0 * rit * gt, ty1 = at1 * rit * gt, ty2 = at2 * rit * gt;
  float ty3 = at3 * rit * gt, ty4 = at4 * rit * gt;
  t[(size_t)nt * 160 + lt * 5 + 0] = ty0;
  t[(size_t)nt * 160 + lt * 5 + 1] = ty1;
  t[(size_t)nt * 160 + lt * 5 + 2] = ty2;
  t[(size_t)nt * 160 + lt * 5 + 3] = ty3;
  t[(size_t)nt * 160 + lt * 5 + 4] = ty4;
  tN[wv][nh][lt * 5 + 0] = ty0;
  tN[wv][nh][lt * 5 + 1] = ty1;
  tN[wv][nh][lt * 5 + 2] = ty2;
  tN[wv][nh][lt * 5 + 3] = ty3;
  tN[wv][nh][lt * 5 + 4] = ty4;
  asm volatile("s_waitcnt lgkmcnt(0)" ::: "memory");
  // ---- transforms for next layer ----
  {
    float cA0 = 0.f, cA1 = 0.f, cB0 = 0.f, cB1 = 0.f;
    #pragma unroll 8
    for (int c = 0; c < 128; c++) {
      float w0 = Ws_src[c * 128 + lane];
      float w1 = Ws_src[c * 128 + 64 + lane];
      float aA = sN[wv][0][c], aB = sN[wv][1][c];
      cA0 += aA * w0; cA1 += aA * w1;
      cB0 += aB * w0; cB1 += aB * w1;
    }
    sWsrc[(size_t)n0 * 128 + lane] = cA0;
    sWsrc[(size_t)n0 * 128 + 64 + lane] = cA1;
    sWsrc[(size_t)n1 * 128 + lane] = cB0;
    sWsrc[(size_t)n1 * 128 + 64 + lane] = cB1;
  }
  {
    float cvA = 0.f, cvB = 0.f, ct = 0.f;
    #pragma unroll 8
    for (int c = 0; c < 128; c++) {
      float wvv = Ws_v[c * 64 + lane];
      float wtt = Ws_t[c * 32 + lt];
      float aA = sN[wv][0][c], aB = sN[wv][1][c];
      cvA += aA * wvv; cvB += aB * wvv;
      ct += sN[wv][nh][c] * wtt;
    }
    sWv[(size_t)n0 * 64 + lane] = cvA;
    sWv[(size_t)n1 * 64 + lane] = cvB;
    sWt[(size_t)nt * 32 + lt] = ct;
  }
  {
    float wA0 = 0.f, wA1 = 0.f, wA2 = 0.f, wB0 = 0.f, wB1 = 0.f, wB2 = 0.f;
    #pragma unroll 8
    for (int c = 0; c < 64; c++) {
      float w = Wv_v[c * 64 + lane];
      wA0 += vN[wv][0][c * 3 + 0] * w;
      wA1 += vN[wv][0][c * 3 + 1] * w;
      wA2 += vN[wv][0][c * 3 + 2] * w;
      wB0 += vN[wv][1][c * 3 + 0] * w;
      wB1 += vN[wv][1][c * 3 + 1] * w;
      wB2 += vN[wv][1][c * 3 + 2] * w;
    }
    vW[(size_t)n0 * 192 + lane] = wA0;
    vW[(size_t)n0 * 192 + 64 + lane] = wA1;
    vW[(size_t)n0 * 192 + 128 + lane] = wA2;
    vW[(size_t)n1 * 192 + lane] = wB0;
    vW[(size_t)n1 * 192 + 64 + lane] = wB1;
    vW[(size_t)n1 * 192 + 128 + lane] = wB2;
  }
  {
    float u0 = 0.f, u1 = 0.f, u2 = 0.f, u3 = 0.f, u4 = 0.f;
    #pragma unroll 4
    for (int c = 0; c < 32; c++) {
      float w = Wt_t[c * 32 + lt];
      u0 += tN[wv][nh][c * 5 + 0] * w;
      u1 += tN[wv][nh][c * 5 + 1] * w;
      u2 += tN[wv][nh][c * 5 + 2] * w;
      u3 += tN[wv][nh][c * 5 + 3] * w;
      u4 += tN[wv][nh][c * 5 + 4] * w;
    }
    tW[(size_t)nt * 160 + lt] = u0;
    tW[(size_t)nt * 160 + 32 + lt] = u1;
    tW[(size_t)nt * 160 + 64 + lt] = u2;
    tW[(size_t)nt * 160 + 96 + lt] = u3;
    tW[(size_t)nt * 160 + 128 + lt] = u4;
  }
}

// ---------------- node update, final layer: wave-per-2-nodes, barrier-free ----------------
__global__ __launch_bounds__(256) void k_node_up(
    float* __restrict__ s, float* __restrict__ v, float* __restrict__ t,
    const float* __restrict__ agg_s, const float* __restrict__ agg_v,
    const float* __restrict__ agg_t, const float* __restrict__ Wo_s,
    const float* __restrict__ Wo_v, const float* __restrict__ Wo_t,
    const float* __restrict__ g_s, const float* __restrict__ b_s,
    const float* __restrict__ g_v, const float* __restrict__ g_t) {
  int wv = threadIdx.x >> 6, lane = threadIdx.x & 63;
  int lt = lane & 31, nh = lane >> 5;
  int n0 = (blockIdx.x * 4 + wv) * 2;
  int n1 = n0 + 1;
  int nt = n0 + nh;
  __shared__ float stg[4][2][192];
  float aS0 = agg_s[(size_t)n0 * 128 + lane];
  float aS1 = agg_s[(size_t)n0 * 128 + 64 + lane];
  float bS0 = agg_s[(size_t)n1 * 128 + lane];
  float bS1 = agg_s[(size_t)n1 * 128 + 64 + lane];
  float sA0 = s[(size_t)n0 * 128 + lane];
  float sA1 = s[(size_t)n0 * 128 + 64 + lane];
  float sB0 = s[(size_t)n1 * 128 + lane];
  float sB1 = s[(size_t)n1 * 128 + 64 + lane];
  stg[wv][0][lane] = aS0; stg[wv][0][64 + lane] = aS1;
  stg[wv][1][lane] = bS0; stg[wv][1][64 + lane] = bS1;
  asm volatile("s_waitcnt lgkmcnt(0)" ::: "memory");
  #pragma unroll 8
  for (int c = 0; c < 128; c++) {
    float w0 = Wo_s[c * 128 + lane];
    float w1 = Wo_s[c * 128 + 64 + lane];
    float ax = stg[wv][0][c], bx = stg[wv][1][c];
    sA0 += ax * w0; sA1 += ax * w1;
    sB0 += bx * w0; sB1 += bx * w1;
  }
  float avA0 = agg_v[(size_t)n0 * 192 + lane];
  float avA1 = agg_v[(size_t)n0 * 192 + 64 + lane];
  float avA2 = agg_v[(size_t)n0 * 192 + 128 + lane];
  float avB0 = agg_v[(size_t)n1 * 192 + lane];
  float avB1 = agg_v[(size_t)n1 * 192 + 64 + lane];
  float avB2 = agg_v[(size_t)n1 * 192 + 128 + lane];
  float voA0 = v[(size_t)n0 * 192 + lane * 3 + 0];
  float voA1 = v[(size_t)n0 * 192 + lane * 3 + 1];
  float voA2 = v[(size_t)n0 * 192 + lane * 3 + 2];
  float voB0 = v[(size_t)n1 * 192 + lane * 3 + 0];
  float voB1 = v[(size_t)n1 * 192 + lane * 3 + 1];
  float voB2 = v[(size_t)n1 * 192 + lane * 3 + 2];
  float smA = sA0 + sA1, sqA = sA0 * sA0 + sA1 * sA1;
  float smB = sB0 + sB1, sqB = sB0 * sB0 + sB1 * sB1;
  #pragma unroll
  for (int m = 1; m < 64; m <<= 1) {
    smA += __shfl_xor(smA, m); sqA += __shfl_xor(sqA, m);
    smB += __shfl_xor(smB, m); sqB += __shfl_xor(sqB, m);
  }
  float muA = smA / 128.0f, muB = smB / 128.0f;
  float varA = sqA / 128.0f - muA * muA; if (varA < 0.f) varA = 0.f;
  float varB = sqB / 128.0f - muB * muB; if (varB < 0.f) varB = 0.f;
  float riA = rsqrtf(varA + 1e-6f), riB = rsqrtf(varB + 1e-6f);
  float gs0 = g_s[lane], gs1 = g_s[64 + lane];
  float bs0 = b_s[lane], bs1 = b_s[64 + lane];
  s[(size_t)n0 * 128 + lane] = (sA0 - muA) * riA * gs0 + bs0;
  s[(size_t)n0 * 128 + 64 + lane] = (sA1 - muA) * riA * gs1 + bs1;
  s[(size_t)n1 * 128 + lane] = (sB0 - muB) * riB * gs0 + bs0;
  s[(size_t)n1 * 128 + 64 + lane] = (sB1 - muB) * riB * gs1 + bs1;
  stg[wv][0][lane] = avA0; stg[wv][0][64 + lane] = avA1; stg[wv][0][128 + lane] = avA2;
  stg[wv][1][lane] = avB0; stg[wv][1][64 + lane] = avB1; stg[wv][1][128 + lane] = avB2;
  asm volatile("s_waitcnt lgkmcnt(0)" ::: "memory");
  float vA0 = voA0, vA1 = voA1, vA2 = voA2;
  float vB0 = voB0, vB1 = voB1, vB2 = voB2;
  #pragma unroll 8
  for (int c = 0; c < 64; c++) {
    float w = Wo_v[c * 64 + lane];
    vA0 += stg[wv][0][c * 3 + 0] * w;
    vA1 += stg[wv][0][c * 3 + 1] * w;
    vA2 += stg[wv][0][c * 3 + 2] * w;
    vB0 += stg[wv][1][c * 3 + 0] * w;
    vB1 += stg[wv][1][c * 3 + 1] * w;
    vB2 += stg[wv][1][c * 3 + 2] * w;
  }
  float btA0 = agg_t[(size_t)n0 * 160 + lane];
  float btA1 = agg_t[(size_t)n0 * 160 + 64 + lane];
  float btA2 = (lane < 32) ? agg_t[(size_t)n0 * 160 + 128 + lane] : 0.f;
  float btB0 = agg_t[(size_t)n1 * 160 + lane];
  float btB1 = agg_t[(size_t)n1 * 160 + 64 + lane];
  float btB2 = (lane < 32) ? agg_t[(size_t)n1 * 160 + 128 + lane] : 0.f;
  float to0 = t[(size_t)nt * 160 + lt * 5 + 0];
  float to1 = t[(size_t)nt * 160 + lt * 5 + 1];
  float to2 = t[(size_t)nt * 160 + lt * 5 + 2];
  float to3 = t[(size_t)nt * 160 + lt * 5 + 3];
  float to4 = t[(size_t)nt * 160 + lt * 5 + 4];
  float ssqA = vA0 * vA0 + vA1 * vA1 + vA2 * vA2;
  float ssqB = vB0 * vB0 + vB1 * vB1 + vB2 * vB2;
  #pragma unroll
  for (int m = 1; m < 64; m <<= 1) {
    ssqA += __shfl_xor(ssqA, m);
    ssqB += __shfl_xor(ssqB, m);
  }
  float rivA = rsqrtf(ssqA / 64.0f + 1e-6f);
  float rivB = rsqrtf(ssqB / 64.0f + 1e-6f);
  float gv = g_v[lane];
  v[(size_t)n0 * 192 + lane * 3 + 0] = vA0 * rivA * gv;
  v[(size_t)n0 * 192 + lane * 3 + 1] = vA1 * rivA * gv;
  v[(size_t)n0 * 192 + lane * 3 + 2] = vA2 * rivA * gv;
  v[(size_t)n1 * 192 + lane * 3 + 0] = vB0 * rivB * gv;
  v[(size_t)n1 * 192 + lane * 3 + 1] = vB1 * rivB * gv;
  v[(size_t)n1 * 192 + lane * 3 + 2] = vB2 * rivB * gv;
  stg[wv][0][lane] = btA0; stg[wv][0][64 + lane] = btA1;
  if (lane < 32) stg[wv][0][128 + lane] = btA2;
  stg[wv][1][lane] = btB0; stg[wv][1][64 + lane] = btB1;
  if (lane < 32) stg[wv][1][128 + lane] = btB2;
  asm volatile("s_waitcnt lgkmcnt(0)" ::: "memory");
  float at0 = to0, at1 = to1, at2 = to2, at3 = to3, at4 = to4;
  #pragma unroll 4
  for (int c = 0; c < 32; c++) {
    float w = Wo_t[c * 32 + lt];
    at0 += stg[wv][nh][c * 5 + 0] * w;
    at1 += stg[wv][nh][c * 5 + 1] * w;
    at2 += stg[wv][nh][c * 5 + 2] * w;
    at3 += stg[wv][nh][c * 5 + 3] * w;
    at4 += stg[wv][nh][c * 5 + 4] * w;
  }
  float ssqt = at0 * at0 + at1 * at1 + at2 * at2 + at3 * at3 + at4 * at4;
  #pragma unroll
  for (int m = 1; m < 32; m <<= 1) ssqt += __shfl_xor(ssqt, m);
  float rit = rsqrtf(ssqt / 32.0f + 1e-6f);
  float gt = g_t[lt];
  t[(size_t)nt * 160 + lt * 5 + 0] = at0 * rit * gt;
  t[(size_t)nt * 160 + lt * 5 + 1] = at1 * rit * gt;
  t[(size_t)nt * 160 + lt * 5 + 2] = at2 * rit * gt;
  t[(size_t)nt * 160 + lt * 5 + 3] = at3 * rit * gt;
  t[(size_t)nt * 160 + lt * 5 + 4] = at4 * rit * gt;
}

// ---------------- readout (conflict-free mapping) ----------------
__global__ __launch_bounds__(256) void k_readout(
    const float* __restrict__ s, const int* __restrict__ batch,
    const float* __restrict__ W_feat, const float* __restrict__ b_feat,
    const float* __restrict__ W_out1, const float* __restrict__ b_out1,
    float* __restrict__ graph) {
  __shared__ float st[64][129];
  __shared__ float gacc[GG];
  int nb = blockIdx.x * 64;
  int fb = blockIdx.y;  // 0..7
  for (int idx = threadIdx.x; idx < 64 * 128; idx += 256) {
    int nl = idx >> 7, c = idx & 127;
    int n = nb + nl;
    st[nl][c] = (n < NN) ? s[(size_t)n * 128 + c] : 0.f;
  }
  if (threadIdx.x < GG) gacc[threadIdx.x] = 0.f;
  __syncthreads();
  int wv = threadIdx.x >> 6, lane = threadIdx.x & 63;
  int fg = lane & 15;
  int ns = lane >> 4;
  int f0 = fb * 64 + fg * 4;
  int nodeb = wv * 16 + ns * 4;
  float acc[4][4];
  #pragma unroll
  for (int nn = 0; nn < 4; nn++)
    #pragma unroll
    for (int k = 0; k < 4; k++) acc[nn][k] = b_feat[f0 + k];
  #pragma unroll 4
  for (int c = 0; c < 128; c++) {
    float4 wq = *(const float4*)&W_feat[(size_t)c * 512 + f0];
    #pragma unroll
    for (int nn = 0; nn < 4; nn++) {
      float sv = st[nodeb + nn][c];
      acc[nn][0] += sv * wq.x;
      acc[nn][1] += sv * wq.y;
      acc[nn][2] += sv * wq.z;
      acc[nn][3] += sv * wq.w;
    }
  }
  float wo[4];
  #pragma unroll
  for (int k = 0; k < 4; k++) wo[k] = W_out1[f0 + k];
  float ep[4];
  #pragma unroll
  for (int nn = 0; nn < 4; nn++) {
    float p = 0.f;
    #pragma unroll
    for (int k = 0; k < 4; k++) p += fgelu(acc[nn][k]) * wo[k];
    ep[nn] = p;
  }
  #pragma unroll
  for (int mm = 1; mm < 16; mm <<= 1) {
    #pragma unroll
    for (int nn = 0; nn < 4; nn++) ep[nn] += __shfl_xor(ep[nn], mm);
  }
  if (fg == 0) {
    #pragma unroll
    for (int nn = 0; nn < 4; nn++) {
      int n = nb + nodeb + nn;
      if (n < NN) {
        float e = ep[nn];
        if (fb == 0) e += b_out1[0];
        atomicAdd(&gacc[batch[n]], e);
      }
    }
  }
  __syncthreads();
  if (threadIdx.x < GG && gacc[threadIdx.x] != 0.f)
    atomicAdd(&graph[threadIdx.x], gacc[threadIdx.x]);
}

__global__ void k_finalize(const float* __restrict__ graph, const float* __restrict__ W_read,
                           const float* __restrict__ b_read, float* __restrict__ out) {
  int g = threadIdx.x;
  if (g < GG) out[g] = graph[g] * W_read[0] + b_read[0];
}

// ---------------- host ----------------
extern "C" void kernel_launch(void* const* d_in, const int* in_sizes, int n_in,
                              void* d_out, int out_size, void* d_ws, size_t ws_size,
                              hipStream_t stream) {
  const float* pos = (const float*)d_in[0];
  const int* node_atom = (const int*)d_in[1];
  const int* batch = (const int*)d_in[2];
  const int* esrc = (const int*)d_in[3];
  const int* edst = (const int*)d_in[4];
  const float* atom_emb = (const float*)d_in[5];
  const float* Wrad1 = (const float*)d_in[6];
  const float* brad1 = (const float*)d_in[7];
  const float* Wrad2 = (const float*)d_in[8];
  const float* brad2 = (const float*)d_in[9];
  const float* Ws_src = (const float*)d_in[10];
  const float* Ww_s = (const float*)d_in[11];
  const float* Ws_v = (const float*)d_in[12];
  const float* Ww_v = (const float*)d_in[13];
  const float* Wv_v = (const float*)d_in[14];
  const float* Ww_vv = (const float*)d_in[15];
  const float* Ws_t = (const float*)d_in[16];
  const float* Ww_t = (const float*)d_in[17];
  const float* Wt_t = (const float*)d_in[18];
  const float* Ww_tt = (const float*)d_in[19];
  const float* attn_a = (const float*)d_in[20];
  const float* Wo_s = (const float*)d_in[21];
  const float* Wo_v = (const float*)d_in[22];
  const float* Wo_t = (const float*)d_in[23];
  const float* g_s = (const float*)d_in[24];
  const float* b_s = (const float*)d_in[25];
  const float* g_v = (const float*)d_in[26];
  const float* g_t = (const float*)d_in[27];
  const float* W_feat = (const float*)d_in[28];
  const float* b_feat = (const float*)d_in[29];
  const float* W_out1 = (const float*)d_in[30];
  const float* b_out1 = (const float*)d_in[31];
  const float* W_read = (const float*)d_in[32];
  const float* b_read = (const float*)d_in[33];
  float* out = (float*)d_out;

  char* base = (char*)d_ws;
  size_t off = 0;
  auto alloc = [&](size_t bytes) -> char* {
    off = (off + 255) & ~(size_t)255;
    char* p = base + off;
    off += bytes;
    return p;
  };
  int* deg = (int*)alloc(NN * 4);
  int* row_off = (int*)alloc((NN + 1) * 4);
  int* cursor = (int*)alloc(NN * 4);
  float* d_csr = (float*)alloc((size_t)EE * 4);
  int* src_csr = (int*)alloc((size_t)EE * 4);
  int* dst_csr = (int*)alloc((size_t)EE * 4);
  int* acnt = (int*)alloc(NN * 4);
  int* act_off = (int*)alloc((NN + 1) * 4);
  int* act_idx = (int*)alloc((size_t)EE * 4);
  int* dbkt = (int*)alloc(128 * 4);
  int* dboff = (int*)alloc(129 * 4);
  int* dbcur = (int*)alloc(128 * 4);
  int* order = (int*)alloc(NN * 4);
  float* d_a = (float*)alloc((size_t)EE * 4);
  int* src_a = (int*)alloc((size_t)EE * 4);
  float* sh_a = (float*)alloc((size_t)EE * 8 * 4);
  float* wtab = (float*)alloc((size_t)LL * TABN * 64 * 4);
  float* gs_tab = (float*)alloc((size_t)LL * TABN * 128 * 4);
  float* gv_tab = (float*)alloc((size_t)LL * TABN * 128 * 4);
  float* gt_tab = (float*)alloc((size_t)LL * TABN * 64 * 4);
  float* s = (float*)alloc((size_t)NN * 128 * 4);
  float* v = (float*)alloc((size_t)NN * 192 * 4);
  float* t = (float*)alloc((size_t)NN * 160 * 4);
  float* sWsrc = (float*)alloc((size_t)NN * 128 * 4);
  float* sWv = (float*)alloc((size_t)NN * 64 * 4);
  float* sWt = (float*)alloc((size_t)NN * 32 * 4);
  float* vW = (float*)alloc((size_t)NN * 192 * 4);
  float* tW = (float*)alloc((size_t)NN * 160 * 4);
  float* agg_s = (float*)alloc((size_t)NN * 128 * 4);
  float* agg_v = (float*)alloc((size_t)NN * 192 * 4);
  float* agg_t = (float*)alloc((size_t)NN * 160 * 4);
  float* graph = (float*)alloc(GG * 4);

  hipMemsetAsync(deg, 0, NN * 4, stream);
  hipMemsetAsync(cursor, 0, NN * 4, stream);
  hipMemsetAsync(dbkt, 0, 128 * 4, stream);
  hipMemsetAsync(dbcur, 0, 128 * 4, stream);
  hipMemsetAsync(graph, 0, GG * 4, stream);
  hipMemsetAsync(v, 0, (size_t)NN * 192 * 4, stream);
  hipMemsetAsync(t, 0, (size_t)NN * 160 * 4, stream);
  // layer-0: v = t = 0  =>  vW = tW = 0 (skip the transform matmuls entirely)
  hipMemsetAsync(vW, 0, (size_t)NN * 192 * 4, stream);
  hipMemsetAsync(tW, 0, (size_t)NN * 160 * 4, stream);

  k_hist<<<(EE + 255) / 256, 256, 0, stream>>>(edst, deg);
  k_scan<<<1, 1024, 0, stream>>>(deg, row_off, NN);
  k_scatter<<<(EE + 255) / 256, 256, 0, stream>>>(esrc, edst, pos, row_off, cursor,
                                                  d_csr, src_csr, dst_csr);
  k_act_cnt<<<(NN + 255) / 256, 256, 0, stream>>>(row_off, d_csr, acnt, dbkt);
  k_scan<<<1, 1024, 0, stream>>>(acnt, act_off, NN);
  k_act_fill<<<(NN + 255) / 256, 256, 0, stream>>>(row_off, d_csr, act_off, act_idx);
  k_scan<<<1, 1024, 0, stream>>>(dbkt, dboff, 128);
  k_dscatter<<<(NN + 255) / 256, 256, 0, stream>>>(acnt, dboff, dbcur, order);
  k_geom_act<<<(EE + 255) / 256, 256, 0, stream>>>(act_idx, src_csr, dst_csr, pos, act_off,
                                                   d_a, src_a, sh_a);
  k_build_wtab<<<LL * (TABN / 16), 256, 0, stream>>>(Wrad1, brad1, Wrad2, brad2, wtab);
  k_build_tabs<<<LL * (TABN / EB), 320, 0, stream>>>(wtab, Ww_s, Ww_v, Ww_vv, Ww_t, Ww_tt,
                                                     gs_tab, gv_tab, gt_tab);
  k_init_s<<<(NN * 128 + 255) / 256, 256, 0, stream>>>(node_atom, atom_emb, s);

  // initial transforms (layer 0, s only — v/t are zero)
  k_node_tf0<<<NN / 16, 256, 0, stream>>>(s, Ws_src, Ws_v, Ws_t, sWsrc, sWv, sWt);

  for (int l = 0; l < LL; l++) {
    const float* gsL = gs_tab + (size_t)l * TABN * 128;
    const float* gvL = gv_tab + (size_t)l * TABN * 128;
    const float* gtL = gt_tab + (size_t)l * TABN * 64;
    k_mega<<<NN / 4, 256, 0, stream>>>(row_off, act_off, order, src_a, d_a, gsL, gvL, gtL,
                                       attn_a + (size_t)l * 128,
                                       sWsrc, sWv, sWt, vW, tW, sh_a, agg_s, agg_v, agg_t);
    if (l < LL - 1) {
      k_node_fused<<<NN / 8, 256, 0, stream>>>(
          s, v, t, agg_s, agg_v, agg_t,
          Wo_s + (size_t)l * 128 * 128, Wo_v + (size_t)l * 64 * 64,
          Wo_t + (size_t)l * 32 * 32,
          g_s + (size_t)l * 128, b_s + (size_t)l * 128,
          g_v + (size_t)l * 64, g_t + (size_t)l * 32,
          Ws_src + (size_t)(l + 1) * 128 * 128, Ws_v + (size_t)(l + 1) * 128 * 64,
          Ws_t + (size_t)(l + 1) * 128 * 32, Wv_v + (size_t)(l + 1) * 64 * 64,
          Wt_t + (size_t)(l + 1) * 32 * 32,
          sWsrc, sWv, sWt, vW, tW);
    } else {
      k_node_up<<<NN / 8, 256, 0, stream>>>(s, v, t, agg_s, agg_v, agg_t,
                                            Wo_s + (size_t)l * 128 * 128,
                                            Wo_v + (size_t)l * 64 * 64, Wo_t + (size_t)l * 32 * 32,
                                            g_s + (size_t)l * 128, b_s + (size_t)l * 128,
                                            g_v + (size_t)l * 64, g_t + (size_t)l * 32);
    }
  }
  dim3 rg((NN + 63) / 64, 8);
  k_readout<<<rg, 256, 0, stream>>>(s, batch, W_feat, b_feat, W_out1, b_out1, graph);
  k_finalize<<<1, 64, 0, stream>>>(graph, W_read, b_read, out);
}

// Round 11
// 987.294 us; speedup vs baseline: 1.0680x; 1.0180x over previous
//
#include <hip/hip_runtime.h>
#include <math.h>

#define NN 10000
#define EE 320000
#define GG 32
#define LL 6
#define TABN 2048
#define TABB (TABN / 64)
#define DTAB 5.45f
#define DCUT 5.4f

__device__ __forceinline__ float fsilu(float x) { return x / (1.0f + __expf(-x)); }
__device__ __forceinline__ float fgelu(float x) {
  float y = 0.7978845608f * (x + 0.044715f * x * x * x);
  float t = 1.0f - 2.0f / (__expf(2.0f * y) + 1.0f);
  return 0.5f * x * (1.0f + t);
}

// ---------------- CSR build ----------------
__global__ void k_hist(const int* __restrict__ dst, int* __restrict__ deg) {
  int e = blockIdx.x * blockDim.x + threadIdx.x;
  if (e < EE) atomicAdd(&deg[dst[e]], 1);
}

// parallel scan: each thread serially scans a chunk, then one scan of totals
__global__ void k_scan(const int* __restrict__ cnt, int* __restrict__ off, int n) {
  __shared__ int tsum[1024];
  int chunk = (n + 1023) / 1024;
  int base = (int)threadIdx.x * chunk;
  int local = 0;
  for (int i = 0; i < chunk; i++) {
    int idx = base + i;
    local += (idx < n) ? cnt[idx] : 0;
  }
  tsum[threadIdx.x] = local;
  __syncthreads();
  for (int o = 1; o < 1024; o <<= 1) {
    int tv = (threadIdx.x >= (unsigned)o) ? tsum[threadIdx.x - o] : 0;
    __syncthreads();
    tsum[threadIdx.x] += tv;
    __syncthreads();
  }
  int run = tsum[threadIdx.x] - local;  // exclusive prefix of this chunk
  for (int i = 0; i < chunk; i++) {
    int idx = base + i;
    if (idx < n) {
      run += cnt[idx];
      off[idx + 1] = run;
    }
  }
  if (threadIdx.x == 0) off[0] = 0;
}

// two independent scans in one launch (block 0: A, block 1: B)
__global__ void k_scan2(const int* __restrict__ cntA, int* __restrict__ offA, int nA,
                        const int* __restrict__ cntB, int* __restrict__ offB, int nB) {
  const int* cnt = (blockIdx.x == 0) ? cntA : cntB;
  int* off = (blockIdx.x == 0) ? offA : offB;
  int n = (blockIdx.x == 0) ? nA : nB;
  __shared__ int tsum[1024];
  int chunk = (n + 1023) / 1024;
  int base = (int)threadIdx.x * chunk;
  int local = 0;
  for (int i = 0; i < chunk; i++) {
    int idx = base + i;
    local += (idx < n) ? cnt[idx] : 0;
  }
  tsum[threadIdx.x] = local;
  __syncthreads();
  for (int o = 1; o < 1024; o <<= 1) {
    int tv = (threadIdx.x >= (unsigned)o) ? tsum[threadIdx.x - o] : 0;
    __syncthreads();
    tsum[threadIdx.x] += tv;
    __syncthreads();
  }
  int run = tsum[threadIdx.x] - local;
  for (int i = 0; i < chunk; i++) {
    int idx = base + i;
    if (idx < n) {
      run += cnt[idx];
      off[idx + 1] = run;
    }
  }
  if (threadIdx.x == 0) off[0] = 0;
}

// scatter + geometry fused: one pass assigns CSR slots and computes distances
__global__ void k_scatter(const int* __restrict__ esrc, const int* __restrict__ edst,
                          const float* __restrict__ pos, const int* __restrict__ row_off,
                          int* __restrict__ cursor, float* __restrict__ d_csr,
                          int* __restrict__ src_csr, int* __restrict__ dst_csr) {
  int e = blockIdx.x * blockDim.x + threadIdx.x;
  if (e < EE) {
    int d = edst[e];
    int s = esrc[e];
    int p = atomicAdd(&cursor[d], 1);
    int slot = row_off[d] + p;
    float rx = pos[d * 3 + 0] - pos[s * 3 + 0];
    float ry = pos[d * 3 + 1] - pos[s * 3 + 1];
    float rz = pos[d * 3 + 2] - pos[s * 3 + 2];
    d_csr[slot] = sqrtf(rx * rx + ry * ry + rz * rz + 1e-6f);
    src_csr[slot] = s;
    dst_csr[slot] = d;
  }
}

// ---------------- active-edge count + degree histogram (fused) ----------------
__global__ void k_act_cnt(const int* __restrict__ row_off, const float* __restrict__ d_csr,
                          int* __restrict__ acnt, int* __restrict__ dbkt) {
  int n = blockIdx.x * blockDim.x + threadIdx.x;
  if (n >= NN) return;
  int c = 0;
  for (int j = row_off[n]; j < row_off[n + 1]; ++j) c += (d_csr[j] < DCUT) ? 1 : 0;
  acnt[n] = c;
  int b = 127 - min(127, c);
  atomicAdd(&dbkt[b], 1);
}

// act_fill + degree-order scatter fused (same per-node domain, independent outputs)
__global__ void k_act_fill(const int* __restrict__ row_off, const float* __restrict__ d_csr,
                           const int* __restrict__ act_off, int* __restrict__ act_idx,
                           const int* __restrict__ acnt, const int* __restrict__ dboff,
                           int* __restrict__ dbcur, int* __restrict__ order) {
  int n = blockIdx.x * blockDim.x + threadIdx.x;
  if (n >= NN) return;
  int a = act_off[n];
  for (int j = row_off[n]; j < row_off[n + 1]; ++j)
    if (d_csr[j] < DCUT) act_idx[a++] = j;
  int b = 127 - min(127, acnt[n]);
  int p = atomicAdd(&dbcur[b], 1);
  order[dboff[b] + p] = n;
}

// ---------------- compacted geometry per active edge (direct CSR arrays) ----------------
__global__ void k_geom_act(const int* __restrict__ act_idx, const int* __restrict__ src_csr,
                           const int* __restrict__ dst_csr, const float* __restrict__ pos,
                           const int* __restrict__ act_off, float* __restrict__ d_a,
                           int* __restrict__ src_a, float* __restrict__ sh_a) {
  int a = blockIdx.x * blockDim.x + threadIdx.x;
  if (a >= act_off[NN]) return;
  int j = act_idx[a];
  int s = src_csr[j], dd = dst_csr[j];
  float rx = pos[dd * 3 + 0] - pos[s * 3 + 0];
  float ry = pos[dd * 3 + 1] - pos[s * 3 + 1];
  float rz = pos[dd * 3 + 2] - pos[s * 3 + 2];
  float d = sqrtf(rx * rx + ry * ry + rz * rz + 1e-6f);
  float inv = 1.0f / d;
  float x = rx * inv, y = ry * inv, z = rz * inv;
  d_a[a] = d;
  src_a[a] = s;
  const float s3 = 1.7320508075688772f;
  const float s5 = 2.23606797749979f;
  const float s15 = 3.872983346207417f;
  sh_a[a * 8 + 0] = s3 * x;
  sh_a[a * 8 + 1] = s3 * y;
  sh_a[a * 8 + 2] = s3 * z;
  sh_a[a * 8 + 3] = s15 * x * y;
  sh_a[a * 8 + 4] = s15 * y * z;
  sh_a[a * 8 + 5] = 0.5f * s5 * (3.0f * z * z - 1.0f);
  sh_a[a * 8 + 6] = s15 * x * z;
  sh_a[a * 8 + 7] = 0.5f * s15 * (x * x - y * y);
}

// ---------------- radial MLP table w(d): 16 entries/block for parallelism ----------------
__global__ void k_build_wtab(const float* __restrict__ Wrad1, const float* __restrict__ brad1,
                             const float* __restrict__ Wrad2, const float* __restrict__ brad2,
                             float* __restrict__ wtab) {
  int l = blockIdx.x / (TABN / 16);
  int blk = blockIdx.x % (TABN / 16);
  __shared__ float W1[128 * 64];
  __shared__ float W2[64 * 64];
  __shared__ float b1[64], b2[64];
  __shared__ float rbf_s[4][128];
  __shared__ float h_s[4][64];
  const float* w1p = Wrad1 + (size_t)l * 128 * 64;
  const float* w2p = Wrad2 + (size_t)l * 64 * 64;
  for (int i = threadIdx.x; i < 128 * 64; i += 256) W1[i] = w1p[i];
  for (int i = threadIdx.x; i < 64 * 64; i += 256) W2[i] = w2p[i];
  if (threadIdx.x < 64) {
    b1[threadIdx.x] = brad1[(size_t)l * 64 + threadIdx.x];
    b2[threadIdx.x] = brad2[(size_t)l * 64 + threadIdx.x];
  }
  __syncthreads();
  int wv = threadIdx.x >> 6, lane = threadIdx.x & 63;
  const float width = 5.0f / 128.0f;
  for (int k = wv; k < 16; k += 4) {
    int i = blk * 16 + k;
    float d = (float)i * (DTAB / (float)(TABN - 1));
    float c0 = (5.0f * (float)lane) / 127.0f;
    float c1 = (5.0f * (float)(lane + 64)) / 127.0f;
    float t0 = (d - c0) / width, t1 = (d - c1) / width;
    rbf_s[wv][lane] = __expf(-0.5f * t0 * t0);
    rbf_s[wv][lane + 64] = __expf(-0.5f * t1 * t1);
    float acc = b1[lane];
    #pragma unroll 8
    for (int i2 = 0; i2 < 128; i2++) acc += rbf_s[wv][i2] * W1[i2 * 64 + lane];
    acc = fsilu(acc);
    h_s[wv][lane] = acc;
    float acc2 = b2[lane];
    #pragma unroll 8
    for (int i2 = 0; i2 < 64; i2++) acc2 += h_s[wv][i2] * W2[i2 * 64 + lane];
    wtab[((size_t)l * TABN + i) * 64 + lane] = fsilu(acc2);
  }
}

// ---------------- fused product-table build: gs, gv, gt in one kernel ----------------
#define EB 8
__global__ __launch_bounds__(320) void k_build_tabs(
    const float* __restrict__ wtab, const float* __restrict__ Ww_s,
    const float* __restrict__ Ww_v, const float* __restrict__ Ww_vv,
    const float* __restrict__ Ww_t, const float* __restrict__ Ww_tt,
    float* __restrict__ gs_tab, float* __restrict__ gv_tab, float* __restrict__ gt_tab) {
  int l = blockIdx.x / (TABN / EB);
  int eb = (blockIdx.x % (TABN / EB)) * EB;
  __shared__ float ws[EB][64];
  int tid = threadIdx.x;
  for (int i = tid; i < EB * 64; i += 320)
    ws[i >> 6][i & 63] = wtab[((size_t)l * TABN + eb + (i >> 6)) * 64 + (i & 63)];
  __syncthreads();
  float acc[EB] = {};
  if (tid < 128) {
    int col = tid;
    const float* W = Ww_s + (size_t)l * 64 * 128;
    #pragma unroll 8
    for (int i = 0; i < 64; i++) {
      float w = W[i * 128 + col];
      #pragma unroll
      for (int e = 0; e < EB; e++) acc[e] += ws[e][i] * w;
    }
    #pragma unroll
    for (int e = 0; e < EB; e++)
      gs_tab[((size_t)l * TABN + eb + e) * 128 + col] = acc[e];
  } else if (tid < 256) {
    int cc = tid - 128;
    int c = cc >> 1;
    const float* W = ((cc & 1) ? Ww_vv : Ww_v) + (size_t)l * 64 * 64;
    #pragma unroll 8
    for (int i = 0; i < 64; i++) {
      float w = W[i * 64 + c];
      #pragma unroll
      for (int e = 0; e < EB; e++) acc[e] += ws[e][i] * w;
    }
    #pragma unroll
    for (int e = 0; e < EB; e++)
      gv_tab[((size_t)l * TABN + eb + e) * 128 + cc] = acc[e];
  } else {
    int cc = tid - 256;
    int c = cc >> 1;
    const float* W = ((cc & 1) ? Ww_tt : Ww_t) + (size_t)l * 64 * 32;
    #pragma unroll 8
    for (int i = 0; i < 64; i++) {
      float w = W[i * 32 + c];
      #pragma unroll
      for (int e = 0; e < EB; e++) acc[e] += ws[e][i] * w;
    }
    #pragma unroll
    for (int e = 0; e < EB; e++)
      gt_tab[((size_t)l * TABN + eb + e) * 64 + cc] = acc[e];
  }
}

// ---------------- layer-0 transforms fused with s-init (v = t = 0) ----------------
__global__ __launch_bounds__(256) void k_node_tf0(
    const int* __restrict__ node_atom, const float* __restrict__ atom_emb,
    float* __restrict__ s, const float* __restrict__ Ws_src,
    const float* __restrict__ Ws_v, const float* __restrict__ Ws_t,
    float* __restrict__ sWsrc, float* __restrict__ sWv, float* __restrict__ sWt) {
  int nb = blockIdx.x * 16;
  int tid = threadIdx.x;
  __shared__ float s16[16][129];
  for (int idx = tid; idx < 16 * 128; idx += 256) {
    int n = idx >> 7, c = idx & 127;
    float val = atom_emb[(size_t)node_atom[nb + n] * 128 + c];
    s16[n][c] = val;
    s[(size_t)(nb + n) * 128 + c] = val;
  }
  __syncthreads();
  {
    int col = tid & 127, ng = tid >> 7;
    float acc[8] = {0, 0, 0, 0, 0, 0, 0, 0};
    for (int c = 0; c < 128; c++) {
      float w = Ws_src[c * 128 + col];
      #pragma unroll
      for (int n = 0; n < 8; n++) acc[n] += s16[ng * 8 + n][c] * w;
    }
    #pragma unroll
    for (int n = 0; n < 8; n++) sWsrc[(size_t)(nb + ng * 8 + n) * 128 + col] = acc[n];
  }
  {
    int col = tid & 63, ng = tid >> 6;
    float acc[4] = {0, 0, 0, 0};
    for (int c = 0; c < 128; c++) {
      float w = Ws_v[c * 64 + col];
      #pragma unroll
      for (int n = 0; n < 4; n++) acc[n] += s16[ng * 4 + n][c] * w;
    }
    #pragma unroll
    for (int n = 0; n < 4; n++) sWv[(size_t)(nb + ng * 4 + n) * 64 + col] = acc[n];
  }
  {
    int col = tid & 31, ng = tid >> 5;
    float acc[2] = {0, 0};
    for (int c = 0; c < 128; c++) {
      float w = Ws_t[c * 32 + col];
      acc[0] += s16[ng * 2 + 0][c] * w;
      acc[1] += s16[ng * 2 + 1][c] * w;
    }
    sWt[(size_t)(nb + ng * 2 + 0) * 32 + col] = acc[0];
    sWt[(size_t)(nb + ng * 2 + 1) * 32 + col] = acc[1];
  }
}

// ---------------- mega: single-pass online-softmax, pair-combined update ----------------
__global__ __launch_bounds__(256) void k_mega(
    const int* __restrict__ row_off, const int* __restrict__ act_off,
    const int* __restrict__ order,
    const int* __restrict__ src_a, const float* __restrict__ d_a,
    const float* __restrict__ gsL, const float* __restrict__ gvL,
    const float* __restrict__ gtL, const float* __restrict__ attn_l,
    const float* __restrict__ sWsrc, const float* __restrict__ sWv,
    const float* __restrict__ sWt, const float* __restrict__ vW,
    const float* __restrict__ tW, const float* __restrict__ sh_a,
    float* __restrict__ agg_s, float* __restrict__ agg_v, float* __restrict__ agg_t) {
  int wv = threadIdx.x >> 6, lane = threadIdx.x & 63;
  int lt = lane & 31;
  int slot = blockIdx.x * 4 + wv;
  if (slot >= NN) return;
  int n = order[slot];
  int alo = act_off[n], ahi = act_off[n + 1];
  int nact = ahi - alo;
  int ninact = (row_off[n + 1] - row_off[n]) - nact;
  const float sc = (float)(TABN - 1) / DTAB;
  float atnA = attn_l[lane];
  float atnB = attn_l[64 + lane];
  float rm0, rm1, rm2, rm3;
  rm0 = rm1 = rm2 = rm3 = (ninact > 0) ? 0.0f : -1e30f;
  float rs0 = 0.f, rs1 = 0.f, rs2 = 0.f, rs3 = 0.f;
  float as0 = 0.f, as1 = 0.f;
  float av0 = 0.f, av1 = 0.f, av2 = 0.f;
  float at0 = 0.f, at1 = 0.f, at2 = 0.f, at3 = 0.f, at4 = 0.f;
  int a = alo;
  for (; a + 1 < ahi; a += 2) {
    int aA = a, aB = a + 1;
    float dA = d_a[aA], dB = d_a[aB];
    int snA = src_a[aA], snB = src_a[aB];
    float xA = fminf(dA * sc, (float)(TABN - 1) - 1.0f);
    float xB = fminf(dB * sc, (float)(TABN - 1) - 1.0f);
    int iA = (int)xA, iB = (int)xB;
    float fA = xA - (float)iA, fB = xB - (float)iB;
    float g1A = 1.0f - fA, g1B = 1.0f - fB;
    const float* gA = gsL + (size_t)iA * 128;
    const float* gB = gsL + (size_t)iB * 128;
    float gsA_A = gA[lane] * g1A + gA[128 + lane] * fA;
    float gsB_A = gA[64 + lane] * g1A + gA[192 + lane] * fA;
    float gsA_B = gB[lane] * g1B + gB[128 + lane] * fB;
    float gsB_B = gB[64 + lane] * g1B + gB[192 + lane] * fB;
    float m0A = sWsrc[(size_t)snA * 128 + lane] * gsA_A;
    float m1A = sWsrc[(size_t)snA * 128 + 64 + lane] * gsB_A;
    float m0B = sWsrc[(size_t)snB * 128 + lane] * gsA_B;
    float m1B = sWsrc[(size_t)snB * 128 + 64 + lane] * gsB_B;
    const float* gvA = gvL + (size_t)iA * 128;
    const float* gvB = gvL + (size_t)iB * 128;
    float2 pA0 = *(const float2*)&gvA[2 * lane];
    float2 pA1 = *(const float2*)&gvA[128 + 2 * lane];
    float2 pB0 = *(const float2*)&gvB[2 * lane];
    float2 pB1 = *(const float2*)&gvB[128 + 2 * lane];
    float gavA = pA0.x * g1A + pA1.x * fA;
    float gbvA = pA0.y * g1A + pA1.y * fA;
    float gavB = pB0.x * g1B + pB1.x * fB;
    float gbvB = pB0.y * g1B + pB1.y * fB;
    float svA = sWv[(size_t)snA * 64 + lane];
    float svB = sWv[(size_t)snB * 64 + lane];
    float4 s1A = *(const float4*)&sh_a[(size_t)aA * 8];
    float4 s2A = *(const float4*)&sh_a[(size_t)aA * 8 + 4];
    float4 s1B = *(const float4*)&sh_a[(size_t)aB * 8];
    float4 s2B = *(const float4*)&sh_a[(size_t)aB * 8 + 4];
    const float* vpA = &vW[(size_t)snA * 192 + lane];
    const float* vpB = &vW[(size_t)snB * 192 + lane];
    float vA0 = vpA[0], vA1 = vpA[64], vA2 = vpA[128];
    float vB0 = vpB[0], vB1 = vpB[64], vB2 = vpB[128];
    float gatA = 0.f, gbtA = 0.f, gatB = 0.f, gbtB = 0.f;
    float stA = 0.f, stB = 0.f;
    float tA0 = 0.f, tA1 = 0.f, tA2 = 0.f, tA3 = 0.f, tA4 = 0.f;
    float tB0 = 0.f, tB1 = 0.f, tB2 = 0.f, tB3 = 0.f, tB4 = 0.f;
    if (lane < 32) {
      const float* gtA = gtL + (size_t)iA * 64;
      const float* gtB = gtL + (size_t)iB * 64;
      float2 qA0 = *(const float2*)&gtA[2 * lt];
      float2 qA1 = *(const float2*)&gtA[64 + 2 * lt];
      float2 qB0 = *(const float2*)&gtB[2 * lt];
      float2 qB1 = *(const float2*)&gtB[64 + 2 * lt];
      gatA = qA0.x * g1A + qA1.x * fA;
      gbtA = qA0.y * g1A + qA1.y * fA;
      gatB = qB0.x * g1B + qB1.x * fB;
      gbtB = qB0.y * g1B + qB1.y * fB;
      stA = sWt[(size_t)snA * 32 + lane];
      stB = sWt[(size_t)snB * 32 + lane];
      const float* tpA = &tW[(size_t)snA * 160 + lane];
      const float* tpB = &tW[(size_t)snB * 160 + lane];
      tA0 = tpA[0]; tA1 = tpA[32]; tA2 = tpA[64]; tA3 = tpA[96]; tA4 = tpA[128];
      tB0 = tpB[0]; tB1 = tpB[32]; tB2 = tpB[64]; tB3 = tpB[96]; tB4 = tpB[128];
    }
    float p01A = m0A * atnA, p23A = m1A * atnB;
    float p01B = m0B * atnA, p23B = m1B * atnB;
    #pragma unroll
    for (int mm = 1; mm < 32; mm <<= 1) {
      p01A += __shfl_xor(p01A, mm);
      p23A += __shfl_xor(p23A, mm);
      p01B += __shfl_xor(p01B, mm);
      p23B += __shfl_xor(p23B, mm);
    }
    float l0A = __shfl(p01A, 0), l1A = __shfl(p01A, 32);
    float l2A = __shfl(p23A, 0), l3A = __shfl(p23A, 32);
    float l0B = __shfl(p01B, 0), l1B = __shfl(p01B, 32);
    float l2B = __shfl(p23B, 0), l3B = __shfl(p23B, 32);
    // combined two-edge online-softmax update (exactly equivalent to sequential)
    float nm0 = fmaxf(rm0, fmaxf(l0A, l0B));
    float nm1 = fmaxf(rm1, fmaxf(l1A, l1B));
    float nm2 = fmaxf(rm2, fmaxf(l2A, l2B));
    float nm3 = fmaxf(rm3, fmaxf(l3A, l3B));
    float wA0 = __expf(l0A - nm0), wA1 = __expf(l1A - nm1);
    float wA2 = __expf(l2A - nm2), wA3 = __expf(l3A - nm3);
    float wB0 = __expf(l0B - nm0), wB1 = __expf(l1B - nm1);
    float wB2 = __expf(l2B - nm2), wB3 = __expf(l3B - nm3);
    float wSA0 = (lane < 32) ? wA0 : wA1, wSA1 = (lane < 32) ? wA2 : wA3;
    float wSB0 = (lane < 32) ? wB0 : wB1, wSB1 = (lane < 32) ? wB2 : wB3;
    float addS0 = wSA0 * m0A + wSB0 * m0B;
    float addS1 = wSA1 * m1A + wSB1 * m1B;
    float wVA = (lane < 16) ? wA0 : (lane < 32) ? wA1 : (lane < 48) ? wA2 : wA3;
    float wVB = (lane < 16) ? wB0 : (lane < 32) ? wB1 : (lane < 48) ? wB2 : wB3;
    float avvA = svA * gavA, avvB = svB * gavB;
    float addV0 = wVA * (avvA * s1A.x + vA0 * gbvA) + wVB * (avvB * s1B.x + vB0 * gbvB);
    float addV1 = wVA * (avvA * s1A.y + vA1 * gbvA) + wVB * (avvB * s1B.y + vB1 * gbvB);
    float addV2 = wVA * (avvA * s1A.z + vA2 * gbvA) + wVB * (avvB * s1B.z + vB2 * gbvB);
    float wTA = (lane < 8) ? wA0 : (lane < 16) ? wA1 : (lane < 24) ? wA2 : wA3;
    float wTB = (lane < 8) ? wB0 : (lane < 16) ? wB1 : (lane < 24) ? wB2 : wB3;
    float attA = stA * gatA, attB = stB * gatB;
    float addT0 = wTA * (attA * s1A.w + tA0 * gbtA) + wTB * (attB * s1B.w + tB0 * gbtB);
    float addT1 = wTA * (attA * s2A.x + tA1 * gbtA) + wTB * (attB * s2B.x + tB1 * gbtB);
    float addT2 = wTA * (attA * s2A.y + tA2 * gbtA) + wTB * (attB * s2B.y + tB2 * gbtB);
    float addT3 = wTA * (attA * s2A.z + tA3 * gbtA) + wTB * (attB * s2B.z + tB3 * gbtB);
    float addT4 = wTA * (attA * s2A.w + tA4 * gbtA) + wTB * (attB * s2B.w + tB4 * gbtB);
    if (nm0 == rm0 && nm1 == rm1 && nm2 == rm2 && nm3 == rm3) {
      rs0 += wA0 + wB0; rs1 += wA1 + wB1; rs2 += wA2 + wB2; rs3 += wA3 + wB3;
      as0 += addS0; as1 += addS1;
      av0 += addV0; av1 += addV1; av2 += addV2;
      at0 += addT0; at1 += addT1; at2 += addT2; at3 += addT3; at4 += addT4;
    } else {
      float f0 = __expf(rm0 - nm0), f1 = __expf(rm1 - nm1);
      float f2 = __expf(rm2 - nm2), f3 = __expf(rm3 - nm3);
      rm0 = nm0; rm1 = nm1; rm2 = nm2; rm3 = nm3;
      rs0 = rs0 * f0 + wA0 + wB0; rs1 = rs1 * f1 + wA1 + wB1;
      rs2 = rs2 * f2 + wA2 + wB2; rs3 = rs3 * f3 + wA3 + wB3;
      float fS0 = (lane < 32) ? f0 : f1, fS1 = (lane < 32) ? f2 : f3;
      as0 = as0 * fS0 + addS0; as1 = as1 * fS1 + addS1;
      float fV = (lane < 16) ? f0 : (lane < 32) ? f1 : (lane < 48) ? f2 : f3;
      av0 = av0 * fV + addV0; av1 = av1 * fV + addV1; av2 = av2 * fV + addV2;
      float fT = (lane < 8) ? f0 : (lane < 16) ? f1 : (lane < 24) ? f2 : f3;
      at0 = at0 * fT + addT0; at1 = at1 * fT + addT1; at2 = at2 * fT + addT2;
      at3 = at3 * fT + addT3; at4 = at4 * fT + addT4;
    }
  }
  for (; a < ahi; ++a) {
    float x = d_a[a] * sc;
    x = fminf(x, (float)(TABN - 1) - 1.0f);
    int i0 = (int)x; float f = x - (float)i0; float g1 = 1.0f - f;
    int sn = src_a[a];
    const float* g0 = gsL + (size_t)i0 * 128;
    float gsA = g0[lane] * g1 + g0[128 + lane] * f;
    float gsB = g0[64 + lane] * g1 + g0[192 + lane] * f;
    float m0 = sWsrc[(size_t)sn * 128 + lane] * gsA;
    float m1 = sWsrc[(size_t)sn * 128 + 64 + lane] * gsB;
    float p01 = m0 * atnA;
    float p23 = m1 * atnB;
    #pragma unroll
    for (int mm = 1; mm < 32; mm <<= 1) {
      p01 += __shfl_xor(p01, mm);
      p23 += __shfl_xor(p23, mm);
    }
    float l0 = __shfl(p01, 0), l1 = __shfl(p01, 32);
    float l2 = __shfl(p23, 0), l3 = __shfl(p23, 32);
    float nm0 = fmaxf(rm0, l0), nm1 = fmaxf(rm1, l1);
    float nm2 = fmaxf(rm2, l2), nm3 = fmaxf(rm3, l3);
    float f0 = __expf(rm0 - nm0), f1 = __expf(rm1 - nm1);
    float f2 = __expf(rm2 - nm2), f3 = __expf(rm3 - nm3);
    float w0 = __expf(l0 - nm0), w1 = __expf(l1 - nm1);
    float w2 = __expf(l2 - nm2), w3 = __expf(l3 - nm3);
    rm0 = nm0; rm1 = nm1; rm2 = nm2; rm3 = nm3;
    rs0 = rs0 * f0 + w0; rs1 = rs1 * f1 + w1;
    rs2 = rs2 * f2 + w2; rs3 = rs3 * f3 + w3;
    float fS0 = (lane < 32) ? f0 : f1;
    float fS1 = (lane < 32) ? f2 : f3;
    float wS0 = (lane < 32) ? w0 : w1;
    float wS1 = (lane < 32) ? w2 : w3;
    as0 = as0 * fS0 + wS0 * m0;
    as1 = as1 * fS1 + wS1 * m1;
    const float* gv0 = gvL + (size_t)i0 * 128;
    float2 p0 = *(const float2*)&gv0[2 * lane];
    float2 p1 = *(const float2*)&gv0[128 + 2 * lane];
    float gav = p0.x * g1 + p1.x * f;
    float gbv = p0.y * g1 + p1.y * f;
    float fV = (lane < 16) ? f0 : (lane < 32) ? f1 : (lane < 48) ? f2 : f3;
    float wV = (lane < 16) ? w0 : (lane < 32) ? w1 : (lane < 48) ? w2 : w3;
    float avv = sWv[(size_t)sn * 64 + lane] * gav;
    float4 s1 = *(const float4*)&sh_a[(size_t)a * 8];
    float4 s2 = *(const float4*)&sh_a[(size_t)a * 8 + 4];
    const float* vp = &vW[(size_t)sn * 192 + lane];
    av0 = av0 * fV + wV * (avv * s1.x + vp[0] * gbv);
    av1 = av1 * fV + wV * (avv * s1.y + vp[64] * gbv);
    av2 = av2 * fV + wV * (avv * s1.z + vp[128] * gbv);
    if (lane < 32) {
      const float* gt0 = gtL + (size_t)i0 * 64;
      float2 q0 = *(const float2*)&gt0[2 * lt];
      float2 q1 = *(const float2*)&gt0[64 + 2 * lt];
      float gat = q0.x * g1 + q1.x * f;
      float gbt = q0.y * g1 + q1.y * f;
      float fT = (lane < 8) ? f0 : (lane < 16) ? f1 : (lane < 24) ? f2 : f3;
      float wT = (lane < 8) ? w0 : (lane < 16) ? w1 : (lane < 24) ? w2 : w3;
      float att = sWt[(size_t)sn * 32 + lane] * gat;
      const float* tp = &tW[(size_t)sn * 160 + lane];
      at0 = at0 * fT + wT * (att * s1.w + tp[0] * gbt);
      at1 = at1 * fT + wT * (att * s2.x + tp[32] * gbt);
      at2 = at2 * fT + wT * (att * s2.y + tp[64] * gbt);
      at3 = at3 * fT + wT * (att * s2.z + tp[96] * gbt);
      at4 = at4 * fT + wT * (att * s2.w + tp[128] * gbt);
    }
  }
  if (ninact > 0) {
    rs0 += (float)ninact * __expf(-rm0);
    rs1 += (float)ninact * __expf(-rm1);
    rs2 += (float)ninact * __expf(-rm2);
    rs3 += (float)ninact * __expf(-rm3);
  }
  float r0 = 1.0f / (rs0 + 1e-9f), r1 = 1.0f / (rs1 + 1e-9f);
  float r2 = 1.0f / (rs2 + 1e-9f), r3 = 1.0f / (rs3 + 1e-9f);
  float rS0 = (lane < 32) ? r0 : r1;
  float rS1 = (lane < 32) ? r2 : r3;
  float rV = (lane < 16) ? r0 : (lane < 32) ? r1 : (lane < 48) ? r2 : r3;
  agg_s[(size_t)n * 128 + lane] = as0 * rS0;
  agg_s[(size_t)n * 128 + 64 + lane] = as1 * rS1;
  agg_v[(size_t)n * 192 + lane * 3 + 0] = av0 * rV;
  agg_v[(size_t)n * 192 + lane * 3 + 1] = av1 * rV;
  agg_v[(size_t)n * 192 + lane * 3 + 2] = av2 * rV;
  if (lane < 32) {
    float rT = (lane < 8) ? r0 : (lane < 16) ? r1 : (lane < 24) ? r2 : r3;
    agg_t[(size_t)n * 160 + lane * 5 + 0] = at0 * rT;
    agg_t[(size_t)n * 160 + lane * 5 + 1] = at1 * rT;
    agg_t[(size_t)n * 160 + lane * 5 + 2] = at2 * rT;
    agg_t[(size_t)n * 160 + lane * 5 + 3] = at3 * rT;
    agg_t[(size_t)n * 160 + lane * 5 + 4] = at4 * rT;
  }
}

// ---------------- fused node update + next-layer transforms: wave-per-2-nodes, barrier-free ----------------
__global__ __launch_bounds__(256) void k_node_fused(
    float* __restrict__ s, float* __restrict__ v, float* __restrict__ t,
    const float* __restrict__ agg_s, const float* __restrict__ agg_v,
    const float* __restrict__ agg_t, const float* __restrict__ Wo_s,
    const float* __restrict__ Wo_v, const float* __restrict__ Wo_t,
    const float* __restrict__ g_s, const float* __restrict__ b_s,
    const float* __restrict__ g_v, const float* __restrict__ g_t,
    const float* __restrict__ Ws_src, const float* __restrict__ Ws_v,
    const float* __restrict__ Ws_t, const float* __restrict__ Wv_v,
    const float* __restrict__ Wt_t, float* __restrict__ sWsrc,
    float* __restrict__ sWv, float* __restrict__ sWt, float* __restrict__ vW,
    float* __restrict__ tW) {
  int wv = threadIdx.x >> 6, lane = threadIdx.x & 63;
  int lt = lane & 31, nh = lane >> 5;
  int n0 = (blockIdx.x * 4 + wv) * 2;
  int n1 = n0 + 1;
  int nt = n0 + nh;
  __shared__ float stg[4][2][192];
  __shared__ float sN[4][2][128];
  __shared__ float vN[4][2][192];
  __shared__ float tN[4][2][160];
  // ---- stage agg_s (both nodes); load s_old ----
  float aS0 = agg_s[(size_t)n0 * 128 + lane];
  float aS1 = agg_s[(size_t)n0 * 128 + 64 + lane];
  float bS0 = agg_s[(size_t)n1 * 128 + lane];
  float bS1 = agg_s[(size_t)n1 * 128 + 64 + lane];
  float sA0 = s[(size_t)n0 * 128 + lane];
  float sA1 = s[(size_t)n0 * 128 + 64 + lane];
  float sB0 = s[(size_t)n1 * 128 + lane];
  float sB1 = s[(size_t)n1 * 128 + 64 + lane];
  stg[wv][0][lane] = aS0; stg[wv][0][64 + lane] = aS1;
  stg[wv][1][lane] = bS0; stg[wv][1][64 + lane] = bS1;
  asm volatile("s_waitcnt lgkmcnt(0)" ::: "memory");
  // ---- s-matmul: s_new = s_old + agg_s @ Wo_s (weights amortized over 2 nodes) ----
  #pragma unroll 8
  for (int c = 0; c < 128; c++) {
    float w0 = Wo_s[c * 128 + lane];
    float w1 = Wo_s[c * 128 + 64 + lane];
    float ax = stg[wv][0][c], bx = stg[wv][1][c];
    sA0 += ax * w0; sA1 += ax * w1;
    sB0 += bx * w0; sB1 += bx * w1;
  }
  // prefetch agg_v + v_old
  float avA0 = agg_v[(size_t)n0 * 192 + lane];
  float avA1 = agg_v[(size_t)n0 * 192 + 64 + lane];
  float avA2 = agg_v[(size_t)n0 * 192 + 128 + lane];
  float avB0 = agg_v[(size_t)n1 * 192 + lane];
  float avB1 = agg_v[(size_t)n1 * 192 + 64 + lane];
  float avB2 = agg_v[(size_t)n1 * 192 + 128 + lane];
  float voA0 = v[(size_t)n0 * 192 + lane * 3 + 0];
  float voA1 = v[(size_t)n0 * 192 + lane * 3 + 1];
  float voA2 = v[(size_t)n0 * 192 + lane * 3 + 2];
  float voB0 = v[(size_t)n1 * 192 + lane * 3 + 0];
  float voB1 = v[(size_t)n1 * 192 + lane * 3 + 1];
  float voB2 = v[(size_t)n1 * 192 + lane * 3 + 2];
  // ---- LayerNorm(s), both nodes ----
  float smA = sA0 + sA1, sqA = sA0 * sA0 + sA1 * sA1;
  float smB = sB0 + sB1, sqB = sB0 * sB0 + sB1 * sB1;
  #pragma unroll
  for (int m = 1; m < 64; m <<= 1) {
    smA += __shfl_xor(smA, m); sqA += __shfl_xor(sqA, m);
    smB += __shfl_xor(smB, m); sqB += __shfl_xor(sqB, m);
  }
  float muA = smA / 128.0f, muB = smB / 128.0f;
  float varA = sqA / 128.0f - muA * muA; if (varA < 0.f) varA = 0.f;
  float varB = sqB / 128.0f - muB * muB; if (varB < 0.f) varB = 0.f;
  float riA = rsqrtf(varA + 1e-6f), riB = rsqrtf(varB + 1e-6f);
  float gs0 = g_s[lane], gs1 = g_s[64 + lane];
  float bs0 = b_s[lane], bs1 = b_s[64 + lane];
  float yA0 = (sA0 - muA) * riA * gs0 + bs0;
  float yA1 = (sA1 - muA) * riA * gs1 + bs1;
  float yB0 = (sB0 - muB) * riB * gs0 + bs0;
  float yB1 = (sB1 - muB) * riB * gs1 + bs1;
  s[(size_t)n0 * 128 + lane] = yA0;
  s[(size_t)n0 * 128 + 64 + lane] = yA1;
  s[(size_t)n1 * 128 + lane] = yB0;
  s[(size_t)n1 * 128 + 64 + lane] = yB1;
  sN[wv][0][lane] = yA0; sN[wv][0][64 + lane] = yA1;
  sN[wv][1][lane] = yB0; sN[wv][1][64 + lane] = yB1;
  // ---- stage agg_v ----
  stg[wv][0][lane] = avA0; stg[wv][0][64 + lane] = avA1; stg[wv][0][128 + lane] = avA2;
  stg[wv][1][lane] = avB0; stg[wv][1][64 + lane] = avB1; stg[wv][1][128 + lane] = avB2;
  asm volatile("s_waitcnt lgkmcnt(0)" ::: "memory");
  // ---- v-matmul: v_new = v_old + agg_v @ Wo_v ----
  float vA0 = voA0, vA1 = voA1, vA2 = voA2;
  float vB0 = voB0, vB1 = voB1, vB2 = voB2;
  #pragma unroll 8
  for (int c = 0; c < 64; c++) {
    float w = Wo_v[c * 64 + lane];
    vA0 += stg[wv][0][c * 3 + 0] * w;
    vA1 += stg[wv][0][c * 3 + 1] * w;
    vA2 += stg[wv][0][c * 3 + 2] * w;
    vB0 += stg[wv][1][c * 3 + 0] * w;
    vB1 += stg[wv][1][c * 3 + 1] * w;
    vB2 += stg[wv][1][c * 3 + 2] * w;
  }
  // prefetch agg_t + t_old (half-trick: lane<32 → n0, lane>=32 → n1)
  float btA0 = agg_t[(size_t)n0 * 160 + lane];
  float btA1 = agg_t[(size_t)n0 * 160 + 64 + lane];
  float btA2 = (lane < 32) ? agg_t[(size_t)n0 * 160 + 128 + lane] : 0.f;
  float btB0 = agg_t[(size_t)n1 * 160 + lane];
  float btB1 = agg_t[(size_t)n1 * 160 + 64 + lane];
  float btB2 = (lane < 32) ? agg_t[(size_t)n1 * 160 + 128 + lane] : 0.f;
  float to0 = t[(size_t)nt * 160 + lt * 5 + 0];
  float to1 = t[(size_t)nt * 160 + lt * 5 + 1];
  float to2 = t[(size_t)nt * 160 + lt * 5 + 2];
  float to3 = t[(size_t)nt * 160 + lt * 5 + 3];
  float to4 = t[(size_t)nt * 160 + lt * 5 + 4];
  // ---- RMS(v), both nodes ----
  float ssqA = vA0 * vA0 + vA1 * vA1 + vA2 * vA2;
  float ssqB = vB0 * vB0 + vB1 * vB1 + vB2 * vB2;
  #pragma unroll
  for (int m = 1; m < 64; m <<= 1) {
    ssqA += __shfl_xor(ssqA, m);
    ssqB += __shfl_xor(ssqB, m);
  }
  float rivA = rsqrtf(ssqA / 64.0f + 1e-6f);
  float rivB = rsqrtf(ssqB / 64.0f + 1e-6f);
  float gv = g_v[lane];
  float vyA0 = vA0 * rivA * gv, vyA1 = vA1 * rivA * gv, vyA2 = vA2 * rivA * gv;
  float vyB0 = vB0 * rivB * gv, vyB1 = vB1 * rivB * gv, vyB2 = vB2 * rivB * gv;
  v[(size_t)n0 * 192 + lane * 3 + 0] = vyA0;
  v[(size_t)n0 * 192 + lane * 3 + 1] = vyA1;
  v[(size_t)n0 * 192 + lane * 3 + 2] = vyA2;
  v[(size_t)n1 * 192 + lane * 3 + 0] = vyB0;
  v[(size_t)n1 * 192 + lane * 3 + 1] = vyB1;
  v[(size_t)n1 * 192 + lane * 3 + 2] = vyB2;
  vN[wv][0][lane * 3 + 0] = vyA0; vN[wv][0][lane * 3 + 1] = vyA1; vN[wv][0][lane * 3 + 2] = vyA2;
  vN[wv][1][lane * 3 + 0] = vyB0; vN[wv][1][lane * 3 + 1] = vyB1; vN[wv][1][lane * 3 + 2] = vyB2;
  // ---- stage agg_t ----
  stg[wv][0][lane] = btA0; stg[wv][0][64 + lane] = btA1;
  if (lane < 32) stg[wv][0][128 + lane] = btA2;
  stg[wv][1][lane] = btB0; stg[wv][1][64 + lane] = btB1;
  if (lane < 32) stg[wv][1][128 + lane] = btB2;
  asm volatile("s_waitcnt lgkmcnt(0)" ::: "memory");
  // ---- t-matmul: half per node ----
  float at0 = to0, at1 = to1, at2 = to2, at3 = to3, at4 = to4;
  #pragma unroll 4
  for (int c = 0; c < 32; c++) {
    float w = Wo_t[c * 32 + lt];
    at0 += stg[wv][nh][c * 5 + 0] * w;
    at1 += stg[wv][nh][c * 5 + 1] * w;
    at2 += stg[wv][nh][c * 5 + 2] * w;
    at3 += stg[wv][nh][c * 5 + 3] * w;
    at4 += stg[wv][nh][c * 5 + 4] * w;
  }
  // ---- RMS(t): reduce within 32-lane half ----
  float ssqt = at0 * at0 + at1 * at1 + at2 * at2 + at3 * at3 + at4 * at4;
  #pragma unroll
  for (int m = 1; m < 32; m <<= 1) ssqt += __shfl_xor(ssqt, m);
  float rit = rsqrtf(ssqt / 32.0f + 1e-6f);
  float gt = g_t[lt];
  float ty0 = at0 * rit * gt, ty1 = at1 * rit * gt, ty2 = at2 * rit * gt;
  float ty3 = at3 * rit * gt, ty4 = at4 * rit * gt;
  t[(size_t)nt * 160 + lt * 5 + 0] = ty0;
  t[(size_t)nt * 160 + lt * 5 + 1] = ty1;
  t[(size_t)nt * 160 + lt * 5 + 2] = ty2;
  t[(size_t)nt * 160 + lt * 5 + 3] = ty3;
  t[(size_t)nt * 160 + lt * 5 + 4] = ty4;
  tN[wv][nh][lt * 5 + 0] = ty0;
  tN[wv][nh][lt * 5 + 1] = ty1;
  tN[wv][nh][lt * 5 + 2] = ty2;
  tN[wv][nh][lt * 5 + 3] = ty3;
  tN[wv][nh][lt * 5 + 4] = ty4;
  asm volatile("s_waitcnt lgkmcnt(0)" ::: "memory");
  // ---- transforms for next layer ----
  {
    float cA0 = 0.f, cA1 = 0.f, cB0 = 0.f, cB1 = 0.f;
    #pragma unroll 8
    for (int c = 0; c < 128; c++) {
      float w0 = Ws_src[c * 128 + lane];
      float w1 = Ws_src[c * 128 + 64 + lane];
      float aA = sN[wv][0][c], aB = sN[wv][1][c];
      cA0 += aA * w0; cA1 += aA * w1;
      cB0 += aB * w0; cB1 += aB * w1;
    }
    sWsrc[(size_t)n0 * 128 + lane] = cA0;
    sWsrc[(size_t)n0 * 128 + 64 + lane] = cA1;
    sWsrc[(size_t)n1 * 128 + lane] = cB0;
    sWsrc[(size_t)n1 * 128 + 64 + lane] = cB1;
  }
  {
    float cvA = 0.f, cvB = 0.f, ct = 0.f;
    #pragma unroll 8
    for (int c = 0; c < 128; c++) {
      float wvv = Ws_v[c * 64 + lane];
      float wtt = Ws_t[c * 32 + lt];
      float aA = sN[wv][0][c], aB = sN[wv][1][c];
      cvA += aA * wvv; cvB += aB * wvv;
      ct += sN[wv][nh][c] * wtt;
    }
    sWv[(size_t)n0 * 64 + lane] = cvA;
    sWv[(size_t)n1 * 64 + lane] = cvB;
    sWt[(size_t)nt * 32 + lt] = ct;
  }
  {
    float wA0 = 0.f, wA1 = 0.f, wA2 = 0.f, wB0 = 0.f, wB1 = 0.f, wB2 = 0.f;
    #pragma unroll 8
    for (int c = 0; c < 64; c++) {
      float w = Wv_v[c * 64 + lane];
      wA0 += vN[wv][0][c * 3 + 0] * w;
      wA1 += vN[wv][0][c * 3 + 1] * w;
      wA2 += vN[wv][0][c * 3 + 2] * w;
      wB0 += vN[wv][1][c * 3 + 0] * w;
      wB1 += vN[wv][1][c * 3 + 1] * w;
      wB2 += vN[wv][1][c * 3 + 2] * w;
    }
    vW[(size_t)n0 * 192 + lane] = wA0;
    vW[(size_t)n0 * 192 + 64 + lane] = wA1;
    vW[(size_t)n0 * 192 + 128 + lane] = wA2;
    vW[(size_t)n1 * 192 + lane] = wB0;
    vW[(size_t)n1 * 192 + 64 + lane] = wB1;
    vW[(size_t)n1 * 192 + 128 + lane] = wB2;
  }
  {
    float u0 = 0.f, u1 = 0.f, u2 = 0.f, u3 = 0.f, u4 = 0.f;
    #pragma unroll 4
    for (int c = 0; c < 32; c++) {
      float w = Wt_t[c * 32 + lt];
      u0 += tN[wv][nh][c * 5 + 0] * w;
      u1 += tN[wv][nh][c * 5 + 1] * w;
      u2 += tN[wv][nh][c * 5 + 2] * w;
      u3 += tN[wv][nh][c * 5 + 3] * w;
      u4 += tN[wv][nh][c * 5 + 4] * w;
    }
    tW[(size_t)nt * 160 + lt] = u0;
    tW[(size_t)nt * 160 + 32 + lt] = u1;
    tW[(size_t)nt * 160 + 64 + lt] = u2;
    tW[(size_t)nt * 160 + 96 + lt] = u3;
    tW[(size_t)nt * 160 + 128 + lt] = u4;
  }
}

// ---------------- node update, final layer: wave-per-2-nodes, barrier-free ----------------
__global__ __launch_bounds__(256) void k_node_up(
    float* __restrict__ s, float* __restrict__ v, float* __restrict__ t,
    const float* __restrict__ agg_s, const float* __restrict__ agg_v,
    const float* __restrict__ agg_t, const float* __restrict__ Wo_s,
    const float* __restrict__ Wo_v, const float* __restrict__ Wo_t,
    const float* __restrict__ g_s, const float* __restrict__ b_s,
    const float* __restrict__ g_v, const float* __restrict__ g_t) {
  int wv = threadIdx.x >> 6, lane = threadIdx.x & 63;
  int lt = lane & 31, nh = lane >> 5;
  int n0 = (blockIdx.x * 4 + wv) * 2;
  int n1 = n0 + 1;
  int nt = n0 + nh;
  __shared__ float stg[4][2][192];
  float aS0 = agg_s[(size_t)n0 * 128 + lane];
  float aS1 = agg_s[(size_t)n0 * 128 + 64 + lane];
  float bS0 = agg_s[(size_t)n1 * 128 + lane];
  float bS1 = agg_s[(size_t)n1 * 128 + 64 + lane];
  float sA0 = s[(size_t)n0 * 128 + lane];
  float sA1 = s[(size_t)n0 * 128 + 64 + lane];
  float sB0 = s[(size_t)n1 * 128 + lane];
  float sB1 = s[(size_t)n1 * 128 + 64 + lane];
  stg[wv][0][lane] = aS0; stg[wv][0][64 + lane] = aS1;
  stg[wv][1][lane] = bS0; stg[wv][1][64 + lane] = bS1;
  asm volatile("s_waitcnt lgkmcnt(0)" ::: "memory");
  #pragma unroll 8
  for (int c = 0; c < 128; c++) {
    float w0 = Wo_s[c * 128 + lane];
    float w1 = Wo_s[c * 128 + 64 + lane];
    float ax = stg[wv][0][c], bx = stg[wv][1][c];
    sA0 += ax * w0; sA1 += ax * w1;
    sB0 += bx * w0; sB1 += bx * w1;
  }
  float avA0 = agg_v[(size_t)n0 * 192 + lane];
  float avA1 = agg_v[(size_t)n0 * 192 + 64 + lane];
  float avA2 = agg_v[(size_t)n0 * 192 + 128 + lane];
  float avB0 = agg_v[(size_t)n1 * 192 + lane];
  float avB1 = agg_v[(size_t)n1 * 192 + 64 + lane];
  float avB2 = agg_v[(size_t)n1 * 192 + 128 + lane];
  float voA0 = v[(size_t)n0 * 192 + lane * 3 + 0];
  float voA1 = v[(size_t)n0 * 192 + lane * 3 + 1];
  float voA2 = v[(size_t)n0 * 192 + lane * 3 + 2];
  float voB0 = v[(size_t)n1 * 192 + lane * 3 + 0];
  float voB1 = v[(size_t)n1 * 192 + lane * 3 + 1];
  float voB2 = v[(size_t)n1 * 192 + lane * 3 + 2];
  float smA = sA0 + sA1, sqA = sA0 * sA0 + sA1 * sA1;
  float smB = sB0 + sB1, sqB = sB0 * sB0 + sB1 * sB1;
  #pragma unroll
  for (int m = 1; m < 64; m <<= 1) {
    smA += __shfl_xor(smA, m); sqA += __shfl_xor(sqA, m);
    smB += __shfl_xor(smB, m); sqB += __shfl_xor(sqB, m);
  }
  float muA = smA / 128.0f, muB = smB / 128.0f;
  float varA = sqA / 128.0f - muA * muA; if (varA < 0.f) varA = 0.f;
  float varB = sqB / 128.0f - muB * muB; if (varB < 0.f) varB = 0.f;
  float riA = rsqrtf(varA + 1e-6f), riB = rsqrtf(varB + 1e-6f);
  float gs0 = g_s[lane], gs1 = g_s[64 + lane];
  float bs0 = b_s[lane], bs1 = b_s[64 + lane];
  s[(size_t)n0 * 128 + lane] = (sA0 - muA) * riA * gs0 + bs0;
  s[(size_t)n0 * 128 + 64 + lane] = (sA1 - muA) * riA * gs1 + bs1;
  s[(size_t)n1 * 128 + lane] = (sB0 - muB) * riB * gs0 + bs0;
  s[(size_t)n1 * 128 + 64 + lane] = (sB1 - muB) * riB * gs1 + bs1;
  stg[wv][0][lane] = avA0; stg[wv][0][64 + lane] = avA1; stg[wv][0][128 + lane] = avA2;
  stg[wv][1][lane] = avB0; stg[wv][1][64 + lane] = avB1; stg[wv][1][128 + lane] = avB2;
  asm volatile("s_waitcnt lgkmcnt(0)" ::: "memory");
  float vA0 = voA0, vA1 = voA1, vA2 = voA2;
  float vB0 = voB0, vB1 = voB1, vB2 = voB2;
  #pragma unroll 8
  for (int c = 0; c < 64; c++) {
    float w = Wo_v[c * 64 + lane];
    vA0 += stg[wv][0][c * 3 + 0] * w;
    vA1 += stg[wv][0][c * 3 + 1] * w;
    vA2 += stg[wv][0][c * 3 + 2] * w;
    vB0 += stg[wv][1][c * 3 + 0] * w;
    vB1 += stg[wv][1][c * 3 + 1] * w;
    vB2 += stg[wv][1][c * 3 + 2] * w;
  }
  float btA0 = agg_t[(size_t)n0 * 160 + lane];
  float btA1 = agg_t[(size_t)n0 * 160 + 64 + lane];
  float btA2 = (lane < 32) ? agg_t[(size_t)n0 * 160 + 128 + lane] : 0.f;
  float btB0 = agg_t[(size_t)n1 * 160 + lane];
  float btB1 = agg_t[(size_t)n1 * 160 + 64 + lane];
  float btB2 = (lane < 32) ? agg_t[(size_t)n1 * 160 + 128 + lane] : 0.f;
  float to0 = t[(size_t)nt * 160 + lt * 5 + 0];
  float to1 = t[(size_t)nt * 160 + lt * 5 + 1];
  float to2 = t[(size_t)nt * 160 + lt * 5 + 2];
  float to3 = t[(size_t)nt * 160 + lt * 5 + 3];
  float to4 = t[(size_t)nt * 160 + lt * 5 + 4];
  float ssqA = vA0 * vA0 + vA1 * vA1 + vA2 * vA2;
  float ssqB = vB0 * vB0 + vB1 * vB1 + vB2 * vB2;
  #pragma unroll
  for (int m = 1; m < 64; m <<= 1) {
    ssqA += __shfl_xor(ssqA, m);
    ssqB += __shfl_xor(ssqB, m);
  }
  float rivA = rsqrtf(ssqA / 64.0f + 1e-6f);
  float rivB = rsqrtf(ssqB / 64.0f + 1e-6f);
  float gv = g_v[lane];
  v[(size_t)n0 * 192 + lane * 3 + 0] = vA0 * rivA * gv;
  v[(size_t)n0 * 192 + lane * 3 + 1] = vA1 * rivA * gv;
  v[(size_t)n0 * 192 + lane * 3 + 2] = vA2 * rivA * gv;
  v[(size_t)n1 * 192 + lane * 3 + 0] = vB0 * rivB * gv;
  v[(size_t)n1 * 192 + lane * 3 + 1] = vB1 * rivB * gv;
  v[(size_t)n1 * 192 + lane * 3 + 2] = vB2 * rivB * gv;
  stg[wv][0][lane] = btA0; stg[wv][0][64 + lane] = btA1;
  if (lane < 32) stg[wv][0][128 + lane] = btA2;
  stg[wv][1][lane] = btB0; stg[wv][1][64 + lane] = btB1;
  if (lane < 32) stg[wv][1][128 + lane] = btB2;
  asm volatile("s_waitcnt lgkmcnt(0)" ::: "memory");
  float at0 = to0, at1 = to1, at2 = to2, at3 = to3, at4 = to4;
  #pragma unroll 4
  for (int c = 0; c < 32; c++) {
    float w = Wo_t[c * 32 + lt];
    at0 += stg[wv][nh][c * 5 + 0] * w;
    at1 += stg[wv][nh][c * 5 + 1] * w;
    at2 += stg[wv][nh][c * 5 + 2] * w;
    at3 += stg[wv][nh][c * 5 + 3] * w;
    at4 += stg[wv][nh][c * 5 + 4] * w;
  }
  float ssqt = at0 * at0 + at1 * at1 + at2 * at2 + at3 * at3 + at4 * at4;
  #pragma unroll
  for (int m = 1; m < 32; m <<= 1) ssqt += __shfl_xor(ssqt, m);
  float rit = rsqrtf(ssqt / 32.0f + 1e-6f);
  float gt = g_t[lt];
  t[(size_t)nt * 160 + lt * 5 + 0] = at0 * rit * gt;
  t[(size_t)nt * 160 + lt * 5 + 1] = at1 * rit * gt;
  t[(size_t)nt * 160 + lt * 5 + 2] = at2 * rit * gt;
  t[(size_t)nt * 160 + lt * 5 + 3] = at3 * rit * gt;
  t[(size_t)nt * 160 + lt * 5 + 4] = at4 * rit * gt;
}

// ---------------- readout (conflict-free mapping) ----------------
__global__ __launch_bounds__(256) void k_readout(
    const float* __restrict__ s, const int* __restrict__ batch,
    const float* __restrict__ W_feat, const float* __restrict__ b_feat,
    const float* __restrict__ W_out1, const float* __restrict__ b_out1,
    float* __restrict__ graph) {
  __shared__ float st[64][129];
  __shared__ float gacc[GG];
  int nb = blockIdx.x * 64;
  int fb = blockIdx.y;  // 0..7
  for (int idx = threadIdx.x; idx < 64 * 128; idx += 256) {
    int nl = idx >> 7, c = idx & 127;
    int n = nb + nl;
    st[nl][c] = (n < NN) ? s[(size_t)n * 128 + c] : 0.f;
  }
  if (threadIdx.x < GG) gacc[threadIdx.x] = 0.f;
  __syncthreads();
  int wv = threadIdx.x >> 6, lane = threadIdx.x & 63;
  int fg = lane & 15;
  int ns = lane >> 4;
  int f0 = fb * 64 + fg * 4;
  int nodeb = wv * 16 + ns * 4;
  float acc[4][4];
  #pragma unroll
  for (int nn = 0; nn < 4; nn++)
    #pragma unroll
    for (int k = 0; k < 4; k++) acc[nn][k] = b_feat[f0 + k];
  #pragma unroll 4
  for (int c = 0; c < 128; c++) {
    float4 wq = *(const float4*)&W_feat[(size_t)c * 512 + f0];
    #pragma unroll
    for (int nn = 0; nn < 4; nn++) {
      float sv = st[nodeb + nn][c];
      acc[nn][0] += sv * wq.x;
      acc[nn][1] += sv * wq.y;
      acc[nn][2] += sv * wq.z;
      acc[nn][3] += sv * wq.w;
    }
  }
  float wo[4];
  #pragma unroll
  for (int k = 0; k < 4; k++) wo[k] = W_out1[f0 + k];
  float ep[4];
  #pragma unroll
  for (int nn = 0; nn < 4; nn++) {
    float p = 0.f;
    #pragma unroll
    for (int k = 0; k < 4; k++) p += fgelu(acc[nn][k]) * wo[k];
    ep[nn] = p;
  }
  #pragma unroll
  for (int mm = 1; mm < 16; mm <<= 1) {
    #pragma unroll
    for (int nn = 0; nn < 4; nn++) ep[nn] += __shfl_xor(ep[nn], mm);
  }
  if (fg == 0) {
    #pragma unroll
    for (int nn = 0; nn < 4; nn++) {
      int n = nb + nodeb + nn;
      if (n < NN) {
        float e = ep[nn];
        if (fb == 0) e += b_out1[0];
        atomicAdd(&gacc[batch[n]], e);
      }
    }
  }
  __syncthreads();
  if (threadIdx.x < GG && gacc[threadIdx.x] != 0.f)
    atomicAdd(&graph[threadIdx.x], gacc[threadIdx.x]);
}

__global__ void k_finalize(const float* __restrict__ graph, const float* __restrict__ W_read,
                           const float* __restrict__ b_read, float* __restrict__ out) {
  int g = threadIdx.x;
  if (g < GG) out[g] = graph[g] * W_read[0] + b_read[0];
}

// ---------------- host ----------------
extern "C" void kernel_launch(void* const* d_in, const int* in_sizes, int n_in,
                              void* d_out, int out_size, void* d_ws, size_t ws_size,
                              hipStream_t stream) {
  const float* pos = (const float*)d_in[0];
  const int* node_atom = (const int*)d_in[1];
  const int* batch = (const int*)d_in[2];
  const int* esrc = (const int*)d_in[3];
  const int* edst = (const int*)d_in[4];
  const float* atom_emb = (const float*)d_in[5];
  const float* Wrad1 = (const float*)d_in[6];
  const float* brad1 = (const float*)d_in[7];
  const float* Wrad2 = (const float*)d_in[8];
  const float* brad2 = (const float*)d_in[9];
  const float* Ws_src = (const float*)d_in[10];
  const float* Ww_s = (const float*)d_in[11];
  const float* Ws_v = (const float*)d_in[12];
  const float* Ww_v = (const float*)d_in[13];
  const float* Wv_v = (const float*)d_in[14];
  const float* Ww_vv = (const float*)d_in[15];
  const float* Ws_t = (const float*)d_in[16];
  const float* Ww_t = (const float*)d_in[17];
  const float* Wt_t = (const float*)d_in[18];
  const float* Ww_tt = (const float*)d_in[19];
  const float* attn_a = (const float*)d_in[20];
  const float* Wo_s = (const float*)d_in[21];
  const float* Wo_v = (const float*)d_in[22];
  const float* Wo_t = (const float*)d_in[23];
  const float* g_s = (const float*)d_in[24];
  const float* b_s = (const float*)d_in[25];
  const float* g_v = (const float*)d_in[26];
  const float* g_t = (const float*)d_in[27];
  const float* W_feat = (const float*)d_in[28];
  const float* b_feat = (const float*)d_in[29];
  const float* W_out1 = (const float*)d_in[30];
  const float* b_out1 = (const float*)d_in[31];
  const float* W_read = (const float*)d_in[32];
  const float* b_read = (const float*)d_in[33];
  float* out = (float*)d_out;

  char* base = (char*)d_ws;
  size_t off = 0;
  auto alloc = [&](size_t bytes) -> char* {
    off = (off + 255) & ~(size_t)255;
    char* p = base + off;
    off += bytes;
    return p;
  };
  // ---- zero-init group A (ints), contiguous ----
  int* deg = (int*)alloc(NN * 4);
  int* cursor = (int*)alloc(NN * 4);
  int* dbkt = (int*)alloc(128 * 4);
  int* dbcur = (int*)alloc(128 * 4);
  float* graph = (float*)alloc(GG * 4);
  char* zeroA_end = base + off;
  // ---- zero-init group B (floats), contiguous ----
  float* v = (float*)alloc((size_t)NN * 192 * 4);
  float* t = (float*)alloc((size_t)NN * 160 * 4);
  float* vW = (float*)alloc((size_t)NN * 192 * 4);
  float* tW = (float*)alloc((size_t)NN * 160 * 4);
  char* zeroB_end = base + off;
  // ---- rest ----
  int* row_off = (int*)alloc((NN + 1) * 4);
  float* d_csr = (float*)alloc((size_t)EE * 4);
  int* src_csr = (int*)alloc((size_t)EE * 4);
  int* dst_csr = (int*)alloc((size_t)EE * 4);
  int* acnt = (int*)alloc(NN * 4);
  int* act_off = (int*)alloc((NN + 1) * 4);
  int* act_idx = (int*)alloc((size_t)EE * 4);
  int* dboff = (int*)alloc(129 * 4);
  int* order = (int*)alloc(NN * 4);
  float* d_a = (float*)alloc((size_t)EE * 4);
  int* src_a = (int*)alloc((size_t)EE * 4);
  float* sh_a = (float*)alloc((size_t)EE * 8 * 4);
  float* wtab = (float*)alloc((size_t)LL * TABN * 64 * 4);
  float* gs_tab = (float*)alloc((size_t)LL * TABN * 128 * 4);
  float* gv_tab = (float*)alloc((size_t)LL * TABN * 128 * 4);
  float* gt_tab = (float*)alloc((size_t)LL * TABN * 64 * 4);
  float* s = (float*)alloc((size_t)NN * 128 * 4);
  float* sWsrc = (float*)alloc((size_t)NN * 128 * 4);
  float* sWv = (float*)alloc((size_t)NN * 64 * 4);
  float* sWt = (float*)alloc((size_t)NN * 32 * 4);
  float* agg_s = (float*)alloc((size_t)NN * 128 * 4);
  float* agg_v = (float*)alloc((size_t)NN * 192 * 4);
  float* agg_t = (float*)alloc((size_t)NN * 160 * 4);

  // two consolidated memsets (cover alignment pads harmlessly)
  hipMemsetAsync(deg, 0, (size_t)(zeroA_end - (char*)deg), stream);
  hipMemsetAsync(v, 0, (size_t)(zeroB_end - (char*)v), stream);

  k_hist<<<(EE + 255) / 256, 256, 0, stream>>>(edst, deg);
  k_scan<<<1, 1024, 0, stream>>>(deg, row_off, NN);
  k_scatter<<<(EE + 255) / 256, 256, 0, stream>>>(esrc, edst, pos, row_off, cursor,
                                                  d_csr, src_csr, dst_csr);
  k_act_cnt<<<(NN + 255) / 256, 256, 0, stream>>>(row_off, d_csr, acnt, dbkt);
  k_scan2<<<2, 1024, 0, stream>>>(acnt, act_off, NN, dbkt, dboff, 128);
  k_act_fill<<<(NN + 255) / 256, 256, 0, stream>>>(row_off, d_csr, act_off, act_idx,
                                                   acnt, dboff, dbcur, order);
  k_geom_act<<<(EE + 255) / 256, 256, 0, stream>>>(act_idx, src_csr, dst_csr, pos, act_off,
                                                   d_a, src_a, sh_a);
  k_build_wtab<<<LL * (TABN / 16), 256, 0, stream>>>(Wrad1, brad1, Wrad2, brad2, wtab);
  k_build_tabs<<<LL * (TABN / EB), 320, 0, stream>>>(wtab, Ww_s, Ww_v, Ww_vv, Ww_t, Ww_tt,
                                                     gs_tab, gv_tab, gt_tab);
  // layer-0 transforms fused with s init (v/t are zero; vW/tW zeroed by group-B memset)
  k_node_tf0<<<NN / 16, 256, 0, stream>>>(node_atom, atom_emb, s, Ws_src, Ws_v, Ws_t,
                                          sWsrc, sWv, sWt);

  for (int l = 0; l < LL; l++) {
    const float* gsL = gs_tab + (size_t)l * TABN * 128;
    const float* gvL = gv_tab + (size_t)l * TABN * 128;
    const float* gtL = gt_tab + (size_t)l * TABN * 64;
    k_mega<<<NN / 4, 256, 0, stream>>>(row_off, act_off, order, src_a, d_a, gsL, gvL, gtL,
                                       attn_a + (size_t)l * 128,
                                       sWsrc, sWv, sWt, vW, tW, sh_a, agg_s, agg_v, agg_t);
    if (l < LL - 1) {
      k_node_fused<<<NN / 8, 256, 0, stream>>>(
          s, v, t, agg_s, agg_v, agg_t,
          Wo_s + (size_t)l * 128 * 128, Wo_v + (size_t)l * 64 * 64,
          Wo_t + (size_t)l * 32 * 32,
          g_s + (size_t)l * 128, b_s + (size_t)l * 128,
          g_v + (size_t)l * 64, g_t + (size_t)l * 32,
          Ws_src + (size_t)(l + 1) * 128 * 128, Ws_v + (size_t)(l + 1) * 128 * 64,
          Ws_t + (size_t)(l + 1) * 128 * 32, Wv_v + (size_t)(l + 1) * 64 * 64,
          Wt_t + (size_t)(l + 1) * 32 * 32,
          sWsrc, sWv, sWt, vW, tW);
    } else {
      k_node_up<<<NN / 8, 256, 0, stream>>>(s, v, t, agg_s, agg_v, agg_t,
                                            Wo_s + (size_t)l * 128 * 128,
                                            Wo_v + (size_t)l * 64 * 64, Wo_t + (size_t)l * 32 * 32,
                                            g_s + (size_t)l * 128, b_s + (size_t)l * 128,
                                            g_v + (size_t)l * 64, g_t + (size_t)l * 32);
    }
  }
  dim3 rg((NN + 63) / 64, 8);
  k_readout<<<rg, 256, 0, stream>>>(s, batch, W_feat, b_feat, W_out1, b_out1, graph);
  k_finalize<<<1, 64, 0, stream>>>(graph, W_read, b_read, out);
}

// Round 12
// 979.328 us; speedup vs baseline: 1.0766x; 1.0081x over previous
//
#include <hip/hip_runtime.h>
#include <math.h>

#define NN 10000
#define EE 320000
#define GG 32
#define LL 6
#define TABN 2048
#define TABB (TABN / 64)
#define DTAB 5.45f
#define DCUT 5.4f

__device__ __forceinline__ float fsilu(float x) { return x / (1.0f + __expf(-x)); }
__device__ __forceinline__ float fgelu(float x) {
  float y = 0.7978845608f * (x + 0.044715f * x * x * x);
  float t = 1.0f - 2.0f / (__expf(2.0f * y) + 1.0f);
  return 0.5f * x * (1.0f + t);
}

// ---------------- CSR build ----------------
__global__ void k_hist(const int* __restrict__ dst, int* __restrict__ deg) {
  int e = blockIdx.x * blockDim.x + threadIdx.x;
  if (e < EE) atomicAdd(&deg[dst[e]], 1);
}

// parallel scan: each thread serially scans a chunk, then one scan of totals
__global__ void k_scan(const int* __restrict__ cnt, int* __restrict__ off, int n) {
  __shared__ int tsum[1024];
  int chunk = (n + 1023) / 1024;
  int base = (int)threadIdx.x * chunk;
  int local = 0;
  for (int i = 0; i < chunk; i++) {
    int idx = base + i;
    local += (idx < n) ? cnt[idx] : 0;
  }
  tsum[threadIdx.x] = local;
  __syncthreads();
  for (int o = 1; o < 1024; o <<= 1) {
    int tv = (threadIdx.x >= (unsigned)o) ? tsum[threadIdx.x - o] : 0;
    __syncthreads();
    tsum[threadIdx.x] += tv;
    __syncthreads();
  }
  int run = tsum[threadIdx.x] - local;  // exclusive prefix of this chunk
  for (int i = 0; i < chunk; i++) {
    int idx = base + i;
    if (idx < n) {
      run += cnt[idx];
      off[idx + 1] = run;
    }
  }
  if (threadIdx.x == 0) off[0] = 0;
}

// two independent scans in one launch (block 0: A, block 1: B)
__global__ void k_scan2(const int* __restrict__ cntA, int* __restrict__ offA, int nA,
                        const int* __restrict__ cntB, int* __restrict__ offB, int nB) {
  const int* cnt = (blockIdx.x == 0) ? cntA : cntB;
  int* off = (blockIdx.x == 0) ? offA : offB;
  int n = (blockIdx.x == 0) ? nA : nB;
  __shared__ int tsum[1024];
  int chunk = (n + 1023) / 1024;
  int base = (int)threadIdx.x * chunk;
  int local = 0;
  for (int i = 0; i < chunk; i++) {
    int idx = base + i;
    local += (idx < n) ? cnt[idx] : 0;
  }
  tsum[threadIdx.x] = local;
  __syncthreads();
  for (int o = 1; o < 1024; o <<= 1) {
    int tv = (threadIdx.x >= (unsigned)o) ? tsum[threadIdx.x - o] : 0;
    __syncthreads();
    tsum[threadIdx.x] += tv;
    __syncthreads();
  }
  int run = tsum[threadIdx.x] - local;
  for (int i = 0; i < chunk; i++) {
    int idx = base + i;
    if (idx < n) {
      run += cnt[idx];
      off[idx + 1] = run;
    }
  }
  if (threadIdx.x == 0) off[0] = 0;
}

// scatter + geometry fused: one pass assigns CSR slots and computes distances
__global__ void k_scatter(const int* __restrict__ esrc, const int* __restrict__ edst,
                          const float* __restrict__ pos, const int* __restrict__ row_off,
                          int* __restrict__ cursor, float* __restrict__ d_csr,
                          int* __restrict__ src_csr, int* __restrict__ dst_csr) {
  int e = blockIdx.x * blockDim.x + threadIdx.x;
  if (e < EE) {
    int d = edst[e];
    int s = esrc[e];
    int p = atomicAdd(&cursor[d], 1);
    int slot = row_off[d] + p;
    float rx = pos[d * 3 + 0] - pos[s * 3 + 0];
    float ry = pos[d * 3 + 1] - pos[s * 3 + 1];
    float rz = pos[d * 3 + 2] - pos[s * 3 + 2];
    d_csr[slot] = sqrtf(rx * rx + ry * ry + rz * rz + 1e-6f);
    src_csr[slot] = s;
    dst_csr[slot] = d;
  }
}

// ---------------- active-edge count + degree histogram (fused) ----------------
__global__ void k_act_cnt(const int* __restrict__ row_off, const float* __restrict__ d_csr,
                          int* __restrict__ acnt, int* __restrict__ dbkt) {
  int n = blockIdx.x * blockDim.x + threadIdx.x;
  if (n >= NN) return;
  int c = 0;
  for (int j = row_off[n]; j < row_off[n + 1]; ++j) c += (d_csr[j] < DCUT) ? 1 : 0;
  acnt[n] = c;
  int b = 127 - min(127, c);
  atomicAdd(&dbkt[b], 1);
}

// act_fill + degree-order scatter fused (same per-node domain, independent outputs)
__global__ void k_act_fill(const int* __restrict__ row_off, const float* __restrict__ d_csr,
                           const int* __restrict__ act_off, int* __restrict__ act_idx,
                           const int* __restrict__ acnt, const int* __restrict__ dboff,
                           int* __restrict__ dbcur, int* __restrict__ order) {
  int n = blockIdx.x * blockDim.x + threadIdx.x;
  if (n >= NN) return;
  int a = act_off[n];
  for (int j = row_off[n]; j < row_off[n + 1]; ++j)
    if (d_csr[j] < DCUT) act_idx[a++] = j;
  int b = 127 - min(127, acnt[n]);
  int p = atomicAdd(&dbcur[b], 1);
  order[dboff[b] + p] = n;
}

// ---------------- compacted geometry per active edge (direct CSR arrays) ----------------
__global__ void k_geom_act(const int* __restrict__ act_idx, const int* __restrict__ src_csr,
                           const int* __restrict__ dst_csr, const float* __restrict__ pos,
                           const int* __restrict__ act_off, float* __restrict__ d_a,
                           int* __restrict__ src_a, float* __restrict__ sh_a) {
  int a = blockIdx.x * blockDim.x + threadIdx.x;
  if (a >= act_off[NN]) return;
  int j = act_idx[a];
  int s = src_csr[j], dd = dst_csr[j];
  float rx = pos[dd * 3 + 0] - pos[s * 3 + 0];
  float ry = pos[dd * 3 + 1] - pos[s * 3 + 1];
  float rz = pos[dd * 3 + 2] - pos[s * 3 + 2];
  float d = sqrtf(rx * rx + ry * ry + rz * rz + 1e-6f);
  float inv = 1.0f / d;
  float x = rx * inv, y = ry * inv, z = rz * inv;
  d_a[a] = d;
  src_a[a] = s;
  const float s3 = 1.7320508075688772f;
  const float s5 = 2.23606797749979f;
  const float s15 = 3.872983346207417f;
  sh_a[a * 8 + 0] = s3 * x;
  sh_a[a * 8 + 1] = s3 * y;
  sh_a[a * 8 + 2] = s3 * z;
  sh_a[a * 8 + 3] = s15 * x * y;
  sh_a[a * 8 + 4] = s15 * y * z;
  sh_a[a * 8 + 5] = 0.5f * s5 * (3.0f * z * z - 1.0f);
  sh_a[a * 8 + 6] = s15 * x * z;
  sh_a[a * 8 + 7] = 0.5f * s15 * (x * x - y * y);
}

// ---------------- radial MLP table w(d): 16 entries/block for parallelism ----------------
__global__ void k_build_wtab(const float* __restrict__ Wrad1, const float* __restrict__ brad1,
                             const float* __restrict__ Wrad2, const float* __restrict__ brad2,
                             float* __restrict__ wtab) {
  int l = blockIdx.x / (TABN / 16);
  int blk = blockIdx.x % (TABN / 16);
  __shared__ float W1[128 * 64];
  __shared__ float W2[64 * 64];
  __shared__ float b1[64], b2[64];
  __shared__ float rbf_s[4][128];
  __shared__ float h_s[4][64];
  const float* w1p = Wrad1 + (size_t)l * 128 * 64;
  const float* w2p = Wrad2 + (size_t)l * 64 * 64;
  for (int i = threadIdx.x; i < 128 * 64; i += 256) W1[i] = w1p[i];
  for (int i = threadIdx.x; i < 64 * 64; i += 256) W2[i] = w2p[i];
  if (threadIdx.x < 64) {
    b1[threadIdx.x] = brad1[(size_t)l * 64 + threadIdx.x];
    b2[threadIdx.x] = brad2[(size_t)l * 64 + threadIdx.x];
  }
  __syncthreads();
  int wv = threadIdx.x >> 6, lane = threadIdx.x & 63;
  const float width = 5.0f / 128.0f;
  for (int k = wv; k < 16; k += 4) {
    int i = blk * 16 + k;
    float d = (float)i * (DTAB / (float)(TABN - 1));
    float c0 = (5.0f * (float)lane) / 127.0f;
    float c1 = (5.0f * (float)(lane + 64)) / 127.0f;
    float t0 = (d - c0) / width, t1 = (d - c1) / width;
    rbf_s[wv][lane] = __expf(-0.5f * t0 * t0);
    rbf_s[wv][lane + 64] = __expf(-0.5f * t1 * t1);
    float acc = b1[lane];
    #pragma unroll 8
    for (int i2 = 0; i2 < 128; i2++) acc += rbf_s[wv][i2] * W1[i2 * 64 + lane];
    acc = fsilu(acc);
    h_s[wv][lane] = acc;
    float acc2 = b2[lane];
    #pragma unroll 8
    for (int i2 = 0; i2 < 64; i2++) acc2 += h_s[wv][i2] * W2[i2 * 64 + lane];
    wtab[((size_t)l * TABN + i) * 64 + lane] = fsilu(acc2);
  }
}

// ---------------- fused product-table build: gs, gv, gt in one kernel ----------------
#define EB 8
__global__ __launch_bounds__(320) void k_build_tabs(
    const float* __restrict__ wtab, const float* __restrict__ Ww_s,
    const float* __restrict__ Ww_v, const float* __restrict__ Ww_vv,
    const float* __restrict__ Ww_t, const float* __restrict__ Ww_tt,
    float* __restrict__ gs_tab, float* __restrict__ gv_tab, float* __restrict__ gt_tab) {
  int l = blockIdx.x / (TABN / EB);
  int eb = (blockIdx.x % (TABN / EB)) * EB;
  __shared__ float ws[EB][64];
  int tid = threadIdx.x;
  for (int i = tid; i < EB * 64; i += 320)
    ws[i >> 6][i & 63] = wtab[((size_t)l * TABN + eb + (i >> 6)) * 64 + (i & 63)];
  __syncthreads();
  float acc[EB] = {};
  if (tid < 128) {
    int col = tid;
    const float* W = Ww_s + (size_t)l * 64 * 128;
    #pragma unroll 8
    for (int i = 0; i < 64; i++) {
      float w = W[i * 128 + col];
      #pragma unroll
      for (int e = 0; e < EB; e++) acc[e] += ws[e][i] * w;
    }
    #pragma unroll
    for (int e = 0; e < EB; e++)
      gs_tab[((size_t)l * TABN + eb + e) * 128 + col] = acc[e];
  } else if (tid < 256) {
    int cc = tid - 128;
    int c = cc >> 1;
    const float* W = ((cc & 1) ? Ww_vv : Ww_v) + (size_t)l * 64 * 64;
    #pragma unroll 8
    for (int i = 0; i < 64; i++) {
      float w = W[i * 64 + c];
      #pragma unroll
      for (int e = 0; e < EB; e++) acc[e] += ws[e][i] * w;
    }
    #pragma unroll
    for (int e = 0; e < EB; e++)
      gv_tab[((size_t)l * TABN + eb + e) * 128 + cc] = acc[e];
  } else {
    int cc = tid - 256;
    int c = cc >> 1;
    const float* W = ((cc & 1) ? Ww_tt : Ww_t) + (size_t)l * 64 * 32;
    #pragma unroll 8
    for (int i = 0; i < 64; i++) {
      float w = W[i * 32 + c];
      #pragma unroll
      for (int e = 0; e < EB; e++) acc[e] += ws[e][i] * w;
    }
    #pragma unroll
    for (int e = 0; e < EB; e++)
      gt_tab[((size_t)l * TABN + eb + e) * 64 + cc] = acc[e];
  }
}

// ---------------- layer-0 transforms fused with s-init (v = t = 0) ----------------
__global__ __launch_bounds__(256) void k_node_tf0(
    const int* __restrict__ node_atom, const float* __restrict__ atom_emb,
    float* __restrict__ s, const float* __restrict__ Ws_src,
    const float* __restrict__ Ws_v, const float* __restrict__ Ws_t,
    float* __restrict__ sWsrc, float* __restrict__ sWv, float* __restrict__ sWt) {
  int nb = blockIdx.x * 16;
  int tid = threadIdx.x;
  __shared__ float s16[16][129];
  for (int idx = tid; idx < 16 * 128; idx += 256) {
    int n = idx >> 7, c = idx & 127;
    float val = atom_emb[(size_t)node_atom[nb + n] * 128 + c];
    s16[n][c] = val;
    s[(size_t)(nb + n) * 128 + c] = val;
  }
  __syncthreads();
  {
    int col = tid & 127, ng = tid >> 7;
    float acc[8] = {0, 0, 0, 0, 0, 0, 0, 0};
    for (int c = 0; c < 128; c++) {
      float w = Ws_src[c * 128 + col];
      #pragma unroll
      for (int n = 0; n < 8; n++) acc[n] += s16[ng * 8 + n][c] * w;
    }
    #pragma unroll
    for (int n = 0; n < 8; n++) sWsrc[(size_t)(nb + ng * 8 + n) * 128 + col] = acc[n];
  }
  {
    int col = tid & 63, ng = tid >> 6;
    float acc[4] = {0, 0, 0, 0};
    for (int c = 0; c < 128; c++) {
      float w = Ws_v[c * 64 + col];
      #pragma unroll
      for (int n = 0; n < 4; n++) acc[n] += s16[ng * 4 + n][c] * w;
    }
    #pragma unroll
    for (int n = 0; n < 4; n++) sWv[(size_t)(nb + ng * 4 + n) * 64 + col] = acc[n];
  }
  {
    int col = tid & 31, ng = tid >> 5;
    float acc[2] = {0, 0};
    for (int c = 0; c < 128; c++) {
      float w = Ws_t[c * 32 + col];
      acc[0] += s16[ng * 2 + 0][c] * w;
      acc[1] += s16[ng * 2 + 1][c] * w;
    }
    sWt[(size_t)(nb + ng * 2 + 0) * 32 + col] = acc[0];
    sWt[(size_t)(nb + ng * 2 + 1) * 32 + col] = acc[1];
  }
}

// ---------------- mega: single-pass online-softmax, pair-combined update (2 waves/block) ----------------
__global__ __launch_bounds__(128) void k_mega(
    const int* __restrict__ row_off, const int* __restrict__ act_off,
    const int* __restrict__ order,
    const int* __restrict__ src_a, const float* __restrict__ d_a,
    const float* __restrict__ gsL, const float* __restrict__ gvL,
    const float* __restrict__ gtL, const float* __restrict__ attn_l,
    const float* __restrict__ sWsrc, const float* __restrict__ sWv,
    const float* __restrict__ sWt, const float* __restrict__ vW,
    const float* __restrict__ tW, const float* __restrict__ sh_a,
    float* __restrict__ agg_s, float* __restrict__ agg_v, float* __restrict__ agg_t) {
  int wv = threadIdx.x >> 6, lane = threadIdx.x & 63;
  int lt = lane & 31;
  int slot = blockIdx.x * 2 + wv;
  if (slot >= NN) return;
  int n = order[slot];
  int alo = act_off[n], ahi = act_off[n + 1];
  int nact = ahi - alo;
  int ninact = (row_off[n + 1] - row_off[n]) - nact;
  const float sc = (float)(TABN - 1) / DTAB;
  float atnA = attn_l[lane];
  float atnB = attn_l[64 + lane];
  float rm0, rm1, rm2, rm3;
  rm0 = rm1 = rm2 = rm3 = (ninact > 0) ? 0.0f : -1e30f;
  float rs0 = 0.f, rs1 = 0.f, rs2 = 0.f, rs3 = 0.f;
  float as0 = 0.f, as1 = 0.f;
  float av0 = 0.f, av1 = 0.f, av2 = 0.f;
  float at0 = 0.f, at1 = 0.f, at2 = 0.f, at3 = 0.f, at4 = 0.f;
  int a = alo;
  for (; a + 1 < ahi; a += 2) {
    int aA = a, aB = a + 1;
    float dA = d_a[aA], dB = d_a[aB];
    int snA = src_a[aA], snB = src_a[aB];
    float xA = fminf(dA * sc, (float)(TABN - 1) - 1.0f);
    float xB = fminf(dB * sc, (float)(TABN - 1) - 1.0f);
    int iA = (int)xA, iB = (int)xB;
    float fA = xA - (float)iA, fB = xB - (float)iB;
    float g1A = 1.0f - fA, g1B = 1.0f - fB;
    const float* gA = gsL + (size_t)iA * 128;
    const float* gB = gsL + (size_t)iB * 128;
    float gsA_A = gA[lane] * g1A + gA[128 + lane] * fA;
    float gsB_A = gA[64 + lane] * g1A + gA[192 + lane] * fA;
    float gsA_B = gB[lane] * g1B + gB[128 + lane] * fB;
    float gsB_B = gB[64 + lane] * g1B + gB[192 + lane] * fB;
    float m0A = sWsrc[(size_t)snA * 128 + lane] * gsA_A;
    float m1A = sWsrc[(size_t)snA * 128 + 64 + lane] * gsB_A;
    float m0B = sWsrc[(size_t)snB * 128 + lane] * gsA_B;
    float m1B = sWsrc[(size_t)snB * 128 + 64 + lane] * gsB_B;
    const float* gvA = gvL + (size_t)iA * 128;
    const float* gvB = gvL + (size_t)iB * 128;
    float2 pA0 = *(const float2*)&gvA[2 * lane];
    float2 pA1 = *(const float2*)&gvA[128 + 2 * lane];
    float2 pB0 = *(const float2*)&gvB[2 * lane];
    float2 pB1 = *(const float2*)&gvB[128 + 2 * lane];
    float gavA = pA0.x * g1A + pA1.x * fA;
    float gbvA = pA0.y * g1A + pA1.y * fA;
    float gavB = pB0.x * g1B + pB1.x * fB;
    float gbvB = pB0.y * g1B + pB1.y * fB;
    float svA = sWv[(size_t)snA * 64 + lane];
    float svB = sWv[(size_t)snB * 64 + lane];
    float4 s1A = *(const float4*)&sh_a[(size_t)aA * 8];
    float4 s2A = *(const float4*)&sh_a[(size_t)aA * 8 + 4];
    float4 s1B = *(const float4*)&sh_a[(size_t)aB * 8];
    float4 s2B = *(const float4*)&sh_a[(size_t)aB * 8 + 4];
    const float* vpA = &vW[(size_t)snA * 192 + lane];
    const float* vpB = &vW[(size_t)snB * 192 + lane];
    float vA0 = vpA[0], vA1 = vpA[64], vA2 = vpA[128];
    float vB0 = vpB[0], vB1 = vpB[64], vB2 = vpB[128];
    float gatA = 0.f, gbtA = 0.f, gatB = 0.f, gbtB = 0.f;
    float stA = 0.f, stB = 0.f;
    float tA0 = 0.f, tA1 = 0.f, tA2 = 0.f, tA3 = 0.f, tA4 = 0.f;
    float tB0 = 0.f, tB1 = 0.f, tB2 = 0.f, tB3 = 0.f, tB4 = 0.f;
    if (lane < 32) {
      const float* gtA = gtL + (size_t)iA * 64;
      const float* gtB = gtL + (size_t)iB * 64;
      float2 qA0 = *(const float2*)&gtA[2 * lt];
      float2 qA1 = *(const float2*)&gtA[64 + 2 * lt];
      float2 qB0 = *(const float2*)&gtB[2 * lt];
      float2 qB1 = *(const float2*)&gtB[64 + 2 * lt];
      gatA = qA0.x * g1A + qA1.x * fA;
      gbtA = qA0.y * g1A + qA1.y * fA;
      gatB = qB0.x * g1B + qB1.x * fB;
      gbtB = qB0.y * g1B + qB1.y * fB;
      stA = sWt[(size_t)snA * 32 + lane];
      stB = sWt[(size_t)snB * 32 + lane];
      const float* tpA = &tW[(size_t)snA * 160 + lane];
      const float* tpB = &tW[(size_t)snB * 160 + lane];
      tA0 = tpA[0]; tA1 = tpA[32]; tA2 = tpA[64]; tA3 = tpA[96]; tA4 = tpA[128];
      tB0 = tpB[0]; tB1 = tpB[32]; tB2 = tpB[64]; tB3 = tpB[96]; tB4 = tpB[128];
    }
    float p01A = m0A * atnA, p23A = m1A * atnB;
    float p01B = m0B * atnA, p23B = m1B * atnB;
    #pragma unroll
    for (int mm = 1; mm < 32; mm <<= 1) {
      p01A += __shfl_xor(p01A, mm);
      p23A += __shfl_xor(p23A, mm);
      p01B += __shfl_xor(p01B, mm);
      p23B += __shfl_xor(p23B, mm);
    }
    float l0A = __shfl(p01A, 0), l1A = __shfl(p01A, 32);
    float l2A = __shfl(p23A, 0), l3A = __shfl(p23A, 32);
    float l0B = __shfl(p01B, 0), l1B = __shfl(p01B, 32);
    float l2B = __shfl(p23B, 0), l3B = __shfl(p23B, 32);
    // combined two-edge online-softmax update (exactly equivalent to sequential)
    float nm0 = fmaxf(rm0, fmaxf(l0A, l0B));
    float nm1 = fmaxf(rm1, fmaxf(l1A, l1B));
    float nm2 = fmaxf(rm2, fmaxf(l2A, l2B));
    float nm3 = fmaxf(rm3, fmaxf(l3A, l3B));
    float wA0 = __expf(l0A - nm0), wA1 = __expf(l1A - nm1);
    float wA2 = __expf(l2A - nm2), wA3 = __expf(l3A - nm3);
    float wB0 = __expf(l0B - nm0), wB1 = __expf(l1B - nm1);
    float wB2 = __expf(l2B - nm2), wB3 = __expf(l3B - nm3);
    float wSA0 = (lane < 32) ? wA0 : wA1, wSA1 = (lane < 32) ? wA2 : wA3;
    float wSB0 = (lane < 32) ? wB0 : wB1, wSB1 = (lane < 32) ? wB2 : wB3;
    float addS0 = wSA0 * m0A + wSB0 * m0B;
    float addS1 = wSA1 * m1A + wSB1 * m1B;
    float wVA = (lane < 16) ? wA0 : (lane < 32) ? wA1 : (lane < 48) ? wA2 : wA3;
    float wVB = (lane < 16) ? wB0 : (lane < 32) ? wB1 : (lane < 48) ? wB2 : wB3;
    float avvA = svA * gavA, avvB = svB * gavB;
    float addV0 = wVA * (avvA * s1A.x + vA0 * gbvA) + wVB * (avvB * s1B.x + vB0 * gbvB);
    float addV1 = wVA * (avvA * s1A.y + vA1 * gbvA) + wVB * (avvB * s1B.y + vB1 * gbvB);
    float addV2 = wVA * (avvA * s1A.z + vA2 * gbvA) + wVB * (avvB * s1B.z + vB2 * gbvB);
    float wTA = (lane < 8) ? wA0 : (lane < 16) ? wA1 : (lane < 24) ? wA2 : wA3;
    float wTB = (lane < 8) ? wB0 : (lane < 16) ? wB1 : (lane < 24) ? wB2 : wB3;
    float attA = stA * gatA, attB = stB * gatB;
    float addT0 = wTA * (attA * s1A.w + tA0 * gbtA) + wTB * (attB * s1B.w + tB0 * gbtB);
    float addT1 = wTA * (attA * s2A.x + tA1 * gbtA) + wTB * (attB * s2B.x + tB1 * gbtB);
    float addT2 = wTA * (attA * s2A.y + tA2 * gbtA) + wTB * (attB * s2B.y + tB2 * gbtB);
    float addT3 = wTA * (attA * s2A.z + tA3 * gbtA) + wTB * (attB * s2B.z + tB3 * gbtB);
    float addT4 = wTA * (attA * s2A.w + tA4 * gbtA) + wTB * (attB * s2B.w + tB4 * gbtB);
    if (nm0 == rm0 && nm1 == rm1 && nm2 == rm2 && nm3 == rm3) {
      rs0 += wA0 + wB0; rs1 += wA1 + wB1; rs2 += wA2 + wB2; rs3 += wA3 + wB3;
      as0 += addS0; as1 += addS1;
      av0 += addV0; av1 += addV1; av2 += addV2;
      at0 += addT0; at1 += addT1; at2 += addT2; at3 += addT3; at4 += addT4;
    } else {
      float f0 = __expf(rm0 - nm0), f1 = __expf(rm1 - nm1);
      float f2 = __expf(rm2 - nm2), f3 = __expf(rm3 - nm3);
      rm0 = nm0; rm1 = nm1; rm2 = nm2; rm3 = nm3;
      rs0 = rs0 * f0 + wA0 + wB0; rs1 = rs1 * f1 + wA1 + wB1;
      rs2 = rs2 * f2 + wA2 + wB2; rs3 = rs3 * f3 + wA3 + wB3;
      float fS0 = (lane < 32) ? f0 : f1, fS1 = (lane < 32) ? f2 : f3;
      as0 = as0 * fS0 + addS0; as1 = as1 * fS1 + addS1;
      float fV = (lane < 16) ? f0 : (lane < 32) ? f1 : (lane < 48) ? f2 : f3;
      av0 = av0 * fV + addV0; av1 = av1 * fV + addV1; av2 = av2 * fV + addV2;
      float fT = (lane < 8) ? f0 : (lane < 16) ? f1 : (lane < 24) ? f2 : f3;
      at0 = at0 * fT + addT0; at1 = at1 * fT + addT1; at2 = at2 * fT + addT2;
      at3 = at3 * fT + addT3; at4 = at4 * fT + addT4;
    }
  }
  for (; a < ahi; ++a) {
    float x = d_a[a] * sc;
    x = fminf(x, (float)(TABN - 1) - 1.0f);
    int i0 = (int)x; float f = x - (float)i0; float g1 = 1.0f - f;
    int sn = src_a[a];
    const float* g0 = gsL + (size_t)i0 * 128;
    float gsA = g0[lane] * g1 + g0[128 + lane] * f;
    float gsB = g0[64 + lane] * g1 + g0[192 + lane] * f;
    float m0 = sWsrc[(size_t)sn * 128 + lane] * gsA;
    float m1 = sWsrc[(size_t)sn * 128 + 64 + lane] * gsB;
    float p01 = m0 * atnA;
    float p23 = m1 * atnB;
    #pragma unroll
    for (int mm = 1; mm < 32; mm <<= 1) {
      p01 += __shfl_xor(p01, mm);
      p23 += __shfl_xor(p23, mm);
    }
    float l0 = __shfl(p01, 0), l1 = __shfl(p01, 32);
    float l2 = __shfl(p23, 0), l3 = __shfl(p23, 32);
    float nm0 = fmaxf(rm0, l0), nm1 = fmaxf(rm1, l1);
    float nm2 = fmaxf(rm2, l2), nm3 = fmaxf(rm3, l3);
    float f0 = __expf(rm0 - nm0), f1 = __expf(rm1 - nm1);
    float f2 = __expf(rm2 - nm2), f3 = __expf(rm3 - nm3);
    float w0 = __expf(l0 - nm0), w1 = __expf(l1 - nm1);
    float w2 = __expf(l2 - nm2), w3 = __expf(l3 - nm3);
    rm0 = nm0; rm1 = nm1; rm2 = nm2; rm3 = nm3;
    rs0 = rs0 * f0 + w0; rs1 = rs1 * f1 + w1;
    rs2 = rs2 * f2 + w2; rs3 = rs3 * f3 + w3;
    float fS0 = (lane < 32) ? f0 : f1;
    float fS1 = (lane < 32) ? f2 : f3;
    float wS0 = (lane < 32) ? w0 : w1;
    float wS1 = (lane < 32) ? w2 : w3;
    as0 = as0 * fS0 + wS0 * m0;
    as1 = as1 * fS1 + wS1 * m1;
    const float* gv0 = gvL + (size_t)i0 * 128;
    float2 p0 = *(const float2*)&gv0[2 * lane];
    float2 p1 = *(const float2*)&gv0[128 + 2 * lane];
    float gav = p0.x * g1 + p1.x * f;
    float gbv = p0.y * g1 + p1.y * f;
    float fV = (lane < 16) ? f0 : (lane < 32) ? f1 : (lane < 48) ? f2 : f3;
    float wV = (lane < 16) ? w0 : (lane < 32) ? w1 : (lane < 48) ? w2 : w3;
    float avv = sWv[(size_t)sn * 64 + lane] * gav;
    float4 s1 = *(const float4*)&sh_a[(size_t)a * 8];
    float4 s2 = *(const float4*)&sh_a[(size_t)a * 8 + 4];
    const float* vp = &vW[(size_t)sn * 192 + lane];
    av0 = av0 * fV + wV * (avv * s1.x + vp[0] * gbv);
    av1 = av1 * fV + wV * (avv * s1.y + vp[64] * gbv);
    av2 = av2 * fV + wV * (avv * s1.z + vp[128] * gbv);
    if (lane < 32) {
      const float* gt0 = gtL + (size_t)i0 * 64;
      float2 q0 = *(const float2*)&gt0[2 * lt];
      float2 q1 = *(const float2*)&gt0[64 + 2 * lt];
      float gat = q0.x * g1 + q1.x * f;
      float gbt = q0.y * g1 + q1.y * f;
      float fT = (lane < 8) ? f0 : (lane < 16) ? f1 : (lane < 24) ? f2 : f3;
      float wT = (lane < 8) ? w0 : (lane < 16) ? w1 : (lane < 24) ? w2 : w3;
      float att = sWt[(size_t)sn * 32 + lane] * gat;
      const float* tp = &tW[(size_t)sn * 160 + lane];
      at0 = at0 * fT + wT * (att * s1.w + tp[0] * gbt);
      at1 = at1 * fT + wT * (att * s2.x + tp[32] * gbt);
      at2 = at2 * fT + wT * (att * s2.y + tp[64] * gbt);
      at3 = at3 * fT + wT * (att * s2.z + tp[96] * gbt);
      at4 = at4 * fT + wT * (att * s2.w + tp[128] * gbt);
    }
  }
  if (ninact > 0) {
    rs0 += (float)ninact * __expf(-rm0);
    rs1 += (float)ninact * __expf(-rm1);
    rs2 += (float)ninact * __expf(-rm2);
    rs3 += (float)ninact * __expf(-rm3);
  }
  float r0 = 1.0f / (rs0 + 1e-9f), r1 = 1.0f / (rs1 + 1e-9f);
  float r2 = 1.0f / (rs2 + 1e-9f), r3 = 1.0f / (rs3 + 1e-9f);
  float rS0 = (lane < 32) ? r0 : r1;
  float rS1 = (lane < 32) ? r2 : r3;
  float rV = (lane < 16) ? r0 : (lane < 32) ? r1 : (lane < 48) ? r2 : r3;
  agg_s[(size_t)n * 128 + lane] = as0 * rS0;
  agg_s[(size_t)n * 128 + 64 + lane] = as1 * rS1;
  agg_v[(size_t)n * 192 + lane * 3 + 0] = av0 * rV;
  agg_v[(size_t)n * 192 + lane * 3 + 1] = av1 * rV;
  agg_v[(size_t)n * 192 + lane * 3 + 2] = av2 * rV;
  if (lane < 32) {
    float rT = (lane < 8) ? r0 : (lane < 16) ? r1 : (lane < 24) ? r2 : r3;
    agg_t[(size_t)n * 160 + lane * 5 + 0] = at0 * rT;
    agg_t[(size_t)n * 160 + lane * 5 + 1] = at1 * rT;
    agg_t[(size_t)n * 160 + lane * 5 + 2] = at2 * rT;
    agg_t[(size_t)n * 160 + lane * 5 + 3] = at3 * rT;
    agg_t[(size_t)n * 160 + lane * 5 + 4] = at4 * rT;
  }
}

// ---------------- fused node update + next-layer transforms: wave-per-2-nodes, 2 waves/block ----------------
__global__ __launch_bounds__(128) void k_node_fused(
    float* __restrict__ s, float* __restrict__ v, float* __restrict__ t,
    const float* __restrict__ agg_s, const float* __restrict__ agg_v,
    const float* __restrict__ agg_t, const float* __restrict__ Wo_s,
    const float* __restrict__ Wo_v, const float* __restrict__ Wo_t,
    const float* __restrict__ g_s, const float* __restrict__ b_s,
    const float* __restrict__ g_v, const float* __restrict__ g_t,
    const float* __restrict__ Ws_src, const float* __restrict__ Ws_v,
    const float* __restrict__ Ws_t, const float* __restrict__ Wv_v,
    const float* __restrict__ Wt_t, float* __restrict__ sWsrc,
    float* __restrict__ sWv, float* __restrict__ sWt, float* __restrict__ vW,
    float* __restrict__ tW) {
  int wv = threadIdx.x >> 6, lane = threadIdx.x & 63;
  int lt = lane & 31, nh = lane >> 5;
  int n0 = (blockIdx.x * 2 + wv) * 2;
  int n1 = n0 + 1;
  int nt = n0 + nh;
  __shared__ float stg[2][2][192];
  __shared__ float sN[2][2][128];
  __shared__ float vN[2][2][192];
  __shared__ float tN[2][2][160];
  // ---- stage agg_s (both nodes); load s_old ----
  float aS0 = agg_s[(size_t)n0 * 128 + lane];
  float aS1 = agg_s[(size_t)n0 * 128 + 64 + lane];
  float bS0 = agg_s[(size_t)n1 * 128 + lane];
  float bS1 = agg_s[(size_t)n1 * 128 + 64 + lane];
  float sA0 = s[(size_t)n0 * 128 + lane];
  float sA1 = s[(size_t)n0 * 128 + 64 + lane];
  float sB0 = s[(size_t)n1 * 128 + lane];
  float sB1 = s[(size_t)n1 * 128 + 64 + lane];
  stg[wv][0][lane] = aS0; stg[wv][0][64 + lane] = aS1;
  stg[wv][1][lane] = bS0; stg[wv][1][64 + lane] = bS1;
  asm volatile("s_waitcnt lgkmcnt(0)" ::: "memory");
  // ---- s-matmul: s_new = s_old + agg_s @ Wo_s (weights amortized over 2 nodes) ----
  #pragma unroll 8
  for (int c = 0; c < 128; c++) {
    float w0 = Wo_s[c * 128 + lane];
    float w1 = Wo_s[c * 128 + 64 + lane];
    float ax = stg[wv][0][c], bx = stg[wv][1][c];
    sA0 += ax * w0; sA1 += ax * w1;
    sB0 += bx * w0; sB1 += bx * w1;
  }
  // prefetch agg_v + v_old
  float avA0 = agg_v[(size_t)n0 * 192 + lane];
  float avA1 = agg_v[(size_t)n0 * 192 + 64 + lane];
  float avA2 = agg_v[(size_t)n0 * 192 + 128 + lane];
  float avB0 = agg_v[(size_t)n1 * 192 + lane];
  float avB1 = agg_v[(size_t)n1 * 192 + 64 + lane];
  float avB2 = agg_v[(size_t)n1 * 192 + 128 + lane];
  float voA0 = v[(size_t)n0 * 192 + lane * 3 + 0];
  float voA1 = v[(size_t)n0 * 192 + lane * 3 + 1];
  float voA2 = v[(size_t)n0 * 192 + lane * 3 + 2];
  float voB0 = v[(size_t)n1 * 192 + lane * 3 + 0];
  float voB1 = v[(size_t)n1 * 192 + lane * 3 + 1];
  float voB2 = v[(size_t)n1 * 192 + lane * 3 + 2];
  // ---- LayerNorm(s), both nodes ----
  float smA = sA0 + sA1, sqA = sA0 * sA0 + sA1 * sA1;
  float smB = sB0 + sB1, sqB = sB0 * sB0 + sB1 * sB1;
  #pragma unroll
  for (int m = 1; m < 64; m <<= 1) {
    smA += __shfl_xor(smA, m); sqA += __shfl_xor(sqA, m);
    smB += __shfl_xor(smB, m); sqB += __shfl_xor(sqB, m);
  }
  float muA = smA / 128.0f, muB = smB / 128.0f;
  float varA = sqA / 128.0f - muA * muA; if (varA < 0.f) varA = 0.f;
  float varB = sqB / 128.0f - muB * muB; if (varB < 0.f) varB = 0.f;
  float riA = rsqrtf(varA + 1e-6f), riB = rsqrtf(varB + 1e-6f);
  float gs0 = g_s[lane], gs1 = g_s[64 + lane];
  float bs0 = b_s[lane], bs1 = b_s[64 + lane];
  float yA0 = (sA0 - muA) * riA * gs0 + bs0;
  float yA1 = (sA1 - muA) * riA * gs1 + bs1;
  float yB0 = (sB0 - muB) * riB * gs0 + bs0;
  float yB1 = (sB1 - muB) * riB * gs1 + bs1;
  s[(size_t)n0 * 128 + lane] = yA0;
  s[(size_t)n0 * 128 + 64 + lane] = yA1;
  s[(size_t)n1 * 128 + lane] = yB0;
  s[(size_t)n1 * 128 + 64 + lane] = yB1;
  sN[wv][0][lane] = yA0; sN[wv][0][64 + lane] = yA1;
  sN[wv][1][lane] = yB0; sN[wv][1][64 + lane] = yB1;
  // ---- stage agg_v ----
  stg[wv][0][lane] = avA0; stg[wv][0][64 + lane] = avA1; stg[wv][0][128 + lane] = avA2;
  stg[wv][1][lane] = avB0; stg[wv][1][64 + lane] = avB1; stg[wv][1][128 + lane] = avB2;
  asm volatile("s_waitcnt lgkmcnt(0)" ::: "memory");
  // ---- v-matmul: v_new = v_old + agg_v @ Wo_v ----
  float vA0 = voA0, vA1 = voA1, vA2 = voA2;
  float vB0 = voB0, vB1 = voB1, vB2 = voB2;
  #pragma unroll 8
  for (int c = 0; c < 64; c++) {
    float w = Wo_v[c * 64 + lane];
    vA0 += stg[wv][0][c * 3 + 0] * w;
    vA1 += stg[wv][0][c * 3 + 1] * w;
    vA2 += stg[wv][0][c * 3 + 2] * w;
    vB0 += stg[wv][1][c * 3 + 0] * w;
    vB1 += stg[wv][1][c * 3 + 1] * w;
    vB2 += stg[wv][1][c * 3 + 2] * w;
  }
  // prefetch agg_t + t_old (half-trick: lane<32 → n0, lane>=32 → n1)
  float btA0 = agg_t[(size_t)n0 * 160 + lane];
  float btA1 = agg_t[(size_t)n0 * 160 + 64 + lane];
  float btA2 = (lane < 32) ? agg_t[(size_t)n0 * 160 + 128 + lane] : 0.f;
  float btB0 = agg_t[(size_t)n1 * 160 + lane];
  float btB1 = agg_t[(size_t)n1 * 160 + 64 + lane];
  float btB2 = (lane < 32) ? agg_t[(size_t)n1 * 160 + 128 + lane] : 0.f;
  float to0 = t[(size_t)nt * 160 + lt * 5 + 0];
  float to1 = t[(size_t)nt * 160 + lt * 5 + 1];
  float to2 = t[(size_t)nt * 160 + lt * 5 + 2];
  float to3 = t[(size_t)nt * 160 + lt * 5 + 3];
  float to4 = t[(size_t)nt * 160 + lt * 5 + 4];
  // ---- RMS(v), both nodes ----
  float ssqA = vA0 * vA0 + vA1 * vA1 + vA2 * vA2;
  float ssqB = vB0 * vB0 + vB1 * vB1 + vB2 * vB2;
  #pragma unroll
  for (int m = 1; m < 64; m <<= 1) {
    ssqA += __shfl_xor(ssqA, m);
    ssqB += __shfl_xor(ssqB, m);
  }
  float rivA = rsqrtf(ssqA / 64.0f + 1e-6f);
  float rivB = rsqrtf(ssqB / 64.0f + 1e-6f);
  float gv = g_v[lane];
  float vyA0 = vA0 * rivA * gv, vyA1 = vA1 * rivA * gv, vyA2 = vA2 * rivA * gv;
  float vyB0 = vB0 * rivB * gv, vyB1 = vB1 * rivB * gv, vyB2 = vB2 * rivB * gv;
  v[(size_t)n0 * 192 + lane * 3 + 0] = vyA0;
  v[(size_t)n0 * 192 + lane * 3 + 1] = vyA1;
  v[(size_t)n0 * 192 + lane * 3 + 2] = vyA2;
  v[(size_t)n1 * 192 + lane * 3 + 0] = vyB0;
  v[(size_t)n1 * 192 + lane * 3 + 1] = vyB1;
  v[(size_t)n1 * 192 + lane * 3 + 2] = vyB2;
  vN[wv][0][lane * 3 + 0] = vyA0; vN[wv][0][lane * 3 + 1] = vyA1; vN[wv][0][lane * 3 + 2] = vyA2;
  vN[wv][1][lane * 3 + 0] = vyB0; vN[wv][1][lane * 3 + 1] = vyB1; vN[wv][1][lane * 3 + 2] = vyB2;
  // ---- stage agg_t ----
  stg[wv][0][lane] = btA0; stg[wv][0][64 + lane] = btA1;
  if (lane < 32) stg[wv][0][128 + lane] = btA2;
  stg[wv][1][lane] = btB0; stg[wv][1][64 + lane] = btB1;
  if (lane < 32) stg[wv][1][128 + lane] = btB2;
  asm volatile("s_waitcnt lgkmcnt(0)" ::: "memory");
  // ---- t-matmul: half per node ----
  float at0 = to0, at1 = to1, at2 = to2, at3 = to3, at4 = to4;
  #pragma unroll 4
  for (int c = 0; c < 32; c++) {
    float w = Wo_t[c * 32 + lt];
    at0 += stg[wv][nh][c * 5 + 0] * w;
    at1 += stg[wv][nh][c * 5 + 1] * w;
    at2 += stg[wv][nh][c * 5 + 2] * w;
    at3 += stg[wv][nh][c * 5 + 3] * w;
    at4 += stg[wv][nh][c * 5 + 4] * w;
  }
  // ---- RMS(t): reduce within 32-lane half ----
  float ssqt = at0 * at0 + at1 * at1 + at2 * at2 + at3 * at3 + at4 * at4;
  #pragma unroll
  for (int m = 1; m < 32; m <<= 1) ssqt += __shfl_xor(ssqt, m);
  float rit = rsqrtf(ssqt / 32.0f + 1e-6f);
  float gt = g_t[lt];
  float ty0 = at0 * rit * gt, ty1 = at1 * rit * gt, ty2 = at2 * rit * gt;
  float ty3 = at3 * rit * gt, ty4 = at4 * rit * gt;
  t[(size_t)nt * 160 + lt * 5 + 0] = ty0;
  t[(size_t)nt * 160 + lt * 5 + 1] = ty1;
  t[(size_t)nt * 160 + lt * 5 + 2] = ty2;
  t[(size_t)nt * 160 + lt * 5 + 3] = ty3;
  t[(size_t)nt * 160 + lt * 5 + 4] = ty4;
  tN[wv][nh][lt * 5 + 0] = ty0;
  tN[wv][nh][lt * 5 + 1] = ty1;
  tN[wv][nh][lt * 5 + 2] = ty2;
  tN[wv][nh][lt * 5 + 3] = ty3;
  tN[wv][nh][lt * 5 + 4] = ty4;
  asm volatile("s_waitcnt lgkmcnt(0)" ::: "memory");
  // ---- transforms for next layer ----
  {
    float cA0 = 0.f, cA1 = 0.f, cB0 = 0.f, cB1 = 0.f;
    #pragma unroll 8
    for (int c = 0; c < 128; c++) {
      float w0 = Ws_src[c * 128 + lane];
      float w1 = Ws_src[c * 128 + 64 + lane];
      float aA = sN[wv][0][c], aB = sN[wv][1][c];
      cA0 += aA * w0; cA1 += aA * w1;
      cB0 += aB * w0; cB1 += aB * w1;
    }
    sWsrc[(size_t)n0 * 128 + lane] = cA0;
    sWsrc[(size_t)n0 * 128 + 64 + lane] = cA1;
    sWsrc[(size_t)n1 * 128 + lane] = cB0;
    sWsrc[(size_t)n1 * 128 + 64 + lane] = cB1;
  }
  {
    float cvA = 0.f, cvB = 0.f, ct = 0.f;
    #pragma unroll 8
    for (int c = 0; c < 128; c++) {
      float wvv = Ws_v[c * 64 + lane];
      float wtt = Ws_t[c * 32 + lt];
      float aA = sN[wv][0][c], aB = sN[wv][1][c];
      cvA += aA * wvv; cvB += aB * wvv;
      ct += sN[wv][nh][c] * wtt;
    }
    sWv[(size_t)n0 * 64 + lane] = cvA;
    sWv[(size_t)n1 * 64 + lane] = cvB;
    sWt[(size_t)nt * 32 + lt] = ct;
  }
  {
    float wA0 = 0.f, wA1 = 0.f, wA2 = 0.f, wB0 = 0.f, wB1 = 0.f, wB2 = 0.f;
    #pragma unroll 8
    for (int c = 0; c < 64; c++) {
      float w = Wv_v[c * 64 + lane];
      wA0 += vN[wv][0][c * 3 + 0] * w;
      wA1 += vN[wv][0][c * 3 + 1] * w;
      wA2 += vN[wv][0][c * 3 + 2] * w;
      wB0 += vN[wv][1][c * 3 + 0] * w;
      wB1 += vN[wv][1][c * 3 + 1] * w;
      wB2 += vN[wv][1][c * 3 + 2] * w;
    }
    vW[(size_t)n0 * 192 + lane] = wA0;
    vW[(size_t)n0 * 192 + 64 + lane] = wA1;
    vW[(size_t)n0 * 192 + 128 + lane] = wA2;
    vW[(size_t)n1 * 192 + lane] = wB0;
    vW[(size_t)n1 * 192 + 64 + lane] = wB1;
    vW[(size_t)n1 * 192 + 128 + lane] = wB2;
  }
  {
    float u0 = 0.f, u1 = 0.f, u2 = 0.f, u3 = 0.f, u4 = 0.f;
    #pragma unroll 4
    for (int c = 0; c < 32; c++) {
      float w = Wt_t[c * 32 + lt];
      u0 += tN[wv][nh][c * 5 + 0] * w;
      u1 += tN[wv][nh][c * 5 + 1] * w;
      u2 += tN[wv][nh][c * 5 + 2] * w;
      u3 += tN[wv][nh][c * 5 + 3] * w;
      u4 += tN[wv][nh][c * 5 + 4] * w;
    }
    tW[(size_t)nt * 160 + lt] = u0;
    tW[(size_t)nt * 160 + 32 + lt] = u1;
    tW[(size_t)nt * 160 + 64 + lt] = u2;
    tW[(size_t)nt * 160 + 96 + lt] = u3;
    tW[(size_t)nt * 160 + 128 + lt] = u4;
  }
}

// ---------------- node update, final layer: wave-per-2-nodes, 2 waves/block ----------------
__global__ __launch_bounds__(128) void k_node_up(
    float* __restrict__ s, float* __restrict__ v, float* __restrict__ t,
    const float* __restrict__ agg_s, const float* __restrict__ agg_v,
    const float* __restrict__ agg_t, const float* __restrict__ Wo_s,
    const float* __restrict__ Wo_v, const float* __restrict__ Wo_t,
    const float* __restrict__ g_s, const float* __restrict__ b_s,
    const float* __restrict__ g_v, const float* __restrict__ g_t) {
  int wv = threadIdx.x >> 6, lane = threadIdx.x & 63;
  int lt = lane & 31, nh = lane >> 5;
  int n0 = (blockIdx.x * 2 + wv) * 2;
  int n1 = n0 + 1;
  int nt = n0 + nh;
  __shared__ float stg[2][2][192];
  float aS0 = agg_s[(size_t)n0 * 128 + lane];
  float aS1 = agg_s[(size_t)n0 * 128 + 64 + lane];
  float bS0 = agg_s[(size_t)n1 * 128 + lane];
  float bS1 = agg_s[(size_t)n1 * 128 + 64 + lane];
  float sA0 = s[(size_t)n0 * 128 + lane];
  float sA1 = s[(size_t)n0 * 128 + 64 + lane];
  float sB0 = s[(size_t)n1 * 128 + lane];
  float sB1 = s[(size_t)n1 * 128 + 64 + lane];
  stg[wv][0][lane] = aS0; stg[wv][0][64 + lane] = aS1;
  stg[wv][1][lane] = bS0; stg[wv][1][64 + lane] = bS1;
  asm volatile("s_waitcnt lgkmcnt(0)" ::: "memory");
  #pragma unroll 8
  for (int c = 0; c < 128; c++) {
    float w0 = Wo_s[c * 128 + lane];
    float w1 = Wo_s[c * 128 + 64 + lane];
    float ax = stg[wv][0][c], bx = stg[wv][1][c];
    sA0 += ax * w0; sA1 += ax * w1;
    sB0 += bx * w0; sB1 += bx * w1;
  }
  float avA0 = agg_v[(size_t)n0 * 192 + lane];
  float avA1 = agg_v[(size_t)n0 * 192 + 64 + lane];
  float avA2 = agg_v[(size_t)n0 * 192 + 128 + lane];
  float avB0 = agg_v[(size_t)n1 * 192 + lane];
  float avB1 = agg_v[(size_t)n1 * 192 + 64 + lane];
  float avB2 = agg_v[(size_t)n1 * 192 + 128 + lane];
  float voA0 = v[(size_t)n0 * 192 + lane * 3 + 0];
  float voA1 = v[(size_t)n0 * 192 + lane * 3 + 1];
  float voA2 = v[(size_t)n0 * 192 + lane * 3 + 2];
  float voB0 = v[(size_t)n1 * 192 + lane * 3 + 0];
  float voB1 = v[(size_t)n1 * 192 + lane * 3 + 1];
  float voB2 = v[(size_t)n1 * 192 + lane * 3 + 2];
  float smA = sA0 + sA1, sqA = sA0 * sA0 + sA1 * sA1;
  float smB = sB0 + sB1, sqB = sB0 * sB0 + sB1 * sB1;
  #pragma unroll
  for (int m = 1; m < 64; m <<= 1) {
    smA += __shfl_xor(smA, m); sqA += __shfl_xor(sqA, m);
    smB += __shfl_xor(smB, m); sqB += __shfl_xor(sqB, m);
  }
  float muA = smA / 128.0f, muB = smB / 128.0f;
  float varA = sqA / 128.0f - muA * muA; if (varA < 0.f) varA = 0.f;
  float varB = sqB / 128.0f - muB * muB; if (varB < 0.f) varB = 0.f;
  float riA = rsqrtf(varA + 1e-6f), riB = rsqrtf(varB + 1e-6f);
  float gs0 = g_s[lane], gs1 = g_s[64 + lane];
  float bs0 = b_s[lane], bs1 = b_s[64 + lane];
  s[(size_t)n0 * 128 + lane] = (sA0 - muA) * riA * gs0 + bs0;
  s[(size_t)n0 * 128 + 64 + lane] = (sA1 - muA) * riA * gs1 + bs1;
  s[(size_t)n1 * 128 + lane] = (sB0 - muB) * riB * gs0 + bs0;
  s[(size_t)n1 * 128 + 64 + lane] = (sB1 - muB) * riB * gs1 + bs1;
  stg[wv][0][lane] = avA0; stg[wv][0][64 + lane] = avA1; stg[wv][0][128 + lane] = avA2;
  stg[wv][1][lane] = avB0; stg[wv][1][64 + lane] = avB1; stg[wv][1][128 + lane] = avB2;
  asm volatile("s_waitcnt lgkmcnt(0)" ::: "memory");
  float vA0 = voA0, vA1 = voA1, vA2 = voA2;
  float vB0 = voB0, vB1 = voB1, vB2 = voB2;
  #pragma unroll 8
  for (int c = 0; c < 64; c++) {
    float w = Wo_v[c * 64 + lane];
    vA0 += stg[wv][0][c * 3 + 0] * w;
    vA1 += stg[wv][0][c * 3 + 1] * w;
    vA2 += stg[wv][0][c * 3 + 2] * w;
    vB0 += stg[wv][1][c * 3 + 0] * w;
    vB1 += stg[wv][1][c * 3 + 1] * w;
    vB2 += stg[wv][1][c * 3 + 2] * w;
  }
  float btA0 = agg_t[(size_t)n0 * 160 + lane];
  float btA1 = agg_t[(size_t)n0 * 160 + 64 + lane];
  float btA2 = (lane < 32) ? agg_t[(size_t)n0 * 160 + 128 + lane] : 0.f;
  float btB0 = agg_t[(size_t)n1 * 160 + lane];
  float btB1 = agg_t[(size_t)n1 * 160 + 64 + lane];
  float btB2 = (lane < 32) ? agg_t[(size_t)n1 * 160 + 128 + lane] : 0.f;
  float to0 = t[(size_t)nt * 160 + lt * 5 + 0];
  float to1 = t[(size_t)nt * 160 + lt * 5 + 1];
  float to2 = t[(size_t)nt * 160 + lt * 5 + 2];
  float to3 = t[(size_t)nt * 160 + lt * 5 + 3];
  float to4 = t[(size_t)nt * 160 + lt * 5 + 4];
  float ssqA = vA0 * vA0 + vA1 * vA1 + vA2 * vA2;
  float ssqB = vB0 * vB0 + vB1 * vB1 + vB2 * vB2;
  #pragma unroll
  for (int m = 1; m < 64; m <<= 1) {
    ssqA += __shfl_xor(ssqA, m);
    ssqB += __shfl_xor(ssqB, m);
  }
  float rivA = rsqrtf(ssqA / 64.0f + 1e-6f);
  float rivB = rsqrtf(ssqB / 64.0f + 1e-6f);
  float gv = g_v[lane];
  v[(size_t)n0 * 192 + lane * 3 + 0] = vA0 * rivA * gv;
  v[(size_t)n0 * 192 + lane * 3 + 1] = vA1 * rivA * gv;
  v[(size_t)n0 * 192 + lane * 3 + 2] = vA2 * rivA * gv;
  v[(size_t)n1 * 192 + lane * 3 + 0] = vB0 * rivB * gv;
  v[(size_t)n1 * 192 + lane * 3 + 1] = vB1 * rivB * gv;
  v[(size_t)n1 * 192 + lane * 3 + 2] = vB2 * rivB * gv;
  stg[wv][0][lane] = btA0; stg[wv][0][64 + lane] = btA1;
  if (lane < 32) stg[wv][0][128 + lane] = btA2;
  stg[wv][1][lane] = btB0; stg[wv][1][64 + lane] = btB1;
  if (lane < 32) stg[wv][1][128 + lane] = btB2;
  asm volatile("s_waitcnt lgkmcnt(0)" ::: "memory");
  float at0 = to0, at1 = to1, at2 = to2, at3 = to3, at4 = to4;
  #pragma unroll 4
  for (int c = 0; c < 32; c++) {
    float w = Wo_t[c * 32 + lt];
    at0 += stg[wv][nh][c * 5 + 0] * w;
    at1 += stg[wv][nh][c * 5 + 1] * w;
    at2 += stg[wv][nh][c * 5 + 2] * w;
    at3 += stg[wv][nh][c * 5 + 3] * w;
    at4 += stg[wv][nh][c * 5 + 4] * w;
  }
  float ssqt = at0 * at0 + at1 * at1 + at2 * at2 + at3 * at3 + at4 * at4;
  #pragma unroll
  for (int m = 1; m < 32; m <<= 1) ssqt += __shfl_xor(ssqt, m);
  float rit = rsqrtf(ssqt / 32.0f + 1e-6f);
  float gt = g_t[lt];
  t[(size_t)nt * 160 + lt * 5 + 0] = at0 * rit * gt;
  t[(size_t)nt * 160 + lt * 5 + 1] = at1 * rit * gt;
  t[(size_t)nt * 160 + lt * 5 + 2] = at2 * rit * gt;
  t[(size_t)nt * 160 + lt * 5 + 3] = at3 * rit * gt;
  t[(size_t)nt * 160 + lt * 5 + 4] = at4 * rit * gt;
}

// ---------------- readout (conflict-free mapping) ----------------
__global__ __launch_bounds__(256) void k_readout(
    const float* __restrict__ s, const int* __restrict__ batch,
    const float* __restrict__ W_feat, const float* __restrict__ b_feat,
    const float* __restrict__ W_out1, const float* __restrict__ b_out1,
    float* __restrict__ graph) {
  __shared__ float st[64][129];
  __shared__ float gacc[GG];
  int nb = blockIdx.x * 64;
  int fb = blockIdx.y;  // 0..7
  for (int idx = threadIdx.x; idx < 64 * 128; idx += 256) {
    int nl = idx >> 7, c = idx & 127;
    int n = nb + nl;
    st[nl][c] = (n < NN) ? s[(size_t)n * 128 + c] : 0.f;
  }
  if (threadIdx.x < GG) gacc[threadIdx.x] = 0.f;
  __syncthreads();
  int wv = threadIdx.x >> 6, lane = threadIdx.x & 63;
  int fg = lane & 15;
  int ns = lane >> 4;
  int f0 = fb * 64 + fg * 4;
  int nodeb = wv * 16 + ns * 4;
  float acc[4][4];
  #pragma unroll
  for (int nn = 0; nn < 4; nn++)
    #pragma unroll
    for (int k = 0; k < 4; k++) acc[nn][k] = b_feat[f0 + k];
  #pragma unroll 4
  for (int c = 0; c < 128; c++) {
    float4 wq = *(const float4*)&W_feat[(size_t)c * 512 + f0];
    #pragma unroll
    for (int nn = 0; nn < 4; nn++) {
      float sv = st[nodeb + nn][c];
      acc[nn][0] += sv * wq.x;
      acc[nn][1] += sv * wq.y;
      acc[nn][2] += sv * wq.z;
      acc[nn][3] += sv * wq.w;
    }
  }
  float wo[4];
  #pragma unroll
  for (int k = 0; k < 4; k++) wo[k] = W_out1[f0 + k];
  float ep[4];
  #pragma unroll
  for (int nn = 0; nn < 4; nn++) {
    float p = 0.f;
    #pragma unroll
    for (int k = 0; k < 4; k++) p += fgelu(acc[nn][k]) * wo[k];
    ep[nn] = p;
  }
  #pragma unroll
  for (int mm = 1; mm < 16; mm <<= 1) {
    #pragma unroll
    for (int nn = 0; nn < 4; nn++) ep[nn] += __shfl_xor(ep[nn], mm);
  }
  if (fg == 0) {
    #pragma unroll
    for (int nn = 0; nn < 4; nn++) {
      int n = nb + nodeb + nn;
      if (n < NN) {
        float e = ep[nn];
        if (fb == 0) e += b_out1[0];
        atomicAdd(&gacc[batch[n]], e);
      }
    }
  }
  __syncthreads();
  if (threadIdx.x < GG && gacc[threadIdx.x] != 0.f)
    atomicAdd(&graph[threadIdx.x], gacc[threadIdx.x]);
}

__global__ void k_finalize(const float* __restrict__ graph, const float* __restrict__ W_read,
                           const float* __restrict__ b_read, float* __restrict__ out) {
  int g = threadIdx.x;
  if (g < GG) out[g] = graph[g] * W_read[0] + b_read[0];
}

// ---------------- host ----------------
extern "C" void kernel_launch(void* const* d_in, const int* in_sizes, int n_in,
                              void* d_out, int out_size, void* d_ws, size_t ws_size,
                              hipStream_t stream) {
  const float* pos = (const float*)d_in[0];
  const int* node_atom = (const int*)d_in[1];
  const int* batch = (const int*)d_in[2];
  const int* esrc = (const int*)d_in[3];
  const int* edst = (const int*)d_in[4];
  const float* atom_emb = (const float*)d_in[5];
  const float* Wrad1 = (const float*)d_in[6];
  const float* brad1 = (const float*)d_in[7];
  const float* Wrad2 = (const float*)d_in[8];
  const float* brad2 = (const float*)d_in[9];
  const float* Ws_src = (const float*)d_in[10];
  const float* Ww_s = (const float*)d_in[11];
  const float* Ws_v = (const float*)d_in[12];
  const float* Ww_v = (const float*)d_in[13];
  const float* Wv_v = (const float*)d_in[14];
  const float* Ww_vv = (const float*)d_in[15];
  const float* Ws_t = (const float*)d_in[16];
  const float* Ww_t = (const float*)d_in[17];
  const float* Wt_t = (const float*)d_in[18];
  const float* Ww_tt = (const float*)d_in[19];
  const float* attn_a = (const float*)d_in[20];
  const float* Wo_s = (const float*)d_in[21];
  const float* Wo_v = (const float*)d_in[22];
  const float* Wo_t = (const float*)d_in[23];
  const float* g_s = (const float*)d_in[24];
  const float* b_s = (const float*)d_in[25];
  const float* g_v = (const float*)d_in[26];
  const float* g_t = (const float*)d_in[27];
  const float* W_feat = (const float*)d_in[28];
  const float* b_feat = (const float*)d_in[29];
  const float* W_out1 = (const float*)d_in[30];
  const float* b_out1 = (const float*)d_in[31];
  const float* W_read = (const float*)d_in[32];
  const float* b_read = (const float*)d_in[33];
  float* out = (float*)d_out;

  char* base = (char*)d_ws;
  size_t off = 0;
  auto alloc = [&](size_t bytes) -> char* {
    off = (off + 255) & ~(size_t)255;
    char* p = base + off;
    off += bytes;
    return p;
  };
  // ---- zero-init group A (ints), contiguous ----
  int* deg = (int*)alloc(NN * 4);
  int* cursor = (int*)alloc(NN * 4);
  int* dbkt = (int*)alloc(128 * 4);
  int* dbcur = (int*)alloc(128 * 4);
  float* graph = (float*)alloc(GG * 4);
  char* zeroA_end = base + off;
  // ---- zero-init group B (floats), contiguous ----
  float* v = (float*)alloc((size_t)NN * 192 * 4);
  float* t = (float*)alloc((size_t)NN * 160 * 4);
  float* vW = (float*)alloc((size_t)NN * 192 * 4);
  float* tW = (float*)alloc((size_t)NN * 160 * 4);
  char* zeroB_end = base + off;
  // ---- rest ----
  int* row_off = (int*)alloc((NN + 1) * 4);
  float* d_csr = (float*)alloc((size_t)EE * 4);
  int* src_csr = (int*)alloc((size_t)EE * 4);
  int* dst_csr = (int*)alloc((size_t)EE * 4);
  int* acnt = (int*)alloc(NN * 4);
  int* act_off = (int*)alloc((NN + 1) * 4);
  int* act_idx = (int*)alloc((size_t)EE * 4);
  int* dboff = (int*)alloc(129 * 4);
  int* order = (int*)alloc(NN * 4);
  float* d_a = (float*)alloc((size_t)EE * 4);
  int* src_a = (int*)alloc((size_t)EE * 4);
  float* sh_a = (float*)alloc((size_t)EE * 8 * 4);
  float* wtab = (float*)alloc((size_t)LL * TABN * 64 * 4);
  float* gs_tab = (float*)alloc((size_t)LL * TABN * 128 * 4);
  float* gv_tab = (float*)alloc((size_t)LL * TABN * 128 * 4);
  float* gt_tab = (float*)alloc((size_t)LL * TABN * 64 * 4);
  float* s = (float*)alloc((size_t)NN * 128 * 4);
  float* sWsrc = (float*)alloc((size_t)NN * 128 * 4);
  float* sWv = (float*)alloc((size_t)NN * 64 * 4);
  float* sWt = (float*)alloc((size_t)NN * 32 * 4);
  float* agg_s = (float*)alloc((size_t)NN * 128 * 4);
  float* agg_v = (float*)alloc((size_t)NN * 192 * 4);
  float* agg_t = (float*)alloc((size_t)NN * 160 * 4);

  // two consolidated memsets (cover alignment pads harmlessly)
  hipMemsetAsync(deg, 0, (size_t)(zeroA_end - (char*)deg), stream);
  hipMemsetAsync(v, 0, (size_t)(zeroB_end - (char*)v), stream);

  k_hist<<<(EE + 255) / 256, 256, 0, stream>>>(edst, deg);
  k_scan<<<1, 1024, 0, stream>>>(deg, row_off, NN);
  k_scatter<<<(EE + 255) / 256, 256, 0, stream>>>(esrc, edst, pos, row_off, cursor,
                                                  d_csr, src_csr, dst_csr);
  k_act_cnt<<<(NN + 255) / 256, 256, 0, stream>>>(row_off, d_csr, acnt, dbkt);
  k_scan2<<<2, 1024, 0, stream>>>(acnt, act_off, NN, dbkt, dboff, 128);
  k_act_fill<<<(NN + 255) / 256, 256, 0, stream>>>(row_off, d_csr, act_off, act_idx,
                                                   acnt, dboff, dbcur, order);
  k_geom_act<<<(EE + 255) / 256, 256, 0, stream>>>(act_idx, src_csr, dst_csr, pos, act_off,
                                                   d_a, src_a, sh_a);
  k_build_wtab<<<LL * (TABN / 16), 256, 0, stream>>>(Wrad1, brad1, Wrad2, brad2, wtab);
  k_build_tabs<<<LL * (TABN / EB), 320, 0, stream>>>(wtab, Ww_s, Ww_v, Ww_vv, Ww_t, Ww_tt,
                                                     gs_tab, gv_tab, gt_tab);
  // layer-0 transforms fused with s init (v/t are zero; vW/tW zeroed by group-B memset)
  k_node_tf0<<<NN / 16, 256, 0, stream>>>(node_atom, atom_emb, s, Ws_src, Ws_v, Ws_t,
                                          sWsrc, sWv, sWt);

  for (int l = 0; l < LL; l++) {
    const float* gsL = gs_tab + (size_t)l * TABN * 128;
    const float* gvL = gv_tab + (size_t)l * TABN * 128;
    const float* gtL = gt_tab + (size_t)l * TABN * 64;
    k_mega<<<NN / 2, 128, 0, stream>>>(row_off, act_off, order, src_a, d_a, gsL, gvL, gtL,
                                       attn_a + (size_t)l * 128,
                                       sWsrc, sWv, sWt, vW, tW, sh_a, agg_s, agg_v, agg_t);
    if (l < LL - 1) {
      k_node_fused<<<NN / 4, 128, 0, stream>>>(
          s, v, t, agg_s, agg_v, agg_t,
          Wo_s + (size_t)l * 128 * 128, Wo_v + (size_t)l * 64 * 64,
          Wo_t + (size_t)l * 32 * 32,
          g_s + (size_t)l * 128, b_s + (size_t)l * 128,
          g_v + (size_t)l * 64, g_t + (size_t)l * 32,
          Ws_src + (size_t)(l + 1) * 128 * 128, Ws_v + (size_t)(l + 1) * 128 * 64,
          Ws_t + (size_t)(l + 1) * 128 * 32, Wv_v + (size_t)(l + 1) * 64 * 64,
          Wt_t + (size_t)(l + 1) * 32 * 32,
          sWsrc, sWv, sWt, vW, tW);
    } else {
      k_node_up<<<NN / 4, 128, 0, stream>>>(s, v, t, agg_s, agg_v, agg_t,
                                            Wo_s + (size_t)l * 128 * 128,
                                            Wo_v + (size_t)l * 64 * 64, Wo_t + (size_t)l * 32 * 32,
                                            g_s + (size_t)l * 128, b_s + (size_t)l * 128,
                                            g_v + (size_t)l * 64, g_t + (size_t)l * 32);
    }
  }
  dim3 rg((NN + 63) / 64, 8);
  k_readout<<<rg, 256, 0, stream>>>(s, batch, W_feat, b_feat, W_out1, b_out1, graph);
  k_finalize<<<1, 64, 0, stream>>>(graph, W_read, b_read, out);
}

// Round 13
// 969.682 us; speedup vs baseline: 1.0874x; 1.0099x over previous
//
#include <hip/hip_runtime.h>
#include <math.h>

#define NN 10000
#define EE 320000
#define GG 32
#define LL 6
#define TABN 2048
#define TABB (TABN / 64)
#define DTAB 5.45f
#define DCUT 5.4f

__device__ __forceinline__ float fsilu(float x) { return x / (1.0f + __expf(-x)); }
__device__ __forceinline__ float fgelu(float x) {
  float y = 0.7978845608f * (x + 0.044715f * x * x * x);
  float t = 1.0f - 2.0f / (__expf(2.0f * y) + 1.0f);
  return 0.5f * x * (1.0f + t);
}

// ---------------- CSR build ----------------
__global__ void k_hist(const int* __restrict__ dst, int* __restrict__ deg) {
  int e = blockIdx.x * blockDim.x + threadIdx.x;
  if (e < EE) atomicAdd(&deg[dst[e]], 1);
}

// parallel scan: each thread serially scans a chunk, then one scan of totals
__global__ void k_scan(const int* __restrict__ cnt, int* __restrict__ off, int n) {
  __shared__ int tsum[1024];
  int chunk = (n + 1023) / 1024;
  int base = (int)threadIdx.x * chunk;
  int local = 0;
  for (int i = 0; i < chunk; i++) {
    int idx = base + i;
    local += (idx < n) ? cnt[idx] : 0;
  }
  tsum[threadIdx.x] = local;
  __syncthreads();
  for (int o = 1; o < 1024; o <<= 1) {
    int tv = (threadIdx.x >= (unsigned)o) ? tsum[threadIdx.x - o] : 0;
    __syncthreads();
    tsum[threadIdx.x] += tv;
    __syncthreads();
  }
  int run = tsum[threadIdx.x] - local;  // exclusive prefix of this chunk
  for (int i = 0; i < chunk; i++) {
    int idx = base + i;
    if (idx < n) {
      run += cnt[idx];
      off[idx + 1] = run;
    }
  }
  if (threadIdx.x == 0) off[0] = 0;
}

// two independent scans in one launch (block 0: A, block 1: B)
__global__ void k_scan2(const int* __restrict__ cntA, int* __restrict__ offA, int nA,
                        const int* __restrict__ cntB, int* __restrict__ offB, int nB) {
  const int* cnt = (blockIdx.x == 0) ? cntA : cntB;
  int* off = (blockIdx.x == 0) ? offA : offB;
  int n = (blockIdx.x == 0) ? nA : nB;
  __shared__ int tsum[1024];
  int chunk = (n + 1023) / 1024;
  int base = (int)threadIdx.x * chunk;
  int local = 0;
  for (int i = 0; i < chunk; i++) {
    int idx = base + i;
    local += (idx < n) ? cnt[idx] : 0;
  }
  tsum[threadIdx.x] = local;
  __syncthreads();
  for (int o = 1; o < 1024; o <<= 1) {
    int tv = (threadIdx.x >= (unsigned)o) ? tsum[threadIdx.x - o] : 0;
    __syncthreads();
    tsum[threadIdx.x] += tv;
    __syncthreads();
  }
  int run = tsum[threadIdx.x] - local;
  for (int i = 0; i < chunk; i++) {
    int idx = base + i;
    if (idx < n) {
      run += cnt[idx];
      off[idx + 1] = run;
    }
  }
  if (threadIdx.x == 0) off[0] = 0;
}

// scatter + geometry fused: one pass assigns CSR slots and computes distances
__global__ void k_scatter(const int* __restrict__ esrc, const int* __restrict__ edst,
                          const float* __restrict__ pos, const int* __restrict__ row_off,
                          int* __restrict__ cursor, float* __restrict__ d_csr,
                          int* __restrict__ src_csr, int* __restrict__ dst_csr) {
  int e = blockIdx.x * blockDim.x + threadIdx.x;
  if (e < EE) {
    int d = edst[e];
    int s = esrc[e];
    int p = atomicAdd(&cursor[d], 1);
    int slot = row_off[d] + p;
    float rx = pos[d * 3 + 0] - pos[s * 3 + 0];
    float ry = pos[d * 3 + 1] - pos[s * 3 + 1];
    float rz = pos[d * 3 + 2] - pos[s * 3 + 2];
    d_csr[slot] = sqrtf(rx * rx + ry * ry + rz * rz + 1e-6f);
    src_csr[slot] = s;
    dst_csr[slot] = d;
  }
}

// ---------------- active-edge count + degree histogram (fused) ----------------
__global__ void k_act_cnt(const int* __restrict__ row_off, const float* __restrict__ d_csr,
                          int* __restrict__ acnt, int* __restrict__ dbkt) {
  int n = blockIdx.x * blockDim.x + threadIdx.x;
  if (n >= NN) return;
  int c = 0;
  for (int j = row_off[n]; j < row_off[n + 1]; ++j) c += (d_csr[j] < DCUT) ? 1 : 0;
  acnt[n] = c;
  int b = 127 - min(127, c);
  atomicAdd(&dbkt[b], 1);
}

// act_fill + degree-order scatter fused (same per-node domain, independent outputs)
__global__ void k_act_fill(const int* __restrict__ row_off, const float* __restrict__ d_csr,
                           const int* __restrict__ act_off, int* __restrict__ act_idx,
                           const int* __restrict__ acnt, const int* __restrict__ dboff,
                           int* __restrict__ dbcur, int* __restrict__ order) {
  int n = blockIdx.x * blockDim.x + threadIdx.x;
  if (n >= NN) return;
  int a = act_off[n];
  for (int j = row_off[n]; j < row_off[n + 1]; ++j)
    if (d_csr[j] < DCUT) act_idx[a++] = j;
  int b = 127 - min(127, acnt[n]);
  int p = atomicAdd(&dbcur[b], 1);
  order[dboff[b] + p] = n;
}

// ---------------- compacted geometry per active edge (direct CSR arrays) ----------------
__global__ void k_geom_act(const int* __restrict__ act_idx, const int* __restrict__ src_csr,
                           const int* __restrict__ dst_csr, const float* __restrict__ pos,
                           const int* __restrict__ act_off, float* __restrict__ d_a,
                           int* __restrict__ src_a, float* __restrict__ sh_a) {
  int a = blockIdx.x * blockDim.x + threadIdx.x;
  if (a >= act_off[NN]) return;
  int j = act_idx[a];
  int s = src_csr[j], dd = dst_csr[j];
  float rx = pos[dd * 3 + 0] - pos[s * 3 + 0];
  float ry = pos[dd * 3 + 1] - pos[s * 3 + 1];
  float rz = pos[dd * 3 + 2] - pos[s * 3 + 2];
  float d = sqrtf(rx * rx + ry * ry + rz * rz + 1e-6f);
  float inv = 1.0f / d;
  float x = rx * inv, y = ry * inv, z = rz * inv;
  d_a[a] = d;
  src_a[a] = s;
  const float s3 = 1.7320508075688772f;
  const float s5 = 2.23606797749979f;
  const float s15 = 3.872983346207417f;
  sh_a[a * 8 + 0] = s3 * x;
  sh_a[a * 8 + 1] = s3 * y;
  sh_a[a * 8 + 2] = s3 * z;
  sh_a[a * 8 + 3] = s15 * x * y;
  sh_a[a * 8 + 4] = s15 * y * z;
  sh_a[a * 8 + 5] = 0.5f * s5 * (3.0f * z * z - 1.0f);
  sh_a[a * 8 + 6] = s15 * x * z;
  sh_a[a * 8 + 7] = 0.5f * s15 * (x * x - y * y);
}

// ---------------- radial MLP table w(d): 16 entries/block for parallelism ----------------
__global__ void k_build_wtab(const float* __restrict__ Wrad1, const float* __restrict__ brad1,
                             const float* __restrict__ Wrad2, const float* __restrict__ brad2,
                             float* __restrict__ wtab) {
  int l = blockIdx.x / (TABN / 16);
  int blk = blockIdx.x % (TABN / 16);
  __shared__ float W1[128 * 64];
  __shared__ float W2[64 * 64];
  __shared__ float b1[64], b2[64];
  __shared__ float rbf_s[4][128];
  __shared__ float h_s[4][64];
  const float* w1p = Wrad1 + (size_t)l * 128 * 64;
  const float* w2p = Wrad2 + (size_t)l * 64 * 64;
  for (int i = threadIdx.x; i < 128 * 64; i += 256) W1[i] = w1p[i];
  for (int i = threadIdx.x; i < 64 * 64; i += 256) W2[i] = w2p[i];
  if (threadIdx.x < 64) {
    b1[threadIdx.x] = brad1[(size_t)l * 64 + threadIdx.x];
    b2[threadIdx.x] = brad2[(size_t)l * 64 + threadIdx.x];
  }
  __syncthreads();
  int wv = threadIdx.x >> 6, lane = threadIdx.x & 63;
  const float width = 5.0f / 128.0f;
  for (int k = wv; k < 16; k += 4) {
    int i = blk * 16 + k;
    float d = (float)i * (DTAB / (float)(TABN - 1));
    float c0 = (5.0f * (float)lane) / 127.0f;
    float c1 = (5.0f * (float)(lane + 64)) / 127.0f;
    float t0 = (d - c0) / width, t1 = (d - c1) / width;
    rbf_s[wv][lane] = __expf(-0.5f * t0 * t0);
    rbf_s[wv][lane + 64] = __expf(-0.5f * t1 * t1);
    float acc = b1[lane];
    #pragma unroll 8
    for (int i2 = 0; i2 < 128; i2++) acc += rbf_s[wv][i2] * W1[i2 * 64 + lane];
    acc = fsilu(acc);
    h_s[wv][lane] = acc;
    float acc2 = b2[lane];
    #pragma unroll 8
    for (int i2 = 0; i2 < 64; i2++) acc2 += h_s[wv][i2] * W2[i2 * 64 + lane];
    wtab[((size_t)l * TABN + i) * 64 + lane] = fsilu(acc2);
  }
}

// ---------------- fused product-table build: gs, gv, gt in one kernel ----------------
#define EB 8
__global__ __launch_bounds__(320) void k_build_tabs(
    const float* __restrict__ wtab, const float* __restrict__ Ww_s,
    const float* __restrict__ Ww_v, const float* __restrict__ Ww_vv,
    const float* __restrict__ Ww_t, const float* __restrict__ Ww_tt,
    float* __restrict__ gs_tab, float* __restrict__ gv_tab, float* __restrict__ gt_tab) {
  int l = blockIdx.x / (TABN / EB);
  int eb = (blockIdx.x % (TABN / EB)) * EB;
  __shared__ float ws[EB][64];
  int tid = threadIdx.x;
  for (int i = tid; i < EB * 64; i += 320)
    ws[i >> 6][i & 63] = wtab[((size_t)l * TABN + eb + (i >> 6)) * 64 + (i & 63)];
  __syncthreads();
  float acc[EB] = {};
  if (tid < 128) {
    int col = tid;
    const float* W = Ww_s + (size_t)l * 64 * 128;
    #pragma unroll 8
    for (int i = 0; i < 64; i++) {
      float w = W[i * 128 + col];
      #pragma unroll
      for (int e = 0; e < EB; e++) acc[e] += ws[e][i] * w;
    }
    #pragma unroll
    for (int e = 0; e < EB; e++)
      gs_tab[((size_t)l * TABN + eb + e) * 128 + col] = acc[e];
  } else if (tid < 256) {
    int cc = tid - 128;
    int c = cc >> 1;
    const float* W = ((cc & 1) ? Ww_vv : Ww_v) + (size_t)l * 64 * 64;
    #pragma unroll 8
    for (int i = 0; i < 64; i++) {
      float w = W[i * 64 + c];
      #pragma unroll
      for (int e = 0; e < EB; e++) acc[e] += ws[e][i] * w;
    }
    #pragma unroll
    for (int e = 0; e < EB; e++)
      gv_tab[((size_t)l * TABN + eb + e) * 128 + cc] = acc[e];
  } else {
    int cc = tid - 256;
    int c = cc >> 1;
    const float* W = ((cc & 1) ? Ww_tt : Ww_t) + (size_t)l * 64 * 32;
    #pragma unroll 8
    for (int i = 0; i < 64; i++) {
      float w = W[i * 32 + c];
      #pragma unroll
      for (int e = 0; e < EB; e++) acc[e] += ws[e][i] * w;
    }
    #pragma unroll
    for (int e = 0; e < EB; e++)
      gt_tab[((size_t)l * TABN + eb + e) * 64 + cc] = acc[e];
  }
}

// ---------------- layer-0 transforms fused with s-init (v = t = 0) ----------------
__global__ __launch_bounds__(256) void k_node_tf0(
    const int* __restrict__ node_atom, const float* __restrict__ atom_emb,
    float* __restrict__ s, const float* __restrict__ Ws_src,
    const float* __restrict__ Ws_v, const float* __restrict__ Ws_t,
    float* __restrict__ sWsrc, float* __restrict__ sWv, float* __restrict__ sWt) {
  int nb = blockIdx.x * 16;
  int tid = threadIdx.x;
  __shared__ float s16[16][129];
  for (int idx = tid; idx < 16 * 128; idx += 256) {
    int n = idx >> 7, c = idx & 127;
    float val = atom_emb[(size_t)node_atom[nb + n] * 128 + c];
    s16[n][c] = val;
    s[(size_t)(nb + n) * 128 + c] = val;
  }
  __syncthreads();
  {
    int col = tid & 127, ng = tid >> 7;
    float acc[8] = {0, 0, 0, 0, 0, 0, 0, 0};
    for (int c = 0; c < 128; c++) {
      float w = Ws_src[c * 128 + col];
      #pragma unroll
      for (int n = 0; n < 8; n++) acc[n] += s16[ng * 8 + n][c] * w;
    }
    #pragma unroll
    for (int n = 0; n < 8; n++) sWsrc[(size_t)(nb + ng * 8 + n) * 128 + col] = acc[n];
  }
  {
    int col = tid & 63, ng = tid >> 6;
    float acc[4] = {0, 0, 0, 0};
    for (int c = 0; c < 128; c++) {
      float w = Ws_v[c * 64 + col];
      #pragma unroll
      for (int n = 0; n < 4; n++) acc[n] += s16[ng * 4 + n][c] * w;
    }
    #pragma unroll
    for (int n = 0; n < 4; n++) sWv[(size_t)(nb + ng * 4 + n) * 64 + col] = acc[n];
  }
  {
    int col = tid & 31, ng = tid >> 5;
    float acc[2] = {0, 0};
    for (int c = 0; c < 128; c++) {
      float w = Ws_t[c * 32 + col];
      acc[0] += s16[ng * 2 + 0][c] * w;
      acc[1] += s16[ng * 2 + 1][c] * w;
    }
    sWt[(size_t)(nb + ng * 2 + 0) * 32 + col] = acc[0];
    sWt[(size_t)(nb + ng * 2 + 1) * 32 + col] = acc[1];
  }
}

// ---------------- mega: single-pass online-softmax, pair-combined update (2 waves/block) ----------------
__global__ __launch_bounds__(128) void k_mega(
    const int* __restrict__ row_off, const int* __restrict__ act_off,
    const int* __restrict__ order,
    const int* __restrict__ src_a, const float* __restrict__ d_a,
    const float* __restrict__ gsL, const float* __restrict__ gvL,
    const float* __restrict__ gtL, const float* __restrict__ attn_l,
    const float* __restrict__ sWsrc, const float* __restrict__ sWv,
    const float* __restrict__ sWt, const float* __restrict__ vW,
    const float* __restrict__ tW, const float* __restrict__ sh_a,
    float* __restrict__ agg_s, float* __restrict__ agg_v, float* __restrict__ agg_t) {
  int wv = threadIdx.x >> 6, lane = threadIdx.x & 63;
  int lt = lane & 31;
  int slot = blockIdx.x * 2 + wv;
  if (slot >= NN) return;
  int n = order[slot];
  int alo = act_off[n], ahi = act_off[n + 1];
  int nact = ahi - alo;
  int ninact = (row_off[n + 1] - row_off[n]) - nact;
  const float sc = (float)(TABN - 1) / DTAB;
  float atnA = attn_l[lane];
  float atnB = attn_l[64 + lane];
  float rm0, rm1, rm2, rm3;
  rm0 = rm1 = rm2 = rm3 = (ninact > 0) ? 0.0f : -1e30f;
  float rs0 = 0.f, rs1 = 0.f, rs2 = 0.f, rs3 = 0.f;
  float as0 = 0.f, as1 = 0.f;
  float av0 = 0.f, av1 = 0.f, av2 = 0.f;
  float at0 = 0.f, at1 = 0.f, at2 = 0.f, at3 = 0.f, at4 = 0.f;
  int a = alo;
  for (; a + 1 < ahi; a += 2) {
    int aA = a, aB = a + 1;
    float dA = d_a[aA], dB = d_a[aB];
    int snA = src_a[aA], snB = src_a[aB];
    float xA = fminf(dA * sc, (float)(TABN - 1) - 1.0f);
    float xB = fminf(dB * sc, (float)(TABN - 1) - 1.0f);
    int iA = (int)xA, iB = (int)xB;
    float fA = xA - (float)iA, fB = xB - (float)iB;
    float g1A = 1.0f - fA, g1B = 1.0f - fB;
    const float* gA = gsL + (size_t)iA * 128;
    const float* gB = gsL + (size_t)iB * 128;
    float gsA_A = gA[lane] * g1A + gA[128 + lane] * fA;
    float gsB_A = gA[64 + lane] * g1A + gA[192 + lane] * fA;
    float gsA_B = gB[lane] * g1B + gB[128 + lane] * fB;
    float gsB_B = gB[64 + lane] * g1B + gB[192 + lane] * fB;
    float m0A = sWsrc[(size_t)snA * 128 + lane] * gsA_A;
    float m1A = sWsrc[(size_t)snA * 128 + 64 + lane] * gsB_A;
    float m0B = sWsrc[(size_t)snB * 128 + lane] * gsA_B;
    float m1B = sWsrc[(size_t)snB * 128 + 64 + lane] * gsB_B;
    const float* gvA = gvL + (size_t)iA * 128;
    const float* gvB = gvL + (size_t)iB * 128;
    float2 pA0 = *(const float2*)&gvA[2 * lane];
    float2 pA1 = *(const float2*)&gvA[128 + 2 * lane];
    float2 pB0 = *(const float2*)&gvB[2 * lane];
    float2 pB1 = *(const float2*)&gvB[128 + 2 * lane];
    float gavA = pA0.x * g1A + pA1.x * fA;
    float gbvA = pA0.y * g1A + pA1.y * fA;
    float gavB = pB0.x * g1B + pB1.x * fB;
    float gbvB = pB0.y * g1B + pB1.y * fB;
    float svA = sWv[(size_t)snA * 64 + lane];
    float svB = sWv[(size_t)snB * 64 + lane];
    float4 s1A = *(const float4*)&sh_a[(size_t)aA * 8];
    float4 s2A = *(const float4*)&sh_a[(size_t)aA * 8 + 4];
    float4 s1B = *(const float4*)&sh_a[(size_t)aB * 8];
    float4 s2B = *(const float4*)&sh_a[(size_t)aB * 8 + 4];
    const float* vpA = &vW[(size_t)snA * 192 + lane];
    const float* vpB = &vW[(size_t)snB * 192 + lane];
    float vA0 = vpA[0], vA1 = vpA[64], vA2 = vpA[128];
    float vB0 = vpB[0], vB1 = vpB[64], vB2 = vpB[128];
    float gatA = 0.f, gbtA = 0.f, gatB = 0.f, gbtB = 0.f;
    float stA = 0.f, stB = 0.f;
    float tA0 = 0.f, tA1 = 0.f, tA2 = 0.f, tA3 = 0.f, tA4 = 0.f;
    float tB0 = 0.f, tB1 = 0.f, tB2 = 0.f, tB3 = 0.f, tB4 = 0.f;
    if (lane < 32) {
      const float* gtA = gtL + (size_t)iA * 64;
      const float* gtB = gtL + (size_t)iB * 64;
      float2 qA0 = *(const float2*)&gtA[2 * lt];
      float2 qA1 = *(const float2*)&gtA[64 + 2 * lt];
      float2 qB0 = *(const float2*)&gtB[2 * lt];
      float2 qB1 = *(const float2*)&gtB[64 + 2 * lt];
      gatA = qA0.x * g1A + qA1.x * fA;
      gbtA = qA0.y * g1A + qA1.y * fA;
      gatB = qB0.x * g1B + qB1.x * fB;
      gbtB = qB0.y * g1B + qB1.y * fB;
      stA = sWt[(size_t)snA * 32 + lane];
      stB = sWt[(size_t)snB * 32 + lane];
      const float* tpA = &tW[(size_t)snA * 160 + lane];
      const float* tpB = &tW[(size_t)snB * 160 + lane];
      tA0 = tpA[0]; tA1 = tpA[32]; tA2 = tpA[64]; tA3 = tpA[96]; tA4 = tpA[128];
      tB0 = tpB[0]; tB1 = tpB[32]; tB2 = tpB[64]; tB3 = tpB[96]; tB4 = tpB[128];
    }
    float p01A = m0A * atnA, p23A = m1A * atnB;
    float p01B = m0B * atnA, p23B = m1B * atnB;
    #pragma unroll
    for (int mm = 1; mm < 32; mm <<= 1) {
      p01A += __shfl_xor(p01A, mm);
      p23A += __shfl_xor(p23A, mm);
      p01B += __shfl_xor(p01B, mm);
      p23B += __shfl_xor(p23B, mm);
    }
    float l0A = __shfl(p01A, 0), l1A = __shfl(p01A, 32);
    float l2A = __shfl(p23A, 0), l3A = __shfl(p23A, 32);
    float l0B = __shfl(p01B, 0), l1B = __shfl(p01B, 32);
    float l2B = __shfl(p23B, 0), l3B = __shfl(p23B, 32);
    // combined two-edge online-softmax update (exactly equivalent to sequential)
    float nm0 = fmaxf(rm0, fmaxf(l0A, l0B));
    float nm1 = fmaxf(rm1, fmaxf(l1A, l1B));
    float nm2 = fmaxf(rm2, fmaxf(l2A, l2B));
    float nm3 = fmaxf(rm3, fmaxf(l3A, l3B));
    float wA0 = __expf(l0A - nm0), wA1 = __expf(l1A - nm1);
    float wA2 = __expf(l2A - nm2), wA3 = __expf(l3A - nm3);
    float wB0 = __expf(l0B - nm0), wB1 = __expf(l1B - nm1);
    float wB2 = __expf(l2B - nm2), wB3 = __expf(l3B - nm3);
    float wSA0 = (lane < 32) ? wA0 : wA1, wSA1 = (lane < 32) ? wA2 : wA3;
    float wSB0 = (lane < 32) ? wB0 : wB1, wSB1 = (lane < 32) ? wB2 : wB3;
    float addS0 = wSA0 * m0A + wSB0 * m0B;
    float addS1 = wSA1 * m1A + wSB1 * m1B;
    float wVA = (lane < 16) ? wA0 : (lane < 32) ? wA1 : (lane < 48) ? wA2 : wA3;
    float wVB = (lane < 16) ? wB0 : (lane < 32) ? wB1 : (lane < 48) ? wB2 : wB3;
    float avvA = svA * gavA, avvB = svB * gavB;
    float addV0 = wVA * (avvA * s1A.x + vA0 * gbvA) + wVB * (avvB * s1B.x + vB0 * gbvB);
    float addV1 = wVA * (avvA * s1A.y + vA1 * gbvA) + wVB * (avvB * s1B.y + vB1 * gbvB);
    float addV2 = wVA * (avvA * s1A.z + vA2 * gbvA) + wVB * (avvB * s1B.z + vB2 * gbvB);
    float wTA = (lane < 8) ? wA0 : (lane < 16) ? wA1 : (lane < 24) ? wA2 : wA3;
    float wTB = (lane < 8) ? wB0 : (lane < 16) ? wB1 : (lane < 24) ? wB2 : wB3;
    float attA = stA * gatA, attB = stB * gatB;
    float addT0 = wTA * (attA * s1A.w + tA0 * gbtA) + wTB * (attB * s1B.w + tB0 * gbtB);
    float addT1 = wTA * (attA * s2A.x + tA1 * gbtA) + wTB * (attB * s2B.x + tB1 * gbtB);
    float addT2 = wTA * (attA * s2A.y + tA2 * gbtA) + wTB * (attB * s2B.y + tB2 * gbtB);
    float addT3 = wTA * (attA * s2A.z + tA3 * gbtA) + wTB * (attB * s2B.z + tB3 * gbtB);
    float addT4 = wTA * (attA * s2A.w + tA4 * gbtA) + wTB * (attB * s2B.w + tB4 * gbtB);
    if (nm0 == rm0 && nm1 == rm1 && nm2 == rm2 && nm3 == rm3) {
      rs0 += wA0 + wB0; rs1 += wA1 + wB1; rs2 += wA2 + wB2; rs3 += wA3 + wB3;
      as0 += addS0; as1 += addS1;
      av0 += addV0; av1 += addV1; av2 += addV2;
      at0 += addT0; at1 += addT1; at2 += addT2; at3 += addT3; at4 += addT4;
    } else {
      float f0 = __expf(rm0 - nm0), f1 = __expf(rm1 - nm1);
      float f2 = __expf(rm2 - nm2), f3 = __expf(rm3 - nm3);
      rm0 = nm0; rm1 = nm1; rm2 = nm2; rm3 = nm3;
      rs0 = rs0 * f0 + wA0 + wB0; rs1 = rs1 * f1 + wA1 + wB1;
      rs2 = rs2 * f2 + wA2 + wB2; rs3 = rs3 * f3 + wA3 + wB3;
      float fS0 = (lane < 32) ? f0 : f1, fS1 = (lane < 32) ? f2 : f3;
      as0 = as0 * fS0 + addS0; as1 = as1 * fS1 + addS1;
      float fV = (lane < 16) ? f0 : (lane < 32) ? f1 : (lane < 48) ? f2 : f3;
      av0 = av0 * fV + addV0; av1 = av1 * fV + addV1; av2 = av2 * fV + addV2;
      float fT = (lane < 8) ? f0 : (lane < 16) ? f1 : (lane < 24) ? f2 : f3;
      at0 = at0 * fT + addT0; at1 = at1 * fT + addT1; at2 = at2 * fT + addT2;
      at3 = at3 * fT + addT3; at4 = at4 * fT + addT4;
    }
  }
  for (; a < ahi; ++a) {
    float x = d_a[a] * sc;
    x = fminf(x, (float)(TABN - 1) - 1.0f);
    int i0 = (int)x; float f = x - (float)i0; float g1 = 1.0f - f;
    int sn = src_a[a];
    const float* g0 = gsL + (size_t)i0 * 128;
    float gsA = g0[lane] * g1 + g0[128 + lane] * f;
    float gsB = g0[64 + lane] * g1 + g0[192 + lane] * f;
    float m0 = sWsrc[(size_t)sn * 128 + lane] * gsA;
    float m1 = sWsrc[(size_t)sn * 128 + 64 + lane] * gsB;
    float p01 = m0 * atnA;
    float p23 = m1 * atnB;
    #pragma unroll
    for (int mm = 1; mm < 32; mm <<= 1) {
      p01 += __shfl_xor(p01, mm);
      p23 += __shfl_xor(p23, mm);
    }
    float l0 = __shfl(p01, 0), l1 = __shfl(p01, 32);
    float l2 = __shfl(p23, 0), l3 = __shfl(p23, 32);
    float nm0 = fmaxf(rm0, l0), nm1 = fmaxf(rm1, l1);
    float nm2 = fmaxf(rm2, l2), nm3 = fmaxf(rm3, l3);
    float f0 = __expf(rm0 - nm0), f1 = __expf(rm1 - nm1);
    float f2 = __expf(rm2 - nm2), f3 = __expf(rm3 - nm3);
    float w0 = __expf(l0 - nm0), w1 = __expf(l1 - nm1);
    float w2 = __expf(l2 - nm2), w3 = __expf(l3 - nm3);
    rm0 = nm0; rm1 = nm1; rm2 = nm2; rm3 = nm3;
    rs0 = rs0 * f0 + w0; rs1 = rs1 * f1 + w1;
    rs2 = rs2 * f2 + w2; rs3 = rs3 * f3 + w3;
    float fS0 = (lane < 32) ? f0 : f1;
    float fS1 = (lane < 32) ? f2 : f3;
    float wS0 = (lane < 32) ? w0 : w1;
    float wS1 = (lane < 32) ? w2 : w3;
    as0 = as0 * fS0 + wS0 * m0;
    as1 = as1 * fS1 + wS1 * m1;
    const float* gv0 = gvL + (size_t)i0 * 128;
    float2 p0 = *(const float2*)&gv0[2 * lane];
    float2 p1 = *(const float2*)&gv0[128 + 2 * lane];
    float gav = p0.x * g1 + p1.x * f;
    float gbv = p0.y * g1 + p1.y * f;
    float fV = (lane < 16) ? f0 : (lane < 32) ? f1 : (lane < 48) ? f2 : f3;
    float wV = (lane < 16) ? w0 : (lane < 32) ? w1 : (lane < 48) ? w2 : w3;
    float avv = sWv[(size_t)sn * 64 + lane] * gav;
    float4 s1 = *(const float4*)&sh_a[(size_t)a * 8];
    float4 s2 = *(const float4*)&sh_a[(size_t)a * 8 + 4];
    const float* vp = &vW[(size_t)sn * 192 + lane];
    av0 = av0 * fV + wV * (avv * s1.x + vp[0] * gbv);
    av1 = av1 * fV + wV * (avv * s1.y + vp[64] * gbv);
    av2 = av2 * fV + wV * (avv * s1.z + vp[128] * gbv);
    if (lane < 32) {
      const float* gt0 = gtL + (size_t)i0 * 64;
      float2 q0 = *(const float2*)&gt0[2 * lt];
      float2 q1 = *(const float2*)&gt0[64 + 2 * lt];
      float gat = q0.x * g1 + q1.x * f;
      float gbt = q0.y * g1 + q1.y * f;
      float fT = (lane < 8) ? f0 : (lane < 16) ? f1 : (lane < 24) ? f2 : f3;
      float wT = (lane < 8) ? w0 : (lane < 16) ? w1 : (lane < 24) ? w2 : w3;
      float att = sWt[(size_t)sn * 32 + lane] * gat;
      const float* tp = &tW[(size_t)sn * 160 + lane];
      at0 = at0 * fT + wT * (att * s1.w + tp[0] * gbt);
      at1 = at1 * fT + wT * (att * s2.x + tp[32] * gbt);
      at2 = at2 * fT + wT * (att * s2.y + tp[64] * gbt);
      at3 = at3 * fT + wT * (att * s2.z + tp[96] * gbt);
      at4 = at4 * fT + wT * (att * s2.w + tp[128] * gbt);
    }
  }
  if (ninact > 0) {
    rs0 += (float)ninact * __expf(-rm0);
    rs1 += (float)ninact * __expf(-rm1);
    rs2 += (float)ninact * __expf(-rm2);
    rs3 += (float)ninact * __expf(-rm3);
  }
  float r0 = 1.0f / (rs0 + 1e-9f), r1 = 1.0f / (rs1 + 1e-9f);
  float r2 = 1.0f / (rs2 + 1e-9f), r3 = 1.0f / (rs3 + 1e-9f);
  float rS0 = (lane < 32) ? r0 : r1;
  float rS1 = (lane < 32) ? r2 : r3;
  float rV = (lane < 16) ? r0 : (lane < 32) ? r1 : (lane < 48) ? r2 : r3;
  agg_s[(size_t)n * 128 + lane] = as0 * rS0;
  agg_s[(size_t)n * 128 + 64 + lane] = as1 * rS1;
  agg_v[(size_t)n * 192 + lane * 3 + 0] = av0 * rV;
  agg_v[(size_t)n * 192 + lane * 3 + 1] = av1 * rV;
  agg_v[(size_t)n * 192 + lane * 3 + 2] = av2 * rV;
  if (lane < 32) {
    float rT = (lane < 8) ? r0 : (lane < 16) ? r1 : (lane < 24) ? r2 : r3;
    agg_t[(size_t)n * 160 + lane * 5 + 0] = at0 * rT;
    agg_t[(size_t)n * 160 + lane * 5 + 1] = at1 * rT;
    agg_t[(size_t)n * 160 + lane * 5 + 2] = at2 * rT;
    agg_t[(size_t)n * 160 + lane * 5 + 3] = at3 * rT;
    agg_t[(size_t)n * 160 + lane * 5 + 4] = at4 * rT;
  }
}

// ---------------- fused node update + next-layer transforms: wave-per-2-nodes, 2 waves/block ----------------
__global__ __launch_bounds__(128) void k_node_fused(
    float* __restrict__ s, float* __restrict__ v, float* __restrict__ t,
    const float* __restrict__ agg_s, const float* __restrict__ agg_v,
    const float* __restrict__ agg_t, const float* __restrict__ Wo_s,
    const float* __restrict__ Wo_v, const float* __restrict__ Wo_t,
    const float* __restrict__ g_s, const float* __restrict__ b_s,
    const float* __restrict__ g_v, const float* __restrict__ g_t,
    const float* __restrict__ Ws_src, const float* __restrict__ Ws_v,
    const float* __restrict__ Ws_t, const float* __restrict__ Wv_v,
    const float* __restrict__ Wt_t, float* __restrict__ sWsrc,
    float* __restrict__ sWv, float* __restrict__ sWt, float* __restrict__ vW,
    float* __restrict__ tW) {
  int wv = threadIdx.x >> 6, lane = threadIdx.x & 63;
  int lt = lane & 31, nh = lane >> 5;
  int n0 = (blockIdx.x * 2 + wv) * 2;
  int n1 = n0 + 1;
  int nt = n0 + nh;
  __shared__ float stg[2][2][192];
  __shared__ float sN[2][2][128];
  __shared__ float vN[2][2][192];
  __shared__ float tN[2][2][160];
  // ---- stage agg_s (both nodes); load s_old ----
  float aS0 = agg_s[(size_t)n0 * 128 + lane];
  float aS1 = agg_s[(size_t)n0 * 128 + 64 + lane];
  float bS0 = agg_s[(size_t)n1 * 128 + lane];
  float bS1 = agg_s[(size_t)n1 * 128 + 64 + lane];
  float sA0 = s[(size_t)n0 * 128 + lane];
  float sA1 = s[(size_t)n0 * 128 + 64 + lane];
  float sB0 = s[(size_t)n1 * 128 + lane];
  float sB1 = s[(size_t)n1 * 128 + 64 + lane];
  stg[wv][0][lane] = aS0; stg[wv][0][64 + lane] = aS1;
  stg[wv][1][lane] = bS0; stg[wv][1][64 + lane] = bS1;
  asm volatile("s_waitcnt lgkmcnt(0)" ::: "memory");
  // ---- s-matmul: s_new = s_old + agg_s @ Wo_s (weights amortized over 2 nodes) ----
  #pragma unroll 8
  for (int c = 0; c < 128; c++) {
    float w0 = Wo_s[c * 128 + lane];
    float w1 = Wo_s[c * 128 + 64 + lane];
    float ax = stg[wv][0][c], bx = stg[wv][1][c];
    sA0 += ax * w0; sA1 += ax * w1;
    sB0 += bx * w0; sB1 += bx * w1;
  }
  // prefetch agg_v + v_old
  float avA0 = agg_v[(size_t)n0 * 192 + lane];
  float avA1 = agg_v[(size_t)n0 * 192 + 64 + lane];
  float avA2 = agg_v[(size_t)n0 * 192 + 128 + lane];
  float avB0 = agg_v[(size_t)n1 * 192 + lane];
  float avB1 = agg_v[(size_t)n1 * 192 + 64 + lane];
  float avB2 = agg_v[(size_t)n1 * 192 + 128 + lane];
  float voA0 = v[(size_t)n0 * 192 + lane * 3 + 0];
  float voA1 = v[(size_t)n0 * 192 + lane * 3 + 1];
  float voA2 = v[(size_t)n0 * 192 + lane * 3 + 2];
  float voB0 = v[(size_t)n1 * 192 + lane * 3 + 0];
  float voB1 = v[(size_t)n1 * 192 + lane * 3 + 1];
  float voB2 = v[(size_t)n1 * 192 + lane * 3 + 2];
  // ---- LayerNorm(s), both nodes ----
  float smA = sA0 + sA1, sqA = sA0 * sA0 + sA1 * sA1;
  float smB = sB0 + sB1, sqB = sB0 * sB0 + sB1 * sB1;
  #pragma unroll
  for (int m = 1; m < 64; m <<= 1) {
    smA += __shfl_xor(smA, m); sqA += __shfl_xor(sqA, m);
    smB += __shfl_xor(smB, m); sqB += __shfl_xor(sqB, m);
  }
  float muA = smA / 128.0f, muB = smB / 128.0f;
  float varA = sqA / 128.0f - muA * muA; if (varA < 0.f) varA = 0.f;
  float varB = sqB / 128.0f - muB * muB; if (varB < 0.f) varB = 0.f;
  float riA = rsqrtf(varA + 1e-6f), riB = rsqrtf(varB + 1e-6f);
  float gs0 = g_s[lane], gs1 = g_s[64 + lane];
  float bs0 = b_s[lane], bs1 = b_s[64 + lane];
  float yA0 = (sA0 - muA) * riA * gs0 + bs0;
  float yA1 = (sA1 - muA) * riA * gs1 + bs1;
  float yB0 = (sB0 - muB) * riB * gs0 + bs0;
  float yB1 = (sB1 - muB) * riB * gs1 + bs1;
  s[(size_t)n0 * 128 + lane] = yA0;
  s[(size_t)n0 * 128 + 64 + lane] = yA1;
  s[(size_t)n1 * 128 + lane] = yB0;
  s[(size_t)n1 * 128 + 64 + lane] = yB1;
  sN[wv][0][lane] = yA0; sN[wv][0][64 + lane] = yA1;
  sN[wv][1][lane] = yB0; sN[wv][1][64 + lane] = yB1;
  // ---- stage agg_v ----
  stg[wv][0][lane] = avA0; stg[wv][0][64 + lane] = avA1; stg[wv][0][128 + lane] = avA2;
  stg[wv][1][lane] = avB0; stg[wv][1][64 + lane] = avB1; stg[wv][1][128 + lane] = avB2;
  asm volatile("s_waitcnt lgkmcnt(0)" ::: "memory");
  // ---- v-matmul: v_new = v_old + agg_v @ Wo_v ----
  float vA0 = voA0, vA1 = voA1, vA2 = voA2;
  float vB0 = voB0, vB1 = voB1, vB2 = voB2;
  #pragma unroll 8
  for (int c = 0; c < 64; c++) {
    float w = Wo_v[c * 64 + lane];
    vA0 += stg[wv][0][c * 3 + 0] * w;
    vA1 += stg[wv][0][c * 3 + 1] * w;
    vA2 += stg[wv][0][c * 3 + 2] * w;
    vB0 += stg[wv][1][c * 3 + 0] * w;
    vB1 += stg[wv][1][c * 3 + 1] * w;
    vB2 += stg[wv][1][c * 3 + 2] * w;
  }
  // prefetch agg_t + t_old (half-trick: lane<32 → n0, lane>=32 → n1)
  float btA0 = agg_t[(size_t)n0 * 160 + lane];
  float btA1 = agg_t[(size_t)n0 * 160 + 64 + lane];
  float btA2 = (lane < 32) ? agg_t[(size_t)n0 * 160 + 128 + lane] : 0.f;
  float btB0 = agg_t[(size_t)n1 * 160 + lane];
  float btB1 = agg_t[(size_t)n1 * 160 + 64 + lane];
  float btB2 = (lane < 32) ? agg_t[(size_t)n1 * 160 + 128 + lane] : 0.f;
  float to0 = t[(size_t)nt * 160 + lt * 5 + 0];
  float to1 = t[(size_t)nt * 160 + lt * 5 + 1];
  float to2 = t[(size_t)nt * 160 + lt * 5 + 2];
  float to3 = t[(size_t)nt * 160 + lt * 5 + 3];
  float to4 = t[(size_t)nt * 160 + lt * 5 + 4];
  // ---- RMS(v), both nodes ----
  float ssqA = vA0 * vA0 + vA1 * vA1 + vA2 * vA2;
  float ssqB = vB0 * vB0 + vB1 * vB1 + vB2 * vB2;
  #pragma unroll
  for (int m = 1; m < 64; m <<= 1) {
    ssqA += __shfl_xor(ssqA, m);
    ssqB += __shfl_xor(ssqB, m);
  }
  float rivA = rsqrtf(ssqA / 64.0f + 1e-6f);
  float rivB = rsqrtf(ssqB / 64.0f + 1e-6f);
  float gv = g_v[lane];
  float vyA0 = vA0 * rivA * gv, vyA1 = vA1 * rivA * gv, vyA2 = vA2 * rivA * gv;
  float vyB0 = vB0 * rivB * gv, vyB1 = vB1 * rivB * gv, vyB2 = vB2 * rivB * gv;
  v[(size_t)n0 * 192 + lane * 3 + 0] = vyA0;
  v[(size_t)n0 * 192 + lane * 3 + 1] = vyA1;
  v[(size_t)n0 * 192 + lane * 3 + 2] = vyA2;
  v[(size_t)n1 * 192 + lane * 3 + 0] = vyB0;
  v[(size_t)n1 * 192 + lane * 3 + 1] = vyB1;
  v[(size_t)n1 * 192 + lane * 3 + 2] = vyB2;
  vN[wv][0][lane * 3 + 0] = vyA0; vN[wv][0][lane * 3 + 1] = vyA1; vN[wv][0][lane * 3 + 2] = vyA2;
  vN[wv][1][lane * 3 + 0] = vyB0; vN[wv][1][lane * 3 + 1] = vyB1; vN[wv][1][lane * 3 + 2] = vyB2;
  // ---- stage agg_t ----
  stg[wv][0][lane] = btA0; stg[wv][0][64 + lane] = btA1;
  if (lane < 32) stg[wv][0][128 + lane] = btA2;
  stg[wv][1][lane] = btB0; stg[wv][1][64 + lane] = btB1;
  if (lane < 32) stg[wv][1][128 + lane] = btB2;
  asm volatile("s_waitcnt lgkmcnt(0)" ::: "memory");
  // ---- t-matmul: half per node ----
  float at0 = to0, at1 = to1, at2 = to2, at3 = to3, at4 = to4;
  #pragma unroll 4
  for (int c = 0; c < 32; c++) {
    float w = Wo_t[c * 32 + lt];
    at0 += stg[wv][nh][c * 5 + 0] * w;
    at1 += stg[wv][nh][c * 5 + 1] * w;
    at2 += stg[wv][nh][c * 5 + 2] * w;
    at3 += stg[wv][nh][c * 5 + 3] * w;
    at4 += stg[wv][nh][c * 5 + 4] * w;
  }
  // ---- RMS(t): reduce within 32-lane half ----
  float ssqt = at0 * at0 + at1 * at1 + at2 * at2 + at3 * at3 + at4 * at4;
  #pragma unroll
  for (int m = 1; m < 32; m <<= 1) ssqt += __shfl_xor(ssqt, m);
  float rit = rsqrtf(ssqt / 32.0f + 1e-6f);
  float gt = g_t[lt];
  float ty0 = at0 * rit * gt, ty1 = at1 * rit * gt, ty2 = at2 * rit * gt;
  float ty3 = at3 * rit * gt, ty4 = at4 * rit * gt;
  t[(size_t)nt * 160 + lt * 5 + 0] = ty0;
  t[(size_t)nt * 160 + lt * 5 + 1] = ty1;
  t[(size_t)nt * 160 + lt * 5 + 2] = ty2;
  t[(size_t)nt * 160 + lt * 5 + 3] = ty3;
  t[(size_t)nt * 160 + lt * 5 + 4] = ty4;
  tN[wv][nh][lt * 5 + 0] = ty0;
  tN[wv][nh][lt * 5 + 1] = ty1;
  tN[wv][nh][lt * 5 + 2] = ty2;
  tN[wv][nh][lt * 5 + 3] = ty3;
  tN[wv][nh][lt * 5 + 4] = ty4;
  asm volatile("s_waitcnt lgkmcnt(0)" ::: "memory");
  // ---- transforms for next layer ----
  {
    float cA0 = 0.f, cA1 = 0.f, cB0 = 0.f, cB1 = 0.f;
    #pragma unroll 8
    for (int c = 0; c < 128; c++) {
      float w0 = Ws_src[c * 128 + lane];
      float w1 = Ws_src[c * 128 + 64 + lane];
      float aA = sN[wv][0][c], aB = sN[wv][1][c];
      cA0 += aA * w0; cA1 += aA * w1;
      cB0 += aB * w0; cB1 += aB * w1;
    }
    sWsrc[(size_t)n0 * 128 + lane] = cA0;
    sWsrc[(size_t)n0 * 128 + 64 + lane] = cA1;
    sWsrc[(size_t)n1 * 128 + lane] = cB0;
    sWsrc[(size_t)n1 * 128 + 64 + lane] = cB1;
  }
  {
    float cvA = 0.f, cvB = 0.f, ct = 0.f;
    #pragma unroll 8
    for (int c = 0; c < 128; c++) {
      float wvv = Ws_v[c * 64 + lane];
      float wtt = Ws_t[c * 32 + lt];
      float aA = sN[wv][0][c], aB = sN[wv][1][c];
      cvA += aA * wvv; cvB += aB * wvv;
      ct += sN[wv][nh][c] * wtt;
    }
    sWv[(size_t)n0 * 64 + lane] = cvA;
    sWv[(size_t)n1 * 64 + lane] = cvB;
    sWt[(size_t)nt * 32 + lt] = ct;
  }
  {
    float wA0 = 0.f, wA1 = 0.f, wA2 = 0.f, wB0 = 0.f, wB1 = 0.f, wB2 = 0.f;
    #pragma unroll 8
    for (int c = 0; c < 64; c++) {
      float w = Wv_v[c * 64 + lane];
      wA0 += vN[wv][0][c * 3 + 0] * w;
      wA1 += vN[wv][0][c * 3 + 1] * w;
      wA2 += vN[wv][0][c * 3 + 2] * w;
      wB0 += vN[wv][1][c * 3 + 0] * w;
      wB1 += vN[wv][1][c * 3 + 1] * w;
      wB2 += vN[wv][1][c * 3 + 2] * w;
    }
    vW[(size_t)n0 * 192 + lane] = wA0;
    vW[(size_t)n0 * 192 + 64 + lane] = wA1;
    vW[(size_t)n0 * 192 + 128 + lane] = wA2;
    vW[(size_t)n1 * 192 + lane] = wB0;
    vW[(size_t)n1 * 192 + 64 + lane] = wB1;
    vW[(size_t)n1 * 192 + 128 + lane] = wB2;
  }
  {
    float u0 = 0.f, u1 = 0.f, u2 = 0.f, u3 = 0.f, u4 = 0.f;
    #pragma unroll 4
    for (int c = 0; c < 32; c++) {
      float w = Wt_t[c * 32 + lt];
      u0 += tN[wv][nh][c * 5 + 0] * w;
      u1 += tN[wv][nh][c * 5 + 1] * w;
      u2 += tN[wv][nh][c * 5 + 2] * w;
      u3 += tN[wv][nh][c * 5 + 3] * w;
      u4 += tN[wv][nh][c * 5 + 4] * w;
    }
    tW[(size_t)nt * 160 + lt] = u0;
    tW[(size_t)nt * 160 + 32 + lt] = u1;
    tW[(size_t)nt * 160 + 64 + lt] = u2;
    tW[(size_t)nt * 160 + 96 + lt] = u3;
    tW[(size_t)nt * 160 + 128 + lt] = u4;
  }
}

// ---------------- node update, final layer: wave-per-2-nodes, 2 waves/block ----------------
__global__ __launch_bounds__(128) void k_node_up(
    float* __restrict__ s, float* __restrict__ v, float* __restrict__ t,
    const float* __restrict__ agg_s, const float* __restrict__ agg_v,
    const float* __restrict__ agg_t, const float* __restrict__ Wo_s,
    const float* __restrict__ Wo_v, const float* __restrict__ Wo_t,
    const float* __restrict__ g_s, const float* __restrict__ b_s,
    const float* __restrict__ g_v, const float* __restrict__ g_t) {
  int wv = threadIdx.x >> 6, lane = threadIdx.x & 63;
  int lt = lane & 31, nh = lane >> 5;
  int n0 = (blockIdx.x * 2 + wv) * 2;
  int n1 = n0 + 1;
  int nt = n0 + nh;
  __shared__ float stg[2][2][192];
  float aS0 = agg_s[(size_t)n0 * 128 + lane];
  float aS1 = agg_s[(size_t)n0 * 128 + 64 + lane];
  float bS0 = agg_s[(size_t)n1 * 128 + lane];
  float bS1 = agg_s[(size_t)n1 * 128 + 64 + lane];
  float sA0 = s[(size_t)n0 * 128 + lane];
  float sA1 = s[(size_t)n0 * 128 + 64 + lane];
  float sB0 = s[(size_t)n1 * 128 + lane];
  float sB1 = s[(size_t)n1 * 128 + 64 + lane];
  stg[wv][0][lane] = aS0; stg[wv][0][64 + lane] = aS1;
  stg[wv][1][lane] = bS0; stg[wv][1][64 + lane] = bS1;
  asm volatile("s_waitcnt lgkmcnt(0)" ::: "memory");
  #pragma unroll 8
  for (int c = 0; c < 128; c++) {
    float w0 = Wo_s[c * 128 + lane];
    float w1 = Wo_s[c * 128 + 64 + lane];
    float ax = stg[wv][0][c], bx = stg[wv][1][c];
    sA0 += ax * w0; sA1 += ax * w1;
    sB0 += bx * w0; sB1 += bx * w1;
  }
  float avA0 = agg_v[(size_t)n0 * 192 + lane];
  float avA1 = agg_v[(size_t)n0 * 192 + 64 + lane];
  float avA2 = agg_v[(size_t)n0 * 192 + 128 + lane];
  float avB0 = agg_v[(size_t)n1 * 192 + lane];
  float avB1 = agg_v[(size_t)n1 * 192 + 64 + lane];
  float avB2 = agg_v[(size_t)n1 * 192 + 128 + lane];
  float voA0 = v[(size_t)n0 * 192 + lane * 3 + 0];
  float voA1 = v[(size_t)n0 * 192 + lane * 3 + 1];
  float voA2 = v[(size_t)n0 * 192 + lane * 3 + 2];
  float voB0 = v[(size_t)n1 * 192 + lane * 3 + 0];
  float voB1 = v[(size_t)n1 * 192 + lane * 3 + 1];
  float voB2 = v[(size_t)n1 * 192 + lane * 3 + 2];
  float smA = sA0 + sA1, sqA = sA0 * sA0 + sA1 * sA1;
  float smB = sB0 + sB1, sqB = sB0 * sB0 + sB1 * sB1;
  #pragma unroll
  for (int m = 1; m < 64; m <<= 1) {
    smA += __shfl_xor(smA, m); sqA += __shfl_xor(sqA, m);
    smB += __shfl_xor(smB, m); sqB += __shfl_xor(sqB, m);
  }
  float muA = smA / 128.0f, muB = smB / 128.0f;
  float varA = sqA / 128.0f - muA * muA; if (varA < 0.f) varA = 0.f;
  float varB = sqB / 128.0f - muB * muB; if (varB < 0.f) varB = 0.f;
  float riA = rsqrtf(varA + 1e-6f), riB = rsqrtf(varB + 1e-6f);
  float gs0 = g_s[lane], gs1 = g_s[64 + lane];
  float bs0 = b_s[lane], bs1 = b_s[64 + lane];
  s[(size_t)n0 * 128 + lane] = (sA0 - muA) * riA * gs0 + bs0;
  s[(size_t)n0 * 128 + 64 + lane] = (sA1 - muA) * riA * gs1 + bs1;
  s[(size_t)n1 * 128 + lane] = (sB0 - muB) * riB * gs0 + bs0;
  s[(size_t)n1 * 128 + 64 + lane] = (sB1 - muB) * riB * gs1 + bs1;
  stg[wv][0][lane] = avA0; stg[wv][0][64 + lane] = avA1; stg[wv][0][128 + lane] = avA2;
  stg[wv][1][lane] = avB0; stg[wv][1][64 + lane] = avB1; stg[wv][1][128 + lane] = avB2;
  asm volatile("s_waitcnt lgkmcnt(0)" ::: "memory");
  float vA0 = voA0, vA1 = voA1, vA2 = voA2;
  float vB0 = voB0, vB1 = voB1, vB2 = voB2;
  #pragma unroll 8
  for (int c = 0; c < 64; c++) {
    float w = Wo_v[c * 64 + lane];
    vA0 += stg[wv][0][c * 3 + 0] * w;
    vA1 += stg[wv][0][c * 3 + 1] * w;
    vA2 += stg[wv][0][c * 3 + 2] * w;
    vB0 += stg[wv][1][c * 3 + 0] * w;
    vB1 += stg[wv][1][c * 3 + 1] * w;
    vB2 += stg[wv][1][c * 3 + 2] * w;
  }
  float btA0 = agg_t[(size_t)n0 * 160 + lane];
  float btA1 = agg_t[(size_t)n0 * 160 + 64 + lane];
  float btA2 = (lane < 32) ? agg_t[(size_t)n0 * 160 + 128 + lane] : 0.f;
  float btB0 = agg_t[(size_t)n1 * 160 + lane];
  float btB1 = agg_t[(size_t)n1 * 160 + 64 + lane];
  float btB2 = (lane < 32) ? agg_t[(size_t)n1 * 160 + 128 + lane] : 0.f;
  float to0 = t[(size_t)nt * 160 + lt * 5 + 0];
  float to1 = t[(size_t)nt * 160 + lt * 5 + 1];
  float to2 = t[(size_t)nt * 160 + lt * 5 + 2];
  float to3 = t[(size_t)nt * 160 + lt * 5 + 3];
  float to4 = t[(size_t)nt * 160 + lt * 5 + 4];
  float ssqA = vA0 * vA0 + vA1 * vA1 + vA2 * vA2;
  float ssqB = vB0 * vB0 + vB1 * vB1 + vB2 * vB2;
  #pragma unroll
  for (int m = 1; m < 64; m <<= 1) {
    ssqA += __shfl_xor(ssqA, m);
    ssqB += __shfl_xor(ssqB, m);
  }
  float rivA = rsqrtf(ssqA / 64.0f + 1e-6f);
  float rivB = rsqrtf(ssqB / 64.0f + 1e-6f);
  float gv = g_v[lane];
  v[(size_t)n0 * 192 + lane * 3 + 0] = vA0 * rivA * gv;
  v[(size_t)n0 * 192 + lane * 3 + 1] = vA1 * rivA * gv;
  v[(size_t)n0 * 192 + lane * 3 + 2] = vA2 * rivA * gv;
  v[(size_t)n1 * 192 + lane * 3 + 0] = vB0 * rivB * gv;
  v[(size_t)n1 * 192 + lane * 3 + 1] = vB1 * rivB * gv;
  v[(size_t)n1 * 192 + lane * 3 + 2] = vB2 * rivB * gv;
  stg[wv][0][lane] = btA0; stg[wv][0][64 + lane] = btA1;
  if (lane < 32) stg[wv][0][128 + lane] = btA2;
  stg[wv][1][lane] = btB0; stg[wv][1][64 + lane] = btB1;
  if (lane < 32) stg[wv][1][128 + lane] = btB2;
  asm volatile("s_waitcnt lgkmcnt(0)" ::: "memory");
  float at0 = to0, at1 = to1, at2 = to2, at3 = to3, at4 = to4;
  #pragma unroll 4
  for (int c = 0; c < 32; c++) {
    float w = Wo_t[c * 32 + lt];
    at0 += stg[wv][nh][c * 5 + 0] * w;
    at1 += stg[wv][nh][c * 5 + 1] * w;
    at2 += stg[wv][nh][c * 5 + 2] * w;
    at3 += stg[wv][nh][c * 5 + 3] * w;
    at4 += stg[wv][nh][c * 5 + 4] * w;
  }
  float ssqt = at0 * at0 + at1 * at1 + at2 * at2 + at3 * at3 + at4 * at4;
  #pragma unroll
  for (int m = 1; m < 32; m <<= 1) ssqt += __shfl_xor(ssqt, m);
  float rit = rsqrtf(ssqt / 32.0f + 1e-6f);
  float gt = g_t[lt];
  t[(size_t)nt * 160 + lt * 5 + 0] = at0 * rit * gt;
  t[(size_t)nt * 160 + lt * 5 + 1] = at1 * rit * gt;
  t[(size_t)nt * 160 + lt * 5 + 2] = at2 * rit * gt;
  t[(size_t)nt * 160 + lt * 5 + 3] = at3 * rit * gt;
  t[(size_t)nt * 160 + lt * 5 + 4] = at4 * rit * gt;
}

// ---------------- readout: 2 feature-blocks per staged s-tile ----------------
__global__ __launch_bounds__(256) void k_readout(
    const float* __restrict__ s, const int* __restrict__ batch,
    const float* __restrict__ W_feat, const float* __restrict__ b_feat,
    const float* __restrict__ W_out1, const float* __restrict__ b_out1,
    float* __restrict__ graph) {
  __shared__ float st[64][129];
  __shared__ float gacc[GG];
  int nb = blockIdx.x * 64;
  int fbb = blockIdx.y * 2;  // 0,2,4,6
  for (int idx = threadIdx.x; idx < 64 * 128; idx += 256) {
    int nl = idx >> 7, c = idx & 127;
    int n = nb + nl;
    st[nl][c] = (n < NN) ? s[(size_t)n * 128 + c] : 0.f;
  }
  if (threadIdx.x < GG) gacc[threadIdx.x] = 0.f;
  __syncthreads();
  int wv = threadIdx.x >> 6, lane = threadIdx.x & 63;
  int fg = lane & 15;
  int ns = lane >> 4;
  int nodeb = wv * 16 + ns * 4;
  #pragma unroll
  for (int sub = 0; sub < 2; sub++) {
    int fb = fbb + sub;
    int f0 = fb * 64 + fg * 4;
    float acc[4][4];
    #pragma unroll
    for (int nn = 0; nn < 4; nn++)
      #pragma unroll
      for (int k = 0; k < 4; k++) acc[nn][k] = b_feat[f0 + k];
    #pragma unroll 4
    for (int c = 0; c < 128; c++) {
      float4 wq = *(const float4*)&W_feat[(size_t)c * 512 + f0];
      #pragma unroll
      for (int nn = 0; nn < 4; nn++) {
        float sv = st[nodeb + nn][c];
        acc[nn][0] += sv * wq.x;
        acc[nn][1] += sv * wq.y;
        acc[nn][2] += sv * wq.z;
        acc[nn][3] += sv * wq.w;
      }
    }
    float wo[4];
    #pragma unroll
    for (int k = 0; k < 4; k++) wo[k] = W_out1[f0 + k];
    float ep[4];
    #pragma unroll
    for (int nn = 0; nn < 4; nn++) {
      float p = 0.f;
      #pragma unroll
      for (int k = 0; k < 4; k++) p += fgelu(acc[nn][k]) * wo[k];
      ep[nn] = p;
    }
    #pragma unroll
    for (int mm = 1; mm < 16; mm <<= 1) {
      #pragma unroll
      for (int nn = 0; nn < 4; nn++) ep[nn] += __shfl_xor(ep[nn], mm);
    }
    if (fg == 0) {
      #pragma unroll
      for (int nn = 0; nn < 4; nn++) {
        int n = nb + nodeb + nn;
        if (n < NN) {
          float e = ep[nn];
          if (fb == 0) e += b_out1[0];
          atomicAdd(&gacc[batch[n]], e);
        }
      }
    }
  }
  __syncthreads();
  if (threadIdx.x < GG && gacc[threadIdx.x] != 0.f)
    atomicAdd(&graph[threadIdx.x], gacc[threadIdx.x]);
}

__global__ void k_finalize(const float* __restrict__ graph, const float* __restrict__ W_read,
                           const float* __restrict__ b_read, float* __restrict__ out) {
  int g = threadIdx.x;
  if (g < GG) out[g] = graph[g] * W_read[0] + b_read[0];
}

// ---------------- host ----------------
extern "C" void kernel_launch(void* const* d_in, const int* in_sizes, int n_in,
                              void* d_out, int out_size, void* d_ws, size_t ws_size,
                              hipStream_t stream) {
  const float* pos = (const float*)d_in[0];
  const int* node_atom = (const int*)d_in[1];
  const int* batch = (const int*)d_in[2];
  const int* esrc = (const int*)d_in[3];
  const int* edst = (const int*)d_in[4];
  const float* atom_emb = (const float*)d_in[5];
  const float* Wrad1 = (const float*)d_in[6];
  const float* brad1 = (const float*)d_in[7];
  const float* Wrad2 = (const float*)d_in[8];
  const float* brad2 = (const float*)d_in[9];
  const float* Ws_src = (const float*)d_in[10];
  const float* Ww_s = (const float*)d_in[11];
  const float* Ws_v = (const float*)d_in[12];
  const float* Ww_v = (const float*)d_in[13];
  const float* Wv_v = (const float*)d_in[14];
  const float* Ww_vv = (const float*)d_in[15];
  const float* Ws_t = (const float*)d_in[16];
  const float* Ww_t = (const float*)d_in[17];
  const float* Wt_t = (const float*)d_in[18];
  const float* Ww_tt = (const float*)d_in[19];
  const float* attn_a = (const float*)d_in[20];
  const float* Wo_s = (const float*)d_in[21];
  const float* Wo_v = (const float*)d_in[22];
  const float* Wo_t = (const float*)d_in[23];
  const float* g_s = (const float*)d_in[24];
  const float* b_s = (const float*)d_in[25];
  const float* g_v = (const float*)d_in[26];
  const float* g_t = (const float*)d_in[27];
  const float* W_feat = (const float*)d_in[28];
  const float* b_feat = (const float*)d_in[29];
  const float* W_out1 = (const float*)d_in[30];
  const float* b_out1 = (const float*)d_in[31];
  const float* W_read = (const float*)d_in[32];
  const float* b_read = (const float*)d_in[33];
  float* out = (float*)d_out;

  char* base = (char*)d_ws;
  size_t off = 0;
  auto alloc = [&](size_t bytes) -> char* {
    off = (off + 255) & ~(size_t)255;
    char* p = base + off;
    off += bytes;
    return p;
  };
  // ---- zero-init group A (ints), contiguous ----
  int* deg = (int*)alloc(NN * 4);
  int* cursor = (int*)alloc(NN * 4);
  int* dbkt = (int*)alloc(128 * 4);
  int* dbcur = (int*)alloc(128 * 4);
  float* graph = (float*)alloc(GG * 4);
  char* zeroA_end = base + off;
  // ---- zero-init group B (floats), contiguous ----
  float* v = (float*)alloc((size_t)NN * 192 * 4);
  float* t = (float*)alloc((size_t)NN * 160 * 4);
  float* vW = (float*)alloc((size_t)NN * 192 * 4);
  float* tW = (float*)alloc((size_t)NN * 160 * 4);
  char* zeroB_end = base + off;
  // ---- rest ----
  int* row_off = (int*)alloc((NN + 1) * 4);
  float* d_csr = (float*)alloc((size_t)EE * 4);
  int* src_csr = (int*)alloc((size_t)EE * 4);
  int* dst_csr = (int*)alloc((size_t)EE * 4);
  int* acnt = (int*)alloc(NN * 4);
  int* act_off = (int*)alloc((NN + 1) * 4);
  int* act_idx = (int*)alloc((size_t)EE * 4);
  int* dboff = (int*)alloc(129 * 4);
  int* order = (int*)alloc(NN * 4);
  float* d_a = (float*)alloc((size_t)EE * 4);
  int* src_a = (int*)alloc((size_t)EE * 4);
  float* sh_a = (float*)alloc((size_t)EE * 8 * 4);
  float* wtab = (float*)alloc((size_t)LL * TABN * 64 * 4);
  float* gs_tab = (float*)alloc((size_t)LL * TABN * 128 * 4);
  float* gv_tab = (float*)alloc((size_t)LL * TABN * 128 * 4);
  float* gt_tab = (float*)alloc((size_t)LL * TABN * 64 * 4);
  float* s = (float*)alloc((size_t)NN * 128 * 4);
  float* sWsrc = (float*)alloc((size_t)NN * 128 * 4);
  float* sWv = (float*)alloc((size_t)NN * 64 * 4);
  float* sWt = (float*)alloc((size_t)NN * 32 * 4);
  float* agg_s = (float*)alloc((size_t)NN * 128 * 4);
  float* agg_v = (float*)alloc((size_t)NN * 192 * 4);
  float* agg_t = (float*)alloc((size_t)NN * 160 * 4);

  // two consolidated memsets (cover alignment pads harmlessly)
  hipMemsetAsync(deg, 0, (size_t)(zeroA_end - (char*)deg), stream);
  hipMemsetAsync(v, 0, (size_t)(zeroB_end - (char*)v), stream);

  k_hist<<<(EE + 255) / 256, 256, 0, stream>>>(edst, deg);
  k_scan<<<1, 1024, 0, stream>>>(deg, row_off, NN);
  k_scatter<<<(EE + 255) / 256, 256, 0, stream>>>(esrc, edst, pos, row_off, cursor,
                                                  d_csr, src_csr, dst_csr);
  k_act_cnt<<<(NN + 255) / 256, 256, 0, stream>>>(row_off, d_csr, acnt, dbkt);
  k_scan2<<<2, 1024, 0, stream>>>(acnt, act_off, NN, dbkt, dboff, 128);
  k_act_fill<<<(NN + 255) / 256, 256, 0, stream>>>(row_off, d_csr, act_off, act_idx,
                                                   acnt, dboff, dbcur, order);
  k_geom_act<<<(EE + 255) / 256, 256, 0, stream>>>(act_idx, src_csr, dst_csr, pos, act_off,
                                                   d_a, src_a, sh_a);
  k_build_wtab<<<LL * (TABN / 16), 256, 0, stream>>>(Wrad1, brad1, Wrad2, brad2, wtab);
  k_build_tabs<<<LL * (TABN / EB), 320, 0, stream>>>(wtab, Ww_s, Ww_v, Ww_vv, Ww_t, Ww_tt,
                                                     gs_tab, gv_tab, gt_tab);
  // layer-0 transforms fused with s init (v/t are zero; vW/tW zeroed by group-B memset)
  k_node_tf0<<<NN / 16, 256, 0, stream>>>(node_atom, atom_emb, s, Ws_src, Ws_v, Ws_t,
                                          sWsrc, sWv, sWt);

  for (int l = 0; l < LL; l++) {
    const float* gsL = gs_tab + (size_t)l * TABN * 128;
    const float* gvL = gv_tab + (size_t)l * TABN * 128;
    const float* gtL = gt_tab + (size_t)l * TABN * 64;
    k_mega<<<NN / 2, 128, 0, stream>>>(row_off, act_off, order, src_a, d_a, gsL, gvL, gtL,
                                       attn_a + (size_t)l * 128,
                                       sWsrc, sWv, sWt, vW, tW, sh_a, agg_s, agg_v, agg_t);
    if (l < LL - 1) {
      k_node_fused<<<NN / 4, 128, 0, stream>>>(
          s, v, t, agg_s, agg_v, agg_t,
          Wo_s + (size_t)l * 128 * 128, Wo_v + (size_t)l * 64 * 64,
          Wo_t + (size_t)l * 32 * 32,
          g_s + (size_t)l * 128, b_s + (size_t)l * 128,
          g_v + (size_t)l * 64, g_t + (size_t)l * 32,
          Ws_src + (size_t)(l + 1) * 128 * 128, Ws_v + (size_t)(l + 1) * 128 * 64,
          Ws_t + (size_t)(l + 1) * 128 * 32, Wv_v + (size_t)(l + 1) * 64 * 64,
          Wt_t + (size_t)(l + 1) * 32 * 32,
          sWsrc, sWv, sWt, vW, tW);
    } else {
      k_node_up<<<NN / 4, 128, 0, stream>>>(s, v, t, agg_s, agg_v, agg_t,
                                            Wo_s + (size_t)l * 128 * 128,
                                            Wo_v + (size_t)l * 64 * 64, Wo_t + (size_t)l * 32 * 32,
                                            g_s + (size_t)l * 128, b_s + (size_t)l * 128,
                                            g_v + (size_t)l * 64, g_t + (size_t)l * 32);
    }
  }
  dim3 rg((NN + 63) / 64, 4);
  k_readout<<<rg, 256, 0, stream>>>(s, batch, W_feat, b_feat, W_out1, b_out1, graph);
  k_finalize<<<1, 64, 0, stream>>>(graph, W_read, b_read, out);
}

// Round 14
// 957.691 us; speedup vs baseline: 1.1010x; 1.0125x over previous
//
#include <hip/hip_runtime.h>
#include <math.h>

#define NN 10000
#define EE 320000
#define GG 32
#define LL 6
#define TABN 2048
#define DTAB 5.45f
#define DCUT 5.4f

__device__ __forceinline__ float fsilu(float x) { return x / (1.0f + __expf(-x)); }
__device__ __forceinline__ float fgelu(float x) {
  float y = 0.7978845608f * (x + 0.044715f * x * x * x);
  float t = 1.0f - 2.0f / (__expf(2.0f * y) + 1.0f);
  return 0.5f * x * (1.0f + t);
}

// ---------------- CSR build ----------------
__global__ void k_hist(const int* __restrict__ dst, int* __restrict__ deg) {
  int e = blockIdx.x * blockDim.x + threadIdx.x;
  if (e < EE) atomicAdd(&deg[dst[e]], 1);
}

__global__ void k_scan(const int* __restrict__ cnt, int* __restrict__ off, int n) {
  __shared__ int tsum[1024];
  int chunk = (n + 1023) / 1024;
  int base = (int)threadIdx.x * chunk;
  int local = 0;
  for (int i = 0; i < chunk; i++) {
    int idx = base + i;
    local += (idx < n) ? cnt[idx] : 0;
  }
  tsum[threadIdx.x] = local;
  __syncthreads();
  for (int o = 1; o < 1024; o <<= 1) {
    int tv = (threadIdx.x >= (unsigned)o) ? tsum[threadIdx.x - o] : 0;
    __syncthreads();
    tsum[threadIdx.x] += tv;
    __syncthreads();
  }
  int run = tsum[threadIdx.x] - local;
  for (int i = 0; i < chunk; i++) {
    int idx = base + i;
    if (idx < n) {
      run += cnt[idx];
      off[idx + 1] = run;
    }
  }
  if (threadIdx.x == 0) off[0] = 0;
}

__global__ void k_scan2(const int* __restrict__ cntA, int* __restrict__ offA, int nA,
                        const int* __restrict__ cntB, int* __restrict__ offB, int nB) {
  const int* cnt = (blockIdx.x == 0) ? cntA : cntB;
  int* off = (blockIdx.x == 0) ? offA : offB;
  int n = (blockIdx.x == 0) ? nA : nB;
  __shared__ int tsum[1024];
  int chunk = (n + 1023) / 1024;
  int base = (int)threadIdx.x * chunk;
  int local = 0;
  for (int i = 0; i < chunk; i++) {
    int idx = base + i;
    local += (idx < n) ? cnt[idx] : 0;
  }
  tsum[threadIdx.x] = local;
  __syncthreads();
  for (int o = 1; o < 1024; o <<= 1) {
    int tv = (threadIdx.x >= (unsigned)o) ? tsum[threadIdx.x - o] : 0;
    __syncthreads();
    tsum[threadIdx.x] += tv;
    __syncthreads();
  }
  int run = tsum[threadIdx.x] - local;
  for (int i = 0; i < chunk; i++) {
    int idx = base + i;
    if (idx < n) {
      run += cnt[idx];
      off[idx + 1] = run;
    }
  }
  if (threadIdx.x == 0) off[0] = 0;
}

__global__ void k_scatter(const int* __restrict__ esrc, const int* __restrict__ edst,
                          const float* __restrict__ pos, const int* __restrict__ row_off,
                          int* __restrict__ cursor, float* __restrict__ d_csr,
                          int* __restrict__ src_csr, int* __restrict__ dst_csr) {
  int e = blockIdx.x * blockDim.x + threadIdx.x;
  if (e < EE) {
    int d = edst[e];
    int s = esrc[e];
    int p = atomicAdd(&cursor[d], 1);
    int slot = row_off[d] + p;
    float rx = pos[d * 3 + 0] - pos[s * 3 + 0];
    float ry = pos[d * 3 + 1] - pos[s * 3 + 1];
    float rz = pos[d * 3 + 2] - pos[s * 3 + 2];
    d_csr[slot] = sqrtf(rx * rx + ry * ry + rz * rz + 1e-6f);
    src_csr[slot] = s;
    dst_csr[slot] = d;
  }
}

__global__ void k_act_cnt(const int* __restrict__ row_off, const float* __restrict__ d_csr,
                          int* __restrict__ acnt, int* __restrict__ dbkt) {
  int n = blockIdx.x * blockDim.x + threadIdx.x;
  if (n >= NN) return;
  int c = 0;
  for (int j = row_off[n]; j < row_off[n + 1]; ++j) c += (d_csr[j] < DCUT) ? 1 : 0;
  acnt[n] = c;
  int b = 127 - min(127, c);
  atomicAdd(&dbkt[b], 1);
}

__global__ void k_act_fill(const int* __restrict__ row_off, const float* __restrict__ d_csr,
                           const int* __restrict__ act_off, int* __restrict__ act_idx,
                           const int* __restrict__ acnt, const int* __restrict__ dboff,
                           int* __restrict__ dbcur, int* __restrict__ order) {
  int n = blockIdx.x * blockDim.x + threadIdx.x;
  if (n >= NN) return;
  int a = act_off[n];
  for (int j = row_off[n]; j < row_off[n + 1]; ++j)
    if (d_csr[j] < DCUT) act_idx[a++] = j;
  int b = 127 - min(127, acnt[n]);
  int p = atomicAdd(&dbcur[b], 1);
  order[dboff[b] + p] = n;
}

__global__ void k_geom_act(const int* __restrict__ act_idx, const int* __restrict__ src_csr,
                           const int* __restrict__ dst_csr, const float* __restrict__ pos,
                           const int* __restrict__ act_off, float* __restrict__ d_a,
                           int* __restrict__ src_a, float* __restrict__ sh_a) {
  int a = blockIdx.x * blockDim.x + threadIdx.x;
  if (a >= act_off[NN]) return;
  int j = act_idx[a];
  int s = src_csr[j], dd = dst_csr[j];
  float rx = pos[dd * 3 + 0] - pos[s * 3 + 0];
  float ry = pos[dd * 3 + 1] - pos[s * 3 + 1];
  float rz = pos[dd * 3 + 2] - pos[s * 3 + 2];
  float d = sqrtf(rx * rx + ry * ry + rz * rz + 1e-6f);
  float inv = 1.0f / d;
  float x = rx * inv, y = ry * inv, z = rz * inv;
  d_a[a] = d;
  src_a[a] = s;
  const float s3 = 1.7320508075688772f;
  const float s5 = 2.23606797749979f;
  const float s15 = 3.872983346207417f;
  sh_a[a * 8 + 0] = s3 * x;
  sh_a[a * 8 + 1] = s3 * y;
  sh_a[a * 8 + 2] = s3 * z;
  sh_a[a * 8 + 3] = s15 * x * y;
  sh_a[a * 8 + 4] = s15 * y * z;
  sh_a[a * 8 + 5] = 0.5f * s5 * (3.0f * z * z - 1.0f);
  sh_a[a * 8 + 6] = s15 * x * z;
  sh_a[a * 8 + 7] = 0.5f * s15 * (x * x - y * y);
}

// ---------------- radial MLP table w(d) ----------------
__global__ void k_build_wtab(const float* __restrict__ Wrad1, const float* __restrict__ brad1,
                             const float* __restrict__ Wrad2, const float* __restrict__ brad2,
                             float* __restrict__ wtab) {
  int l = blockIdx.x / (TABN / 16);
  int blk = blockIdx.x % (TABN / 16);
  __shared__ float W1[128 * 64];
  __shared__ float W2[64 * 64];
  __shared__ float b1[64], b2[64];
  __shared__ float rbf_s[4][128];
  __shared__ float h_s[4][64];
  const float* w1p = Wrad1 + (size_t)l * 128 * 64;
  const float* w2p = Wrad2 + (size_t)l * 64 * 64;
  for (int i = threadIdx.x; i < 128 * 64; i += 256) W1[i] = w1p[i];
  for (int i = threadIdx.x; i < 64 * 64; i += 256) W2[i] = w2p[i];
  if (threadIdx.x < 64) {
    b1[threadIdx.x] = brad1[(size_t)l * 64 + threadIdx.x];
    b2[threadIdx.x] = brad2[(size_t)l * 64 + threadIdx.x];
  }
  __syncthreads();
  int wv = threadIdx.x >> 6, lane = threadIdx.x & 63;
  const float width = 5.0f / 128.0f;
  for (int k = wv; k < 16; k += 4) {
    int i = blk * 16 + k;
    float d = (float)i * (DTAB / (float)(TABN - 1));
    float c0 = (5.0f * (float)lane) / 127.0f;
    float c1 = (5.0f * (float)(lane + 64)) / 127.0f;
    float t0 = (d - c0) / width, t1 = (d - c1) / width;
    rbf_s[wv][lane] = __expf(-0.5f * t0 * t0);
    rbf_s[wv][lane + 64] = __expf(-0.5f * t1 * t1);
    float acc = b1[lane];
    #pragma unroll 8
    for (int i2 = 0; i2 < 128; i2++) acc += rbf_s[wv][i2] * W1[i2 * 64 + lane];
    acc = fsilu(acc);
    h_s[wv][lane] = acc;
    float acc2 = b2[lane];
    #pragma unroll 8
    for (int i2 = 0; i2 < 64; i2++) acc2 += h_s[wv][i2] * W2[i2 * 64 + lane];
    wtab[((size_t)l * TABN + i) * 64 + lane] = fsilu(acc2);
  }
}

// ---------------- fused product-table build ----------------
#define EB 8
__global__ __launch_bounds__(320) void k_build_tabs(
    const float* __restrict__ wtab, const float* __restrict__ Ww_s,
    const float* __restrict__ Ww_v, const float* __restrict__ Ww_vv,
    const float* __restrict__ Ww_t, const float* __restrict__ Ww_tt,
    float* __restrict__ gs_tab, float* __restrict__ gv_tab, float* __restrict__ gt_tab) {
  int l = blockIdx.x / (TABN / EB);
  int eb = (blockIdx.x % (TABN / EB)) * EB;
  __shared__ float ws[EB][64];
  int tid = threadIdx.x;
  for (int i = tid; i < EB * 64; i += 320)
    ws[i >> 6][i & 63] = wtab[((size_t)l * TABN + eb + (i >> 6)) * 64 + (i & 63)];
  __syncthreads();
  float acc[EB] = {};
  if (tid < 128) {
    int col = tid;
    const float* W = Ww_s + (size_t)l * 64 * 128;
    #pragma unroll 8
    for (int i = 0; i < 64; i++) {
      float w = W[i * 128 + col];
      #pragma unroll
      for (int e = 0; e < EB; e++) acc[e] += ws[e][i] * w;
    }
    #pragma unroll
    for (int e = 0; e < EB; e++)
      gs_tab[((size_t)l * TABN + eb + e) * 128 + col] = acc[e];
  } else if (tid < 256) {
    int cc = tid - 128;
    int c = cc >> 1;
    const float* W = ((cc & 1) ? Ww_vv : Ww_v) + (size_t)l * 64 * 64;
    #pragma unroll 8
    for (int i = 0; i < 64; i++) {
      float w = W[i * 64 + c];
      #pragma unroll
      for (int e = 0; e < EB; e++) acc[e] += ws[e][i] * w;
    }
    #pragma unroll
    for (int e = 0; e < EB; e++)
      gv_tab[((size_t)l * TABN + eb + e) * 128 + cc] = acc[e];
  } else {
    int cc = tid - 256;
    int c = cc >> 1;
    const float* W = ((cc & 1) ? Ww_tt : Ww_t) + (size_t)l * 64 * 32;
    #pragma unroll 8
    for (int i = 0; i < 64; i++) {
      float w = W[i * 32 + c];
      #pragma unroll
      for (int e = 0; e < EB; e++) acc[e] += ws[e][i] * w;
    }
    #pragma unroll
    for (int e = 0; e < EB; e++)
      gt_tab[((size_t)l * TABN + eb + e) * 64 + cc] = acc[e];
  }
}

// ---------------- layer-0 transforms fused with s-init ----------------
__global__ __launch_bounds__(256) void k_node_tf0(
    const int* __restrict__ node_atom, const float* __restrict__ atom_emb,
    float* __restrict__ s, const float* __restrict__ Ws_src,
    const float* __restrict__ Ws_v, const float* __restrict__ Ws_t,
    float* __restrict__ sWsrc, float* __restrict__ sWv, float* __restrict__ sWt) {
  int nb = blockIdx.x * 16;
  int tid = threadIdx.x;
  __shared__ float s16[16][129];
  for (int idx = tid; idx < 16 * 128; idx += 256) {
    int n = idx >> 7, c = idx & 127;
    float val = atom_emb[(size_t)node_atom[nb + n] * 128 + c];
    s16[n][c] = val;
    s[(size_t)(nb + n) * 128 + c] = val;
  }
  __syncthreads();
  {
    int col = tid & 127, ng = tid >> 7;
    float acc[8] = {0, 0, 0, 0, 0, 0, 0, 0};
    for (int c = 0; c < 128; c++) {
      float w = Ws_src[c * 128 + col];
      #pragma unroll
      for (int n = 0; n < 8; n++) acc[n] += s16[ng * 8 + n][c] * w;
    }
    #pragma unroll
    for (int n = 0; n < 8; n++) sWsrc[(size_t)(nb + ng * 8 + n) * 128 + col] = acc[n];
  }
  {
    int col = tid & 63, ng = tid >> 6;
    float acc[4] = {0, 0, 0, 0};
    for (int c = 0; c < 128; c++) {
      float w = Ws_v[c * 64 + col];
      #pragma unroll
      for (int n = 0; n < 4; n++) acc[n] += s16[ng * 4 + n][c] * w;
    }
    #pragma unroll
    for (int n = 0; n < 4; n++) sWv[(size_t)(nb + ng * 4 + n) * 64 + col] = acc[n];
  }
  {
    int col = tid & 31, ng = tid >> 5;
    float acc[2] = {0, 0};
    for (int c = 0; c < 128; c++) {
      float w = Ws_t[c * 32 + col];
      acc[0] += s16[ng * 2 + 0][c] * w;
      acc[1] += s16[ng * 2 + 1][c] * w;
    }
    sWt[(size_t)(nb + ng * 2 + 0) * 32 + col] = acc[0];
    sWt[(size_t)(nb + ng * 2 + 1) * 32 + col] = acc[1];
  }
}

// ---------------- merged layer kernel: mega (per wave) + node update (wave 0) ----------------
// Grid = NN/2 blocks x 128 threads. Wave wv computes agg for node order[blockIdx*2+wv]
// into LDS; after one barrier, wave 0 runs the pair node-update + (optionally) the
// next-layer transforms into the double-buffered output arrays. Transform inputs are
// read from the *other* buffer, so no cross-block race exists within the launch.
__global__ __launch_bounds__(128) void k_layer(
    const int* __restrict__ row_off, const int* __restrict__ act_off,
    const int* __restrict__ order,
    const int* __restrict__ src_a, const float* __restrict__ d_a,
    const float* __restrict__ gsL, const float* __restrict__ gvL,
    const float* __restrict__ gtL, const float* __restrict__ attn_l,
    const float* __restrict__ sWsrc, const float* __restrict__ sWv,
    const float* __restrict__ sWt, const float* __restrict__ vW,
    const float* __restrict__ tW, const float* __restrict__ sh_a,
    float* __restrict__ s, float* __restrict__ v, float* __restrict__ t,
    const float* __restrict__ Wo_s, const float* __restrict__ Wo_v,
    const float* __restrict__ Wo_t, const float* __restrict__ g_s,
    const float* __restrict__ b_s, const float* __restrict__ g_v,
    const float* __restrict__ g_t, int do_tf,
    const float* __restrict__ Ws_src, const float* __restrict__ Ws_v2,
    const float* __restrict__ Ws_t2, const float* __restrict__ Wv_v,
    const float* __restrict__ Wt_t, float* __restrict__ sWsrcO,
    float* __restrict__ sWvO, float* __restrict__ sWtO,
    float* __restrict__ vWO, float* __restrict__ tWO) {
  __shared__ float stgS[2][128];
  __shared__ float stgV[2][192];
  __shared__ float stgT[2][160];
  __shared__ float sN[2][128];
  __shared__ float vN[2][192];
  __shared__ float tN[2][160];
  __shared__ int nodesh[2];
  int wv = threadIdx.x >> 6, lane = threadIdx.x & 63;
  int lt = lane & 31, nh = lane >> 5;
  int slot = blockIdx.x * 2 + wv;
  int n = order[slot];
  int alo = act_off[n], ahi = act_off[n + 1];
  int nact = ahi - alo;
  int ninact = (row_off[n + 1] - row_off[n]) - nact;
  const float sc = (float)(TABN - 1) / DTAB;
  float atnA = attn_l[lane];
  float atnB = attn_l[64 + lane];
  float rm0, rm1, rm2, rm3;
  rm0 = rm1 = rm2 = rm3 = (ninact > 0) ? 0.0f : -1e30f;
  float rs0 = 0.f, rs1 = 0.f, rs2 = 0.f, rs3 = 0.f;
  float as0 = 0.f, as1 = 0.f;
  float av0 = 0.f, av1 = 0.f, av2 = 0.f;
  float at0 = 0.f, at1 = 0.f, at2 = 0.f, at3 = 0.f, at4 = 0.f;
  int a = alo;
  for (; a + 1 < ahi; a += 2) {
    int aA = a, aB = a + 1;
    float dA = d_a[aA], dB = d_a[aB];
    int snA = src_a[aA], snB = src_a[aB];
    float xA = fminf(dA * sc, (float)(TABN - 1) - 1.0f);
    float xB = fminf(dB * sc, (float)(TABN - 1) - 1.0f);
    int iA = (int)xA, iB = (int)xB;
    float fA = xA - (float)iA, fB = xB - (float)iB;
    float g1A = 1.0f - fA, g1B = 1.0f - fB;
    const float* gA = gsL + (size_t)iA * 128;
    const float* gB = gsL + (size_t)iB * 128;
    float gsA_A = gA[lane] * g1A + gA[128 + lane] * fA;
    float gsB_A = gA[64 + lane] * g1A + gA[192 + lane] * fA;
    float gsA_B = gB[lane] * g1B + gB[128 + lane] * fB;
    float gsB_B = gB[64 + lane] * g1B + gB[192 + lane] * fB;
    float m0A = sWsrc[(size_t)snA * 128 + lane] * gsA_A;
    float m1A = sWsrc[(size_t)snA * 128 + 64 + lane] * gsB_A;
    float m0B = sWsrc[(size_t)snB * 128 + lane] * gsA_B;
    float m1B = sWsrc[(size_t)snB * 128 + 64 + lane] * gsB_B;
    const float* gvA = gvL + (size_t)iA * 128;
    const float* gvB = gvL + (size_t)iB * 128;
    float2 pA0 = *(const float2*)&gvA[2 * lane];
    float2 pA1 = *(const float2*)&gvA[128 + 2 * lane];
    float2 pB0 = *(const float2*)&gvB[2 * lane];
    float2 pB1 = *(const float2*)&gvB[128 + 2 * lane];
    float gavA = pA0.x * g1A + pA1.x * fA;
    float gbvA = pA0.y * g1A + pA1.y * fA;
    float gavB = pB0.x * g1B + pB1.x * fB;
    float gbvB = pB0.y * g1B + pB1.y * fB;
    float svA = sWv[(size_t)snA * 64 + lane];
    float svB = sWv[(size_t)snB * 64 + lane];
    float4 s1A = *(const float4*)&sh_a[(size_t)aA * 8];
    float4 s2A = *(const float4*)&sh_a[(size_t)aA * 8 + 4];
    float4 s1B = *(const float4*)&sh_a[(size_t)aB * 8];
    float4 s2B = *(const float4*)&sh_a[(size_t)aB * 8 + 4];
    const float* vpA = &vW[(size_t)snA * 192 + lane];
    const float* vpB = &vW[(size_t)snB * 192 + lane];
    float vA0 = vpA[0], vA1 = vpA[64], vA2 = vpA[128];
    float vB0 = vpB[0], vB1 = vpB[64], vB2 = vpB[128];
    float gatA = 0.f, gbtA = 0.f, gatB = 0.f, gbtB = 0.f;
    float stA = 0.f, stB = 0.f;
    float tA0 = 0.f, tA1 = 0.f, tA2 = 0.f, tA3 = 0.f, tA4 = 0.f;
    float tB0 = 0.f, tB1 = 0.f, tB2 = 0.f, tB3 = 0.f, tB4 = 0.f;
    if (lane < 32) {
      const float* gtA = gtL + (size_t)iA * 64;
      const float* gtB = gtL + (size_t)iB * 64;
      float2 qA0 = *(const float2*)&gtA[2 * lt];
      float2 qA1 = *(const float2*)&gtA[64 + 2 * lt];
      float2 qB0 = *(const float2*)&gtB[2 * lt];
      float2 qB1 = *(const float2*)&gtB[64 + 2 * lt];
      gatA = qA0.x * g1A + qA1.x * fA;
      gbtA = qA0.y * g1A + qA1.y * fA;
      gatB = qB0.x * g1B + qB1.x * fB;
      gbtB = qB0.y * g1B + qB1.y * fB;
      stA = sWt[(size_t)snA * 32 + lane];
      stB = sWt[(size_t)snB * 32 + lane];
      const float* tpA = &tW[(size_t)snA * 160 + lane];
      const float* tpB = &tW[(size_t)snB * 160 + lane];
      tA0 = tpA[0]; tA1 = tpA[32]; tA2 = tpA[64]; tA3 = tpA[96]; tA4 = tpA[128];
      tB0 = tpB[0]; tB1 = tpB[32]; tB2 = tpB[64]; tB3 = tpB[96]; tB4 = tpB[128];
    }
    float p01A = m0A * atnA, p23A = m1A * atnB;
    float p01B = m0B * atnA, p23B = m1B * atnB;
    #pragma unroll
    for (int mm = 1; mm < 32; mm <<= 1) {
      p01A += __shfl_xor(p01A, mm);
      p23A += __shfl_xor(p23A, mm);
      p01B += __shfl_xor(p01B, mm);
      p23B += __shfl_xor(p23B, mm);
    }
    float l0A = __shfl(p01A, 0), l1A = __shfl(p01A, 32);
    float l2A = __shfl(p23A, 0), l3A = __shfl(p23A, 32);
    float l0B = __shfl(p01B, 0), l1B = __shfl(p01B, 32);
    float l2B = __shfl(p23B, 0), l3B = __shfl(p23B, 32);
    float nm0 = fmaxf(rm0, fmaxf(l0A, l0B));
    float nm1 = fmaxf(rm1, fmaxf(l1A, l1B));
    float nm2 = fmaxf(rm2, fmaxf(l2A, l2B));
    float nm3 = fmaxf(rm3, fmaxf(l3A, l3B));
    float wA0 = __expf(l0A - nm0), wA1 = __expf(l1A - nm1);
    float wA2 = __expf(l2A - nm2), wA3 = __expf(l3A - nm3);
    float wB0 = __expf(l0B - nm0), wB1 = __expf(l1B - nm1);
    float wB2 = __expf(l2B - nm2), wB3 = __expf(l3B - nm3);
    float wSA0 = (lane < 32) ? wA0 : wA1, wSA1 = (lane < 32) ? wA2 : wA3;
    float wSB0 = (lane < 32) ? wB0 : wB1, wSB1 = (lane < 32) ? wB2 : wB3;
    float addS0 = wSA0 * m0A + wSB0 * m0B;
    float addS1 = wSA1 * m1A + wSB1 * m1B;
    float wVA = (lane < 16) ? wA0 : (lane < 32) ? wA1 : (lane < 48) ? wA2 : wA3;
    float wVB = (lane < 16) ? wB0 : (lane < 32) ? wB1 : (lane < 48) ? wB2 : wB3;
    float avvA = svA * gavA, avvB = svB * gavB;
    float addV0 = wVA * (avvA * s1A.x + vA0 * gbvA) + wVB * (avvB * s1B.x + vB0 * gbvB);
    float addV1 = wVA * (avvA * s1A.y + vA1 * gbvA) + wVB * (avvB * s1B.y + vB1 * gbvB);
    float addV2 = wVA * (avvA * s1A.z + vA2 * gbvA) + wVB * (avvB * s1B.z + vB2 * gbvB);
    float wTA = (lane < 8) ? wA0 : (lane < 16) ? wA1 : (lane < 24) ? wA2 : wA3;
    float wTB = (lane < 8) ? wB0 : (lane < 16) ? wB1 : (lane < 24) ? wB2 : wB3;
    float attA = stA * gatA, attB = stB * gatB;
    float addT0 = wTA * (attA * s1A.w + tA0 * gbtA) + wTB * (attB * s1B.w + tB0 * gbtB);
    float addT1 = wTA * (attA * s2A.x + tA1 * gbtA) + wTB * (attB * s2B.x + tB1 * gbtB);
    float addT2 = wTA * (attA * s2A.y + tA2 * gbtA) + wTB * (attB * s2B.y + tB2 * gbtB);
    float addT3 = wTA * (attA * s2A.z + tA3 * gbtA) + wTB * (attB * s2B.z + tB3 * gbtB);
    float addT4 = wTA * (attA * s2A.w + tA4 * gbtA) + wTB * (attB * s2B.w + tB4 * gbtB);
    if (nm0 == rm0 && nm1 == rm1 && nm2 == rm2 && nm3 == rm3) {
      rs0 += wA0 + wB0; rs1 += wA1 + wB1; rs2 += wA2 + wB2; rs3 += wA3 + wB3;
      as0 += addS0; as1 += addS1;
      av0 += addV0; av1 += addV1; av2 += addV2;
      at0 += addT0; at1 += addT1; at2 += addT2; at3 += addT3; at4 += addT4;
    } else {
      float f0 = __expf(rm0 - nm0), f1 = __expf(rm1 - nm1);
      float f2 = __expf(rm2 - nm2), f3 = __expf(rm3 - nm3);
      rm0 = nm0; rm1 = nm1; rm2 = nm2; rm3 = nm3;
      rs0 = rs0 * f0 + wA0 + wB0; rs1 = rs1 * f1 + wA1 + wB1;
      rs2 = rs2 * f2 + wA2 + wB2; rs3 = rs3 * f3 + wA3 + wB3;
      float fS0 = (lane < 32) ? f0 : f1, fS1 = (lane < 32) ? f2 : f3;
      as0 = as0 * fS0 + addS0; as1 = as1 * fS1 + addS1;
      float fV = (lane < 16) ? f0 : (lane < 32) ? f1 : (lane < 48) ? f2 : f3;
      av0 = av0 * fV + addV0; av1 = av1 * fV + addV1; av2 = av2 * fV + addV2;
      float fT = (lane < 8) ? f0 : (lane < 16) ? f1 : (lane < 24) ? f2 : f3;
      at0 = at0 * fT + addT0; at1 = at1 * fT + addT1; at2 = at2 * fT + addT2;
      at3 = at3 * fT + addT3; at4 = at4 * fT + addT4;
    }
  }
  for (; a < ahi; ++a) {
    float x = d_a[a] * sc;
    x = fminf(x, (float)(TABN - 1) - 1.0f);
    int i0 = (int)x; float f = x - (float)i0; float g1 = 1.0f - f;
    int sn = src_a[a];
    const float* g0 = gsL + (size_t)i0 * 128;
    float gsA = g0[lane] * g1 + g0[128 + lane] * f;
    float gsB = g0[64 + lane] * g1 + g0[192 + lane] * f;
    float m0 = sWsrc[(size_t)sn * 128 + lane] * gsA;
    float m1 = sWsrc[(size_t)sn * 128 + 64 + lane] * gsB;
    float p01 = m0 * atnA;
    float p23 = m1 * atnB;
    #pragma unroll
    for (int mm = 1; mm < 32; mm <<= 1) {
      p01 += __shfl_xor(p01, mm);
      p23 += __shfl_xor(p23, mm);
    }
    float l0 = __shfl(p01, 0), l1 = __shfl(p01, 32);
    float l2 = __shfl(p23, 0), l3 = __shfl(p23, 32);
    float nm0 = fmaxf(rm0, l0), nm1 = fmaxf(rm1, l1);
    float nm2 = fmaxf(rm2, l2), nm3 = fmaxf(rm3, l3);
    float f0 = __expf(rm0 - nm0), f1 = __expf(rm1 - nm1);
    float f2 = __expf(rm2 - nm2), f3 = __expf(rm3 - nm3);
    float w0 = __expf(l0 - nm0), w1 = __expf(l1 - nm1);
    float w2 = __expf(l2 - nm2), w3 = __expf(l3 - nm3);
    rm0 = nm0; rm1 = nm1; rm2 = nm2; rm3 = nm3;
    rs0 = rs0 * f0 + w0; rs1 = rs1 * f1 + w1;
    rs2 = rs2 * f2 + w2; rs3 = rs3 * f3 + w3;
    float fS0 = (lane < 32) ? f0 : f1;
    float fS1 = (lane < 32) ? f2 : f3;
    float wS0 = (lane < 32) ? w0 : w1;
    float wS1 = (lane < 32) ? w2 : w3;
    as0 = as0 * fS0 + wS0 * m0;
    as1 = as1 * fS1 + wS1 * m1;
    const float* gv0 = gvL + (size_t)i0 * 128;
    float2 p0 = *(const float2*)&gv0[2 * lane];
    float2 p1 = *(const float2*)&gv0[128 + 2 * lane];
    float gav = p0.x * g1 + p1.x * f;
    float gbv = p0.y * g1 + p1.y * f;
    float fV = (lane < 16) ? f0 : (lane < 32) ? f1 : (lane < 48) ? f2 : f3;
    float wV = (lane < 16) ? w0 : (lane < 32) ? w1 : (lane < 48) ? w2 : w3;
    float avv = sWv[(size_t)sn * 64 + lane] * gav;
    float4 s1 = *(const float4*)&sh_a[(size_t)a * 8];
    float4 s2 = *(const float4*)&sh_a[(size_t)a * 8 + 4];
    const float* vp = &vW[(size_t)sn * 192 + lane];
    av0 = av0 * fV + wV * (avv * s1.x + vp[0] * gbv);
    av1 = av1 * fV + wV * (avv * s1.y + vp[64] * gbv);
    av2 = av2 * fV + wV * (avv * s1.z + vp[128] * gbv);
    if (lane < 32) {
      const float* gt0 = gtL + (size_t)i0 * 64;
      float2 q0 = *(const float2*)&gt0[2 * lt];
      float2 q1 = *(const float2*)&gt0[64 + 2 * lt];
      float gat = q0.x * g1 + q1.x * f;
      float gbt = q0.y * g1 + q1.y * f;
      float fT = (lane < 8) ? f0 : (lane < 16) ? f1 : (lane < 24) ? f2 : f3;
      float wT = (lane < 8) ? w0 : (lane < 16) ? w1 : (lane < 24) ? w2 : w3;
      float att = sWt[(size_t)sn * 32 + lane] * gat;
      const float* tp = &tW[(size_t)sn * 160 + lane];
      at0 = at0 * fT + wT * (att * s1.w + tp[0] * gbt);
      at1 = at1 * fT + wT * (att * s2.x + tp[32] * gbt);
      at2 = at2 * fT + wT * (att * s2.y + tp[64] * gbt);
      at3 = at3 * fT + wT * (att * s2.z + tp[96] * gbt);
      at4 = at4 * fT + wT * (att * s2.w + tp[128] * gbt);
    }
  }
  if (ninact > 0) {
    rs0 += (float)ninact * __expf(-rm0);
    rs1 += (float)ninact * __expf(-rm1);
    rs2 += (float)ninact * __expf(-rm2);
    rs3 += (float)ninact * __expf(-rm3);
  }
  float r0 = 1.0f / (rs0 + 1e-9f), r1 = 1.0f / (rs1 + 1e-9f);
  float r2 = 1.0f / (rs2 + 1e-9f), r3 = 1.0f / (rs3 + 1e-9f);
  float rS0 = (lane < 32) ? r0 : r1;
  float rS1 = (lane < 32) ? r2 : r3;
  float rV = (lane < 16) ? r0 : (lane < 32) ? r1 : (lane < 48) ? r2 : r3;
  // deposit normalized agg into LDS (same layout the update staging used)
  stgS[wv][lane] = as0 * rS0;
  stgS[wv][64 + lane] = as1 * rS1;
  stgV[wv][lane * 3 + 0] = av0 * rV;
  stgV[wv][lane * 3 + 1] = av1 * rV;
  stgV[wv][lane * 3 + 2] = av2 * rV;
  if (lane < 32) {
    float rT = (lane < 8) ? r0 : (lane < 16) ? r1 : (lane < 24) ? r2 : r3;
    stgT[wv][lane * 5 + 0] = at0 * rT;
    stgT[wv][lane * 5 + 1] = at1 * rT;
    stgT[wv][lane * 5 + 2] = at2 * rT;
    stgT[wv][lane * 5 + 3] = at3 * rT;
    stgT[wv][lane * 5 + 4] = at4 * rT;
  }
  if (lane == 0) nodesh[wv] = n;
  __syncthreads();
  if (wv != 0) return;
  // ---- update phase (wave 0 only; identical math to the verified pair-body) ----
  int nA = nodesh[0], nB = nodesh[1];
  int ntt = nh ? nB : nA;
  float sA0 = s[(size_t)nA * 128 + lane];
  float sA1 = s[(size_t)nA * 128 + 64 + lane];
  float sB0 = s[(size_t)nB * 128 + lane];
  float sB1 = s[(size_t)nB * 128 + 64 + lane];
  #pragma unroll 8
  for (int c = 0; c < 128; c++) {
    float w0 = Wo_s[c * 128 + lane];
    float w1 = Wo_s[c * 128 + 64 + lane];
    float ax = stgS[0][c], bx = stgS[1][c];
    sA0 += ax * w0; sA1 += ax * w1;
    sB0 += bx * w0; sB1 += bx * w1;
  }
  // prefetch v_old / t_old
  float voA0 = v[(size_t)nA * 192 + lane * 3 + 0];
  float voA1 = v[(size_t)nA * 192 + lane * 3 + 1];
  float voA2 = v[(size_t)nA * 192 + lane * 3 + 2];
  float voB0 = v[(size_t)nB * 192 + lane * 3 + 0];
  float voB1 = v[(size_t)nB * 192 + lane * 3 + 1];
  float voB2 = v[(size_t)nB * 192 + lane * 3 + 2];
  // LayerNorm(s)
  float smA = sA0 + sA1, sqA = sA0 * sA0 + sA1 * sA1;
  float smB = sB0 + sB1, sqB = sB0 * sB0 + sB1 * sB1;
  #pragma unroll
  for (int m = 1; m < 64; m <<= 1) {
    smA += __shfl_xor(smA, m); sqA += __shfl_xor(sqA, m);
    smB += __shfl_xor(smB, m); sqB += __shfl_xor(sqB, m);
  }
  float muA = smA / 128.0f, muB = smB / 128.0f;
  float varA = sqA / 128.0f - muA * muA; if (varA < 0.f) varA = 0.f;
  float varB = sqB / 128.0f - muB * muB; if (varB < 0.f) varB = 0.f;
  float riA = rsqrtf(varA + 1e-6f), riB = rsqrtf(varB + 1e-6f);
  float gs0 = g_s[lane], gs1 = g_s[64 + lane];
  float bs0 = b_s[lane], bs1 = b_s[64 + lane];
  float yA0 = (sA0 - muA) * riA * gs0 + bs0;
  float yA1 = (sA1 - muA) * riA * gs1 + bs1;
  float yB0 = (sB0 - muB) * riB * gs0 + bs0;
  float yB1 = (sB1 - muB) * riB * gs1 + bs1;
  s[(size_t)nA * 128 + lane] = yA0;
  s[(size_t)nA * 128 + 64 + lane] = yA1;
  s[(size_t)nB * 128 + lane] = yB0;
  s[(size_t)nB * 128 + 64 + lane] = yB1;
  sN[0][lane] = yA0; sN[0][64 + lane] = yA1;
  sN[1][lane] = yB0; sN[1][64 + lane] = yB1;
  // v-matmul
  float vA0 = voA0, vA1 = voA1, vA2 = voA2;
  float vB0 = voB0, vB1 = voB1, vB2 = voB2;
  #pragma unroll 8
  for (int c = 0; c < 64; c++) {
    float w = Wo_v[c * 64 + lane];
    vA0 += stgV[0][c * 3 + 0] * w;
    vA1 += stgV[0][c * 3 + 1] * w;
    vA2 += stgV[0][c * 3 + 2] * w;
    vB0 += stgV[1][c * 3 + 0] * w;
    vB1 += stgV[1][c * 3 + 1] * w;
    vB2 += stgV[1][c * 3 + 2] * w;
  }
  float to0 = t[(size_t)ntt * 160 + lt * 5 + 0];
  float to1 = t[(size_t)ntt * 160 + lt * 5 + 1];
  float to2 = t[(size_t)ntt * 160 + lt * 5 + 2];
  float to3 = t[(size_t)ntt * 160 + lt * 5 + 3];
  float to4 = t[(size_t)ntt * 160 + lt * 5 + 4];
  // RMS(v)
  float ssqA = vA0 * vA0 + vA1 * vA1 + vA2 * vA2;
  float ssqB = vB0 * vB0 + vB1 * vB1 + vB2 * vB2;
  #pragma unroll
  for (int m = 1; m < 64; m <<= 1) {
    ssqA += __shfl_xor(ssqA, m);
    ssqB += __shfl_xor(ssqB, m);
  }
  float rivA = rsqrtf(ssqA / 64.0f + 1e-6f);
  float rivB = rsqrtf(ssqB / 64.0f + 1e-6f);
  float gv = g_v[lane];
  float vyA0 = vA0 * rivA * gv, vyA1 = vA1 * rivA * gv, vyA2 = vA2 * rivA * gv;
  float vyB0 = vB0 * rivB * gv, vyB1 = vB1 * rivB * gv, vyB2 = vB2 * rivB * gv;
  v[(size_t)nA * 192 + lane * 3 + 0] = vyA0;
  v[(size_t)nA * 192 + lane * 3 + 1] = vyA1;
  v[(size_t)nA * 192 + lane * 3 + 2] = vyA2;
  v[(size_t)nB * 192 + lane * 3 + 0] = vyB0;
  v[(size_t)nB * 192 + lane * 3 + 1] = vyB1;
  v[(size_t)nB * 192 + lane * 3 + 2] = vyB2;
  vN[0][lane * 3 + 0] = vyA0; vN[0][lane * 3 + 1] = vyA1; vN[0][lane * 3 + 2] = vyA2;
  vN[1][lane * 3 + 0] = vyB0; vN[1][lane * 3 + 1] = vyB1; vN[1][lane * 3 + 2] = vyB2;
  // t-matmul (half-trick)
  float at0u = to0, at1u = to1, at2u = to2, at3u = to3, at4u = to4;
  #pragma unroll 4
  for (int c = 0; c < 32; c++) {
    float w = Wo_t[c * 32 + lt];
    at0u += stgT[nh][c * 5 + 0] * w;
    at1u += stgT[nh][c * 5 + 1] * w;
    at2u += stgT[nh][c * 5 + 2] * w;
    at3u += stgT[nh][c * 5 + 3] * w;
    at4u += stgT[nh][c * 5 + 4] * w;
  }
  float ssqt = at0u * at0u + at1u * at1u + at2u * at2u + at3u * at3u + at4u * at4u;
  #pragma unroll
  for (int m = 1; m < 32; m <<= 1) ssqt += __shfl_xor(ssqt, m);
  float rit = rsqrtf(ssqt / 32.0f + 1e-6f);
  float gt = g_t[lt];
  float ty0 = at0u * rit * gt, ty1 = at1u * rit * gt, ty2 = at2u * rit * gt;
  float ty3 = at3u * rit * gt, ty4 = at4u * rit * gt;
  t[(size_t)ntt * 160 + lt * 5 + 0] = ty0;
  t[(size_t)ntt * 160 + lt * 5 + 1] = ty1;
  t[(size_t)ntt * 160 + lt * 5 + 2] = ty2;
  t[(size_t)ntt * 160 + lt * 5 + 3] = ty3;
  t[(size_t)ntt * 160 + lt * 5 + 4] = ty4;
  if (!do_tf) return;
  tN[nh][lt * 5 + 0] = ty0;
  tN[nh][lt * 5 + 1] = ty1;
  tN[nh][lt * 5 + 2] = ty2;
  tN[nh][lt * 5 + 3] = ty3;
  tN[nh][lt * 5 + 4] = ty4;
  asm volatile("s_waitcnt lgkmcnt(0)" ::: "memory");
  // ---- transforms for next layer ----
  {
    float cA0 = 0.f, cA1 = 0.f, cB0 = 0.f, cB1 = 0.f;
    #pragma unroll 8
    for (int c = 0; c < 128; c++) {
      float w0 = Ws_src[c * 128 + lane];
      float w1 = Ws_src[c * 128 + 64 + lane];
      float aA = sN[0][c], aB = sN[1][c];
      cA0 += aA * w0; cA1 += aA * w1;
      cB0 += aB * w0; cB1 += aB * w1;
    }
    sWsrcO[(size_t)nA * 128 + lane] = cA0;
    sWsrcO[(size_t)nA * 128 + 64 + lane] = cA1;
    sWsrcO[(size_t)nB * 128 + lane] = cB0;
    sWsrcO[(size_t)nB * 128 + 64 + lane] = cB1;
  }
  {
    float cvA = 0.f, cvB = 0.f, ct = 0.f;
    #pragma unroll 8
    for (int c = 0; c < 128; c++) {
      float wvv = Ws_v2[c * 64 + lane];
      float wtt = Ws_t2[c * 32 + lt];
      float aA = sN[0][c], aB = sN[1][c];
      cvA += aA * wvv; cvB += aB * wvv;
      ct += sN[nh][c] * wtt;
    }
    sWvO[(size_t)nA * 64 + lane] = cvA;
    sWvO[(size_t)nB * 64 + lane] = cvB;
    sWtO[(size_t)ntt * 32 + lt] = ct;
  }
  {
    float wA0 = 0.f, wA1 = 0.f, wA2 = 0.f, wB0 = 0.f, wB1 = 0.f, wB2 = 0.f;
    #pragma unroll 8
    for (int c = 0; c < 64; c++) {
      float w = Wv_v[c * 64 + lane];
      wA0 += vN[0][c * 3 + 0] * w;
      wA1 += vN[0][c * 3 + 1] * w;
      wA2 += vN[0][c * 3 + 2] * w;
      wB0 += vN[1][c * 3 + 0] * w;
      wB1 += vN[1][c * 3 + 1] * w;
      wB2 += vN[1][c * 3 + 2] * w;
    }
    vWO[(size_t)nA * 192 + lane] = wA0;
    vWO[(size_t)nA * 192 + 64 + lane] = wA1;
    vWO[(size_t)nA * 192 + 128 + lane] = wA2;
    vWO[(size_t)nB * 192 + lane] = wB0;
    vWO[(size_t)nB * 192 + 64 + lane] = wB1;
    vWO[(size_t)nB * 192 + 128 + lane] = wB2;
  }
  {
    float u0 = 0.f, u1 = 0.f, u2 = 0.f, u3 = 0.f, u4 = 0.f;
    #pragma unroll 4
    for (int c = 0; c < 32; c++) {
      float w = Wt_t[c * 32 + lt];
      u0 += tN[nh][c * 5 + 0] * w;
      u1 += tN[nh][c * 5 + 1] * w;
      u2 += tN[nh][c * 5 + 2] * w;
      u3 += tN[nh][c * 5 + 3] * w;
      u4 += tN[nh][c * 5 + 4] * w;
    }
    tWO[(size_t)ntt * 160 + lt] = u0;
    tWO[(size_t)ntt * 160 + 32 + lt] = u1;
    tWO[(size_t)ntt * 160 + 64 + lt] = u2;
    tWO[(size_t)ntt * 160 + 96 + lt] = u3;
    tWO[(size_t)ntt * 160 + 128 + lt] = u4;
  }
}

// ---------------- readout: 2 feature-blocks per staged s-tile ----------------
__global__ __launch_bounds__(256) void k_readout(
    const float* __restrict__ s, const int* __restrict__ batch,
    const float* __restrict__ W_feat, const float* __restrict__ b_feat,
    const float* __restrict__ W_out1, const float* __restrict__ b_out1,
    float* __restrict__ graph) {
  __shared__ float st[64][129];
  __shared__ float gacc[GG];
  int nb = blockIdx.x * 64;
  int fbb = blockIdx.y * 2;
  for (int idx = threadIdx.x; idx < 64 * 128; idx += 256) {
    int nl = idx >> 7, c = idx & 127;
    int n = nb + nl;
    st[nl][c] = (n < NN) ? s[(size_t)n * 128 + c] : 0.f;
  }
  if (threadIdx.x < GG) gacc[threadIdx.x] = 0.f;
  __syncthreads();
  int wv = threadIdx.x >> 6, lane = threadIdx.x & 63;
  int fg = lane & 15;
  int ns = lane >> 4;
  int nodeb = wv * 16 + ns * 4;
  #pragma unroll
  for (int sub = 0; sub < 2; sub++) {
    int fb = fbb + sub;
    int f0 = fb * 64 + fg * 4;
    float acc[4][4];
    #pragma unroll
    for (int nn = 0; nn < 4; nn++)
      #pragma unroll
      for (int k = 0; k < 4; k++) acc[nn][k] = b_feat[f0 + k];
    #pragma unroll 4
    for (int c = 0; c < 128; c++) {
      float4 wq = *(const float4*)&W_feat[(size_t)c * 512 + f0];
      #pragma unroll
      for (int nn = 0; nn < 4; nn++) {
        float sv = st[nodeb + nn][c];
        acc[nn][0] += sv * wq.x;
        acc[nn][1] += sv * wq.y;
        acc[nn][2] += sv * wq.z;
        acc[nn][3] += sv * wq.w;
      }
    }
    float wo[4];
    #pragma unroll
    for (int k = 0; k < 4; k++) wo[k] = W_out1[f0 + k];
    float ep[4];
    #pragma unroll
    for (int nn = 0; nn < 4; nn++) {
      float p = 0.f;
      #pragma unroll
      for (int k = 0; k < 4; k++) p += fgelu(acc[nn][k]) * wo[k];
      ep[nn] = p;
    }
    #pragma unroll
    for (int mm = 1; mm < 16; mm <<= 1) {
      #pragma unroll
      for (int nn = 0; nn < 4; nn++) ep[nn] += __shfl_xor(ep[nn], mm);
    }
    if (fg == 0) {
      #pragma unroll
      for (int nn = 0; nn < 4; nn++) {
        int n = nb + nodeb + nn;
        if (n < NN) {
          float e = ep[nn];
          if (fb == 0) e += b_out1[0];
          atomicAdd(&gacc[batch[n]], e);
        }
      }
    }
  }
  __syncthreads();
  if (threadIdx.x < GG && gacc[threadIdx.x] != 0.f)
    atomicAdd(&graph[threadIdx.x], gacc[threadIdx.x]);
}

__global__ void k_finalize(const float* __restrict__ graph, const float* __restrict__ W_read,
                           const float* __restrict__ b_read, float* __restrict__ out) {
  int g = threadIdx.x;
  if (g < GG) out[g] = graph[g] * W_read[0] + b_read[0];
}

// ---------------- host ----------------
extern "C" void kernel_launch(void* const* d_in, const int* in_sizes, int n_in,
                              void* d_out, int out_size, void* d_ws, size_t ws_size,
                              hipStream_t stream) {
  const float* pos = (const float*)d_in[0];
  const int* node_atom = (const int*)d_in[1];
  const int* batch = (const int*)d_in[2];
  const int* esrc = (const int*)d_in[3];
  const int* edst = (const int*)d_in[4];
  const float* atom_emb = (const float*)d_in[5];
  const float* Wrad1 = (const float*)d_in[6];
  const float* brad1 = (const float*)d_in[7];
  const float* Wrad2 = (const float*)d_in[8];
  const float* brad2 = (const float*)d_in[9];
  const float* Ws_src = (const float*)d_in[10];
  const float* Ww_s = (const float*)d_in[11];
  const float* Ws_v = (const float*)d_in[12];
  const float* Ww_v = (const float*)d_in[13];
  const float* Wv_v = (const float*)d_in[14];
  const float* Ww_vv = (const float*)d_in[15];
  const float* Ws_t = (const float*)d_in[16];
  const float* Ww_t = (const float*)d_in[17];
  const float* Wt_t = (const float*)d_in[18];
  const float* Ww_tt = (const float*)d_in[19];
  const float* attn_a = (const float*)d_in[20];
  const float* Wo_s = (const float*)d_in[21];
  const float* Wo_v = (const float*)d_in[22];
  const float* Wo_t = (const float*)d_in[23];
  const float* g_s = (const float*)d_in[24];
  const float* b_s = (const float*)d_in[25];
  const float* g_v = (const float*)d_in[26];
  const float* g_t = (const float*)d_in[27];
  const float* W_feat = (const float*)d_in[28];
  const float* b_feat = (const float*)d_in[29];
  const float* W_out1 = (const float*)d_in[30];
  const float* b_out1 = (const float*)d_in[31];
  const float* W_read = (const float*)d_in[32];
  const float* b_read = (const float*)d_in[33];
  float* out = (float*)d_out;

  char* base = (char*)d_ws;
  size_t off = 0;
  auto alloc = [&](size_t bytes) -> char* {
    off = (off + 255) & ~(size_t)255;
    char* p = base + off;
    off += bytes;
    return p;
  };
  // ---- zero-init group A (ints), contiguous ----
  int* deg = (int*)alloc(NN * 4);
  int* cursor = (int*)alloc(NN * 4);
  int* dbkt = (int*)alloc(128 * 4);
  int* dbcur = (int*)alloc(128 * 4);
  float* graph = (float*)alloc(GG * 4);
  char* zeroA_end = base + off;
  // ---- zero-init group B (floats), contiguous: v, t, vW buffer A, tW buffer A ----
  float* v = (float*)alloc((size_t)NN * 192 * 4);
  float* t = (float*)alloc((size_t)NN * 160 * 4);
  float* vWA = (float*)alloc((size_t)NN * 192 * 4);
  float* tWA = (float*)alloc((size_t)NN * 160 * 4);
  char* zeroB_end = base + off;
  // ---- rest ----
  int* row_off = (int*)alloc((NN + 1) * 4);
  float* d_csr = (float*)alloc((size_t)EE * 4);
  int* src_csr = (int*)alloc((size_t)EE * 4);
  int* dst_csr = (int*)alloc((size_t)EE * 4);
  int* acnt = (int*)alloc(NN * 4);
  int* act_off = (int*)alloc((NN + 1) * 4);
  int* act_idx = (int*)alloc((size_t)EE * 4);
  int* dboff = (int*)alloc(129 * 4);
  int* order = (int*)alloc(NN * 4);
  float* d_a = (float*)alloc((size_t)EE * 4);
  int* src_a = (int*)alloc((size_t)EE * 4);
  float* sh_a = (float*)alloc((size_t)EE * 8 * 4);
  float* wtab = (float*)alloc((size_t)LL * TABN * 64 * 4);
  float* gs_tab = (float*)alloc((size_t)LL * TABN * 128 * 4);
  float* gv_tab = (float*)alloc((size_t)LL * TABN * 128 * 4);
  float* gt_tab = (float*)alloc((size_t)LL * TABN * 64 * 4);
  float* s = (float*)alloc((size_t)NN * 128 * 4);
  float* sWsrcA = (float*)alloc((size_t)NN * 128 * 4);
  float* sWvA = (float*)alloc((size_t)NN * 64 * 4);
  float* sWtA = (float*)alloc((size_t)NN * 32 * 4);
  float* sWsrcB = (float*)alloc((size_t)NN * 128 * 4);
  float* sWvB = (float*)alloc((size_t)NN * 64 * 4);
  float* sWtB = (float*)alloc((size_t)NN * 32 * 4);
  float* vWB = (float*)alloc((size_t)NN * 192 * 4);
  float* tWB = (float*)alloc((size_t)NN * 160 * 4);

  hipMemsetAsync(deg, 0, (size_t)(zeroA_end - (char*)deg), stream);
  hipMemsetAsync(v, 0, (size_t)(zeroB_end - (char*)v), stream);

  k_hist<<<(EE + 255) / 256, 256, 0, stream>>>(edst, deg);
  k_scan<<<1, 1024, 0, stream>>>(deg, row_off, NN);
  k_scatter<<<(EE + 255) / 256, 256, 0, stream>>>(esrc, edst, pos, row_off, cursor,
                                                  d_csr, src_csr, dst_csr);
  k_act_cnt<<<(NN + 255) / 256, 256, 0, stream>>>(row_off, d_csr, acnt, dbkt);
  k_scan2<<<2, 1024, 0, stream>>>(acnt, act_off, NN, dbkt, dboff, 128);
  k_act_fill<<<(NN + 255) / 256, 256, 0, stream>>>(row_off, d_csr, act_off, act_idx,
                                                   acnt, dboff, dbcur, order);
  k_geom_act<<<(EE + 255) / 256, 256, 0, stream>>>(act_idx, src_csr, dst_csr, pos, act_off,
                                                   d_a, src_a, sh_a);
  k_build_wtab<<<LL * (TABN / 16), 256, 0, stream>>>(Wrad1, brad1, Wrad2, brad2, wtab);
  k_build_tabs<<<LL * (TABN / EB), 320, 0, stream>>>(wtab, Ww_s, Ww_v, Ww_vv, Ww_t, Ww_tt,
                                                     gs_tab, gv_tab, gt_tab);
  // layer-0 transforms fused with s init (v/t zero; vWA/tWA zeroed by group-B memset)
  k_node_tf0<<<NN / 16, 256, 0, stream>>>(node_atom, atom_emb, s, Ws_src, Ws_v, Ws_t,
                                          sWsrcA, sWvA, sWtA);

  for (int l = 0; l < LL; l++) {
    const float* gsL = gs_tab + (size_t)l * TABN * 128;
    const float* gvL = gv_tab + (size_t)l * TABN * 128;
    const float* gtL = gt_tab + (size_t)l * TABN * 64;
    int even = ((l & 1) == 0);
    const float* sWsrcI = even ? sWsrcA : sWsrcB;
    const float* sWvI = even ? sWvA : sWvB;
    const float* sWtI = even ? sWtA : sWtB;
    const float* vWI = even ? vWA : vWB;
    const float* tWI = even ? tWA : tWB;
    float* sWsrcO = even ? sWsrcB : sWsrcA;
    float* sWvO = even ? sWvB : sWvA;
    float* sWtO = even ? sWtB : sWtA;
    float* vWO = even ? vWB : vWA;
    float* tWO = even ? tWB : tWA;
    int dtf = (l < LL - 1) ? 1 : 0;
    int ln = (l < LL - 1) ? (l + 1) : l;  // clamp (unused when dtf==0)
    k_layer<<<NN / 2, 128, 0, stream>>>(
        row_off, act_off, order, src_a, d_a, gsL, gvL, gtL,
        attn_a + (size_t)l * 128,
        sWsrcI, sWvI, sWtI, vWI, tWI, sh_a, s, v, t,
        Wo_s + (size_t)l * 128 * 128, Wo_v + (size_t)l * 64 * 64,
        Wo_t + (size_t)l * 32 * 32,
        g_s + (size_t)l * 128, b_s + (size_t)l * 128,
        g_v + (size_t)l * 64, g_t + (size_t)l * 32, dtf,
        Ws_src + (size_t)ln * 128 * 128, Ws_v + (size_t)ln * 128 * 64,
        Ws_t + (size_t)ln * 128 * 32, Wv_v + (size_t)ln * 64 * 64,
        Wt_t + (size_t)ln * 32 * 32,
        sWsrcO, sWvO, sWtO, vWO, tWO);
  }
  dim3 rg((NN + 63) / 64, 4);
  k_readout<<<rg, 256, 0, stream>>>(s, batch, W_feat, b_feat, W_out1, b_out1, graph);
  k_finalize<<<1, 64, 0, stream>>>(graph, W_read, b_read, out);
}

// Round 15
// 942.272 us; speedup vs baseline: 1.1190x; 1.0164x over previous
//
#include <hip/hip_runtime.h>
#include <math.h>

#define NN 10000
#define EE 320000
#define GG 32
#define LL 6
#define TABN 2048
#define DTAB 5.45f
#define DCUT 5.4f

__device__ __forceinline__ float fsilu(float x) { return x / (1.0f + __expf(-x)); }
__device__ __forceinline__ float fgelu(float x) {
  float y = 0.7978845608f * (x + 0.044715f * x * x * x);
  float t = 1.0f - 2.0f / (__expf(2.0f * y) + 1.0f);
  return 0.5f * x * (1.0f + t);
}

// ---------------- CSR build ----------------
__global__ void k_hist(const int* __restrict__ dst, int* __restrict__ deg) {
  int e = blockIdx.x * blockDim.x + threadIdx.x;
  if (e < EE) atomicAdd(&deg[dst[e]], 1);
}

__global__ void k_scan(const int* __restrict__ cnt, int* __restrict__ off, int n) {
  __shared__ int tsum[1024];
  int chunk = (n + 1023) / 1024;
  int base = (int)threadIdx.x * chunk;
  int local = 0;
  for (int i = 0; i < chunk; i++) {
    int idx = base + i;
    local += (idx < n) ? cnt[idx] : 0;
  }
  tsum[threadIdx.x] = local;
  __syncthreads();
  for (int o = 1; o < 1024; o <<= 1) {
    int tv = (threadIdx.x >= (unsigned)o) ? tsum[threadIdx.x - o] : 0;
    __syncthreads();
    tsum[threadIdx.x] += tv;
    __syncthreads();
  }
  int run = tsum[threadIdx.x] - local;
  for (int i = 0; i < chunk; i++) {
    int idx = base + i;
    if (idx < n) {
      run += cnt[idx];
      off[idx + 1] = run;
    }
  }
  if (threadIdx.x == 0) off[0] = 0;
}

__global__ void k_scan2(const int* __restrict__ cntA, int* __restrict__ offA, int nA,
                        const int* __restrict__ cntB, int* __restrict__ offB, int nB) {
  const int* cnt = (blockIdx.x == 0) ? cntA : cntB;
  int* off = (blockIdx.x == 0) ? offA : offB;
  int n = (blockIdx.x == 0) ? nA : nB;
  __shared__ int tsum[1024];
  int chunk = (n + 1023) / 1024;
  int base = (int)threadIdx.x * chunk;
  int local = 0;
  for (int i = 0; i < chunk; i++) {
    int idx = base + i;
    local += (idx < n) ? cnt[idx] : 0;
  }
  tsum[threadIdx.x] = local;
  __syncthreads();
  for (int o = 1; o < 1024; o <<= 1) {
    int tv = (threadIdx.x >= (unsigned)o) ? tsum[threadIdx.x - o] : 0;
    __syncthreads();
    tsum[threadIdx.x] += tv;
    __syncthreads();
  }
  int run = tsum[threadIdx.x] - local;
  for (int i = 0; i < chunk; i++) {
    int idx = base + i;
    if (idx < n) {
      run += cnt[idx];
      off[idx + 1] = run;
    }
  }
  if (threadIdx.x == 0) off[0] = 0;
}

__global__ void k_scatter(const int* __restrict__ esrc, const int* __restrict__ edst,
                          const float* __restrict__ pos, const int* __restrict__ row_off,
                          int* __restrict__ cursor, float* __restrict__ d_csr,
                          int* __restrict__ src_csr, int* __restrict__ dst_csr) {
  int e = blockIdx.x * blockDim.x + threadIdx.x;
  if (e < EE) {
    int d = edst[e];
    int s = esrc[e];
    int p = atomicAdd(&cursor[d], 1);
    int slot = row_off[d] + p;
    float rx = pos[d * 3 + 0] - pos[s * 3 + 0];
    float ry = pos[d * 3 + 1] - pos[s * 3 + 1];
    float rz = pos[d * 3 + 2] - pos[s * 3 + 2];
    d_csr[slot] = sqrtf(rx * rx + ry * ry + rz * rz + 1e-6f);
    src_csr[slot] = s;
    dst_csr[slot] = d;
  }
}

__global__ void k_act_cnt(const int* __restrict__ row_off, const float* __restrict__ d_csr,
                          int* __restrict__ acnt, int* __restrict__ dbkt) {
  int n = blockIdx.x * blockDim.x + threadIdx.x;
  if (n >= NN) return;
  int c = 0;
  for (int j = row_off[n]; j < row_off[n + 1]; ++j) c += (d_csr[j] < DCUT) ? 1 : 0;
  acnt[n] = c;
  int b = 127 - min(127, c);
  atomicAdd(&dbkt[b], 1);
}

__global__ void k_act_fill(const int* __restrict__ row_off, const float* __restrict__ d_csr,
                           const int* __restrict__ act_off, int* __restrict__ act_idx,
                           const int* __restrict__ acnt, const int* __restrict__ dboff,
                           int* __restrict__ dbcur, int* __restrict__ order) {
  int n = blockIdx.x * blockDim.x + threadIdx.x;
  if (n >= NN) return;
  int a = act_off[n];
  for (int j = row_off[n]; j < row_off[n + 1]; ++j)
    if (d_csr[j] < DCUT) act_idx[a++] = j;
  int b = 127 - min(127, acnt[n]);
  int p = atomicAdd(&dbcur[b], 1);
  order[dboff[b] + p] = n;
}

__global__ void k_geom_act(const int* __restrict__ act_idx, const int* __restrict__ src_csr,
                           const int* __restrict__ dst_csr, const float* __restrict__ pos,
                           const int* __restrict__ act_off, float* __restrict__ d_a,
                           int* __restrict__ src_a, float* __restrict__ sh_a) {
  int a = blockIdx.x * blockDim.x + threadIdx.x;
  if (a >= act_off[NN]) return;
  int j = act_idx[a];
  int s = src_csr[j], dd = dst_csr[j];
  float rx = pos[dd * 3 + 0] - pos[s * 3 + 0];
  float ry = pos[dd * 3 + 1] - pos[s * 3 + 1];
  float rz = pos[dd * 3 + 2] - pos[s * 3 + 2];
  float d = sqrtf(rx * rx + ry * ry + rz * rz + 1e-6f);
  float inv = 1.0f / d;
  float x = rx * inv, y = ry * inv, z = rz * inv;
  d_a[a] = d;
  src_a[a] = s;
  const float s3 = 1.7320508075688772f;
  const float s5 = 2.23606797749979f;
  const float s15 = 3.872983346207417f;
  sh_a[a * 8 + 0] = s3 * x;
  sh_a[a * 8 + 1] = s3 * y;
  sh_a[a * 8 + 2] = s3 * z;
  sh_a[a * 8 + 3] = s15 * x * y;
  sh_a[a * 8 + 4] = s15 * y * z;
  sh_a[a * 8 + 5] = 0.5f * s5 * (3.0f * z * z - 1.0f);
  sh_a[a * 8 + 6] = s15 * x * z;
  sh_a[a * 8 + 7] = 0.5f * s15 * (x * x - y * y);
}

// ---------------- radial MLP table w(d) ----------------
__global__ void k_build_wtab(const float* __restrict__ Wrad1, const float* __restrict__ brad1,
                             const float* __restrict__ Wrad2, const float* __restrict__ brad2,
                             float* __restrict__ wtab) {
  int l = blockIdx.x / (TABN / 16);
  int blk = blockIdx.x % (TABN / 16);
  __shared__ float W1[128 * 64];
  __shared__ float W2[64 * 64];
  __shared__ float b1[64], b2[64];
  __shared__ float rbf_s[4][128];
  __shared__ float h_s[4][64];
  const float* w1p = Wrad1 + (size_t)l * 128 * 64;
  const float* w2p = Wrad2 + (size_t)l * 64 * 64;
  for (int i = threadIdx.x; i < 128 * 64; i += 256) W1[i] = w1p[i];
  for (int i = threadIdx.x; i < 64 * 64; i += 256) W2[i] = w2p[i];
  if (threadIdx.x < 64) {
    b1[threadIdx.x] = brad1[(size_t)l * 64 + threadIdx.x];
    b2[threadIdx.x] = brad2[(size_t)l * 64 + threadIdx.x];
  }
  __syncthreads();
  int wv = threadIdx.x >> 6, lane = threadIdx.x & 63;
  const float width = 5.0f / 128.0f;
  for (int k = wv; k < 16; k += 4) {
    int i = blk * 16 + k;
    float d = (float)i * (DTAB / (float)(TABN - 1));
    float c0 = (5.0f * (float)lane) / 127.0f;
    float c1 = (5.0f * (float)(lane + 64)) / 127.0f;
    float t0 = (d - c0) / width, t1 = (d - c1) / width;
    rbf_s[wv][lane] = __expf(-0.5f * t0 * t0);
    rbf_s[wv][lane + 64] = __expf(-0.5f * t1 * t1);
    float acc = b1[lane];
    #pragma unroll 8
    for (int i2 = 0; i2 < 128; i2++) acc += rbf_s[wv][i2] * W1[i2 * 64 + lane];
    acc = fsilu(acc);
    h_s[wv][lane] = acc;
    float acc2 = b2[lane];
    #pragma unroll 8
    for (int i2 = 0; i2 < 64; i2++) acc2 += h_s[wv][i2] * W2[i2 * 64 + lane];
    wtab[((size_t)l * TABN + i) * 64 + lane] = fsilu(acc2);
  }
}

// ---------------- fused product-table build ----------------
#define EB 8
__global__ __launch_bounds__(320) void k_build_tabs(
    const float* __restrict__ wtab, const float* __restrict__ Ww_s,
    const float* __restrict__ Ww_v, const float* __restrict__ Ww_vv,
    const float* __restrict__ Ww_t, const float* __restrict__ Ww_tt,
    float* __restrict__ gs_tab, float* __restrict__ gv_tab, float* __restrict__ gt_tab) {
  int l = blockIdx.x / (TABN / EB);
  int eb = (blockIdx.x % (TABN / EB)) * EB;
  __shared__ float ws[EB][64];
  int tid = threadIdx.x;
  for (int i = tid; i < EB * 64; i += 320)
    ws[i >> 6][i & 63] = wtab[((size_t)l * TABN + eb + (i >> 6)) * 64 + (i & 63)];
  __syncthreads();
  float acc[EB] = {};
  if (tid < 128) {
    int col = tid;
    const float* W = Ww_s + (size_t)l * 64 * 128;
    #pragma unroll 8
    for (int i = 0; i < 64; i++) {
      float w = W[i * 128 + col];
      #pragma unroll
      for (int e = 0; e < EB; e++) acc[e] += ws[e][i] * w;
    }
    #pragma unroll
    for (int e = 0; e < EB; e++)
      gs_tab[((size_t)l * TABN + eb + e) * 128 + col] = acc[e];
  } else if (tid < 256) {
    int cc = tid - 128;
    int c = cc >> 1;
    const float* W = ((cc & 1) ? Ww_vv : Ww_v) + (size_t)l * 64 * 64;
    #pragma unroll 8
    for (int i = 0; i < 64; i++) {
      float w = W[i * 64 + c];
      #pragma unroll
      for (int e = 0; e < EB; e++) acc[e] += ws[e][i] * w;
    }
    #pragma unroll
    for (int e = 0; e < EB; e++)
      gv_tab[((size_t)l * TABN + eb + e) * 128 + cc] = acc[e];
  } else {
    int cc = tid - 256;
    int c = cc >> 1;
    const float* W = ((cc & 1) ? Ww_tt : Ww_t) + (size_t)l * 64 * 32;
    #pragma unroll 8
    for (int i = 0; i < 64; i++) {
      float w = W[i * 32 + c];
      #pragma unroll
      for (int e = 0; e < EB; e++) acc[e] += ws[e][i] * w;
    }
    #pragma unroll
    for (int e = 0; e < EB; e++)
      gt_tab[((size_t)l * TABN + eb + e) * 64 + cc] = acc[e];
  }
}

// ---------------- layer-0 transforms fused with s-init ----------------
__global__ __launch_bounds__(256) void k_node_tf0(
    const int* __restrict__ node_atom, const float* __restrict__ atom_emb,
    float* __restrict__ s, const float* __restrict__ Ws_src,
    const float* __restrict__ Ws_v, const float* __restrict__ Ws_t,
    float* __restrict__ sWsrc, float* __restrict__ sWv, float* __restrict__ sWt) {
  int nb = blockIdx.x * 16;
  int tid = threadIdx.x;
  __shared__ float s16[16][129];
  for (int idx = tid; idx < 16 * 128; idx += 256) {
    int n = idx >> 7, c = idx & 127;
    float val = atom_emb[(size_t)node_atom[nb + n] * 128 + c];
    s16[n][c] = val;
    s[(size_t)(nb + n) * 128 + c] = val;
  }
  __syncthreads();
  {
    int col = tid & 127, ng = tid >> 7;
    float acc[8] = {0, 0, 0, 0, 0, 0, 0, 0};
    for (int c = 0; c < 128; c++) {
      float w = Ws_src[c * 128 + col];
      #pragma unroll
      for (int n = 0; n < 8; n++) acc[n] += s16[ng * 8 + n][c] * w;
    }
    #pragma unroll
    for (int n = 0; n < 8; n++) sWsrc[(size_t)(nb + ng * 8 + n) * 128 + col] = acc[n];
  }
  {
    int col = tid & 63, ng = tid >> 6;
    float acc[4] = {0, 0, 0, 0};
    for (int c = 0; c < 128; c++) {
      float w = Ws_v[c * 64 + col];
      #pragma unroll
      for (int n = 0; n < 4; n++) acc[n] += s16[ng * 4 + n][c] * w;
    }
    #pragma unroll
    for (int n = 0; n < 4; n++) sWv[(size_t)(nb + ng * 4 + n) * 64 + col] = acc[n];
  }
  {
    int col = tid & 31, ng = tid >> 5;
    float acc[2] = {0, 0};
    for (int c = 0; c < 128; c++) {
      float w = Ws_t[c * 32 + col];
      acc[0] += s16[ng * 2 + 0][c] * w;
      acc[1] += s16[ng * 2 + 1][c] * w;
    }
    sWt[(size_t)(nb + ng * 2 + 0) * 32 + col] = acc[0];
    sWt[(size_t)(nb + ng * 2 + 1) * 32 + col] = acc[1];
  }
}

// ---------------- merged layer kernel: mega (per wave) + split update/transforms ----------------
// Wave wv computes agg for node order[blockIdx*2+wv] into LDS. After barrier:
// wave0 runs the s-path update; wave1 runs the v+t-path updates (independent inputs).
// Second barrier; transforms split: wave0 does sWsrc+tW, wave1 does sWv/sWt+vW.
__global__ __launch_bounds__(128) void k_layer(
    const int* __restrict__ row_off, const int* __restrict__ act_off,
    const int* __restrict__ order,
    const int* __restrict__ src_a, const float* __restrict__ d_a,
    const float* __restrict__ gsL, const float* __restrict__ gvL,
    const float* __restrict__ gtL, const float* __restrict__ attn_l,
    const float* __restrict__ sWsrc, const float* __restrict__ sWv,
    const float* __restrict__ sWt, const float* __restrict__ vW,
    const float* __restrict__ tW, const float* __restrict__ sh_a,
    float* __restrict__ s, float* __restrict__ v, float* __restrict__ t,
    const float* __restrict__ Wo_s, const float* __restrict__ Wo_v,
    const float* __restrict__ Wo_t, const float* __restrict__ g_s,
    const float* __restrict__ b_s, const float* __restrict__ g_v,
    const float* __restrict__ g_t, int do_tf,
    const float* __restrict__ Ws_src, const float* __restrict__ Ws_v2,
    const float* __restrict__ Ws_t2, const float* __restrict__ Wv_v,
    const float* __restrict__ Wt_t, float* __restrict__ sWsrcO,
    float* __restrict__ sWvO, float* __restrict__ sWtO,
    float* __restrict__ vWO, float* __restrict__ tWO) {
  __shared__ float stgS[2][128];
  __shared__ float stgV[2][192];
  __shared__ float stgT[2][160];
  __shared__ float sN[2][128];
  __shared__ float vN[2][192];
  __shared__ float tN[2][160];
  __shared__ int nodesh[2];
  int wv = threadIdx.x >> 6, lane = threadIdx.x & 63;
  int lt = lane & 31, nh = lane >> 5;
  int slot = blockIdx.x * 2 + wv;
  int n = order[slot];
  int alo = act_off[n], ahi = act_off[n + 1];
  int nact = ahi - alo;
  int ninact = (row_off[n + 1] - row_off[n]) - nact;
  const float sc = (float)(TABN - 1) / DTAB;
  float atnA = attn_l[lane];
  float atnB = attn_l[64 + lane];
  float rm0, rm1, rm2, rm3;
  rm0 = rm1 = rm2 = rm3 = (ninact > 0) ? 0.0f : -1e30f;
  float rs0 = 0.f, rs1 = 0.f, rs2 = 0.f, rs3 = 0.f;
  float as0 = 0.f, as1 = 0.f;
  float av0 = 0.f, av1 = 0.f, av2 = 0.f;
  float at0 = 0.f, at1 = 0.f, at2 = 0.f, at3 = 0.f, at4 = 0.f;
  int a = alo;
  for (; a + 1 < ahi; a += 2) {
    int aA = a, aB = a + 1;
    float dA = d_a[aA], dB = d_a[aB];
    int snA = src_a[aA], snB = src_a[aB];
    float xA = fminf(dA * sc, (float)(TABN - 1) - 1.0f);
    float xB = fminf(dB * sc, (float)(TABN - 1) - 1.0f);
    int iA = (int)xA, iB = (int)xB;
    float fA = xA - (float)iA, fB = xB - (float)iB;
    float g1A = 1.0f - fA, g1B = 1.0f - fB;
    const float* gA = gsL + (size_t)iA * 128;
    const float* gB = gsL + (size_t)iB * 128;
    float gsA_A = gA[lane] * g1A + gA[128 + lane] * fA;
    float gsB_A = gA[64 + lane] * g1A + gA[192 + lane] * fA;
    float gsA_B = gB[lane] * g1B + gB[128 + lane] * fB;
    float gsB_B = gB[64 + lane] * g1B + gB[192 + lane] * fB;
    float m0A = sWsrc[(size_t)snA * 128 + lane] * gsA_A;
    float m1A = sWsrc[(size_t)snA * 128 + 64 + lane] * gsB_A;
    float m0B = sWsrc[(size_t)snB * 128 + lane] * gsA_B;
    float m1B = sWsrc[(size_t)snB * 128 + 64 + lane] * gsB_B;
    const float* gvA = gvL + (size_t)iA * 128;
    const float* gvB = gvL + (size_t)iB * 128;
    float2 pA0 = *(const float2*)&gvA[2 * lane];
    float2 pA1 = *(const float2*)&gvA[128 + 2 * lane];
    float2 pB0 = *(const float2*)&gvB[2 * lane];
    float2 pB1 = *(const float2*)&gvB[128 + 2 * lane];
    float gavA = pA0.x * g1A + pA1.x * fA;
    float gbvA = pA0.y * g1A + pA1.y * fA;
    float gavB = pB0.x * g1B + pB1.x * fB;
    float gbvB = pB0.y * g1B + pB1.y * fB;
    float svA = sWv[(size_t)snA * 64 + lane];
    float svB = sWv[(size_t)snB * 64 + lane];
    float4 s1A = *(const float4*)&sh_a[(size_t)aA * 8];
    float4 s2A = *(const float4*)&sh_a[(size_t)aA * 8 + 4];
    float4 s1B = *(const float4*)&sh_a[(size_t)aB * 8];
    float4 s2B = *(const float4*)&sh_a[(size_t)aB * 8 + 4];
    const float* vpA = &vW[(size_t)snA * 192 + lane];
    const float* vpB = &vW[(size_t)snB * 192 + lane];
    float vA0 = vpA[0], vA1 = vpA[64], vA2 = vpA[128];
    float vB0 = vpB[0], vB1 = vpB[64], vB2 = vpB[128];
    float gatA = 0.f, gbtA = 0.f, gatB = 0.f, gbtB = 0.f;
    float stA = 0.f, stB = 0.f;
    float tA0 = 0.f, tA1 = 0.f, tA2 = 0.f, tA3 = 0.f, tA4 = 0.f;
    float tB0 = 0.f, tB1 = 0.f, tB2 = 0.f, tB3 = 0.f, tB4 = 0.f;
    if (lane < 32) {
      const float* gtA = gtL + (size_t)iA * 64;
      const float* gtB = gtL + (size_t)iB * 64;
      float2 qA0 = *(const float2*)&gtA[2 * lt];
      float2 qA1 = *(const float2*)&gtA[64 + 2 * lt];
      float2 qB0 = *(const float2*)&gtB[2 * lt];
      float2 qB1 = *(const float2*)&gtB[64 + 2 * lt];
      gatA = qA0.x * g1A + qA1.x * fA;
      gbtA = qA0.y * g1A + qA1.y * fA;
      gatB = qB0.x * g1B + qB1.x * fB;
      gbtB = qB0.y * g1B + qB1.y * fB;
      stA = sWt[(size_t)snA * 32 + lane];
      stB = sWt[(size_t)snB * 32 + lane];
      const float* tpA = &tW[(size_t)snA * 160 + lane];
      const float* tpB = &tW[(size_t)snB * 160 + lane];
      tA0 = tpA[0]; tA1 = tpA[32]; tA2 = tpA[64]; tA3 = tpA[96]; tA4 = tpA[128];
      tB0 = tpB[0]; tB1 = tpB[32]; tB2 = tpB[64]; tB3 = tpB[96]; tB4 = tpB[128];
    }
    float p01A = m0A * atnA, p23A = m1A * atnB;
    float p01B = m0B * atnA, p23B = m1B * atnB;
    #pragma unroll
    for (int mm = 1; mm < 32; mm <<= 1) {
      p01A += __shfl_xor(p01A, mm);
      p23A += __shfl_xor(p23A, mm);
      p01B += __shfl_xor(p01B, mm);
      p23B += __shfl_xor(p23B, mm);
    }
    float l0A = __shfl(p01A, 0), l1A = __shfl(p01A, 32);
    float l2A = __shfl(p23A, 0), l3A = __shfl(p23A, 32);
    float l0B = __shfl(p01B, 0), l1B = __shfl(p01B, 32);
    float l2B = __shfl(p23B, 0), l3B = __shfl(p23B, 32);
    float nm0 = fmaxf(rm0, fmaxf(l0A, l0B));
    float nm1 = fmaxf(rm1, fmaxf(l1A, l1B));
    float nm2 = fmaxf(rm2, fmaxf(l2A, l2B));
    float nm3 = fmaxf(rm3, fmaxf(l3A, l3B));
    float wA0 = __expf(l0A - nm0), wA1 = __expf(l1A - nm1);
    float wA2 = __expf(l2A - nm2), wA3 = __expf(l3A - nm3);
    float wB0 = __expf(l0B - nm0), wB1 = __expf(l1B - nm1);
    float wB2 = __expf(l2B - nm2), wB3 = __expf(l3B - nm3);
    float wSA0 = (lane < 32) ? wA0 : wA1, wSA1 = (lane < 32) ? wA2 : wA3;
    float wSB0 = (lane < 32) ? wB0 : wB1, wSB1 = (lane < 32) ? wB2 : wB3;
    float addS0 = wSA0 * m0A + wSB0 * m0B;
    float addS1 = wSA1 * m1A + wSB1 * m1B;
    float wVA = (lane < 16) ? wA0 : (lane < 32) ? wA1 : (lane < 48) ? wA2 : wA3;
    float wVB = (lane < 16) ? wB0 : (lane < 32) ? wB1 : (lane < 48) ? wB2 : wB3;
    float avvA = svA * gavA, avvB = svB * gavB;
    float addV0 = wVA * (avvA * s1A.x + vA0 * gbvA) + wVB * (avvB * s1B.x + vB0 * gbvB);
    float addV1 = wVA * (avvA * s1A.y + vA1 * gbvA) + wVB * (avvB * s1B.y + vB1 * gbvB);
    float addV2 = wVA * (avvA * s1A.z + vA2 * gbvA) + wVB * (avvB * s1B.z + vB2 * gbvB);
    float wTA = (lane < 8) ? wA0 : (lane < 16) ? wA1 : (lane < 24) ? wA2 : wA3;
    float wTB = (lane < 8) ? wB0 : (lane < 16) ? wB1 : (lane < 24) ? wB2 : wB3;
    float attA = stA * gatA, attB = stB * gatB;
    float addT0 = wTA * (attA * s1A.w + tA0 * gbtA) + wTB * (attB * s1B.w + tB0 * gbtB);
    float addT1 = wTA * (attA * s2A.x + tA1 * gbtA) + wTB * (attB * s2B.x + tB1 * gbtB);
    float addT2 = wTA * (attA * s2A.y + tA2 * gbtA) + wTB * (attB * s2B.y + tB2 * gbtB);
    float addT3 = wTA * (attA * s2A.z + tA3 * gbtA) + wTB * (attB * s2B.z + tB3 * gbtB);
    float addT4 = wTA * (attA * s2A.w + tA4 * gbtA) + wTB * (attB * s2B.w + tB4 * gbtB);
    if (nm0 == rm0 && nm1 == rm1 && nm2 == rm2 && nm3 == rm3) {
      rs0 += wA0 + wB0; rs1 += wA1 + wB1; rs2 += wA2 + wB2; rs3 += wA3 + wB3;
      as0 += addS0; as1 += addS1;
      av0 += addV0; av1 += addV1; av2 += addV2;
      at0 += addT0; at1 += addT1; at2 += addT2; at3 += addT3; at4 += addT4;
    } else {
      float f0 = __expf(rm0 - nm0), f1 = __expf(rm1 - nm1);
      float f2 = __expf(rm2 - nm2), f3 = __expf(rm3 - nm3);
      rm0 = nm0; rm1 = nm1; rm2 = nm2; rm3 = nm3;
      rs0 = rs0 * f0 + wA0 + wB0; rs1 = rs1 * f1 + wA1 + wB1;
      rs2 = rs2 * f2 + wA2 + wB2; rs3 = rs3 * f3 + wA3 + wB3;
      float fS0 = (lane < 32) ? f0 : f1, fS1 = (lane < 32) ? f2 : f3;
      as0 = as0 * fS0 + addS0; as1 = as1 * fS1 + addS1;
      float fV = (lane < 16) ? f0 : (lane < 32) ? f1 : (lane < 48) ? f2 : f3;
      av0 = av0 * fV + addV0; av1 = av1 * fV + addV1; av2 = av2 * fV + addV2;
      float fT = (lane < 8) ? f0 : (lane < 16) ? f1 : (lane < 24) ? f2 : f3;
      at0 = at0 * fT + addT0; at1 = at1 * fT + addT1; at2 = at2 * fT + addT2;
      at3 = at3 * fT + addT3; at4 = at4 * fT + addT4;
    }
  }
  for (; a < ahi; ++a) {
    float x = d_a[a] * sc;
    x = fminf(x, (float)(TABN - 1) - 1.0f);
    int i0 = (int)x; float f = x - (float)i0; float g1 = 1.0f - f;
    int sn = src_a[a];
    const float* g0 = gsL + (size_t)i0 * 128;
    float gsA = g0[lane] * g1 + g0[128 + lane] * f;
    float gsB = g0[64 + lane] * g1 + g0[192 + lane] * f;
    float m0 = sWsrc[(size_t)sn * 128 + lane] * gsA;
    float m1 = sWsrc[(size_t)sn * 128 + 64 + lane] * gsB;
    float p01 = m0 * atnA;
    float p23 = m1 * atnB;
    #pragma unroll
    for (int mm = 1; mm < 32; mm <<= 1) {
      p01 += __shfl_xor(p01, mm);
      p23 += __shfl_xor(p23, mm);
    }
    float l0 = __shfl(p01, 0), l1 = __shfl(p01, 32);
    float l2 = __shfl(p23, 0), l3 = __shfl(p23, 32);
    float nm0 = fmaxf(rm0, l0), nm1 = fmaxf(rm1, l1);
    float nm2 = fmaxf(rm2, l2), nm3 = fmaxf(rm3, l3);
    float f0 = __expf(rm0 - nm0), f1 = __expf(rm1 - nm1);
    float f2 = __expf(rm2 - nm2), f3 = __expf(rm3 - nm3);
    float w0 = __expf(l0 - nm0), w1 = __expf(l1 - nm1);
    float w2 = __expf(l2 - nm2), w3 = __expf(l3 - nm3);
    rm0 = nm0; rm1 = nm1; rm2 = nm2; rm3 = nm3;
    rs0 = rs0 * f0 + w0; rs1 = rs1 * f1 + w1;
    rs2 = rs2 * f2 + w2; rs3 = rs3 * f3 + w3;
    float fS0 = (lane < 32) ? f0 : f1;
    float fS1 = (lane < 32) ? f2 : f3;
    float wS0 = (lane < 32) ? w0 : w1;
    float wS1 = (lane < 32) ? w2 : w3;
    as0 = as0 * fS0 + wS0 * m0;
    as1 = as1 * fS1 + wS1 * m1;
    const float* gv0 = gvL + (size_t)i0 * 128;
    float2 p0 = *(const float2*)&gv0[2 * lane];
    float2 p1 = *(const float2*)&gv0[128 + 2 * lane];
    float gav = p0.x * g1 + p1.x * f;
    float gbv = p0.y * g1 + p1.y * f;
    float fV = (lane < 16) ? f0 : (lane < 32) ? f1 : (lane < 48) ? f2 : f3;
    float wV = (lane < 16) ? w0 : (lane < 32) ? w1 : (lane < 48) ? w2 : w3;
    float avv = sWv[(size_t)sn * 64 + lane] * gav;
    float4 s1 = *(const float4*)&sh_a[(size_t)a * 8];
    float4 s2 = *(const float4*)&sh_a[(size_t)a * 8 + 4];
    const float* vp = &vW[(size_t)sn * 192 + lane];
    av0 = av0 * fV + wV * (avv * s1.x + vp[0] * gbv);
    av1 = av1 * fV + wV * (avv * s1.y + vp[64] * gbv);
    av2 = av2 * fV + wV * (avv * s1.z + vp[128] * gbv);
    if (lane < 32) {
      const float* gt0 = gtL + (size_t)i0 * 64;
      float2 q0 = *(const float2*)&gt0[2 * lt];
      float2 q1 = *(const float2*)&gt0[64 + 2 * lt];
      float gat = q0.x * g1 + q1.x * f;
      float gbt = q0.y * g1 + q1.y * f;
      float fT = (lane < 8) ? f0 : (lane < 16) ? f1 : (lane < 24) ? f2 : f3;
      float wT = (lane < 8) ? w0 : (lane < 16) ? w1 : (lane < 24) ? w2 : w3;
      float att = sWt[(size_t)sn * 32 + lane] * gat;
      const float* tp = &tW[(size_t)sn * 160 + lane];
      at0 = at0 * fT + wT * (att * s1.w + tp[0] * gbt);
      at1 = at1 * fT + wT * (att * s2.x + tp[32] * gbt);
      at2 = at2 * fT + wT * (att * s2.y + tp[64] * gbt);
      at3 = at3 * fT + wT * (att * s2.z + tp[96] * gbt);
      at4 = at4 * fT + wT * (att * s2.w + tp[128] * gbt);
    }
  }
  if (ninact > 0) {
    rs0 += (float)ninact * __expf(-rm0);
    rs1 += (float)ninact * __expf(-rm1);
    rs2 += (float)ninact * __expf(-rm2);
    rs3 += (float)ninact * __expf(-rm3);
  }
  float r0 = 1.0f / (rs0 + 1e-9f), r1 = 1.0f / (rs1 + 1e-9f);
  float r2 = 1.0f / (rs2 + 1e-9f), r3 = 1.0f / (rs3 + 1e-9f);
  float rS0 = (lane < 32) ? r0 : r1;
  float rS1 = (lane < 32) ? r2 : r3;
  float rV = (lane < 16) ? r0 : (lane < 32) ? r1 : (lane < 48) ? r2 : r3;
  stgS[wv][lane] = as0 * rS0;
  stgS[wv][64 + lane] = as1 * rS1;
  stgV[wv][lane * 3 + 0] = av0 * rV;
  stgV[wv][lane * 3 + 1] = av1 * rV;
  stgV[wv][lane * 3 + 2] = av2 * rV;
  if (lane < 32) {
    float rT = (lane < 8) ? r0 : (lane < 16) ? r1 : (lane < 24) ? r2 : r3;
    stgT[wv][lane * 5 + 0] = at0 * rT;
    stgT[wv][lane * 5 + 1] = at1 * rT;
    stgT[wv][lane * 5 + 2] = at2 * rT;
    stgT[wv][lane * 5 + 3] = at3 * rT;
    stgT[wv][lane * 5 + 4] = at4 * rT;
  }
  if (lane == 0) nodesh[wv] = n;
  __syncthreads();
  int nA = nodesh[0], nB = nodesh[1];
  int ntt = nh ? nB : nA;
  if (wv == 0) {
    // ---- s-path: matmul + LayerNorm (both nodes) ----
    float sA0 = s[(size_t)nA * 128 + lane];
    float sA1 = s[(size_t)nA * 128 + 64 + lane];
    float sB0 = s[(size_t)nB * 128 + lane];
    float sB1 = s[(size_t)nB * 128 + 64 + lane];
    #pragma unroll 8
    for (int c = 0; c < 128; c++) {
      float w0 = Wo_s[c * 128 + lane];
      float w1 = Wo_s[c * 128 + 64 + lane];
      float ax = stgS[0][c], bx = stgS[1][c];
      sA0 += ax * w0; sA1 += ax * w1;
      sB0 += bx * w0; sB1 += bx * w1;
    }
    float smA = sA0 + sA1, sqA = sA0 * sA0 + sA1 * sA1;
    float smB = sB0 + sB1, sqB = sB0 * sB0 + sB1 * sB1;
    #pragma unroll
    for (int m = 1; m < 64; m <<= 1) {
      smA += __shfl_xor(smA, m); sqA += __shfl_xor(sqA, m);
      smB += __shfl_xor(smB, m); sqB += __shfl_xor(sqB, m);
    }
    float muA = smA / 128.0f, muB = smB / 128.0f;
    float varA = sqA / 128.0f - muA * muA; if (varA < 0.f) varA = 0.f;
    float varB = sqB / 128.0f - muB * muB; if (varB < 0.f) varB = 0.f;
    float riA = rsqrtf(varA + 1e-6f), riB = rsqrtf(varB + 1e-6f);
    float gs0 = g_s[lane], gs1 = g_s[64 + lane];
    float bs0 = b_s[lane], bs1 = b_s[64 + lane];
    float yA0 = (sA0 - muA) * riA * gs0 + bs0;
    float yA1 = (sA1 - muA) * riA * gs1 + bs1;
    float yB0 = (sB0 - muB) * riB * gs0 + bs0;
    float yB1 = (sB1 - muB) * riB * gs1 + bs1;
    s[(size_t)nA * 128 + lane] = yA0;
    s[(size_t)nA * 128 + 64 + lane] = yA1;
    s[(size_t)nB * 128 + lane] = yB0;
    s[(size_t)nB * 128 + 64 + lane] = yB1;
    sN[0][lane] = yA0; sN[0][64 + lane] = yA1;
    sN[1][lane] = yB0; sN[1][64 + lane] = yB1;
  } else {
    // ---- v-path: matmul + RMS (both nodes) ----
    float voA0 = v[(size_t)nA * 192 + lane * 3 + 0];
    float voA1 = v[(size_t)nA * 192 + lane * 3 + 1];
    float voA2 = v[(size_t)nA * 192 + lane * 3 + 2];
    float voB0 = v[(size_t)nB * 192 + lane * 3 + 0];
    float voB1 = v[(size_t)nB * 192 + lane * 3 + 1];
    float voB2 = v[(size_t)nB * 192 + lane * 3 + 2];
    float vA0 = voA0, vA1 = voA1, vA2 = voA2;
    float vB0 = voB0, vB1 = voB1, vB2 = voB2;
    #pragma unroll 8
    for (int c = 0; c < 64; c++) {
      float w = Wo_v[c * 64 + lane];
      vA0 += stgV[0][c * 3 + 0] * w;
      vA1 += stgV[0][c * 3 + 1] * w;
      vA2 += stgV[0][c * 3 + 2] * w;
      vB0 += stgV[1][c * 3 + 0] * w;
      vB1 += stgV[1][c * 3 + 1] * w;
      vB2 += stgV[1][c * 3 + 2] * w;
    }
    float to0 = t[(size_t)ntt * 160 + lt * 5 + 0];
    float to1 = t[(size_t)ntt * 160 + lt * 5 + 1];
    float to2 = t[(size_t)ntt * 160 + lt * 5 + 2];
    float to3 = t[(size_t)ntt * 160 + lt * 5 + 3];
    float to4 = t[(size_t)ntt * 160 + lt * 5 + 4];
    float ssqA = vA0 * vA0 + vA1 * vA1 + vA2 * vA2;
    float ssqB = vB0 * vB0 + vB1 * vB1 + vB2 * vB2;
    #pragma unroll
    for (int m = 1; m < 64; m <<= 1) {
      ssqA += __shfl_xor(ssqA, m);
      ssqB += __shfl_xor(ssqB, m);
    }
    float rivA = rsqrtf(ssqA / 64.0f + 1e-6f);
    float rivB = rsqrtf(ssqB / 64.0f + 1e-6f);
    float gv = g_v[lane];
    float vyA0 = vA0 * rivA * gv, vyA1 = vA1 * rivA * gv, vyA2 = vA2 * rivA * gv;
    float vyB0 = vB0 * rivB * gv, vyB1 = vB1 * rivB * gv, vyB2 = vB2 * rivB * gv;
    v[(size_t)nA * 192 + lane * 3 + 0] = vyA0;
    v[(size_t)nA * 192 + lane * 3 + 1] = vyA1;
    v[(size_t)nA * 192 + lane * 3 + 2] = vyA2;
    v[(size_t)nB * 192 + lane * 3 + 0] = vyB0;
    v[(size_t)nB * 192 + lane * 3 + 1] = vyB1;
    v[(size_t)nB * 192 + lane * 3 + 2] = vyB2;
    vN[0][lane * 3 + 0] = vyA0; vN[0][lane * 3 + 1] = vyA1; vN[0][lane * 3 + 2] = vyA2;
    vN[1][lane * 3 + 0] = vyB0; vN[1][lane * 3 + 1] = vyB1; vN[1][lane * 3 + 2] = vyB2;
    // ---- t-path: matmul + RMS (half-trick) ----
    float at0u = to0, at1u = to1, at2u = to2, at3u = to3, at4u = to4;
    #pragma unroll 4
    for (int c = 0; c < 32; c++) {
      float w = Wo_t[c * 32 + lt];
      at0u += stgT[nh][c * 5 + 0] * w;
      at1u += stgT[nh][c * 5 + 1] * w;
      at2u += stgT[nh][c * 5 + 2] * w;
      at3u += stgT[nh][c * 5 + 3] * w;
      at4u += stgT[nh][c * 5 + 4] * w;
    }
    float ssqt = at0u * at0u + at1u * at1u + at2u * at2u + at3u * at3u + at4u * at4u;
    #pragma unroll
    for (int m = 1; m < 32; m <<= 1) ssqt += __shfl_xor(ssqt, m);
    float rit = rsqrtf(ssqt / 32.0f + 1e-6f);
    float gt = g_t[lt];
    float ty0 = at0u * rit * gt, ty1 = at1u * rit * gt, ty2 = at2u * rit * gt;
    float ty3 = at3u * rit * gt, ty4 = at4u * rit * gt;
    t[(size_t)ntt * 160 + lt * 5 + 0] = ty0;
    t[(size_t)ntt * 160 + lt * 5 + 1] = ty1;
    t[(size_t)ntt * 160 + lt * 5 + 2] = ty2;
    t[(size_t)ntt * 160 + lt * 5 + 3] = ty3;
    t[(size_t)ntt * 160 + lt * 5 + 4] = ty4;
    tN[nh][lt * 5 + 0] = ty0;
    tN[nh][lt * 5 + 1] = ty1;
    tN[nh][lt * 5 + 2] = ty2;
    tN[nh][lt * 5 + 3] = ty3;
    tN[nh][lt * 5 + 4] = ty4;
  }
  if (do_tf) {
    __syncthreads();
    if (wv == 0) {
      // ---- sWsrc transform (both nodes) ----
      float cA0 = 0.f, cA1 = 0.f, cB0 = 0.f, cB1 = 0.f;
      #pragma unroll 8
      for (int c = 0; c < 128; c++) {
        float w0 = Ws_src[c * 128 + lane];
        float w1 = Ws_src[c * 128 + 64 + lane];
        float aA = sN[0][c], aB = sN[1][c];
        cA0 += aA * w0; cA1 += aA * w1;
        cB0 += aB * w0; cB1 += aB * w1;
      }
      sWsrcO[(size_t)nA * 128 + lane] = cA0;
      sWsrcO[(size_t)nA * 128 + 64 + lane] = cA1;
      sWsrcO[(size_t)nB * 128 + lane] = cB0;
      sWsrcO[(size_t)nB * 128 + 64 + lane] = cB1;
      // ---- tW transform (half-trick) ----
      float u0 = 0.f, u1 = 0.f, u2 = 0.f, u3 = 0.f, u4 = 0.f;
      #pragma unroll 4
      for (int c = 0; c < 32; c++) {
        float w = Wt_t[c * 32 + lt];
        u0 += tN[nh][c * 5 + 0] * w;
        u1 += tN[nh][c * 5 + 1] * w;
        u2 += tN[nh][c * 5 + 2] * w;
        u3 += tN[nh][c * 5 + 3] * w;
        u4 += tN[nh][c * 5 + 4] * w;
      }
      tWO[(size_t)ntt * 160 + lt] = u0;
      tWO[(size_t)ntt * 160 + 32 + lt] = u1;
      tWO[(size_t)ntt * 160 + 64 + lt] = u2;
      tWO[(size_t)ntt * 160 + 96 + lt] = u3;
      tWO[(size_t)ntt * 160 + 128 + lt] = u4;
    } else {
      // ---- sWv / sWt transforms ----
      float cvA = 0.f, cvB = 0.f, ct = 0.f;
      #pragma unroll 8
      for (int c = 0; c < 128; c++) {
        float wvv = Ws_v2[c * 64 + lane];
        float wtt = Ws_t2[c * 32 + lt];
        float aA = sN[0][c], aB = sN[1][c];
        cvA += aA * wvv; cvB += aB * wvv;
        ct += sN[nh][c] * wtt;
      }
      sWvO[(size_t)nA * 64 + lane] = cvA;
      sWvO[(size_t)nB * 64 + lane] = cvB;
      sWtO[(size_t)ntt * 32 + lt] = ct;
      // ---- vW transform (both nodes) ----
      float wA0 = 0.f, wA1 = 0.f, wA2 = 0.f, wB0 = 0.f, wB1 = 0.f, wB2 = 0.f;
      #pragma unroll 8
      for (int c = 0; c < 64; c++) {
        float w = Wv_v[c * 64 + lane];
        wA0 += vN[0][c * 3 + 0] * w;
        wA1 += vN[0][c * 3 + 1] * w;
        wA2 += vN[0][c * 3 + 2] * w;
        wB0 += vN[1][c * 3 + 0] * w;
        wB1 += vN[1][c * 3 + 1] * w;
        wB2 += vN[1][c * 3 + 2] * w;
      }
      vWO[(size_t)nA * 192 + lane] = wA0;
      vWO[(size_t)nA * 192 + 64 + lane] = wA1;
      vWO[(size_t)nA * 192 + 128 + lane] = wA2;
      vWO[(size_t)nB * 192 + lane] = wB0;
      vWO[(size_t)nB * 192 + 64 + lane] = wB1;
      vWO[(size_t)nB * 192 + 128 + lane] = wB2;
    }
  }
}

// ---------------- readout: 2 feature-blocks per staged s-tile ----------------
__global__ __launch_bounds__(256) void k_readout(
    const float* __restrict__ s, const int* __restrict__ batch,
    const float* __restrict__ W_feat, const float* __restrict__ b_feat,
    const float* __restrict__ W_out1, const float* __restrict__ b_out1,
    float* __restrict__ graph) {
  __shared__ float st[64][129];
  __shared__ float gacc[GG];
  int nb = blockIdx.x * 64;
  int fbb = blockIdx.y * 2;
  for (int idx = threadIdx.x; idx < 64 * 128; idx += 256) {
    int nl = idx >> 7, c = idx & 127;
    int n = nb + nl;
    st[nl][c] = (n < NN) ? s[(size_t)n * 128 + c] : 0.f;
  }
  if (threadIdx.x < GG) gacc[threadIdx.x] = 0.f;
  __syncthreads();
  int wv = threadIdx.x >> 6, lane = threadIdx.x & 63;
  int fg = lane & 15;
  int ns = lane >> 4;
  int nodeb = wv * 16 + ns * 4;
  #pragma unroll
  for (int sub = 0; sub < 2; sub++) {
    int fb = fbb + sub;
    int f0 = fb * 64 + fg * 4;
    float acc[4][4];
    #pragma unroll
    for (int nn = 0; nn < 4; nn++)
      #pragma unroll
      for (int k = 0; k < 4; k++) acc[nn][k] = b_feat[f0 + k];
    #pragma unroll 4
    for (int c = 0; c < 128; c++) {
      float4 wq = *(const float4*)&W_feat[(size_t)c * 512 + f0];
      #pragma unroll
      for (int nn = 0; nn < 4; nn++) {
        float sv = st[nodeb + nn][c];
        acc[nn][0] += sv * wq.x;
        acc[nn][1] += sv * wq.y;
        acc[nn][2] += sv * wq.z;
        acc[nn][3] += sv * wq.w;
      }
    }
    float wo[4];
    #pragma unroll
    for (int k = 0; k < 4; k++) wo[k] = W_out1[f0 + k];
    float ep[4];
    #pragma unroll
    for (int nn = 0; nn < 4; nn++) {
      float p = 0.f;
      #pragma unroll
      for (int k = 0; k < 4; k++) p += fgelu(acc[nn][k]) * wo[k];
      ep[nn] = p;
    }
    #pragma unroll
    for (int mm = 1; mm < 16; mm <<= 1) {
      #pragma unroll
      for (int nn = 0; nn < 4; nn++) ep[nn] += __shfl_xor(ep[nn], mm);
    }
    if (fg == 0) {
      #pragma unroll
      for (int nn = 0; nn < 4; nn++) {
        int n = nb + nodeb + nn;
        if (n < NN) {
          float e = ep[nn];
          if (fb == 0) e += b_out1[0];
          atomicAdd(&gacc[batch[n]], e);
        }
      }
    }
  }
  __syncthreads();
  if (threadIdx.x < GG && gacc[threadIdx.x] != 0.f)
    atomicAdd(&graph[threadIdx.x], gacc[threadIdx.x]);
}

__global__ void k_finalize(const float* __restrict__ graph, const float* __restrict__ W_read,
                           const float* __restrict__ b_read, float* __restrict__ out) {
  int g = threadIdx.x;
  if (g < GG) out[g] = graph[g] * W_read[0] + b_read[0];
}

// ---------------- host ----------------
extern "C" void kernel_launch(void* const* d_in, const int* in_sizes, int n_in,
                              void* d_out, int out_size, void* d_ws, size_t ws_size,
                              hipStream_t stream) {
  const float* pos = (const float*)d_in[0];
  const int* node_atom = (const int*)d_in[1];
  const int* batch = (const int*)d_in[2];
  const int* esrc = (const int*)d_in[3];
  const int* edst = (const int*)d_in[4];
  const float* atom_emb = (const float*)d_in[5];
  const float* Wrad1 = (const float*)d_in[6];
  const float* brad1 = (const float*)d_in[7];
  const float* Wrad2 = (const float*)d_in[8];
  const float* brad2 = (const float*)d_in[9];
  const float* Ws_src = (const float*)d_in[10];
  const float* Ww_s = (const float*)d_in[11];
  const float* Ws_v = (const float*)d_in[12];
  const float* Ww_v = (const float*)d_in[13];
  const float* Wv_v = (const float*)d_in[14];
  const float* Ww_vv = (const float*)d_in[15];
  const float* Ws_t = (const float*)d_in[16];
  const float* Ww_t = (const float*)d_in[17];
  const float* Wt_t = (const float*)d_in[18];
  const float* Ww_tt = (const float*)d_in[19];
  const float* attn_a = (const float*)d_in[20];
  const float* Wo_s = (const float*)d_in[21];
  const float* Wo_v = (const float*)d_in[22];
  const float* Wo_t = (const float*)d_in[23];
  const float* g_s = (const float*)d_in[24];
  const float* b_s = (const float*)d_in[25];
  const float* g_v = (const float*)d_in[26];
  const float* g_t = (const float*)d_in[27];
  const float* W_feat = (const float*)d_in[28];
  const float* b_feat = (const float*)d_in[29];
  const float* W_out1 = (const float*)d_in[30];
  const float* b_out1 = (const float*)d_in[31];
  const float* W_read = (const float*)d_in[32];
  const float* b_read = (const float*)d_in[33];
  float* out = (float*)d_out;

  char* base = (char*)d_ws;
  size_t off = 0;
  auto alloc = [&](size_t bytes) -> char* {
    off = (off + 255) & ~(size_t)255;
    char* p = base + off;
    off += bytes;
    return p;
  };
  // ---- zero-init group A (ints), contiguous ----
  int* deg = (int*)alloc(NN * 4);
  int* cursor = (int*)alloc(NN * 4);
  int* dbkt = (int*)alloc(128 * 4);
  int* dbcur = (int*)alloc(128 * 4);
  float* graph = (float*)alloc(GG * 4);
  char* zeroA_end = base + off;
  // ---- zero-init group B (floats), contiguous: v, t, vW buffer A, tW buffer A ----
  float* v = (float*)alloc((size_t)NN * 192 * 4);
  float* t = (float*)alloc((size_t)NN * 160 * 4);
  float* vWA = (float*)alloc((size_t)NN * 192 * 4);
  float* tWA = (float*)alloc((size_t)NN * 160 * 4);
  char* zeroB_end = base + off;
  // ---- rest ----
  int* row_off = (int*)alloc((NN + 1) * 4);
  float* d_csr = (float*)alloc((size_t)EE * 4);
  int* src_csr = (int*)alloc((size_t)EE * 4);
  int* dst_csr = (int*)alloc((size_t)EE * 4);
  int* acnt = (int*)alloc(NN * 4);
  int* act_off = (int*)alloc((NN + 1) * 4);
  int* act_idx = (int*)alloc((size_t)EE * 4);
  int* dboff = (int*)alloc(129 * 4);
  int* order = (int*)alloc(NN * 4);
  float* d_a = (float*)alloc((size_t)EE * 4);
  int* src_a = (int*)alloc((size_t)EE * 4);
  float* sh_a = (float*)alloc((size_t)EE * 8 * 4);
  float* wtab = (float*)alloc((size_t)LL * TABN * 64 * 4);
  float* gs_tab = (float*)alloc((size_t)LL * TABN * 128 * 4);
  float* gv_tab = (float*)alloc((size_t)LL * TABN * 128 * 4);
  float* gt_tab = (float*)alloc((size_t)LL * TABN * 64 * 4);
  float* s = (float*)alloc((size_t)NN * 128 * 4);
  float* sWsrcA = (float*)alloc((size_t)NN * 128 * 4);
  float* sWvA = (float*)alloc((size_t)NN * 64 * 4);
  float* sWtA = (float*)alloc((size_t)NN * 32 * 4);
  float* sWsrcB = (float*)alloc((size_t)NN * 128 * 4);
  float* sWvB = (float*)alloc((size_t)NN * 64 * 4);
  float* sWtB = (float*)alloc((size_t)NN * 32 * 4);
  float* vWB = (float*)alloc((size_t)NN * 192 * 4);
  float* tWB = (float*)alloc((size_t)NN * 160 * 4);

  hipMemsetAsync(deg, 0, (size_t)(zeroA_end - (char*)deg), stream);
  hipMemsetAsync(v, 0, (size_t)(zeroB_end - (char*)v), stream);

  k_hist<<<(EE + 255) / 256, 256, 0, stream>>>(edst, deg);
  k_scan<<<1, 1024, 0, stream>>>(deg, row_off, NN);
  k_scatter<<<(EE + 255) / 256, 256, 0, stream>>>(esrc, edst, pos, row_off, cursor,
                                                  d_csr, src_csr, dst_csr);
  k_act_cnt<<<(NN + 255) / 256, 256, 0, stream>>>(row_off, d_csr, acnt, dbkt);
  k_scan2<<<2, 1024, 0, stream>>>(acnt, act_off, NN, dbkt, dboff, 128);
  k_act_fill<<<(NN + 255) / 256, 256, 0, stream>>>(row_off, d_csr, act_off, act_idx,
                                                   acnt, dboff, dbcur, order);
  k_geom_act<<<(EE + 255) / 256, 256, 0, stream>>>(act_idx, src_csr, dst_csr, pos, act_off,
                                                   d_a, src_a, sh_a);
  k_build_wtab<<<LL * (TABN / 16), 256, 0, stream>>>(Wrad1, brad1, Wrad2, brad2, wtab);
  k_build_tabs<<<LL * (TABN / EB), 320, 0, stream>>>(wtab, Ww_s, Ww_v, Ww_vv, Ww_t, Ww_tt,
                                                     gs_tab, gv_tab, gt_tab);
  k_node_tf0<<<NN / 16, 256, 0, stream>>>(node_atom, atom_emb, s, Ws_src, Ws_v, Ws_t,
                                          sWsrcA, sWvA, sWtA);

  for (int l = 0; l < LL; l++) {
    const float* gsL = gs_tab + (size_t)l * TABN * 128;
    const float* gvL = gv_tab + (size_t)l * TABN * 128;
    const float* gtL = gt_tab + (size_t)l * TABN * 64;
    int even = ((l & 1) == 0);
    const float* sWsrcI = even ? sWsrcA : sWsrcB;
    const float* sWvI = even ? sWvA : sWvB;
    const float* sWtI = even ? sWtA : sWtB;
    const float* vWI = even ? vWA : vWB;
    const float* tWI = even ? tWA : tWB;
    float* sWsrcO = even ? sWsrcB : sWsrcA;
    float* sWvO = even ? sWvB : sWvA;
    float* sWtO = even ? sWtB : sWtA;
    float* vWO = even ? vWB : vWA;
    float* tWO = even ? tWB : tWA;
    int dtf = (l < LL - 1) ? 1 : 0;
    int ln = (l < LL - 1) ? (l + 1) : l;
    k_layer<<<NN / 2, 128, 0, stream>>>(
        row_off, act_off, order, src_a, d_a, gsL, gvL, gtL,
        attn_a + (size_t)l * 128,
        sWsrcI, sWvI, sWtI, vWI, tWI, sh_a, s, v, t,
        Wo_s + (size_t)l * 128 * 128, Wo_v + (size_t)l * 64 * 64,
        Wo_t + (size_t)l * 32 * 32,
        g_s + (size_t)l * 128, b_s + (size_t)l * 128,
        g_v + (size_t)l * 64, g_t + (size_t)l * 32, dtf,
        Ws_src + (size_t)ln * 128 * 128, Ws_v + (size_t)ln * 128 * 64,
        Ws_t + (size_t)ln * 128 * 32, Wv_v + (size_t)ln * 64 * 64,
        Wt_t + (size_t)ln * 32 * 32,
        sWsrcO, sWvO, sWtO, vWO, tWO);
  }
  dim3 rg((NN + 63) / 64, 4);
  k_readout<<<rg, 256, 0, stream>>>(s, batch, W_feat, b_feat, W_out1, b_out1, graph);
  k_finalize<<<1, 64, 0, stream>>>(graph, W_read, b_read, out);
}